// Round 6
// baseline (1504.832 us; speedup 1.0000x reference)
//
#include <hip/hip_runtime.h>
#include <hip/hip_bf16.h>
#include <math.h>

// ---------------- problem constants ----------------
namespace {
constexpr int kV  = 3;
constexpr int kN  = 20000;
constexpr int kF  = 256;
constexpr int kH  = 256;
constexpr int kE  = 160000;
constexpr int kC  = 32;
constexpr int kNH = 8;
constexpr int kSN = kV * kN;     // 60000
constexpr int kE2 = kE + kN;     // 180000
constexpr int kMP = 60160;       // padded rows for bf16 GEMM-A buffers

// fp32 workspace layout (float element offsets)
constexpr size_t OFF_T1   = 0;
constexpr size_t OFF_T2   = OFF_T1 + (size_t)kMP * 256;
constexpr size_t OFF_T3   = OFF_T2 + (size_t)kMP * 256;
constexpr size_t OFF_BIGB = OFF_T3 + (size_t)kMP * 256;          // bf16 [kMP*1024]
constexpr size_t OFF_SB   = OFF_BIGB + (size_t)kMP * 512;        // bf16 [kMP*256]
constexpr size_t OFF_AB   = OFF_SB + (size_t)kMP * 128;          // bf16 [kMP*256]
constexpr size_t OFF_WB   = OFF_AB + (size_t)kMP * 128;          // bf16 enc weights
constexpr size_t OFF_GWB  = OFF_WB + 786432;
constexpr size_t OFF_PB   = OFF_GWB + 196608;
constexpr size_t OFF_DEG  = OFF_PB + 32768;
constexpr size_t OFF_EL   = OFF_DEG + (size_t)kV * kN;
constexpr size_t OFF_ER   = OFF_EL  + (size_t)kV * kN;
constexpr size_t OFF_W0   = OFF_ER  + (size_t)kV * kN;
constexpr size_t OFF_W1   = OFF_W0  + (size_t)kV * kN;
constexpr size_t OFF_FB   = OFF_W1  + (size_t)kV * kN;
constexpr size_t OFF_R2   = OFF_FB  + (size_t)kN * kC;
constexpr size_t OFF_RST  = OFF_R2  + (size_t)kN * kC;
constexpr size_t OFF_EL2  = OFF_RST + (size_t)kN * kC;
constexpr size_t OFF_ER2  = OFF_EL2 + kN;
constexpr size_t OFF_ST   = OFF_ER2 + kN;
constexpr size_t OFF_INT  = OFF_ST + 4;
// int layout
constexpr size_t ICNT  = 0;
constexpr size_t ICNT2 = ICNT  + (size_t)kV * kN;
constexpr size_t IOFF  = ICNT2 + kN;
constexpr size_t IOFF2 = IOFF  + (size_t)kV * kN;
constexpr size_t ICUR  = IOFF2 + kN;
constexpr size_t ICUR2 = ICUR  + (size_t)kV * kN;
constexpr size_t ICSR  = ICUR2 + kN;
constexpr size_t ICSR2 = ICSR  + (size_t)kV * kE;
} // namespace

typedef __attribute__((ext_vector_type(4))) float f32x4;
typedef __attribute__((ext_vector_type(8))) __bf16 bf16x8;

__device__ __forceinline__ float lrelu(float x) { return x > 0.f ? x : 0.2f * x; }
__device__ __forceinline__ unsigned short f2b(float f) {
    unsigned u = __float_as_uint(f);
    return (unsigned short)((u + 0x7FFFu + ((u >> 16) & 1u)) >> 16);
}
__device__ __forceinline__ float b2f(unsigned short h) {
    return __uint_as_float((unsigned)h << 16);
}

// ---------------- conversion kernels ----------------

__global__ void cvt_k(const float* __restrict__ in, unsigned short* __restrict__ out, int n4) {
    int i = blockIdx.x * 256 + threadIdx.x;
    if (i >= n4) return;
    float4 v = reinterpret_cast<const float4*>(in)[i];
    ushort4 o;
    o.x = f2b(v.x); o.y = f2b(v.y); o.z = f2b(v.z); o.w = f2b(v.w);
    reinterpret_cast<ushort4*>(out)[i] = o;
}

__global__ void tcvt_k(const float* __restrict__ in, unsigned short* __restrict__ out,
                       int K, int N, int total) {
    int gid = blockIdx.x * 256 + threadIdx.x;
    if (gid >= total) return;
    int per = K * N;
    int v = gid / per, r = gid - v * per;
    int n = r / K, k = r - n * K;
    out[gid] = f2b(in[(size_t)v * per + (size_t)k * N + n]);
}

// ---------------- MFMA bf16 GEMM (m97 K-loop + LDS-staged coalesced epilogue) ----------------
// C[M,N] = act(A[M,K] @ W[N,K]^T + bias). 128x128 tile, BK=32, 4 waves.
// XCD-chunked block swizzle (m204 bijective) for A-panel L2 locality.
template <int ACT, bool WF32, bool WB16>
__global__ __launch_bounds__(256) void mgemm_k(const unsigned short* __restrict__ A,
                                               const unsigned short* __restrict__ W,
                                               const float* __restrict__ bias,
                                               float* __restrict__ Cf,
                                               unsigned short* __restrict__ Cb,
                                               int M, int N, int K,
                                               long zA, long zW, long zC) {
    static_assert(WF32 != WB16, "exactly one output path");
    __shared__ __align__(16) unsigned short shbuf[16384];   // 32 KB: staging (16 KB) then epilogue
    unsigned short* As = shbuf;            // [128*32]
    unsigned short* Ws = shbuf + 4096;     // [128*32]

    const int tid  = threadIdx.x;
    const int lane = tid & 63;

    // bijective XCD-chunked swizzle of the (x,y) tile index (m204)
    const int gx = gridDim.x;
    const int nwg = gx * gridDim.y;
    const int orig = blockIdx.y * gx + blockIdx.x;
    const int q = nwg >> 3, rr = nwg & 7;
    const int xcd = orig & 7, pos = orig >> 3;
    const int nid = (xcd < rr ? xcd * (q + 1) : rr * (q + 1) + (xcd - rr) * q) + pos;
    const int bm = (nid / gx) * 128, bn = (nid % gx) * 128;

    A += (size_t)blockIdx.z * zA;
    W += (size_t)blockIdx.z * zW;
    const size_t zrow = (size_t)blockIdx.z * zC;

    const int wv = tid >> 6;
    const int wm = (wv >> 1) * 64, wn = (wv & 1) * 64;
    const int fr = lane & 15;
    const int fk = (lane >> 4) * 8;

    f32x4 acc[4][4] = {};

    for (int k0 = 0; k0 < K; k0 += 32) {
#pragma unroll
        for (int i = 0; i < 2; ++i) {
            const int f = i * 256 + tid;
            const int r = f >> 2, sl = (f & 3) * 8;
            const unsigned short* ga = A + (size_t)(bm + r) * K + (k0 + sl);
            const unsigned short* gw = W + (size_t)(bn + r) * K + (k0 + sl);
            __builtin_amdgcn_global_load_lds((const __attribute__((address_space(1))) void*)ga,
                                             (__attribute__((address_space(3))) void*)(As + f * 8), 16, 0, 0);
            __builtin_amdgcn_global_load_lds((const __attribute__((address_space(1))) void*)gw,
                                             (__attribute__((address_space(3))) void*)(Ws + f * 8), 16, 0, 0);
        }
        __syncthreads();
        bf16x8 av[4], bv[4];
#pragma unroll
        for (int mi = 0; mi < 4; ++mi)
            av[mi] = *reinterpret_cast<const bf16x8*>(As + (wm + mi * 16 + fr) * 32 + fk);
#pragma unroll
        for (int ni = 0; ni < 4; ++ni)
            bv[ni] = *reinterpret_cast<const bf16x8*>(Ws + (wn + ni * 16 + fr) * 32 + fk);
#pragma unroll
        for (int mi = 0; mi < 4; ++mi)
#pragma unroll
            for (int ni = 0; ni < 4; ++ni)
                acc[mi][ni] = __builtin_amdgcn_mfma_f32_16x16x32_bf16(av[mi], bv[ni], acc[mi][ni], 0, 0, 0);
        __syncthreads();
    }
    // all LDS reads of staging complete (final barrier above) -> reuse shbuf for epilogue

    const int crow = (lane >> 4) * 4;
    const int ccol = lane & 15;

    if (WB16) {
        // stage full 128x128 bf16 tile in LDS, then coalesced 16B stores
#pragma unroll
        for (int mi = 0; mi < 4; ++mi)
#pragma unroll
            for (int r = 0; r < 4; ++r) {
                const int row = wm + mi * 16 + crow + r;
#pragma unroll
                for (int ni = 0; ni < 4; ++ni) {
                    const int col = wn + ni * 16 + ccol;
                    float v = acc[mi][ni][r];
                    if (bias) v += bias[bn + col];
                    if (ACT == 1) v = fmaxf(v, 0.f);
                    if (ACT == 2) v = tanhf(v);
                    shbuf[row * 128 + col] = f2b(v);
                }
            }
        __syncthreads();
#pragma unroll
        for (int it = 0; it < 8; ++it) {
            const int fl = it * 2048 + tid * 8;      // ushort index in [128][128]
            const int row = fl >> 7, col = fl & 127;
            const int grow = bm + row;
            if (grow < M) {
                uint4 d = *reinterpret_cast<const uint4*>(shbuf + row * 128 + col);
                *reinterpret_cast<uint4*>(Cb + (zrow + grow) * (size_t)N + bn + col) = d;
            }
        }
    } else {
        // f32: two 64-row chunks (32 KB each)
        float* epf = reinterpret_cast<float*>(shbuf);   // [64][128]
#pragma unroll
        for (int half = 0; half < 2; ++half) {
            if ((wm >> 6) == half) {
#pragma unroll
                for (int mi = 0; mi < 4; ++mi)
#pragma unroll
                    for (int r = 0; r < 4; ++r) {
                        const int row = mi * 16 + crow + r;   // 0..63 within chunk
#pragma unroll
                        for (int ni = 0; ni < 4; ++ni) {
                            const int col = wn + ni * 16 + ccol;
                            float v = acc[mi][ni][r];
                            if (bias) v += bias[bn + col];
                            if (ACT == 1) v = fmaxf(v, 0.f);
                            if (ACT == 2) v = tanhf(v);
                            epf[row * 128 + col] = v;
                        }
                    }
            }
            __syncthreads();
#pragma unroll
            for (int it = 0; it < 8; ++it) {
                const int fl = it * 1024 + tid * 4;   // float index in [64][128]
                const int row = fl >> 7, col = fl & 127;
                const int grow = bm + half * 64 + row;
                if (grow < M) {
                    float4 d = *reinterpret_cast<const float4*>(epf + row * 128 + col);
                    *reinterpret_cast<float4*>(Cf + (zrow + grow) * (size_t)N + bn + col) = d;
                }
            }
            __syncthreads();   // drain reads before chunk-2 overwrite
        }
    }
}

// ---------------- fp32 GEMM (N=32 tail) ----------------
template <int ACT>
__global__ __launch_bounds__(256) void gemm_k(const float* __restrict__ A,
                                              const float* __restrict__ B,
                                              const float* __restrict__ bias,
                                              float* __restrict__ Cmat,
                                              int M, int Nn, int K) {
    __shared__ float As[16][64];
    __shared__ float Bs[16][68];
    const int tid  = threadIdx.x;
    const int bm   = blockIdx.y * 64;
    const int bn   = blockIdx.x * 64;
    const int tx   = tid & 15, ty = tid >> 4;
    const int arow = tid >> 2;
    const int acol = (tid & 3) << 2;
    const int brow = tid >> 4;
    const int bcol = (tid & 15) << 2;
    const int gm   = bm + arow;
    float acc[4][4] = {{0.f,0.f,0.f,0.f},{0.f,0.f,0.f,0.f},{0.f,0.f,0.f,0.f},{0.f,0.f,0.f,0.f}};

    for (int k0 = 0; k0 < K; k0 += 16) {
        float4 av = make_float4(0.f, 0.f, 0.f, 0.f);
        if (gm < M) av = *reinterpret_cast<const float4*>(A + (size_t)gm * K + (k0 + acol));
        As[acol + 0][arow] = av.x;
        As[acol + 1][arow] = av.y;
        As[acol + 2][arow] = av.z;
        As[acol + 3][arow] = av.w;

        const int gn = bn + bcol;
        const float* Brow = B + (size_t)(k0 + brow) * Nn;
        float4 bv;
        if (gn + 3 < Nn) {
            bv = *reinterpret_cast<const float4*>(Brow + gn);
        } else {
            bv.x = (gn + 0 < Nn) ? Brow[gn + 0] : 0.f;
            bv.y = (gn + 1 < Nn) ? Brow[gn + 1] : 0.f;
            bv.z = (gn + 2 < Nn) ? Brow[gn + 2] : 0.f;
            bv.w = (gn + 3 < Nn) ? Brow[gn + 3] : 0.f;
        }
        *reinterpret_cast<float4*>(&Bs[brow][bcol]) = bv;
        __syncthreads();

#pragma unroll
        for (int k = 0; k < 16; ++k) {
            float4 a4 = *reinterpret_cast<const float4*>(&As[k][ty << 2]);
            float4 b4 = *reinterpret_cast<const float4*>(&Bs[k][tx << 2]);
            acc[0][0] += a4.x * b4.x; acc[0][1] += a4.x * b4.y; acc[0][2] += a4.x * b4.z; acc[0][3] += a4.x * b4.w;
            acc[1][0] += a4.y * b4.x; acc[1][1] += a4.y * b4.y; acc[1][2] += a4.y * b4.z; acc[1][3] += a4.y * b4.w;
            acc[2][0] += a4.z * b4.x; acc[2][1] += a4.z * b4.y; acc[2][2] += a4.z * b4.z; acc[2][3] += a4.z * b4.w;
            acc[3][0] += a4.w * b4.x; acc[3][1] += a4.w * b4.y; acc[3][2] += a4.w * b4.z; acc[3][3] += a4.w * b4.w;
        }
        __syncthreads();
    }

#pragma unroll
    for (int i = 0; i < 4; ++i) {
        int m = bm + (ty << 2) + i;
        if (m >= M) continue;
#pragma unroll
        for (int j = 0; j < 4; ++j) {
            int n = bn + (tx << 2) + j;
            if (n >= Nn) continue;
            float v = acc[i][j];
            if (bias) v += bias[n];
            if (ACT == 1) v = fmaxf(v, 0.f);
            if (ACT == 2) v = tanhf(v);
            Cmat[(size_t)m * Nn + n] = v;
        }
    }
}

// out = LN(x+y)*g+b; wave per row, float4 per lane, 4 rows per block (shuffle-only)
__global__ __launch_bounds__(256) void ln_add_k(const float* __restrict__ x, const float* __restrict__ y,
                                                const float* __restrict__ g, const float* __restrict__ b,
                                                float* __restrict__ out, unsigned short* __restrict__ outb,
                                                int rows) {
    int r = blockIdx.x * 4 + (threadIdx.x >> 6);
    if (r >= rows) return;
    int lane = threadIdx.x & 63;
    size_t base = (size_t)r * 256 + lane * 4;
    float4 xv = *reinterpret_cast<const float4*>(x + base);
    float4 yv = *reinterpret_cast<const float4*>(y + base);
    float4 t;
    t.x = xv.x + yv.x; t.y = xv.y + yv.y; t.z = xv.z + yv.z; t.w = xv.w + yv.w;
    float s = t.x + t.y + t.z + t.w;
#pragma unroll
    for (int off = 32; off > 0; off >>= 1) s += __shfl_xor(s, off, 64);
    float mean = s * (1.0f / 256.0f);
    float4 d;
    d.x = t.x - mean; d.y = t.y - mean; d.z = t.z - mean; d.w = t.w - mean;
    float s2 = d.x * d.x + d.y * d.y + d.z * d.z + d.w * d.w;
#pragma unroll
    for (int off = 32; off > 0; off >>= 1) s2 += __shfl_xor(s2, off, 64);
    float rs = rsqrtf(s2 * (1.0f / 256.0f) + 1e-5f);
    float4 gv = *reinterpret_cast<const float4*>(g + lane * 4);
    float4 bv = *reinterpret_cast<const float4*>(b + lane * 4);
    float4 o;
    o.x = d.x * rs * gv.x + bv.x;
    o.y = d.y * rs * gv.y + bv.y;
    o.z = d.z * rs * gv.z + bv.z;
    o.w = d.w * rs * gv.w + bv.w;
    *reinterpret_cast<float4*>(out + base) = o;
    ushort4 ob;
    ob.x = f2b(o.x); ob.y = f2b(o.y); ob.z = f2b(o.z); ob.w = f2b(o.w);
    *reinterpret_cast<ushort4*>(outb + base) = ob;
}

// per-row dual dot products, fp32 A
__global__ void rowdot2_k(const float* __restrict__ A, const float* __restrict__ v1,
                          const float* __restrict__ v2, float* __restrict__ o1,
                          float* __restrict__ o2, int rows, int K, int rowsPerVec, int vecStride) {
    int r = blockIdx.x;
    if (r >= rows) return;
    int lane = threadIdx.x;
    const float* base = A + (size_t)r * K;
    int vo = (r / rowsPerVec) * vecStride;
    float s1 = 0.f, s2 = 0.f;
    for (int c = lane; c < K; c += 64) {
        float a = base[c];
        s1 += a * v1[vo + c];
        if (v2) s2 += a * v2[vo + c];
    }
#pragma unroll
    for (int off = 32; off > 0; off >>= 1) {
        s1 += __shfl_xor(s1, off, 64);
        s2 += __shfl_xor(s2, off, 64);
    }
    if (lane == 0) { o1[r] = s1; if (o2) o2[r] = s2; }
}

// per-row dual dot products, bf16 A, ushort4 per lane
__global__ void rowdot2b_k(const unsigned short* __restrict__ A, const float* __restrict__ v1,
                           const float* __restrict__ v2, float* __restrict__ o1,
                           float* __restrict__ o2, int rows, int K, int rowsPerVec, int vecStride) {
    int r = blockIdx.x;
    if (r >= rows) return;
    int lane = threadIdx.x;
    const unsigned short* base = A + (size_t)r * K;
    int vo = (r / rowsPerVec) * vecStride;
    float s1 = 0.f, s2 = 0.f;
    for (int c = lane * 4; c < K; c += 256) {
        ushort4 a4 = *reinterpret_cast<const ushort4*>(base + c);
        float4 w1 = *reinterpret_cast<const float4*>(v1 + vo + c);
        float4 w2 = *reinterpret_cast<const float4*>(v2 + vo + c);
        s1 += b2f(a4.x) * w1.x + b2f(a4.y) * w1.y + b2f(a4.z) * w1.z + b2f(a4.w) * w1.w;
        s2 += b2f(a4.x) * w2.x + b2f(a4.y) * w2.y + b2f(a4.z) * w2.z + b2f(a4.w) * w2.w;
    }
#pragma unroll
    for (int off = 32; off > 0; off >>= 1) {
        s1 += __shfl_xor(s1, off, 64);
        s2 += __shfl_xor(s2, off, 64);
    }
    if (lane == 0) { o1[r] = s1; o2[r] = s2; }
}

// ---------------- CSR build ----------------

__global__ void count_k(const int* __restrict__ dst, int* __restrict__ cnt, int nE, int nN, int total) {
    int gid = blockIdx.x * 256 + threadIdx.x;
    if (gid >= total) return;
    int v = gid / nE;
    atomicAdd(&cnt[(size_t)v * nN + dst[gid]], 1);
}

__global__ __launch_bounds__(1024) void scan_k(const int* __restrict__ cnt, int* __restrict__ offs,
                                               int* __restrict__ cursor, int nN) {
    int v = blockIdx.x;
    const int* c = cnt + (size_t)v * nN;
    int* o  = offs + (size_t)v * nN;
    int* cu = cursor + (size_t)v * nN;
    int tid = threadIdx.x;
    int chunk = (nN + 1023) >> 10;
    int lo = tid * chunk;
    int hi = lo + chunk < nN ? lo + chunk : nN;
    int s = 0;
    for (int i = lo; i < hi; ++i) s += c[i];
    int lane = tid & 63, wid = tid >> 6;
    int x = s;
#pragma unroll
    for (int off = 1; off < 64; off <<= 1) {
        int y = __shfl_up(x, off, 64);
        if (lane >= off) x += y;
    }
    __shared__ int wsum[16];
    if (lane == 63) wsum[wid] = x;
    __syncthreads();
    if (tid == 0) {
        int a = 0;
        for (int w = 0; w < 16; ++w) { int t = wsum[w]; wsum[w] = a; a += t; }
    }
    __syncthreads();
    int base = x - s + wsum[wid];
    for (int i = lo; i < hi; ++i) { o[i] = base; cu[i] = base; base += c[i]; }
}

__global__ void fill_csr_k(const int* __restrict__ src, const int* __restrict__ dst,
                           int* __restrict__ cursor, int* __restrict__ csr,
                           int nE, int nN, int total) {
    int gid = blockIdx.x * 256 + threadIdx.x;
    if (gid >= total) return;
    int v = gid / nE;
    int pos = atomicAdd(&cursor[(size_t)v * nN + dst[gid]], 1);
    csr[(size_t)v * nE + pos] = src[gid];
}

__global__ void dinv_k(const int* __restrict__ cnt, float* __restrict__ dinv, int n) {
    int gid = blockIdx.x * 256 + threadIdx.x;
    if (gid < n) dinv[gid] = rsqrtf((float)cnt[gid] + 1.0f);
}

// ---------------- GCN gather: one WAVE per node, LDS-free, ushort4/lane ----------------

__global__ __launch_bounds__(256) void gcn_gather_k(const int* __restrict__ csr, const int* __restrict__ offs,
                                                    const int* __restrict__ cnt, const float* __restrict__ dinv,
                                                    const unsigned short* __restrict__ h, const float* __restrict__ b,
                                                    float* __restrict__ out, unsigned short* __restrict__ outb) {
    int nd = blockIdx.x * 4 + (threadIdx.x >> 6);
    if (nd >= kV * kN) return;
    int v  = nd / kN;
    int lane = threadIdx.x & 63;
    int c4 = lane * 4;
    const int* base = csr + (size_t)v * kE;
    int o0 = offs[nd], n = cnt[nd];
    float dd = dinv[nd];
    const float* dv = dinv + (size_t)v * kN;
    const unsigned short* hb = h + (size_t)v * kN * kH;

    ushort4 hs = *reinterpret_cast<const ushort4*>(h + (size_t)nd * kH + c4);
    float wts = dd * dd;
    float4 acc;
    acc.x = b2f(hs.x) * wts; acc.y = b2f(hs.y) * wts;
    acc.z = b2f(hs.z) * wts; acc.w = b2f(hs.w) * wts;
    int i = 0;
    for (; i + 2 <= n; i += 2) {
        int s0 = base[o0 + i], s1 = base[o0 + i + 1];
        float w0 = dv[s0] * dd, w1 = dv[s1] * dd;
        ushort4 h0 = *reinterpret_cast<const ushort4*>(hb + (size_t)s0 * kH + c4);
        ushort4 h1 = *reinterpret_cast<const ushort4*>(hb + (size_t)s1 * kH + c4);
        acc.x += b2f(h0.x) * w0 + b2f(h1.x) * w1;
        acc.y += b2f(h0.y) * w0 + b2f(h1.y) * w1;
        acc.z += b2f(h0.z) * w0 + b2f(h1.z) * w1;
        acc.w += b2f(h0.w) * w0 + b2f(h1.w) * w1;
    }
    if (i < n) {
        int s0 = base[o0 + i];
        float w0 = dv[s0] * dd;
        ushort4 h0 = *reinterpret_cast<const ushort4*>(hb + (size_t)s0 * kH + c4);
        acc.x += b2f(h0.x) * w0; acc.y += b2f(h0.y) * w0;
        acc.z += b2f(h0.z) * w0; acc.w += b2f(h0.w) * w0;
    }
    float4 bb = *reinterpret_cast<const float4*>(b + (size_t)v * kH + c4);
    float4 r;
    r.x = fmaxf(acc.x + bb.x, 0.f);
    r.y = fmaxf(acc.y + bb.y, 0.f);
    r.z = fmaxf(acc.z + bb.z, 0.f);
    r.w = fmaxf(acc.w + bb.w, 0.f);
    *reinterpret_cast<float4*>(out + (size_t)nd * kH + c4) = r;
    ushort4 ob;
    ob.x = f2b(r.x); ob.y = f2b(r.y); ob.z = f2b(r.z); ob.w = f2b(r.w);
    *reinterpret_cast<ushort4*>(outb + (size_t)nd * kH + c4) = ob;
}

// ---------------- GAT gather: one WAVE per node, LDS-free ----------------

__global__ __launch_bounds__(256) void gat_gather_k(const int* __restrict__ csr, const int* __restrict__ offs,
                                                    const int* __restrict__ cnt, const float* __restrict__ el,
                                                    const float* __restrict__ er, const unsigned short* __restrict__ h,
                                                    const float* __restrict__ b, float* __restrict__ out,
                                                    unsigned short* __restrict__ outb) {
    int nd = blockIdx.x * 4 + (threadIdx.x >> 6);
    if (nd >= kV * kN) return;
    int v  = nd / kN;
    int lane = threadIdx.x & 63;
    int c4 = lane * 4;
    const int* base = csr + (size_t)v * kE;
    int o0 = offs[nd], n = cnt[nd];
    float erd = er[nd];
    const float* elv = el + (size_t)v * kN;
    const unsigned short* hb = h + (size_t)v * kN * kH;
    float eself = lrelu(el[nd] + erd);

    float m = eself;
    for (int i = 0; i < n; ++i) m = fmaxf(m, lrelu(elv[base[o0 + i]] + erd));

    float es = __expf(eself - m);
    float z = es;
    ushort4 hs = *reinterpret_cast<const ushort4*>(h + (size_t)nd * kH + c4);
    float4 acc;
    acc.x = b2f(hs.x) * es; acc.y = b2f(hs.y) * es;
    acc.z = b2f(hs.z) * es; acc.w = b2f(hs.w) * es;
    int i = 0;
    for (; i + 2 <= n; i += 2) {
        int s0 = base[o0 + i], s1 = base[o0 + i + 1];
        float e0 = __expf(lrelu(elv[s0] + erd) - m);
        float e1 = __expf(lrelu(elv[s1] + erd) - m);
        z += e0 + e1;
        ushort4 h0 = *reinterpret_cast<const ushort4*>(hb + (size_t)s0 * kH + c4);
        ushort4 h1 = *reinterpret_cast<const ushort4*>(hb + (size_t)s1 * kH + c4);
        acc.x += b2f(h0.x) * e0 + b2f(h1.x) * e1;
        acc.y += b2f(h0.y) * e0 + b2f(h1.y) * e1;
        acc.z += b2f(h0.z) * e0 + b2f(h1.z) * e1;
        acc.w += b2f(h0.w) * e0 + b2f(h1.w) * e1;
    }
    if (i < n) {
        int s0 = base[o0 + i];
        float e0 = __expf(lrelu(elv[s0] + erd) - m);
        z += e0;
        ushort4 h0 = *reinterpret_cast<const ushort4*>(hb + (size_t)s0 * kH + c4);
        acc.x += b2f(h0.x) * e0; acc.y += b2f(h0.y) * e0;
        acc.z += b2f(h0.z) * e0; acc.w += b2f(h0.w) * e0;
    }
    float iz = 1.0f / z;
    float4 bb = *reinterpret_cast<const float4*>(b + (size_t)v * kH + c4);
    float4 r;
    r.x = fmaxf(acc.x * iz + bb.x, 0.f);
    r.y = fmaxf(acc.y * iz + bb.y, 0.f);
    r.z = fmaxf(acc.z * iz + bb.z, 0.f);
    r.w = fmaxf(acc.w * iz + bb.w, 0.f);
    *reinterpret_cast<float4*>(out + (size_t)nd * kH + c4) = r;
    ushort4 ob;
    ob.x = f2b(r.x); ob.y = f2b(r.y); ob.z = f2b(r.z); ob.w = f2b(r.w);
    *reinterpret_cast<ushort4*>(outb + (size_t)nd * kH + c4) = ob;
}

// ---------------- transformer: 3x3 attention, 8 lanes per (node,head), ushort4 ----------------

__global__ __launch_bounds__(256) void mha3_k(const unsigned short* __restrict__ qkv, unsigned short* __restrict__ o) {
    int grp = blockIdx.x * 32 + (threadIdx.x >> 3);
    int l8 = threadIdx.x & 7;
    if (grp >= kN * kNH) return;
    int b = grp / kNH, h = grp - b * kNH;
    float4 q[3], k[3], vv[3];
#pragma unroll
    for (int s = 0; s < 3; ++s) {
        size_t base = ((size_t)s * kN + b) * 768 + h * 32 + l8 * 4;
        ushort4 qu = *reinterpret_cast<const ushort4*>(qkv + base);
        ushort4 ku = *reinterpret_cast<const ushort4*>(qkv + base + 256);
        ushort4 vu = *reinterpret_cast<const ushort4*>(qkv + base + 512);
        q[s].x = b2f(qu.x); q[s].y = b2f(qu.y); q[s].z = b2f(qu.z); q[s].w = b2f(qu.w);
        k[s].x = b2f(ku.x); k[s].y = b2f(ku.y); k[s].z = b2f(ku.z); k[s].w = b2f(ku.w);
        vv[s].x = b2f(vu.x); vv[s].y = b2f(vu.y); vv[s].z = b2f(vu.z); vv[s].w = b2f(vu.w);
    }
    float sc[3][3];
#pragma unroll
    for (int s = 0; s < 3; ++s)
#pragma unroll
        for (int t = 0; t < 3; ++t) {
            float d = q[s].x * k[t].x + q[s].y * k[t].y + q[s].z * k[t].z + q[s].w * k[t].w;
            d += __shfl_xor(d, 1, 64);
            d += __shfl_xor(d, 2, 64);
            d += __shfl_xor(d, 4, 64);
            sc[s][t] = d * 0.17677669529663687f;
        }
#pragma unroll
    for (int s = 0; s < 3; ++s) {
        float m = fmaxf(sc[s][0], fmaxf(sc[s][1], sc[s][2]));
        float e0 = __expf(sc[s][0] - m), e1 = __expf(sc[s][1] - m), e2 = __expf(sc[s][2] - m);
        float iz = 1.0f / (e0 + e1 + e2);
        ushort4 ob;
        ob.x = f2b((e0 * vv[0].x + e1 * vv[1].x + e2 * vv[2].x) * iz);
        ob.y = f2b((e0 * vv[0].y + e1 * vv[1].y + e2 * vv[2].y) * iz);
        ob.z = f2b((e0 * vv[0].z + e1 * vv[1].z + e2 * vv[2].z) * iz);
        ob.w = f2b((e0 * vv[0].w + e1 * vv[1].w + e2 * vv[2].w) * iz);
        *reinterpret_cast<ushort4*>(o + ((size_t)s * kN + b) * kH + h * 32 + l8 * 4) = ob;
    }
}

// ---------------- view attention / blend ----------------

__global__ void view_comb_k(const float* __restrict__ a1, const float* __restrict__ w0,
                            const float* __restrict__ w1, float* __restrict__ x1,
                            float* __restrict__ x2) {
    int gid = blockIdx.x * 256 + threadIdx.x;
    if (gid >= kN * 64) return;
    int n = gid >> 6;
    int c4 = (gid & 63) << 2;
    float u0 = w0[n], u1 = w0[kN + n], u2 = w0[2 * kN + n];
    float m = fmaxf(u0, fmaxf(u1, u2));
    float e0 = expf(u0 - m), e1 = expf(u1 - m), e2 = expf(u2 - m);
    float iz = 1.f / (e0 + e1 + e2);
    float p0 = e0 * iz, p1 = e1 * iz, p2 = e2 * iz;
    float q0 = w1[n], q1 = w1[kN + n], q2 = w1[2 * kN + n];
    float mq = fmaxf(q0, fmaxf(q1, q2));
    float f0 = expf(q0 - mq), f1 = expf(q1 - mq), f2 = expf(q2 - mq);
    float izq = 1.f / (f0 + f1 + f2);
    float r0 = f0 * izq, r1 = f1 * izq, r2 = f2 * izq;
    float4 A0 = *reinterpret_cast<const float4*>(a1 + ((size_t)0 * kN + n) * 256 + c4);
    float4 A1 = *reinterpret_cast<const float4*>(a1 + ((size_t)1 * kN + n) * 256 + c4);
    float4 A2 = *reinterpret_cast<const float4*>(a1 + ((size_t)2 * kN + n) * 256 + c4);
    float4 o1, o2;
    o1.x = p0 * A0.x + p1 * A1.x + p2 * A2.x;  o2.x = r0 * A0.x + r1 * A1.x + r2 * A2.x;
    o1.y = p0 * A0.y + p1 * A1.y + p2 * A2.y;  o2.y = r0 * A0.y + r1 * A1.y + r2 * A2.y;
    o1.z = p0 * A0.z + p1 * A1.z + p2 * A2.z;  o2.z = r0 * A0.z + r1 * A1.z + r2 * A2.z;
    o1.w = p0 * A0.w + p1 * A1.w + p2 * A2.w;  o2.w = r0 * A0.w + r1 * A1.w + r2 * A2.w;
    *reinterpret_cast<float4*>(x1 + (size_t)n * 256 + c4) = o1;
    *reinterpret_cast<float4*>(x2 + (size_t)n * 256 + c4) = o2;
}

__global__ __launch_bounds__(1024) void randsm_k(const float* __restrict__ rw, float* __restrict__ stats) {
    __shared__ float sm[16];
    __shared__ float ss[16];
    int tid = threadIdx.x;
    float m = -1e30f;
    for (int i = tid; i < kN; i += 1024) m = fmaxf(m, rw[i]);
#pragma unroll
    for (int off = 32; off > 0; off >>= 1) m = fmaxf(m, __shfl_xor(m, off, 64));
    if ((tid & 63) == 0) sm[tid >> 6] = m;
    __syncthreads();
    if (tid == 0) {
        float mm = sm[0];
        for (int i = 1; i < 16; ++i) mm = fmaxf(mm, sm[i]);
        sm[0] = mm;
    }
    __syncthreads();
    float mx = sm[0];
    float s = 0.f;
    for (int i = tid; i < kN; i += 1024) s += expf(rw[i] - mx);
#pragma unroll
    for (int off = 32; off > 0; off >>= 1) s += __shfl_xor(s, off, 64);
    if ((tid & 63) == 0) ss[tid >> 6] = s;
    __syncthreads();
    if (tid == 0) {
        float z = 0.f;
        for (int i = 0; i < 16; ++i) z += ss[i];
        stats[0] = mx;
        stats[1] = z;
    }
}

__global__ void blend_k(const float* __restrict__ x1, const float* __restrict__ x2,
                        const float* __restrict__ rw, const float* __restrict__ stats,
                        float* __restrict__ g) {
    int gid = blockIdx.x * 256 + threadIdx.x;
    if (gid >= kN * 64) return;
    int n = gid >> 6;
    int c4 = (gid & 63) << 2;
    float aw = expf(rw[n] - stats[0]) / stats[1];
    float4 v1 = *reinterpret_cast<const float4*>(x1 + (size_t)n * 256 + c4);
    float4 v2 = *reinterpret_cast<const float4*>(x2 + (size_t)n * 256 + c4);
    float4 o;
    o.x = aw * v1.x + (1.f - aw) * v2.x;
    o.y = aw * v1.y + (1.f - aw) * v2.y;
    o.z = aw * v1.z + (1.f - aw) * v2.z;
    o.w = aw * v1.w + (1.f - aw) * v2.w;
    *reinterpret_cast<float4*>(g + (size_t)n * 256 + c4) = o;
}

// ---------------- myGAT gather ----------------

__global__ __launch_bounds__(256) void mygat_gather_k(const int* __restrict__ csr, const int* __restrict__ offs,
                                                      const int* __restrict__ cnt, const float* __restrict__ el,
                                                      const float* __restrict__ er, const float* __restrict__ f,
                                                      float* __restrict__ rst) {
    int node = blockIdx.x * 8 + (threadIdx.x >> 5);
    int c = threadIdx.x & 31;
    if (node >= kN) return;
    int o0 = offs[node], n = cnt[node];
    float erd = er[node];
    float m = -1e30f;
    for (int i = 0; i < n; ++i) {
        int s = csr[o0 + i];
        m = fmaxf(m, lrelu(el[s] + erd));
    }
    float z = 0.f, acc = 0.f;
    for (int i = 0; i < n; ++i) {
        int s = csr[o0 + i];
        float e = __expf(lrelu(el[s] + erd) - m);
        z += e;
        acc += f[(size_t)s * kC + c] * e;
    }
    rst[(size_t)node * kC + c] = acc / z;
}

__global__ void final_k(const float* __restrict__ rst, const float* __restrict__ r2,
                        float* __restrict__ logits) {
    int n = blockIdx.x * 256 + threadIdx.x;
    if (n >= kN) return;
    float vals[kC];
    float ssum = 0.f;
#pragma unroll
    for (int c = 0; c < kC; ++c) {
        vals[c] = rst[(size_t)n * kC + c] + r2[(size_t)n * kC + c];
        ssum += vals[c] * vals[c];
    }
    float inv = 1.0f / fmaxf(sqrtf(ssum), 1e-12f);
#pragma unroll
    for (int c = 0; c < kC; ++c) logits[(size_t)n * kC + c] = vals[c] * inv;
}

// ---------------- host orchestration ----------------

static void run_encoder(const float* xinF, const unsigned short* xinB, float* outp,
                        unsigned short* outB, float* ws, int e,
                        const float* bqkv, const float* bo, const float* b1, const float* b2,
                        const float* g1, const float* be1, const float* g2, const float* be2,
                        hipStream_t stream) {
    float* T2 = ws + OFF_T2;
    float* T3 = ws + OFF_T3;
    unsigned short* BIGB = (unsigned short*)(ws + OFF_BIGB);
    unsigned short* OB   = BIGB + (size_t)kMP * 768;
    unsigned short* SB   = (unsigned short*)(ws + OFF_SB);
    unsigned short* WB   = (unsigned short*)(ws + OFF_WB);
    const unsigned short* WQ = WB + (size_t)e * 196608;
    const unsigned short* WO = WB + 393216 + (size_t)e * 65536;
    const unsigned short* W1 = WB + 524288 + (size_t)e * 262144;
    const unsigned short* W2 = WB + 1048576 + (size_t)e * 262144;
    dim3 blk(256);

    mgemm_k<0, false, true><<<dim3(6, 469, 1), blk, 0, stream>>>(
        xinB, WQ, bqkv, nullptr, BIGB, kSN, 768, 256, 0, 0, 0);
    mha3_k<<<dim3((kN * kNH) / 32), blk, 0, stream>>>(BIGB, OB);
    mgemm_k<0, true, false><<<dim3(2, 469, 1), blk, 0, stream>>>(
        OB, WO, bo, T2, nullptr, kSN, 256, 256, 0, 0, 0);
    ln_add_k<<<dim3(kSN / 4), blk, 0, stream>>>(xinF, T2, g1, be1, T3, SB, kSN);
    mgemm_k<1, false, true><<<dim3(8, 469, 1), blk, 0, stream>>>(
        SB, W1, b1, nullptr, BIGB, kSN, 1024, 256, 0, 0, 0);
    mgemm_k<0, true, false><<<dim3(2, 469, 1), blk, 0, stream>>>(
        BIGB, W2, b2, T2, nullptr, kSN, 256, 1024, 0, 0, 0);
    ln_add_k<<<dim3(kSN / 4), blk, 0, stream>>>(T3, T2, g2, be2, outp, outB, kSN);
}

extern "C" void kernel_launch(void* const* d_in, const int* in_sizes, int n_in,
                              void* d_out, int out_size, void* d_ws, size_t ws_size,
                              hipStream_t stream) {
    (void)in_sizes; (void)n_in; (void)out_size; (void)ws_size;

    const float* x      = (const float*)d_in[0];
    const int*   e_src  = (const int*)d_in[1];
    const int*   e_dst  = (const int*)d_in[2];
    const int*   gsrc   = (const int*)d_in[3];
    const int*   gdst   = (const int*)d_in[4];
    const float* rand_w = (const float*)d_in[5];
    const float* gcn_W  = (const float*)d_in[6];
    const float* gcn_b  = (const float*)d_in[7];
    const float* gat_W  = (const float*)d_in[8];
    const float* gat_as = (const float*)d_in[9];
    const float* gat_ad = (const float*)d_in[10];
    const float* gat_b  = (const float*)d_in[11];
    const float* Wqkv   = (const float*)d_in[12];
    const float* bqkv   = (const float*)d_in[13];
    const float* Wo     = (const float*)d_in[14];
    const float* bo     = (const float*)d_in[15];
    const float* W1     = (const float*)d_in[16];
    const float* b1     = (const float*)d_in[17];
    const float* W2     = (const float*)d_in[18];
    const float* b2     = (const float*)d_in[19];
    const float* ln1g   = (const float*)d_in[20];
    const float* ln1b   = (const float*)d_in[21];
    const float* ln2g   = (const float*)d_in[22];
    const float* ln2b   = (const float*)d_in[23];
    const float* att_P  = (const float*)d_in[24];
    const float* att_Pb = (const float*)d_in[25];
    const float* att_q  = (const float*)d_in[26];
    const float* mg_fc  = (const float*)d_in[27];
    const float* mg_al  = (const float*)d_in[28];
    const float* mg_ar  = (const float*)d_in[29];
    const float* mg_res = (const float*)d_in[30];

    float* ws  = (float*)d_ws;
    float* T1  = ws + OFF_T1;
    float* T2  = ws + OFF_T2;
    float* T3  = ws + OFF_T3;
    float* DNV = ws + OFF_DEG;
    float* EL  = ws + OFF_EL;
    float* ER  = ws + OFF_ER;
    float* W0b = ws + OFF_W0;
    float* W1b = ws + OFF_W1;
    float* FB  = ws + OFF_FB;
    float* R2  = ws + OFF_R2;
    float* RST = ws + OFF_RST;
    float* EL2 = ws + OFF_EL2;
    float* ER2 = ws + OFF_ER2;
    float* ST  = ws + OFF_ST;

    unsigned short* BIGB = (unsigned short*)(ws + OFF_BIGB);
    unsigned short* HB   = BIGB;
    unsigned short* SB   = (unsigned short*)(ws + OFF_SB);
    unsigned short* AB   = (unsigned short*)(ws + OFF_AB);
    unsigned short* WB   = (unsigned short*)(ws + OFF_WB);
    unsigned short* GWB  = (unsigned short*)(ws + OFF_GWB);
    unsigned short* PB   = (unsigned short*)(ws + OFF_PB);

    int* ib    = (int*)(ws + OFF_INT);
    int* CNT   = ib + ICNT;
    int* CNT2  = ib + ICNT2;
    int* OFFS  = ib + IOFF;
    int* OFFS2 = ib + IOFF2;
    int* CUR   = ib + ICUR;
    int* CUR2  = ib + ICUR2;
    int* CSR   = ib + ICSR;
    int* CSR2  = ib + ICSR2;

    float* outp   = (float*)d_out;
    float* a0     = outp;
    float* a1     = outp + (size_t)kSN * kH;
    float* logits = outp + 2 * (size_t)kSN * kH;
    float* gemb   = outp + 2 * (size_t)kSN * kH + (size_t)kN * kC;

    dim3 blk(256);

    // ---- 0a. zero pad-tail rows of bf16 GEMM-A buffers ----
    hipMemsetAsync(SB + (size_t)kSN * 256, 0, (size_t)(kMP - kSN) * 256 * sizeof(unsigned short), stream);
    hipMemsetAsync(AB + (size_t)kSN * 256, 0, (size_t)(kMP - kSN) * 256 * sizeof(unsigned short), stream);
    hipMemsetAsync(BIGB + (size_t)kSN * 1024, 0, (size_t)(kMP - kSN) * 1024 * sizeof(unsigned short), stream);

    // ---- 0b. CSR build ----
    hipMemsetAsync(CNT, 0, (size_t)(kV * kN + kN) * sizeof(int), stream);
    count_k<<<dim3((kV * kE + 255) / 256), blk, 0, stream>>>(e_dst, CNT, kE, kN, kV * kE);
    count_k<<<dim3((kE2 + 255) / 256), blk, 0, stream>>>(gdst, CNT2, kE2, kN, kE2);
    scan_k<<<dim3(kV), dim3(1024), 0, stream>>>(CNT, OFFS, CUR, kN);
    scan_k<<<dim3(1), dim3(1024), 0, stream>>>(CNT2, OFFS2, CUR2, kN);
    fill_csr_k<<<dim3((kV * kE + 255) / 256), blk, 0, stream>>>(e_src, e_dst, CUR, CSR, kE, kN, kV * kE);
    fill_csr_k<<<dim3((kE2 + 255) / 256), blk, 0, stream>>>(gsrc, gdst, CUR2, CSR2, kE2, kN, kE2);
    dinv_k<<<dim3((kV * kN + 255) / 256), blk, 0, stream>>>(CNT, DNV, kV * kN);

    // ---- 0c. weight/activation bf16 conversion ----
    cvt_k<<<dim3((393216 / 4 + 255) / 256), blk, 0, stream>>>(Wqkv, WB, 393216 / 4);
    cvt_k<<<dim3((131072 / 4 + 255) / 256), blk, 0, stream>>>(Wo, WB + 393216, 131072 / 4);
    cvt_k<<<dim3((524288 / 4 + 255) / 256), blk, 0, stream>>>(W1, WB + 524288, 524288 / 4);
    cvt_k<<<dim3((524288 / 4 + 255) / 256), blk, 0, stream>>>(W2, WB + 1048576, 524288 / 4);
    tcvt_k<<<dim3((3 * 65536 + 255) / 256), blk, 0, stream>>>(gcn_W, GWB, 256, 256, 3 * 65536);
    tcvt_k<<<dim3((3 * 65536 + 255) / 256), blk, 0, stream>>>(gat_W, GWB + 3 * 65536, 256, 256, 3 * 65536);
    tcvt_k<<<dim3((2 * 32768 + 255) / 256), blk, 0, stream>>>(att_P, PB, 256, 128, 2 * 32768);
    cvt_k<<<dim3((kSN * 256 / 4 + 255) / 256), blk, 0, stream>>>(x, AB, kSN * 256 / 4);

    // ---- 1. multi-view GCN + relu ----
    mgemm_k<0, false, true><<<dim3(2, 157, 3), blk, 0, stream>>>(
        AB, GWB, nullptr, nullptr, HB, kN, 256, 256, (long)kN * 256, 65536, kN);
    gcn_gather_k<<<dim3(kSN / 4), blk, 0, stream>>>(CSR, OFFS, CNT, DNV, HB, gcn_b, T1, SB);

    // ---- 2. encoder 0 -> a0 ----
    run_encoder(T1, SB, a0, AB, ws, 0, bqkv, bo, b1, b2, ln1g, ln1b, ln2g, ln2b, stream);

    // ---- 3. multi-view GAT + relu ----
    mgemm_k<0, false, true><<<dim3(2, 157, 3), blk, 0, stream>>>(
        AB, GWB + 3 * 65536, nullptr, nullptr, HB, kN, 256, 256, (long)kN * 256, 65536, kN);
    rowdot2b_k<<<dim3(kSN), dim3(64), 0, stream>>>(HB, gat_as, gat_ad, EL, ER, kSN, 256, kN, kH);
    gat_gather_k<<<dim3(kSN / 4), blk, 0, stream>>>(CSR, OFFS, CNT, EL, ER, HB, gat_b, T1, SB);

    // ---- 4. encoder 1 -> a1 ----
    run_encoder(T1, SB, a1, AB, ws, 1, bqkv + 768, bo + 256, b1 + 1024, b2 + 256,
                ln1g + 256, ln1b + 256, ln2g + 256, ln2b + 256, stream);

    // ---- 5. view attention + blend -> gemb ----
    mgemm_k<2, true, false><<<dim3(1, 469, 1), blk, 0, stream>>>(
        AB, PB, att_Pb, T2, nullptr, kSN, 128, 256, 0, 0, 0);
    rowdot2_k<<<dim3(kSN), dim3(64), 0, stream>>>(T2, att_q, (const float*)nullptr, W0b, (float*)nullptr, kSN, 128, kSN, 0);
    mgemm_k<1, true, false><<<dim3(1, 469, 1), blk, 0, stream>>>(
        AB, PB + 32768, att_Pb + 128, T3, nullptr, kSN, 128, 256, 0, 0, 0);
    rowdot2_k<<<dim3(kSN), dim3(64), 0, stream>>>(T3, att_q + 128, (const float*)nullptr, W1b, (float*)nullptr, kSN, 128, kSN, 0);
    float* X1 = T2;
    float* X2 = T2 + (size_t)kN * kH;
    view_comb_k<<<dim3((kN * 64 + 255) / 256), blk, 0, stream>>>(a1, W0b, W1b, X1, X2);
    randsm_k<<<dim3(1), dim3(1024), 0, stream>>>(rand_w, ST);
    blend_k<<<dim3((kN * 64 + 255) / 256), blk, 0, stream>>>(X1, X2, rand_w, ST, gemb);

    // ---- 6. myGATConv -> logits ----
    gemm_k<0><<<dim3(1, (kN + 63) / 64), blk, 0, stream>>>(gemb, mg_fc, (const float*)nullptr, FB, kN, kC, 256);
    rowdot2_k<<<dim3(kN), dim3(64), 0, stream>>>(FB, mg_al, mg_ar, EL2, ER2, kN, kC, kN, 0);
    mygat_gather_k<<<dim3((kN + 7) / 8), blk, 0, stream>>>(CSR2, OFFS2, CNT2, EL2, ER2, FB, RST);
    gemm_k<0><<<dim3(1, (kN + 63) / 64), blk, 0, stream>>>(gemb, mg_res, (const float*)nullptr, R2, kN, kC, 256);
    final_k<<<dim3((kN + 255) / 256), blk, 0, stream>>>(RST, R2, logits);
}

// Round 7
// 1428.821 us; speedup vs baseline: 1.0532x; 1.0532x over previous
//
#include <hip/hip_runtime.h>
#include <hip/hip_bf16.h>
#include <math.h>

// ---------------- problem constants ----------------
namespace {
constexpr int kV  = 3;
constexpr int kN  = 20000;
constexpr int kF  = 256;
constexpr int kH  = 256;
constexpr int kE  = 160000;
constexpr int kC  = 32;
constexpr int kNH = 8;
constexpr int kSN = kV * kN;     // 60000
constexpr int kE2 = kE + kN;     // 180000
constexpr int kMP = 60160;       // padded rows for bf16 GEMM-A buffers

// fp32 workspace layout (float element offsets)
constexpr size_t OFF_T1   = 0;
constexpr size_t OFF_T2   = OFF_T1 + (size_t)kMP * 256;
constexpr size_t OFF_T3   = OFF_T2 + (size_t)kMP * 256;
constexpr size_t OFF_BIGB = OFF_T3 + (size_t)kMP * 256;          // bf16 [kMP*1024]
constexpr size_t OFF_SB   = OFF_BIGB + (size_t)kMP * 512;        // bf16 [kMP*256]
constexpr size_t OFF_AB   = OFF_SB + (size_t)kMP * 128;          // bf16 [kMP*256]
constexpr size_t OFF_WB   = OFF_AB + (size_t)kMP * 128;          // bf16 enc weights
constexpr size_t OFF_GWB  = OFF_WB + 786432;
constexpr size_t OFF_PB   = OFF_GWB + 196608;
constexpr size_t OFF_DEG  = OFF_PB + 32768;
constexpr size_t OFF_EL   = OFF_DEG + (size_t)kV * kN;
constexpr size_t OFF_ER   = OFF_EL  + (size_t)kV * kN;
constexpr size_t OFF_W0   = OFF_ER  + (size_t)kV * kN;
constexpr size_t OFF_W1   = OFF_W0  + (size_t)kV * kN;
constexpr size_t OFF_FB   = OFF_W1  + (size_t)kV * kN;
constexpr size_t OFF_R2   = OFF_FB  + (size_t)kN * kC;
constexpr size_t OFF_RST  = OFF_R2  + (size_t)kN * kC;
constexpr size_t OFF_EL2  = OFF_RST + (size_t)kN * kC;
constexpr size_t OFF_ER2  = OFF_EL2 + kN;
constexpr size_t OFF_ST   = OFF_ER2 + kN;
constexpr size_t OFF_INT  = OFF_ST + 4;
// int layout
constexpr size_t ICNT  = 0;
constexpr size_t ICNT2 = ICNT  + (size_t)kV * kN;
constexpr size_t IOFF  = ICNT2 + kN;
constexpr size_t IOFF2 = IOFF  + (size_t)kV * kN;
constexpr size_t ICUR  = IOFF2 + kN;
constexpr size_t ICUR2 = ICUR  + (size_t)kV * kN;
constexpr size_t ICSR  = ICUR2 + kN;
constexpr size_t ICSR2 = ICSR  + (size_t)kV * kE;
} // namespace

typedef __attribute__((ext_vector_type(4))) float f32x4;
typedef __attribute__((ext_vector_type(8))) __bf16 bf16x8;

__device__ __forceinline__ float lrelu(float x) { return x > 0.f ? x : 0.2f * x; }
__device__ __forceinline__ unsigned short f2b(float f) {
    unsigned u = __float_as_uint(f);
    return (unsigned short)((u + 0x7FFFu + ((u >> 16) & 1u)) >> 16);
}
__device__ __forceinline__ float b2f(unsigned short h) {
    return __uint_as_float((unsigned)h << 16);
}

// ---------------- conversion kernels ----------------

__global__ void cvt_k(const float* __restrict__ in, unsigned short* __restrict__ out, int n4) {
    int i = blockIdx.x * 256 + threadIdx.x;
    if (i >= n4) return;
    float4 v = reinterpret_cast<const float4*>(in)[i];
    ushort4 o;
    o.x = f2b(v.x); o.y = f2b(v.y); o.z = f2b(v.z); o.w = f2b(v.w);
    reinterpret_cast<ushort4*>(out)[i] = o;
}

__global__ void tcvt_k(const float* __restrict__ in, unsigned short* __restrict__ out,
                       int K, int N, int total) {
    int gid = blockIdx.x * 256 + threadIdx.x;
    if (gid >= total) return;
    int per = K * N;
    int v = gid / per, r = gid - v * per;
    int n = r / K, k = r - n * K;
    out[gid] = f2b(in[(size_t)v * per + (size_t)k * N + n]);
}

// ---------------- MFMA bf16 GEMM: double-buffered staging + coalesced epilogue ----------------
// C[M,N] = act(A[M,K] @ W[N,K]^T + bias). 128x128 tile, BK=32, 4 waves, 2-phase dbuf.
// XCD-chunked block swizzle (m204 bijective) for A-panel L2 locality.
template <int ACT, bool WF32, bool WB16>
__global__ __launch_bounds__(256) void mgemm_k(const unsigned short* __restrict__ A,
                                               const unsigned short* __restrict__ W,
                                               const float* __restrict__ bias,
                                               float* __restrict__ Cf,
                                               unsigned short* __restrict__ Cb,
                                               int M, int N, int K,
                                               long zA, long zW, long zC) {
    static_assert(WF32 != WB16, "exactly one output path");
    // 32 KB: 2 x (As 8KB + Ws 8KB) staging buffers; epilogue reuses all of it.
    __shared__ __align__(16) unsigned short shbuf[16384];

    const int tid  = threadIdx.x;
    const int lane = tid & 63;

    // bijective XCD-chunked swizzle of the (x,y) tile index (m204)
    const int gx = gridDim.x;
    const int nwg = gx * gridDim.y;
    const int orig = blockIdx.y * gx + blockIdx.x;
    const int q = nwg >> 3, rr = nwg & 7;
    const int xcd = orig & 7, pos = orig >> 3;
    const int nid = (xcd < rr ? xcd * (q + 1) : rr * (q + 1) + (xcd - rr) * q) + pos;
    const int bm = (nid / gx) * 128, bn = (nid % gx) * 128;

    A += (size_t)blockIdx.z * zA;
    W += (size_t)blockIdx.z * zW;
    const size_t zrow = (size_t)blockIdx.z * zC;

    const int wv = tid >> 6;
    const int wm = (wv >> 1) * 64, wn = (wv & 1) * 64;
    const int fr = lane & 15;
    const int fk = (lane >> 4) * 8;

    // per-thread staging coords (fixed across iterations)
    const int r0 = tid >> 2, sl0 = (tid & 3) * 8;              // i=0
    const int r1 = (256 + tid) >> 2, sl1 = ((256 + tid) & 3) * 8; // i=1

    f32x4 acc[4][4] = {};

    // prologue: stage tile 0 into buffer 0
    {
        unsigned short* As = shbuf;
        unsigned short* Ws = shbuf + 4096;
        __builtin_amdgcn_global_load_lds((const __attribute__((address_space(1))) void*)(A + (size_t)(bm + r0) * K + sl0),
                                         (__attribute__((address_space(3))) void*)(As + tid * 8), 16, 0, 0);
        __builtin_amdgcn_global_load_lds((const __attribute__((address_space(1))) void*)(W + (size_t)(bn + r0) * K + sl0),
                                         (__attribute__((address_space(3))) void*)(Ws + tid * 8), 16, 0, 0);
        __builtin_amdgcn_global_load_lds((const __attribute__((address_space(1))) void*)(A + (size_t)(bm + r1) * K + sl1),
                                         (__attribute__((address_space(3))) void*)(As + (256 + tid) * 8), 16, 0, 0);
        __builtin_amdgcn_global_load_lds((const __attribute__((address_space(1))) void*)(W + (size_t)(bn + r1) * K + sl1),
                                         (__attribute__((address_space(3))) void*)(Ws + (256 + tid) * 8), 16, 0, 0);
    }
    __syncthreads();

    int cur = 0;
    for (int k0 = 0; k0 < K; k0 += 32) {
        // issue next-tile loads into the other buffer (overlaps with this tile's compute)
        if (k0 + 32 < K) {
            unsigned short* As = shbuf + (cur ^ 1) * 8192;
            unsigned short* Ws = As + 4096;
            const int kn = k0 + 32;
            __builtin_amdgcn_global_load_lds((const __attribute__((address_space(1))) void*)(A + (size_t)(bm + r0) * K + kn + sl0),
                                             (__attribute__((address_space(3))) void*)(As + tid * 8), 16, 0, 0);
            __builtin_amdgcn_global_load_lds((const __attribute__((address_space(1))) void*)(W + (size_t)(bn + r0) * K + kn + sl0),
                                             (__attribute__((address_space(3))) void*)(Ws + tid * 8), 16, 0, 0);
            __builtin_amdgcn_global_load_lds((const __attribute__((address_space(1))) void*)(A + (size_t)(bm + r1) * K + kn + sl1),
                                             (__attribute__((address_space(3))) void*)(As + (256 + tid) * 8), 16, 0, 0);
            __builtin_amdgcn_global_load_lds((const __attribute__((address_space(1))) void*)(W + (size_t)(bn + r1) * K + kn + sl1),
                                             (__attribute__((address_space(3))) void*)(Ws + (256 + tid) * 8), 16, 0, 0);
        }
        // compute current buffer
        const unsigned short* As = shbuf + cur * 8192;
        const unsigned short* Ws = As + 4096;
        bf16x8 av[4], bv[4];
#pragma unroll
        for (int mi = 0; mi < 4; ++mi)
            av[mi] = *reinterpret_cast<const bf16x8*>(As + (wm + mi * 16 + fr) * 32 + fk);
#pragma unroll
        for (int ni = 0; ni < 4; ++ni)
            bv[ni] = *reinterpret_cast<const bf16x8*>(Ws + (wn + ni * 16 + fr) * 32 + fk);
#pragma unroll
        for (int mi = 0; mi < 4; ++mi)
#pragma unroll
            for (int ni = 0; ni < 4; ++ni)
                acc[mi][ni] = __builtin_amdgcn_mfma_f32_16x16x32_bf16(av[mi], bv[ni], acc[mi][ni], 0, 0, 0);
        __syncthreads();   // drains next-tile loads (in flight during MFMA) + this tile's ds_reads
        cur ^= 1;
    }
    // epilogue: reuse all 32 KB of shbuf (no staging reads remain past the final barrier)

    const int crow = (lane >> 4) * 4;
    const int ccol = lane & 15;

    if (WB16) {
        // full 128x128 bf16 tile in LDS, then coalesced 16B stores
#pragma unroll
        for (int mi = 0; mi < 4; ++mi)
#pragma unroll
            for (int r = 0; r < 4; ++r) {
                const int row = wm + mi * 16 + crow + r;
#pragma unroll
                for (int ni = 0; ni < 4; ++ni) {
                    const int col = wn + ni * 16 + ccol;
                    float v = acc[mi][ni][r];
                    if (bias) v += bias[bn + col];
                    if (ACT == 1) v = fmaxf(v, 0.f);
                    if (ACT == 2) v = tanhf(v);
                    shbuf[row * 128 + col] = f2b(v);
                }
            }
        __syncthreads();
#pragma unroll
        for (int it = 0; it < 8; ++it) {
            const int fl = it * 2048 + tid * 8;      // ushort index in [128][128]
            const int row = fl >> 7, col = fl & 127;
            const int grow = bm + row;
            if (grow < M) {
                uint4 d = *reinterpret_cast<const uint4*>(shbuf + row * 128 + col);
                *reinterpret_cast<uint4*>(Cb + (zrow + grow) * (size_t)N + bn + col) = d;
            }
        }
    } else {
        // f32: two 64-row chunks (32 KB each)
        float* epf = reinterpret_cast<float*>(shbuf);   // [64][128]
#pragma unroll
        for (int half = 0; half < 2; ++half) {
            if ((wm >> 6) == half) {
#pragma unroll
                for (int mi = 0; mi < 4; ++mi)
#pragma unroll
                    for (int r = 0; r < 4; ++r) {
                        const int row = mi * 16 + crow + r;   // 0..63 within chunk
#pragma unroll
                        for (int ni = 0; ni < 4; ++ni) {
                            const int col = wn + ni * 16 + ccol;
                            float v = acc[mi][ni][r];
                            if (bias) v += bias[bn + col];
                            if (ACT == 1) v = fmaxf(v, 0.f);
                            if (ACT == 2) v = tanhf(v);
                            epf[row * 128 + col] = v;
                        }
                    }
            }
            __syncthreads();
#pragma unroll
            for (int it = 0; it < 8; ++it) {
                const int fl = it * 1024 + tid * 4;   // float index in [64][128]
                const int row = fl >> 7, col = fl & 127;
                const int grow = bm + half * 64 + row;
                if (grow < M) {
                    float4 d = *reinterpret_cast<const float4*>(epf + row * 128 + col);
                    *reinterpret_cast<float4*>(Cf + (zrow + grow) * (size_t)N + bn + col) = d;
                }
            }
            __syncthreads();   // drain reads before chunk-2 overwrite
        }
    }
}

// ---------------- fp32 GEMM (N=32 tail) ----------------
template <int ACT>
__global__ __launch_bounds__(256) void gemm_k(const float* __restrict__ A,
                                              const float* __restrict__ B,
                                              const float* __restrict__ bias,
                                              float* __restrict__ Cmat,
                                              int M, int Nn, int K) {
    __shared__ float As[16][64];
    __shared__ float Bs[16][68];
    const int tid  = threadIdx.x;
    const int bm   = blockIdx.y * 64;
    const int bn   = blockIdx.x * 64;
    const int tx   = tid & 15, ty = tid >> 4;
    const int arow = tid >> 2;
    const int acol = (tid & 3) << 2;
    const int brow = tid >> 4;
    const int bcol = (tid & 15) << 2;
    const int gm   = bm + arow;
    float acc[4][4] = {{0.f,0.f,0.f,0.f},{0.f,0.f,0.f,0.f},{0.f,0.f,0.f,0.f},{0.f,0.f,0.f,0.f}};

    for (int k0 = 0; k0 < K; k0 += 16) {
        float4 av = make_float4(0.f, 0.f, 0.f, 0.f);
        if (gm < M) av = *reinterpret_cast<const float4*>(A + (size_t)gm * K + (k0 + acol));
        As[acol + 0][arow] = av.x;
        As[acol + 1][arow] = av.y;
        As[acol + 2][arow] = av.z;
        As[acol + 3][arow] = av.w;

        const int gn = bn + bcol;
        const float* Brow = B + (size_t)(k0 + brow) * Nn;
        float4 bv;
        if (gn + 3 < Nn) {
            bv = *reinterpret_cast<const float4*>(Brow + gn);
        } else {
            bv.x = (gn + 0 < Nn) ? Brow[gn + 0] : 0.f;
            bv.y = (gn + 1 < Nn) ? Brow[gn + 1] : 0.f;
            bv.z = (gn + 2 < Nn) ? Brow[gn + 2] : 0.f;
            bv.w = (gn + 3 < Nn) ? Brow[gn + 3] : 0.f;
        }
        *reinterpret_cast<float4*>(&Bs[brow][bcol]) = bv;
        __syncthreads();

#pragma unroll
        for (int k = 0; k < 16; ++k) {
            float4 a4 = *reinterpret_cast<const float4*>(&As[k][ty << 2]);
            float4 b4 = *reinterpret_cast<const float4*>(&Bs[k][tx << 2]);
            acc[0][0] += a4.x * b4.x; acc[0][1] += a4.x * b4.y; acc[0][2] += a4.x * b4.z; acc[0][3] += a4.x * b4.w;
            acc[1][0] += a4.y * b4.x; acc[1][1] += a4.y * b4.y; acc[1][2] += a4.y * b4.z; acc[1][3] += a4.y * b4.w;
            acc[2][0] += a4.z * b4.x; acc[2][1] += a4.z * b4.y; acc[2][2] += a4.z * b4.z; acc[2][3] += a4.z * b4.w;
            acc[3][0] += a4.w * b4.x; acc[3][1] += a4.w * b4.y; acc[3][2] += a4.w * b4.z; acc[3][3] += a4.w * b4.w;
        }
        __syncthreads();
    }

#pragma unroll
    for (int i = 0; i < 4; ++i) {
        int m = bm + (ty << 2) + i;
        if (m >= M) continue;
#pragma unroll
        for (int j = 0; j < 4; ++j) {
            int n = bn + (tx << 2) + j;
            if (n >= Nn) continue;
            float v = acc[i][j];
            if (bias) v += bias[n];
            if (ACT == 1) v = fmaxf(v, 0.f);
            if (ACT == 2) v = tanhf(v);
            Cmat[(size_t)m * Nn + n] = v;
        }
    }
}

// out = LN(x+y)*g+b; wave per row, float4 per lane, 4 rows per block (shuffle-only)
__global__ __launch_bounds__(256) void ln_add_k(const float* __restrict__ x, const float* __restrict__ y,
                                                const float* __restrict__ g, const float* __restrict__ b,
                                                float* __restrict__ out, unsigned short* __restrict__ outb,
                                                int rows) {
    int r = blockIdx.x * 4 + (threadIdx.x >> 6);
    if (r >= rows) return;
    int lane = threadIdx.x & 63;
    size_t base = (size_t)r * 256 + lane * 4;
    float4 xv = *reinterpret_cast<const float4*>(x + base);
    float4 yv = *reinterpret_cast<const float4*>(y + base);
    float4 t;
    t.x = xv.x + yv.x; t.y = xv.y + yv.y; t.z = xv.z + yv.z; t.w = xv.w + yv.w;
    float s = t.x + t.y + t.z + t.w;
#pragma unroll
    for (int off = 32; off > 0; off >>= 1) s += __shfl_xor(s, off, 64);
    float mean = s * (1.0f / 256.0f);
    float4 d;
    d.x = t.x - mean; d.y = t.y - mean; d.z = t.z - mean; d.w = t.w - mean;
    float s2 = d.x * d.x + d.y * d.y + d.z * d.z + d.w * d.w;
#pragma unroll
    for (int off = 32; off > 0; off >>= 1) s2 += __shfl_xor(s2, off, 64);
    float rs = rsqrtf(s2 * (1.0f / 256.0f) + 1e-5f);
    float4 gv = *reinterpret_cast<const float4*>(g + lane * 4);
    float4 bv = *reinterpret_cast<const float4*>(b + lane * 4);
    float4 o;
    o.x = d.x * rs * gv.x + bv.x;
    o.y = d.y * rs * gv.y + bv.y;
    o.z = d.z * rs * gv.z + bv.z;
    o.w = d.w * rs * gv.w + bv.w;
    *reinterpret_cast<float4*>(out + base) = o;
    ushort4 ob;
    ob.x = f2b(o.x); ob.y = f2b(o.y); ob.z = f2b(o.z); ob.w = f2b(o.w);
    *reinterpret_cast<ushort4*>(outb + base) = ob;
}

// per-row dual dot products, fp32 A
__global__ void rowdot2_k(const float* __restrict__ A, const float* __restrict__ v1,
                          const float* __restrict__ v2, float* __restrict__ o1,
                          float* __restrict__ o2, int rows, int K, int rowsPerVec, int vecStride) {
    int r = blockIdx.x;
    if (r >= rows) return;
    int lane = threadIdx.x;
    const float* base = A + (size_t)r * K;
    int vo = (r / rowsPerVec) * vecStride;
    float s1 = 0.f, s2 = 0.f;
    for (int c = lane; c < K; c += 64) {
        float a = base[c];
        s1 += a * v1[vo + c];
        if (v2) s2 += a * v2[vo + c];
    }
#pragma unroll
    for (int off = 32; off > 0; off >>= 1) {
        s1 += __shfl_xor(s1, off, 64);
        s2 += __shfl_xor(s2, off, 64);
    }
    if (lane == 0) { o1[r] = s1; if (o2) o2[r] = s2; }
}

// per-row dual dot products, bf16 A, ushort4 per lane
__global__ void rowdot2b_k(const unsigned short* __restrict__ A, const float* __restrict__ v1,
                           const float* __restrict__ v2, float* __restrict__ o1,
                           float* __restrict__ o2, int rows, int K, int rowsPerVec, int vecStride) {
    int r = blockIdx.x;
    if (r >= rows) return;
    int lane = threadIdx.x;
    const unsigned short* base = A + (size_t)r * K;
    int vo = (r / rowsPerVec) * vecStride;
    float s1 = 0.f, s2 = 0.f;
    for (int c = lane * 4; c < K; c += 256) {
        ushort4 a4 = *reinterpret_cast<const ushort4*>(base + c);
        float4 w1 = *reinterpret_cast<const float4*>(v1 + vo + c);
        float4 w2 = *reinterpret_cast<const float4*>(v2 + vo + c);
        s1 += b2f(a4.x) * w1.x + b2f(a4.y) * w1.y + b2f(a4.z) * w1.z + b2f(a4.w) * w1.w;
        s2 += b2f(a4.x) * w2.x + b2f(a4.y) * w2.y + b2f(a4.z) * w2.z + b2f(a4.w) * w2.w;
    }
#pragma unroll
    for (int off = 32; off > 0; off >>= 1) {
        s1 += __shfl_xor(s1, off, 64);
        s2 += __shfl_xor(s2, off, 64);
    }
    if (lane == 0) { o1[r] = s1; o2[r] = s2; }
}

// ---------------- CSR build ----------------

__global__ void count_k(const int* __restrict__ dst, int* __restrict__ cnt, int nE, int nN, int total) {
    int gid = blockIdx.x * 256 + threadIdx.x;
    if (gid >= total) return;
    int v = gid / nE;
    atomicAdd(&cnt[(size_t)v * nN + dst[gid]], 1);
}

__global__ __launch_bounds__(1024) void scan_k(const int* __restrict__ cnt, int* __restrict__ offs,
                                               int* __restrict__ cursor, int nN) {
    int v = blockIdx.x;
    const int* c = cnt + (size_t)v * nN;
    int* o  = offs + (size_t)v * nN;
    int* cu = cursor + (size_t)v * nN;
    int tid = threadIdx.x;
    int chunk = (nN + 1023) >> 10;
    int lo = tid * chunk;
    int hi = lo + chunk < nN ? lo + chunk : nN;
    int s = 0;
    for (int i = lo; i < hi; ++i) s += c[i];
    int lane = tid & 63, wid = tid >> 6;
    int x = s;
#pragma unroll
    for (int off = 1; off < 64; off <<= 1) {
        int y = __shfl_up(x, off, 64);
        if (lane >= off) x += y;
    }
    __shared__ int wsum[16];
    if (lane == 63) wsum[wid] = x;
    __syncthreads();
    if (tid == 0) {
        int a = 0;
        for (int w = 0; w < 16; ++w) { int t = wsum[w]; wsum[w] = a; a += t; }
    }
    __syncthreads();
    int base = x - s + wsum[wid];
    for (int i = lo; i < hi; ++i) { o[i] = base; cu[i] = base; base += c[i]; }
}

__global__ void fill_csr_k(const int* __restrict__ src, const int* __restrict__ dst,
                           int* __restrict__ cursor, int* __restrict__ csr,
                           int nE, int nN, int total) {
    int gid = blockIdx.x * 256 + threadIdx.x;
    if (gid >= total) return;
    int v = gid / nE;
    int pos = atomicAdd(&cursor[(size_t)v * nN + dst[gid]], 1);
    csr[(size_t)v * nE + pos] = src[gid];
}

__global__ void dinv_k(const int* __restrict__ cnt, float* __restrict__ dinv, int n) {
    int gid = blockIdx.x * 256 + threadIdx.x;
    if (gid < n) dinv[gid] = rsqrtf((float)cnt[gid] + 1.0f);
}

// ---------------- GCN gather: one WAVE per node, LDS-free, ushort4/lane ----------------

__global__ __launch_bounds__(256) void gcn_gather_k(const int* __restrict__ csr, const int* __restrict__ offs,
                                                    const int* __restrict__ cnt, const float* __restrict__ dinv,
                                                    const unsigned short* __restrict__ h, const float* __restrict__ b,
                                                    float* __restrict__ out, unsigned short* __restrict__ outb) {
    int nd = blockIdx.x * 4 + (threadIdx.x >> 6);
    if (nd >= kV * kN) return;
    int v  = nd / kN;
    int lane = threadIdx.x & 63;
    int c4 = lane * 4;
    const int* base = csr + (size_t)v * kE;
    int o0 = offs[nd], n = cnt[nd];
    float dd = dinv[nd];
    const float* dv = dinv + (size_t)v * kN;
    const unsigned short* hb = h + (size_t)v * kN * kH;

    ushort4 hs = *reinterpret_cast<const ushort4*>(h + (size_t)nd * kH + c4);
    float wts = dd * dd;
    float4 acc;
    acc.x = b2f(hs.x) * wts; acc.y = b2f(hs.y) * wts;
    acc.z = b2f(hs.z) * wts; acc.w = b2f(hs.w) * wts;
    int i = 0;
    for (; i + 2 <= n; i += 2) {
        int s0 = base[o0 + i], s1 = base[o0 + i + 1];
        float w0 = dv[s0] * dd, w1 = dv[s1] * dd;
        ushort4 h0 = *reinterpret_cast<const ushort4*>(hb + (size_t)s0 * kH + c4);
        ushort4 h1 = *reinterpret_cast<const ushort4*>(hb + (size_t)s1 * kH + c4);
        acc.x += b2f(h0.x) * w0 + b2f(h1.x) * w1;
        acc.y += b2f(h0.y) * w0 + b2f(h1.y) * w1;
        acc.z += b2f(h0.z) * w0 + b2f(h1.z) * w1;
        acc.w += b2f(h0.w) * w0 + b2f(h1.w) * w1;
    }
    if (i < n) {
        int s0 = base[o0 + i];
        float w0 = dv[s0] * dd;
        ushort4 h0 = *reinterpret_cast<const ushort4*>(hb + (size_t)s0 * kH + c4);
        acc.x += b2f(h0.x) * w0; acc.y += b2f(h0.y) * w0;
        acc.z += b2f(h0.z) * w0; acc.w += b2f(h0.w) * w0;
    }
    float4 bb = *reinterpret_cast<const float4*>(b + (size_t)v * kH + c4);
    float4 r;
    r.x = fmaxf(acc.x + bb.x, 0.f);
    r.y = fmaxf(acc.y + bb.y, 0.f);
    r.z = fmaxf(acc.z + bb.z, 0.f);
    r.w = fmaxf(acc.w + bb.w, 0.f);
    *reinterpret_cast<float4*>(out + (size_t)nd * kH + c4) = r;
    ushort4 ob;
    ob.x = f2b(r.x); ob.y = f2b(r.y); ob.z = f2b(r.z); ob.w = f2b(r.w);
    *reinterpret_cast<ushort4*>(outb + (size_t)nd * kH + c4) = ob;
}

// ---------------- GAT gather: one WAVE per node, LDS-free ----------------

__global__ __launch_bounds__(256) void gat_gather_k(const int* __restrict__ csr, const int* __restrict__ offs,
                                                    const int* __restrict__ cnt, const float* __restrict__ el,
                                                    const float* __restrict__ er, const unsigned short* __restrict__ h,
                                                    const float* __restrict__ b, float* __restrict__ out,
                                                    unsigned short* __restrict__ outb) {
    int nd = blockIdx.x * 4 + (threadIdx.x >> 6);
    if (nd >= kV * kN) return;
    int v  = nd / kN;
    int lane = threadIdx.x & 63;
    int c4 = lane * 4;
    const int* base = csr + (size_t)v * kE;
    int o0 = offs[nd], n = cnt[nd];
    float erd = er[nd];
    const float* elv = el + (size_t)v * kN;
    const unsigned short* hb = h + (size_t)v * kN * kH;
    float eself = lrelu(el[nd] + erd);

    float m = eself;
    for (int i = 0; i < n; ++i) m = fmaxf(m, lrelu(elv[base[o0 + i]] + erd));

    float es = __expf(eself - m);
    float z = es;
    ushort4 hs = *reinterpret_cast<const ushort4*>(h + (size_t)nd * kH + c4);
    float4 acc;
    acc.x = b2f(hs.x) * es; acc.y = b2f(hs.y) * es;
    acc.z = b2f(hs.z) * es; acc.w = b2f(hs.w) * es;
    int i = 0;
    for (; i + 2 <= n; i += 2) {
        int s0 = base[o0 + i], s1 = base[o0 + i + 1];
        float e0 = __expf(lrelu(elv[s0] + erd) - m);
        float e1 = __expf(lrelu(elv[s1] + erd) - m);
        z += e0 + e1;
        ushort4 h0 = *reinterpret_cast<const ushort4*>(hb + (size_t)s0 * kH + c4);
        ushort4 h1 = *reinterpret_cast<const ushort4*>(hb + (size_t)s1 * kH + c4);
        acc.x += b2f(h0.x) * e0 + b2f(h1.x) * e1;
        acc.y += b2f(h0.y) * e0 + b2f(h1.y) * e1;
        acc.z += b2f(h0.z) * e0 + b2f(h1.z) * e1;
        acc.w += b2f(h0.w) * e0 + b2f(h1.w) * e1;
    }
    if (i < n) {
        int s0 = base[o0 + i];
        float e0 = __expf(lrelu(elv[s0] + erd) - m);
        z += e0;
        ushort4 h0 = *reinterpret_cast<const ushort4*>(hb + (size_t)s0 * kH + c4);
        acc.x += b2f(h0.x) * e0; acc.y += b2f(h0.y) * e0;
        acc.z += b2f(h0.z) * e0; acc.w += b2f(h0.w) * e0;
    }
    float iz = 1.0f / z;
    float4 bb = *reinterpret_cast<const float4*>(b + (size_t)v * kH + c4);
    float4 r;
    r.x = fmaxf(acc.x * iz + bb.x, 0.f);
    r.y = fmaxf(acc.y * iz + bb.y, 0.f);
    r.z = fmaxf(acc.z * iz + bb.z, 0.f);
    r.w = fmaxf(acc.w * iz + bb.w, 0.f);
    *reinterpret_cast<float4*>(out + (size_t)nd * kH + c4) = r;
    ushort4 ob;
    ob.x = f2b(r.x); ob.y = f2b(r.y); ob.z = f2b(r.z); ob.w = f2b(r.w);
    *reinterpret_cast<ushort4*>(outb + (size_t)nd * kH + c4) = ob;
}

// ---------------- transformer: 3x3 attention, 8 lanes per (node,head), ushort4 ----------------

__global__ __launch_bounds__(256) void mha3_k(const unsigned short* __restrict__ qkv, unsigned short* __restrict__ o) {
    int grp = blockIdx.x * 32 + (threadIdx.x >> 3);
    int l8 = threadIdx.x & 7;
    if (grp >= kN * kNH) return;
    int b = grp / kNH, h = grp - b * kNH;
    float4 q[3], k[3], vv[3];
#pragma unroll
    for (int s = 0; s < 3; ++s) {
        size_t base = ((size_t)s * kN + b) * 768 + h * 32 + l8 * 4;
        ushort4 qu = *reinterpret_cast<const ushort4*>(qkv + base);
        ushort4 ku = *reinterpret_cast<const ushort4*>(qkv + base + 256);
        ushort4 vu = *reinterpret_cast<const ushort4*>(qkv + base + 512);
        q[s].x = b2f(qu.x); q[s].y = b2f(qu.y); q[s].z = b2f(qu.z); q[s].w = b2f(qu.w);
        k[s].x = b2f(ku.x); k[s].y = b2f(ku.y); k[s].z = b2f(ku.z); k[s].w = b2f(ku.w);
        vv[s].x = b2f(vu.x); vv[s].y = b2f(vu.y); vv[s].z = b2f(vu.z); vv[s].w = b2f(vu.w);
    }
    float sc[3][3];
#pragma unroll
    for (int s = 0; s < 3; ++s)
#pragma unroll
        for (int t = 0; t < 3; ++t) {
            float d = q[s].x * k[t].x + q[s].y * k[t].y + q[s].z * k[t].z + q[s].w * k[t].w;
            d += __shfl_xor(d, 1, 64);
            d += __shfl_xor(d, 2, 64);
            d += __shfl_xor(d, 4, 64);
            sc[s][t] = d * 0.17677669529663687f;
        }
#pragma unroll
    for (int s = 0; s < 3; ++s) {
        float m = fmaxf(sc[s][0], fmaxf(sc[s][1], sc[s][2]));
        float e0 = __expf(sc[s][0] - m), e1 = __expf(sc[s][1] - m), e2 = __expf(sc[s][2] - m);
        float iz = 1.0f / (e0 + e1 + e2);
        ushort4 ob;
        ob.x = f2b((e0 * vv[0].x + e1 * vv[1].x + e2 * vv[2].x) * iz);
        ob.y = f2b((e0 * vv[0].y + e1 * vv[1].y + e2 * vv[2].y) * iz);
        ob.z = f2b((e0 * vv[0].z + e1 * vv[1].z + e2 * vv[2].z) * iz);
        ob.w = f2b((e0 * vv[0].w + e1 * vv[1].w + e2 * vv[2].w) * iz);
        *reinterpret_cast<ushort4*>(o + ((size_t)s * kN + b) * kH + h * 32 + l8 * 4) = ob;
    }
}

// ---------------- view attention / blend ----------------

__global__ void view_comb_k(const float* __restrict__ a1, const float* __restrict__ w0,
                            const float* __restrict__ w1, float* __restrict__ x1,
                            float* __restrict__ x2) {
    int gid = blockIdx.x * 256 + threadIdx.x;
    if (gid >= kN * 64) return;
    int n = gid >> 6;
    int c4 = (gid & 63) << 2;
    float u0 = w0[n], u1 = w0[kN + n], u2 = w0[2 * kN + n];
    float m = fmaxf(u0, fmaxf(u1, u2));
    float e0 = expf(u0 - m), e1 = expf(u1 - m), e2 = expf(u2 - m);
    float iz = 1.f / (e0 + e1 + e2);
    float p0 = e0 * iz, p1 = e1 * iz, p2 = e2 * iz;
    float q0 = w1[n], q1 = w1[kN + n], q2 = w1[2 * kN + n];
    float mq = fmaxf(q0, fmaxf(q1, q2));
    float f0 = expf(q0 - mq), f1 = expf(q1 - mq), f2 = expf(q2 - mq);
    float izq = 1.f / (f0 + f1 + f2);
    float r0 = f0 * izq, r1 = f1 * izq, r2 = f2 * izq;
    float4 A0 = *reinterpret_cast<const float4*>(a1 + ((size_t)0 * kN + n) * 256 + c4);
    float4 A1 = *reinterpret_cast<const float4*>(a1 + ((size_t)1 * kN + n) * 256 + c4);
    float4 A2 = *reinterpret_cast<const float4*>(a1 + ((size_t)2 * kN + n) * 256 + c4);
    float4 o1, o2;
    o1.x = p0 * A0.x + p1 * A1.x + p2 * A2.x;  o2.x = r0 * A0.x + r1 * A1.x + r2 * A2.x;
    o1.y = p0 * A0.y + p1 * A1.y + p2 * A2.y;  o2.y = r0 * A0.y + r1 * A1.y + r2 * A2.y;
    o1.z = p0 * A0.z + p1 * A1.z + p2 * A2.z;  o2.z = r0 * A0.z + r1 * A1.z + r2 * A2.z;
    o1.w = p0 * A0.w + p1 * A1.w + p2 * A2.w;  o2.w = r0 * A0.w + r1 * A1.w + r2 * A2.w;
    *reinterpret_cast<float4*>(x1 + (size_t)n * 256 + c4) = o1;
    *reinterpret_cast<float4*>(x2 + (size_t)n * 256 + c4) = o2;
}

__global__ __launch_bounds__(1024) void randsm_k(const float* __restrict__ rw, float* __restrict__ stats) {
    __shared__ float sm[16];
    __shared__ float ss[16];
    int tid = threadIdx.x;
    float m = -1e30f;
    for (int i = tid; i < kN; i += 1024) m = fmaxf(m, rw[i]);
#pragma unroll
    for (int off = 32; off > 0; off >>= 1) m = fmaxf(m, __shfl_xor(m, off, 64));
    if ((tid & 63) == 0) sm[tid >> 6] = m;
    __syncthreads();
    if (tid == 0) {
        float mm = sm[0];
        for (int i = 1; i < 16; ++i) mm = fmaxf(mm, sm[i]);
        sm[0] = mm;
    }
    __syncthreads();
    float mx = sm[0];
    float s = 0.f;
    for (int i = tid; i < kN; i += 1024) s += expf(rw[i] - mx);
#pragma unroll
    for (int off = 32; off > 0; off >>= 1) s += __shfl_xor(s, off, 64);
    if ((tid & 63) == 0) ss[tid >> 6] = s;
    __syncthreads();
    if (tid == 0) {
        float z = 0.f;
        for (int i = 0; i < 16; ++i) z += ss[i];
        stats[0] = mx;
        stats[1] = z;
    }
}

__global__ void blend_k(const float* __restrict__ x1, const float* __restrict__ x2,
                        const float* __restrict__ rw, const float* __restrict__ stats,
                        float* __restrict__ g) {
    int gid = blockIdx.x * 256 + threadIdx.x;
    if (gid >= kN * 64) return;
    int n = gid >> 6;
    int c4 = (gid & 63) << 2;
    float aw = expf(rw[n] - stats[0]) / stats[1];
    float4 v1 = *reinterpret_cast<const float4*>(x1 + (size_t)n * 256 + c4);
    float4 v2 = *reinterpret_cast<const float4*>(x2 + (size_t)n * 256 + c4);
    float4 o;
    o.x = aw * v1.x + (1.f - aw) * v2.x;
    o.y = aw * v1.y + (1.f - aw) * v2.y;
    o.z = aw * v1.z + (1.f - aw) * v2.z;
    o.w = aw * v1.w + (1.f - aw) * v2.w;
    *reinterpret_cast<float4*>(g + (size_t)n * 256 + c4) = o;
}

// ---------------- myGAT gather ----------------

__global__ __launch_bounds__(256) void mygat_gather_k(const int* __restrict__ csr, const int* __restrict__ offs,
                                                      const int* __restrict__ cnt, const float* __restrict__ el,
                                                      const float* __restrict__ er, const float* __restrict__ f,
                                                      float* __restrict__ rst) {
    int node = blockIdx.x * 8 + (threadIdx.x >> 5);
    int c = threadIdx.x & 31;
    if (node >= kN) return;
    int o0 = offs[node], n = cnt[node];
    float erd = er[node];
    float m = -1e30f;
    for (int i = 0; i < n; ++i) {
        int s = csr[o0 + i];
        m = fmaxf(m, lrelu(el[s] + erd));
    }
    float z = 0.f, acc = 0.f;
    for (int i = 0; i < n; ++i) {
        int s = csr[o0 + i];
        float e = __expf(lrelu(el[s] + erd) - m);
        z += e;
        acc += f[(size_t)s * kC + c] * e;
    }
    rst[(size_t)node * kC + c] = acc / z;
}

__global__ void final_k(const float* __restrict__ rst, const float* __restrict__ r2,
                        float* __restrict__ logits) {
    int n = blockIdx.x * 256 + threadIdx.x;
    if (n >= kN) return;
    float vals[kC];
    float ssum = 0.f;
#pragma unroll
    for (int c = 0; c < kC; ++c) {
        vals[c] = rst[(size_t)n * kC + c] + r2[(size_t)n * kC + c];
        ssum += vals[c] * vals[c];
    }
    float inv = 1.0f / fmaxf(sqrtf(ssum), 1e-12f);
#pragma unroll
    for (int c = 0; c < kC; ++c) logits[(size_t)n * kC + c] = vals[c] * inv;
}

// ---------------- host orchestration ----------------

static void run_encoder(const float* xinF, const unsigned short* xinB, float* outp,
                        unsigned short* outB, float* ws, int e,
                        const float* bqkv, const float* bo, const float* b1, const float* b2,
                        const float* g1, const float* be1, const float* g2, const float* be2,
                        hipStream_t stream) {
    float* T2 = ws + OFF_T2;
    float* T3 = ws + OFF_T3;
    unsigned short* BIGB = (unsigned short*)(ws + OFF_BIGB);
    unsigned short* OB   = BIGB + (size_t)kMP * 768;
    unsigned short* SB   = (unsigned short*)(ws + OFF_SB);
    unsigned short* WB   = (unsigned short*)(ws + OFF_WB);
    const unsigned short* WQ = WB + (size_t)e * 196608;
    const unsigned short* WO = WB + 393216 + (size_t)e * 65536;
    const unsigned short* W1 = WB + 524288 + (size_t)e * 262144;
    const unsigned short* W2 = WB + 1048576 + (size_t)e * 262144;
    dim3 blk(256);

    mgemm_k<0, false, true><<<dim3(6, 469, 1), blk, 0, stream>>>(
        xinB, WQ, bqkv, nullptr, BIGB, kSN, 768, 256, 0, 0, 0);
    mha3_k<<<dim3((kN * kNH) / 32), blk, 0, stream>>>(BIGB, OB);
    mgemm_k<0, true, false><<<dim3(2, 469, 1), blk, 0, stream>>>(
        OB, WO, bo, T2, nullptr, kSN, 256, 256, 0, 0, 0);
    ln_add_k<<<dim3(kSN / 4), blk, 0, stream>>>(xinF, T2, g1, be1, T3, SB, kSN);
    mgemm_k<1, false, true><<<dim3(8, 469, 1), blk, 0, stream>>>(
        SB, W1, b1, nullptr, BIGB, kSN, 1024, 256, 0, 0, 0);
    mgemm_k<0, true, false><<<dim3(2, 469, 1), blk, 0, stream>>>(
        BIGB, W2, b2, T2, nullptr, kSN, 256, 1024, 0, 0, 0);
    ln_add_k<<<dim3(kSN / 4), blk, 0, stream>>>(T3, T2, g2, be2, outp, outB, kSN);
}

extern "C" void kernel_launch(void* const* d_in, const int* in_sizes, int n_in,
                              void* d_out, int out_size, void* d_ws, size_t ws_size,
                              hipStream_t stream) {
    (void)in_sizes; (void)n_in; (void)out_size; (void)ws_size;

    const float* x      = (const float*)d_in[0];
    const int*   e_src  = (const int*)d_in[1];
    const int*   e_dst  = (const int*)d_in[2];
    const int*   gsrc   = (const int*)d_in[3];
    const int*   gdst   = (const int*)d_in[4];
    const float* rand_w = (const float*)d_in[5];
    const float* gcn_W  = (const float*)d_in[6];
    const float* gcn_b  = (const float*)d_in[7];
    const float* gat_W  = (const float*)d_in[8];
    const float* gat_as = (const float*)d_in[9];
    const float* gat_ad = (const float*)d_in[10];
    const float* gat_b  = (const float*)d_in[11];
    const float* Wqkv   = (const float*)d_in[12];
    const float* bqkv   = (const float*)d_in[13];
    const float* Wo     = (const float*)d_in[14];
    const float* bo     = (const float*)d_in[15];
    const float* W1     = (const float*)d_in[16];
    const float* b1     = (const float*)d_in[17];
    const float* W2     = (const float*)d_in[18];
    const float* b2     = (const float*)d_in[19];
    const float* ln1g   = (const float*)d_in[20];
    const float* ln1b   = (const float*)d_in[21];
    const float* ln2g   = (const float*)d_in[22];
    const float* ln2b   = (const float*)d_in[23];
    const float* att_P  = (const float*)d_in[24];
    const float* att_Pb = (const float*)d_in[25];
    const float* att_q  = (const float*)d_in[26];
    const float* mg_fc  = (const float*)d_in[27];
    const float* mg_al  = (const float*)d_in[28];
    const float* mg_ar  = (const float*)d_in[29];
    const float* mg_res = (const float*)d_in[30];

    float* ws  = (float*)d_ws;
    float* T1  = ws + OFF_T1;
    float* T2  = ws + OFF_T2;
    float* T3  = ws + OFF_T3;
    float* DNV = ws + OFF_DEG;
    float* EL  = ws + OFF_EL;
    float* ER  = ws + OFF_ER;
    float* W0b = ws + OFF_W0;
    float* W1b = ws + OFF_W1;
    float* FB  = ws + OFF_FB;
    float* R2  = ws + OFF_R2;
    float* RST = ws + OFF_RST;
    float* EL2 = ws + OFF_EL2;
    float* ER2 = ws + OFF_ER2;
    float* ST  = ws + OFF_ST;

    unsigned short* BIGB = (unsigned short*)(ws + OFF_BIGB);
    unsigned short* HB   = BIGB;
    unsigned short* SB   = (unsigned short*)(ws + OFF_SB);
    unsigned short* AB   = (unsigned short*)(ws + OFF_AB);
    unsigned short* WB   = (unsigned short*)(ws + OFF_WB);
    unsigned short* GWB  = (unsigned short*)(ws + OFF_GWB);
    unsigned short* PB   = (unsigned short*)(ws + OFF_PB);

    int* ib    = (int*)(ws + OFF_INT);
    int* CNT   = ib + ICNT;
    int* CNT2  = ib + ICNT2;
    int* OFFS  = ib + IOFF;
    int* OFFS2 = ib + IOFF2;
    int* CUR   = ib + ICUR;
    int* CUR2  = ib + ICUR2;
    int* CSR   = ib + ICSR;
    int* CSR2  = ib + ICSR2;

    float* outp   = (float*)d_out;
    float* a0     = outp;
    float* a1     = outp + (size_t)kSN * kH;
    float* logits = outp + 2 * (size_t)kSN * kH;
    float* gemb   = outp + 2 * (size_t)kSN * kH + (size_t)kN * kC;

    dim3 blk(256);

    // ---- 0a. zero pad-tail rows of bf16 GEMM-A buffers ----
    hipMemsetAsync(SB + (size_t)kSN * 256, 0, (size_t)(kMP - kSN) * 256 * sizeof(unsigned short), stream);
    hipMemsetAsync(AB + (size_t)kSN * 256, 0, (size_t)(kMP - kSN) * 256 * sizeof(unsigned short), stream);
    hipMemsetAsync(BIGB + (size_t)kSN * 1024, 0, (size_t)(kMP - kSN) * 1024 * sizeof(unsigned short), stream);

    // ---- 0b. CSR build ----
    hipMemsetAsync(CNT, 0, (size_t)(kV * kN + kN) * sizeof(int), stream);
    count_k<<<dim3((kV * kE + 255) / 256), blk, 0, stream>>>(e_dst, CNT, kE, kN, kV * kE);
    count_k<<<dim3((kE2 + 255) / 256), blk, 0, stream>>>(gdst, CNT2, kE2, kN, kE2);
    scan_k<<<dim3(kV), dim3(1024), 0, stream>>>(CNT, OFFS, CUR, kN);
    scan_k<<<dim3(1), dim3(1024), 0, stream>>>(CNT2, OFFS2, CUR2, kN);
    fill_csr_k<<<dim3((kV * kE + 255) / 256), blk, 0, stream>>>(e_src, e_dst, CUR, CSR, kE, kN, kV * kE);
    fill_csr_k<<<dim3((kE2 + 255) / 256), blk, 0, stream>>>(gsrc, gdst, CUR2, CSR2, kE2, kN, kE2);
    dinv_k<<<dim3((kV * kN + 255) / 256), blk, 0, stream>>>(CNT, DNV, kV * kN);

    // ---- 0c. weight/activation bf16 conversion ----
    cvt_k<<<dim3((393216 / 4 + 255) / 256), blk, 0, stream>>>(Wqkv, WB, 393216 / 4);
    cvt_k<<<dim3((131072 / 4 + 255) / 256), blk, 0, stream>>>(Wo, WB + 393216, 131072 / 4);
    cvt_k<<<dim3((524288 / 4 + 255) / 256), blk, 0, stream>>>(W1, WB + 524288, 524288 / 4);
    cvt_k<<<dim3((524288 / 4 + 255) / 256), blk, 0, stream>>>(W2, WB + 1048576, 524288 / 4);
    tcvt_k<<<dim3((3 * 65536 + 255) / 256), blk, 0, stream>>>(gcn_W, GWB, 256, 256, 3 * 65536);
    tcvt_k<<<dim3((3 * 65536 + 255) / 256), blk, 0, stream>>>(gat_W, GWB + 3 * 65536, 256, 256, 3 * 65536);
    tcvt_k<<<dim3((2 * 32768 + 255) / 256), blk, 0, stream>>>(att_P, PB, 256, 128, 2 * 32768);
    cvt_k<<<dim3((kSN * 256 / 4 + 255) / 256), blk, 0, stream>>>(x, AB, kSN * 256 / 4);

    // ---- 1. multi-view GCN + relu ----
    mgemm_k<0, false, true><<<dim3(2, 157, 3), blk, 0, stream>>>(
        AB, GWB, nullptr, nullptr, HB, kN, 256, 256, (long)kN * 256, 65536, kN);
    gcn_gather_k<<<dim3(kSN / 4), blk, 0, stream>>>(CSR, OFFS, CNT, DNV, HB, gcn_b, T1, SB);

    // ---- 2. encoder 0 -> a0 ----
    run_encoder(T1, SB, a0, AB, ws, 0, bqkv, bo, b1, b2, ln1g, ln1b, ln2g, ln2b, stream);

    // ---- 3. multi-view GAT + relu ----
    mgemm_k<0, false, true><<<dim3(2, 157, 3), blk, 0, stream>>>(
        AB, GWB + 3 * 65536, nullptr, nullptr, HB, kN, 256, 256, (long)kN * 256, 65536, kN);
    rowdot2b_k<<<dim3(kSN), dim3(64), 0, stream>>>(HB, gat_as, gat_ad, EL, ER, kSN, 256, kN, kH);
    gat_gather_k<<<dim3(kSN / 4), blk, 0, stream>>>(CSR, OFFS, CNT, EL, ER, HB, gat_b, T1, SB);

    // ---- 4. encoder 1 -> a1 ----
    run_encoder(T1, SB, a1, AB, ws, 1, bqkv + 768, bo + 256, b1 + 1024, b2 + 256,
                ln1g + 256, ln1b + 256, ln2g + 256, ln2b + 256, stream);

    // ---- 5. view attention + blend -> gemb ----
    mgemm_k<2, true, false><<<dim3(1, 469, 1), blk, 0, stream>>>(
        AB, PB, att_Pb, T2, nullptr, kSN, 128, 256, 0, 0, 0);
    rowdot2_k<<<dim3(kSN), dim3(64), 0, stream>>>(T2, att_q, (const float*)nullptr, W0b, (float*)nullptr, kSN, 128, kSN, 0);
    mgemm_k<1, true, false><<<dim3(1, 469, 1), blk, 0, stream>>>(
        AB, PB + 32768, att_Pb + 128, T3, nullptr, kSN, 128, 256, 0, 0, 0);
    rowdot2_k<<<dim3(kSN), dim3(64), 0, stream>>>(T3, att_q + 128, (const float*)nullptr, W1b, (float*)nullptr, kSN, 128, kSN, 0);
    float* X1 = T2;
    float* X2 = T2 + (size_t)kN * kH;
    view_comb_k<<<dim3((kN * 64 + 255) / 256), blk, 0, stream>>>(a1, W0b, W1b, X1, X2);
    randsm_k<<<dim3(1), dim3(1024), 0, stream>>>(rand_w, ST);
    blend_k<<<dim3((kN * 64 + 255) / 256), blk, 0, stream>>>(X1, X2, rand_w, ST, gemb);

    // ---- 6. myGATConv -> logits ----
    gemm_k<0><<<dim3(1, (kN + 63) / 64), blk, 0, stream>>>(gemb, mg_fc, (const float*)nullptr, FB, kN, kC, 256);
    rowdot2_k<<<dim3(kN), dim3(64), 0, stream>>>(FB, mg_al, mg_ar, EL2, ER2, kN, kC, kN, 0);
    mygat_gather_k<<<dim3((kN + 7) / 8), blk, 0, stream>>>(CSR2, OFFS2, CNT2, EL2, ER2, FB, RST);
    gemm_k<0><<<dim3(1, (kN + 63) / 64), blk, 0, stream>>>(gemb, mg_res, (const float*)nullptr, R2, kN, kC, 256);
    final_k<<<dim3((kN + 255) / 256), blk, 0, stream>>>(RST, R2, logits);
}

// Round 8
// 1329.970 us; speedup vs baseline: 1.1315x; 1.0743x over previous
//
#include <hip/hip_runtime.h>
#include <hip/hip_bf16.h>
#include <math.h>

// ---------------- problem constants ----------------
namespace {
constexpr int kV  = 3;
constexpr int kN  = 20000;
constexpr int kF  = 256;
constexpr int kH  = 256;
constexpr int kE  = 160000;
constexpr int kC  = 32;
constexpr int kNH = 8;
constexpr int kSN = kV * kN;     // 60000
constexpr int kE2 = kE + kN;     // 180000
constexpr int kMP = 60160;       // padded rows for bf16 GEMM-A buffers

// fp32 workspace layout (float element offsets)
constexpr size_t OFF_T1   = 0;
constexpr size_t OFF_T2   = OFF_T1 + (size_t)kMP * 256;
constexpr size_t OFF_T3   = OFF_T2 + (size_t)kMP * 256;
constexpr size_t OFF_BIGB = OFF_T3 + (size_t)kMP * 256;          // bf16 [kMP*1024]
constexpr size_t OFF_SB   = OFF_BIGB + (size_t)kMP * 512;        // bf16 [kMP*256]
constexpr size_t OFF_AB   = OFF_SB + (size_t)kMP * 128;          // bf16 [kMP*256]
constexpr size_t OFF_WB   = OFF_AB + (size_t)kMP * 128;          // bf16 enc weights
constexpr size_t OFF_GWB  = OFF_WB + 786432;
constexpr size_t OFF_PB   = OFF_GWB + 196608;
constexpr size_t OFF_DEG  = OFF_PB + 32768;
constexpr size_t OFF_EL   = OFF_DEG + (size_t)kV * kN;
constexpr size_t OFF_ER   = OFF_EL  + (size_t)kV * kN;
constexpr size_t OFF_W0   = OFF_ER  + (size_t)kV * kN;
constexpr size_t OFF_W1   = OFF_W0  + (size_t)kV * kN;
constexpr size_t OFF_FB   = OFF_W1  + (size_t)kV * kN;
constexpr size_t OFF_R2   = OFF_FB  + (size_t)kN * kC;
constexpr size_t OFF_RST  = OFF_R2  + (size_t)kN * kC;
constexpr size_t OFF_EL2  = OFF_RST + (size_t)kN * kC;
constexpr size_t OFF_ER2  = OFF_EL2 + kN;
constexpr size_t OFF_ST   = OFF_ER2 + kN;
constexpr size_t OFF_INT  = OFF_ST + 4;
// int layout
constexpr size_t ICNT  = 0;
constexpr size_t ICNT2 = ICNT  + (size_t)kV * kN;
constexpr size_t IOFF  = ICNT2 + kN;
constexpr size_t IOFF2 = IOFF  + (size_t)kV * kN;
constexpr size_t ICUR  = IOFF2 + kN;
constexpr size_t ICUR2 = ICUR  + (size_t)kV * kN;
constexpr size_t ICSR  = ICUR2 + kN;
constexpr size_t ICSR2 = ICSR  + (size_t)kV * kE;
} // namespace

typedef __attribute__((ext_vector_type(4))) float f32x4;
typedef __attribute__((ext_vector_type(8))) __bf16 bf16x8;

__device__ __forceinline__ float lrelu(float x) { return x > 0.f ? x : 0.2f * x; }
__device__ __forceinline__ unsigned short f2b(float f) {
    unsigned u = __float_as_uint(f);
    return (unsigned short)((u + 0x7FFFu + ((u >> 16) & 1u)) >> 16);
}
__device__ __forceinline__ float b2f(unsigned short h) {
    return __uint_as_float((unsigned)h << 16);
}
// tanh via HW exp: tanh(x) = (e^{2x}-1)/(e^{2x}+1), clamped
__device__ __forceinline__ float fast_tanh(float x) {
    float xc = fminf(fmaxf(x, -15.f), 15.f);
    float e = __expf(2.0f * xc);
    return (e - 1.0f) / (e + 1.0f);
}

// ---------------- conversion kernels ----------------

__global__ void cvt_k(const float* __restrict__ in, unsigned short* __restrict__ out, int n4) {
    int i = blockIdx.x * 256 + threadIdx.x;
    if (i >= n4) return;
    float4 v = reinterpret_cast<const float4*>(in)[i];
    ushort4 o;
    o.x = f2b(v.x); o.y = f2b(v.y); o.z = f2b(v.z); o.w = f2b(v.w);
    reinterpret_cast<ushort4*>(out)[i] = o;
}

__global__ void tcvt_k(const float* __restrict__ in, unsigned short* __restrict__ out,
                       int K, int N, int total) {
    int gid = blockIdx.x * 256 + threadIdx.x;
    if (gid >= total) return;
    int per = K * N;
    int v = gid / per, r = gid - v * per;
    int n = r / K, k = r - n * K;
    out[gid] = f2b(in[(size_t)v * per + (size_t)k * N + n]);
}

// ---------------- MFMA bf16 GEMM: double-buffered staging + coalesced epilogue ----------------
// C[M,N] = act(A[M,K] @ W[N,K]^T + bias). 128x128 tile, BK=32, 4 waves, 2-phase dbuf.
// ACT: 0 none, 1 relu, 2 tanh, 3 split (global col<128 tanh else relu).
template <int ACT, bool WF32, bool WB16>
__global__ __launch_bounds__(256) void mgemm_k(const unsigned short* __restrict__ A,
                                               const unsigned short* __restrict__ W,
                                               const float* __restrict__ bias,
                                               float* __restrict__ Cf,
                                               unsigned short* __restrict__ Cb,
                                               int M, int N, int K,
                                               long zA, long zW, long zC) {
    static_assert(WF32 != WB16, "exactly one output path");
    __shared__ __align__(16) unsigned short shbuf[16384];   // 2 x (As 8KB + Ws 8KB); epilogue reuses

    const int tid  = threadIdx.x;
    const int lane = tid & 63;

    // bijective XCD-chunked swizzle of the (x,y) tile index (m204)
    const int gx = gridDim.x;
    const int nwg = gx * gridDim.y;
    const int orig = blockIdx.y * gx + blockIdx.x;
    const int q = nwg >> 3, rr = nwg & 7;
    const int xcd = orig & 7, pos = orig >> 3;
    const int nid = (xcd < rr ? xcd * (q + 1) : rr * (q + 1) + (xcd - rr) * q) + pos;
    const int bm = (nid / gx) * 128, bn = (nid % gx) * 128;

    A += (size_t)blockIdx.z * zA;
    W += (size_t)blockIdx.z * zW;
    const size_t zrow = (size_t)blockIdx.z * zC;

    const int wv = tid >> 6;
    const int wm = (wv >> 1) * 64, wn = (wv & 1) * 64;
    const int fr = lane & 15;
    const int fk = (lane >> 4) * 8;

    const int r0 = tid >> 2, sl0 = (tid & 3) * 8;
    const int r1 = (256 + tid) >> 2, sl1 = ((256 + tid) & 3) * 8;

    f32x4 acc[4][4] = {};

    // prologue: stage tile 0 into buffer 0
    {
        unsigned short* As = shbuf;
        unsigned short* Ws = shbuf + 4096;
        __builtin_amdgcn_global_load_lds((const __attribute__((address_space(1))) void*)(A + (size_t)(bm + r0) * K + sl0),
                                         (__attribute__((address_space(3))) void*)(As + tid * 8), 16, 0, 0);
        __builtin_amdgcn_global_load_lds((const __attribute__((address_space(1))) void*)(W + (size_t)(bn + r0) * K + sl0),
                                         (__attribute__((address_space(3))) void*)(Ws + tid * 8), 16, 0, 0);
        __builtin_amdgcn_global_load_lds((const __attribute__((address_space(1))) void*)(A + (size_t)(bm + r1) * K + sl1),
                                         (__attribute__((address_space(3))) void*)(As + (256 + tid) * 8), 16, 0, 0);
        __builtin_amdgcn_global_load_lds((const __attribute__((address_space(1))) void*)(W + (size_t)(bn + r1) * K + sl1),
                                         (__attribute__((address_space(3))) void*)(Ws + (256 + tid) * 8), 16, 0, 0);
    }
    __syncthreads();

    int cur = 0;
    for (int k0 = 0; k0 < K; k0 += 32) {
        if (k0 + 32 < K) {
            unsigned short* As = shbuf + (cur ^ 1) * 8192;
            unsigned short* Ws = As + 4096;
            const int kn = k0 + 32;
            __builtin_amdgcn_global_load_lds((const __attribute__((address_space(1))) void*)(A + (size_t)(bm + r0) * K + kn + sl0),
                                             (__attribute__((address_space(3))) void*)(As + tid * 8), 16, 0, 0);
            __builtin_amdgcn_global_load_lds((const __attribute__((address_space(1))) void*)(W + (size_t)(bn + r0) * K + kn + sl0),
                                             (__attribute__((address_space(3))) void*)(Ws + tid * 8), 16, 0, 0);
            __builtin_amdgcn_global_load_lds((const __attribute__((address_space(1))) void*)(A + (size_t)(bm + r1) * K + kn + sl1),
                                             (__attribute__((address_space(3))) void*)(As + (256 + tid) * 8), 16, 0, 0);
            __builtin_amdgcn_global_load_lds((const __attribute__((address_space(1))) void*)(W + (size_t)(bn + r1) * K + kn + sl1),
                                             (__attribute__((address_space(3))) void*)(Ws + (256 + tid) * 8), 16, 0, 0);
        }
        const unsigned short* As = shbuf + cur * 8192;
        const unsigned short* Ws = As + 4096;
        bf16x8 av[4], bv[4];
#pragma unroll
        for (int mi = 0; mi < 4; ++mi)
            av[mi] = *reinterpret_cast<const bf16x8*>(As + (wm + mi * 16 + fr) * 32 + fk);
#pragma unroll
        for (int ni = 0; ni < 4; ++ni)
            bv[ni] = *reinterpret_cast<const bf16x8*>(Ws + (wn + ni * 16 + fr) * 32 + fk);
#pragma unroll
        for (int mi = 0; mi < 4; ++mi)
#pragma unroll
            for (int ni = 0; ni < 4; ++ni)
                acc[mi][ni] = __builtin_amdgcn_mfma_f32_16x16x32_bf16(av[mi], bv[ni], acc[mi][ni], 0, 0, 0);
        __syncthreads();
        cur ^= 1;
    }

    const int crow = (lane >> 4) * 4;
    const int ccol = lane & 15;

    if (WB16) {
#pragma unroll
        for (int mi = 0; mi < 4; ++mi)
#pragma unroll
            for (int r = 0; r < 4; ++r) {
                const int row = wm + mi * 16 + crow + r;
#pragma unroll
                for (int ni = 0; ni < 4; ++ni) {
                    const int col = wn + ni * 16 + ccol;
                    float v = acc[mi][ni][r];
                    if (bias) v += bias[bn + col];
                    if (ACT == 1) v = fmaxf(v, 0.f);
                    if (ACT == 2) v = fast_tanh(v);
                    if (ACT == 3) v = (bn + col < 128) ? fast_tanh(v) : fmaxf(v, 0.f);
                    shbuf[row * 128 + col] = f2b(v);
                }
            }
        __syncthreads();
#pragma unroll
        for (int it = 0; it < 8; ++it) {
            const int fl = it * 2048 + tid * 8;
            const int row = fl >> 7, col = fl & 127;
            const int grow = bm + row;
            if (grow < M) {
                uint4 d = *reinterpret_cast<const uint4*>(shbuf + row * 128 + col);
                *reinterpret_cast<uint4*>(Cb + (zrow + grow) * (size_t)N + bn + col) = d;
            }
        }
    } else {
        float* epf = reinterpret_cast<float*>(shbuf);
#pragma unroll
        for (int half = 0; half < 2; ++half) {
            if ((wm >> 6) == half) {
#pragma unroll
                for (int mi = 0; mi < 4; ++mi)
#pragma unroll
                    for (int r = 0; r < 4; ++r) {
                        const int row = mi * 16 + crow + r;
#pragma unroll
                        for (int ni = 0; ni < 4; ++ni) {
                            const int col = wn + ni * 16 + ccol;
                            float v = acc[mi][ni][r];
                            if (bias) v += bias[bn + col];
                            if (ACT == 1) v = fmaxf(v, 0.f);
                            if (ACT == 2) v = fast_tanh(v);
                            if (ACT == 3) v = (bn + col < 128) ? fast_tanh(v) : fmaxf(v, 0.f);
                            epf[row * 128 + col] = v;
                        }
                    }
            }
            __syncthreads();
#pragma unroll
            for (int it = 0; it < 8; ++it) {
                const int fl = it * 1024 + tid * 4;
                const int row = fl >> 7, col = fl & 127;
                const int grow = bm + half * 64 + row;
                if (grow < M) {
                    float4 d = *reinterpret_cast<const float4*>(epf + row * 128 + col);
                    *reinterpret_cast<float4*>(Cf + (zrow + grow) * (size_t)N + bn + col) = d;
                }
            }
            __syncthreads();
        }
    }
}

// ---------------- fp32 GEMM (N=32 tail) ----------------
template <int ACT>
__global__ __launch_bounds__(256) void gemm_k(const float* __restrict__ A,
                                              const float* __restrict__ B,
                                              const float* __restrict__ bias,
                                              float* __restrict__ Cmat,
                                              int M, int Nn, int K) {
    __shared__ float As[16][64];
    __shared__ float Bs[16][68];
    const int tid  = threadIdx.x;
    const int bm   = blockIdx.y * 64;
    const int bn   = blockIdx.x * 64;
    const int tx   = tid & 15, ty = tid >> 4;
    const int arow = tid >> 2;
    const int acol = (tid & 3) << 2;
    const int brow = tid >> 4;
    const int bcol = (tid & 15) << 2;
    const int gm   = bm + arow;
    float acc[4][4] = {{0.f,0.f,0.f,0.f},{0.f,0.f,0.f,0.f},{0.f,0.f,0.f,0.f},{0.f,0.f,0.f,0.f}};

    for (int k0 = 0; k0 < K; k0 += 16) {
        float4 av = make_float4(0.f, 0.f, 0.f, 0.f);
        if (gm < M) av = *reinterpret_cast<const float4*>(A + (size_t)gm * K + (k0 + acol));
        As[acol + 0][arow] = av.x;
        As[acol + 1][arow] = av.y;
        As[acol + 2][arow] = av.z;
        As[acol + 3][arow] = av.w;

        const int gn = bn + bcol;
        const float* Brow = B + (size_t)(k0 + brow) * Nn;
        float4 bv;
        if (gn + 3 < Nn) {
            bv = *reinterpret_cast<const float4*>(Brow + gn);
        } else {
            bv.x = (gn + 0 < Nn) ? Brow[gn + 0] : 0.f;
            bv.y = (gn + 1 < Nn) ? Brow[gn + 1] : 0.f;
            bv.z = (gn + 2 < Nn) ? Brow[gn + 2] : 0.f;
            bv.w = (gn + 3 < Nn) ? Brow[gn + 3] : 0.f;
        }
        *reinterpret_cast<float4*>(&Bs[brow][bcol]) = bv;
        __syncthreads();

#pragma unroll
        for (int k = 0; k < 16; ++k) {
            float4 a4 = *reinterpret_cast<const float4*>(&As[k][ty << 2]);
            float4 b4 = *reinterpret_cast<const float4*>(&Bs[k][tx << 2]);
            acc[0][0] += a4.x * b4.x; acc[0][1] += a4.x * b4.y; acc[0][2] += a4.x * b4.z; acc[0][3] += a4.x * b4.w;
            acc[1][0] += a4.y * b4.x; acc[1][1] += a4.y * b4.y; acc[1][2] += a4.y * b4.z; acc[1][3] += a4.y * b4.w;
            acc[2][0] += a4.z * b4.x; acc[2][1] += a4.z * b4.y; acc[2][2] += a4.z * b4.z; acc[2][3] += a4.z * b4.w;
            acc[3][0] += a4.w * b4.x; acc[3][1] += a4.w * b4.y; acc[3][2] += a4.w * b4.z; acc[3][3] += a4.w * b4.w;
        }
        __syncthreads();
    }

#pragma unroll
    for (int i = 0; i < 4; ++i) {
        int m = bm + (ty << 2) + i;
        if (m >= M) continue;
#pragma unroll
        for (int j = 0; j < 4; ++j) {
            int n = bn + (tx << 2) + j;
            if (n >= Nn) continue;
            float v = acc[i][j];
            if (bias) v += bias[n];
            if (ACT == 1) v = fmaxf(v, 0.f);
            if (ACT == 2) v = fast_tanh(v);
            Cmat[(size_t)m * Nn + n] = v;
        }
    }
}

// out = LN(x+y)*g+b; wave per row, float4 per lane, 4 rows per block (shuffle-only)
__global__ __launch_bounds__(256) void ln_add_k(const float* __restrict__ x, const float* __restrict__ y,
                                                const float* __restrict__ g, const float* __restrict__ b,
                                                float* __restrict__ out, unsigned short* __restrict__ outb,
                                                int rows) {
    int r = blockIdx.x * 4 + (threadIdx.x >> 6);
    if (r >= rows) return;
    int lane = threadIdx.x & 63;
    size_t base = (size_t)r * 256 + lane * 4;
    float4 xv = *reinterpret_cast<const float4*>(x + base);
    float4 yv = *reinterpret_cast<const float4*>(y + base);
    float4 t;
    t.x = xv.x + yv.x; t.y = xv.y + yv.y; t.z = xv.z + yv.z; t.w = xv.w + yv.w;
    float s = t.x + t.y + t.z + t.w;
#pragma unroll
    for (int off = 32; off > 0; off >>= 1) s += __shfl_xor(s, off, 64);
    float mean = s * (1.0f / 256.0f);
    float4 d;
    d.x = t.x - mean; d.y = t.y - mean; d.z = t.z - mean; d.w = t.w - mean;
    float s2 = d.x * d.x + d.y * d.y + d.z * d.z + d.w * d.w;
#pragma unroll
    for (int off = 32; off > 0; off >>= 1) s2 += __shfl_xor(s2, off, 64);
    float rs = rsqrtf(s2 * (1.0f / 256.0f) + 1e-5f);
    float4 gv = *reinterpret_cast<const float4*>(g + lane * 4);
    float4 bv = *reinterpret_cast<const float4*>(b + lane * 4);
    float4 o;
    o.x = d.x * rs * gv.x + bv.x;
    o.y = d.y * rs * gv.y + bv.y;
    o.z = d.z * rs * gv.z + bv.z;
    o.w = d.w * rs * gv.w + bv.w;
    *reinterpret_cast<float4*>(out + base) = o;
    ushort4 ob;
    ob.x = f2b(o.x); ob.y = f2b(o.y); ob.z = f2b(o.z); ob.w = f2b(o.w);
    *reinterpret_cast<ushort4*>(outb + base) = ob;
}

// per-row dual dot products, fp32 A
__global__ void rowdot2_k(const float* __restrict__ A, const float* __restrict__ v1,
                          const float* __restrict__ v2, float* __restrict__ o1,
                          float* __restrict__ o2, int rows, int K, int rowsPerVec, int vecStride) {
    int r = blockIdx.x;
    if (r >= rows) return;
    int lane = threadIdx.x;
    const float* base = A + (size_t)r * K;
    int vo = (r / rowsPerVec) * vecStride;
    float s1 = 0.f, s2 = 0.f;
    for (int c = lane; c < K; c += 64) {
        float a = base[c];
        s1 += a * v1[vo + c];
        if (v2) s2 += a * v2[vo + c];
    }
#pragma unroll
    for (int off = 32; off > 0; off >>= 1) {
        s1 += __shfl_xor(s1, off, 64);
        s2 += __shfl_xor(s2, off, 64);
    }
    if (lane == 0) { o1[r] = s1; if (o2) o2[r] = s2; }
}

// fused dual 128-dot from [rows][256]: o1 = row[0:128).q[0:128), o2 = row[128:256).q[128:256)
__global__ __launch_bounds__(256) void attdot_k(const float* __restrict__ A, const float* __restrict__ q,
                                                float* __restrict__ o1, float* __restrict__ o2, int rows) {
    int r = blockIdx.x * 4 + (threadIdx.x >> 6);
    if (r >= rows) return;
    int lane = threadIdx.x & 63;
    const float* row = A + (size_t)r * 256;
    float2 va = *reinterpret_cast<const float2*>(row + lane * 2);
    float2 vb = *reinterpret_cast<const float2*>(row + 128 + lane * 2);
    float2 qa = *reinterpret_cast<const float2*>(q + lane * 2);
    float2 qb = *reinterpret_cast<const float2*>(q + 128 + lane * 2);
    float s1 = va.x * qa.x + va.y * qa.y;
    float s2 = vb.x * qb.x + vb.y * qb.y;
#pragma unroll
    for (int off = 32; off > 0; off >>= 1) {
        s1 += __shfl_xor(s1, off, 64);
        s2 += __shfl_xor(s2, off, 64);
    }
    if (lane == 0) { o1[r] = s1; o2[r] = s2; }
}

// per-row dual dot products, bf16 A, ushort4 per lane
__global__ void rowdot2b_k(const unsigned short* __restrict__ A, const float* __restrict__ v1,
                           const float* __restrict__ v2, float* __restrict__ o1,
                           float* __restrict__ o2, int rows, int K, int rowsPerVec, int vecStride) {
    int r = blockIdx.x;
    if (r >= rows) return;
    int lane = threadIdx.x;
    const unsigned short* base = A + (size_t)r * K;
    int vo = (r / rowsPerVec) * vecStride;
    float s1 = 0.f, s2 = 0.f;
    for (int c = lane * 4; c < K; c += 256) {
        ushort4 a4 = *reinterpret_cast<const ushort4*>(base + c);
        float4 w1 = *reinterpret_cast<const float4*>(v1 + vo + c);
        float4 w2 = *reinterpret_cast<const float4*>(v2 + vo + c);
        s1 += b2f(a4.x) * w1.x + b2f(a4.y) * w1.y + b2f(a4.z) * w1.z + b2f(a4.w) * w1.w;
        s2 += b2f(a4.x) * w2.x + b2f(a4.y) * w2.y + b2f(a4.z) * w2.z + b2f(a4.w) * w2.w;
    }
#pragma unroll
    for (int off = 32; off > 0; off >>= 1) {
        s1 += __shfl_xor(s1, off, 64);
        s2 += __shfl_xor(s2, off, 64);
    }
    if (lane == 0) { o1[r] = s1; o2[r] = s2; }
}

// ---------------- CSR build ----------------

__global__ void count_k(const int* __restrict__ dst, int* __restrict__ cnt, int nE, int nN, int total) {
    int gid = blockIdx.x * 256 + threadIdx.x;
    if (gid >= total) return;
    int v = gid / nE;
    atomicAdd(&cnt[(size_t)v * nN + dst[gid]], 1);
}

__global__ __launch_bounds__(1024) void scan_k(const int* __restrict__ cnt, int* __restrict__ offs,
                                               int* __restrict__ cursor, int nN) {
    int v = blockIdx.x;
    const int* c = cnt + (size_t)v * nN;
    int* o  = offs + (size_t)v * nN;
    int* cu = cursor + (size_t)v * nN;
    int tid = threadIdx.x;
    int chunk = (nN + 1023) >> 10;
    int lo = tid * chunk;
    int hi = lo + chunk < nN ? lo + chunk : nN;
    int s = 0;
    for (int i = lo; i < hi; ++i) s += c[i];
    int lane = tid & 63, wid = tid >> 6;
    int x = s;
#pragma unroll
    for (int off = 1; off < 64; off <<= 1) {
        int y = __shfl_up(x, off, 64);
        if (lane >= off) x += y;
    }
    __shared__ int wsum[16];
    if (lane == 63) wsum[wid] = x;
    __syncthreads();
    if (tid == 0) {
        int a = 0;
        for (int w = 0; w < 16; ++w) { int t = wsum[w]; wsum[w] = a; a += t; }
    }
    __syncthreads();
    int base = x - s + wsum[wid];
    for (int i = lo; i < hi; ++i) { o[i] = base; cu[i] = base; base += c[i]; }
}

__global__ void fill_csr_k(const int* __restrict__ src, const int* __restrict__ dst,
                           int* __restrict__ cursor, int* __restrict__ csr,
                           int nE, int nN, int total) {
    int gid = blockIdx.x * 256 + threadIdx.x;
    if (gid >= total) return;
    int v = gid / nE;
    int pos = atomicAdd(&cursor[(size_t)v * nN + dst[gid]], 1);
    csr[(size_t)v * nE + pos] = src[gid];
}

__global__ void dinv_k(const int* __restrict__ cnt, float* __restrict__ dinv, int n) {
    int gid = blockIdx.x * 256 + threadIdx.x;
    if (gid < n) dinv[gid] = rsqrtf((float)cnt[gid] + 1.0f);
}

// ---------------- GCN gather: one WAVE per node, LDS-free, ushort4/lane ----------------

__global__ __launch_bounds__(256) void gcn_gather_k(const int* __restrict__ csr, const int* __restrict__ offs,
                                                    const int* __restrict__ cnt, const float* __restrict__ dinv,
                                                    const unsigned short* __restrict__ h, const float* __restrict__ b,
                                                    float* __restrict__ out, unsigned short* __restrict__ outb) {
    int nd = blockIdx.x * 4 + (threadIdx.x >> 6);
    if (nd >= kV * kN) return;
    int v  = nd / kN;
    int lane = threadIdx.x & 63;
    int c4 = lane * 4;
    const int* base = csr + (size_t)v * kE;
    int o0 = offs[nd], n = cnt[nd];
    float dd = dinv[nd];
    const float* dv = dinv + (size_t)v * kN;
    const unsigned short* hb = h + (size_t)v * kN * kH;

    ushort4 hs = *reinterpret_cast<const ushort4*>(h + (size_t)nd * kH + c4);
    float wts = dd * dd;
    float4 acc;
    acc.x = b2f(hs.x) * wts; acc.y = b2f(hs.y) * wts;
    acc.z = b2f(hs.z) * wts; acc.w = b2f(hs.w) * wts;
    int i = 0;
    for (; i + 2 <= n; i += 2) {
        int s0 = base[o0 + i], s1 = base[o0 + i + 1];
        float w0 = dv[s0] * dd, w1 = dv[s1] * dd;
        ushort4 h0 = *reinterpret_cast<const ushort4*>(hb + (size_t)s0 * kH + c4);
        ushort4 h1 = *reinterpret_cast<const ushort4*>(hb + (size_t)s1 * kH + c4);
        acc.x += b2f(h0.x) * w0 + b2f(h1.x) * w1;
        acc.y += b2f(h0.y) * w0 + b2f(h1.y) * w1;
        acc.z += b2f(h0.z) * w0 + b2f(h1.z) * w1;
        acc.w += b2f(h0.w) * w0 + b2f(h1.w) * w1;
    }
    if (i < n) {
        int s0 = base[o0 + i];
        float w0 = dv[s0] * dd;
        ushort4 h0 = *reinterpret_cast<const ushort4*>(hb + (size_t)s0 * kH + c4);
        acc.x += b2f(h0.x) * w0; acc.y += b2f(h0.y) * w0;
        acc.z += b2f(h0.z) * w0; acc.w += b2f(h0.w) * w0;
    }
    float4 bb = *reinterpret_cast<const float4*>(b + (size_t)v * kH + c4);
    float4 r;
    r.x = fmaxf(acc.x + bb.x, 0.f);
    r.y = fmaxf(acc.y + bb.y, 0.f);
    r.z = fmaxf(acc.z + bb.z, 0.f);
    r.w = fmaxf(acc.w + bb.w, 0.f);
    *reinterpret_cast<float4*>(out + (size_t)nd * kH + c4) = r;
    ushort4 ob;
    ob.x = f2b(r.x); ob.y = f2b(r.y); ob.z = f2b(r.z); ob.w = f2b(r.w);
    *reinterpret_cast<ushort4*>(outb + (size_t)nd * kH + c4) = ob;
}

// ---------------- GAT gather: one WAVE per node, LDS-free ----------------

__global__ __launch_bounds__(256) void gat_gather_k(const int* __restrict__ csr, const int* __restrict__ offs,
                                                    const int* __restrict__ cnt, const float* __restrict__ el,
                                                    const float* __restrict__ er, const unsigned short* __restrict__ h,
                                                    const float* __restrict__ b, float* __restrict__ out,
                                                    unsigned short* __restrict__ outb) {
    int nd = blockIdx.x * 4 + (threadIdx.x >> 6);
    if (nd >= kV * kN) return;
    int v  = nd / kN;
    int lane = threadIdx.x & 63;
    int c4 = lane * 4;
    const int* base = csr + (size_t)v * kE;
    int o0 = offs[nd], n = cnt[nd];
    float erd = er[nd];
    const float* elv = el + (size_t)v * kN;
    const unsigned short* hb = h + (size_t)v * kN * kH;
    float eself = lrelu(el[nd] + erd);

    float m = eself;
    for (int i = 0; i < n; ++i) m = fmaxf(m, lrelu(elv[base[o0 + i]] + erd));

    float es = __expf(eself - m);
    float z = es;
    ushort4 hs = *reinterpret_cast<const ushort4*>(h + (size_t)nd * kH + c4);
    float4 acc;
    acc.x = b2f(hs.x) * es; acc.y = b2f(hs.y) * es;
    acc.z = b2f(hs.z) * es; acc.w = b2f(hs.w) * es;
    int i = 0;
    for (; i + 2 <= n; i += 2) {
        int s0 = base[o0 + i], s1 = base[o0 + i + 1];
        float e0 = __expf(lrelu(elv[s0] + erd) - m);
        float e1 = __expf(lrelu(elv[s1] + erd) - m);
        z += e0 + e1;
        ushort4 h0 = *reinterpret_cast<const ushort4*>(hb + (size_t)s0 * kH + c4);
        ushort4 h1 = *reinterpret_cast<const ushort4*>(hb + (size_t)s1 * kH + c4);
        acc.x += b2f(h0.x) * e0 + b2f(h1.x) * e1;
        acc.y += b2f(h0.y) * e0 + b2f(h1.y) * e1;
        acc.z += b2f(h0.z) * e0 + b2f(h1.z) * e1;
        acc.w += b2f(h0.w) * e0 + b2f(h1.w) * e1;
    }
    if (i < n) {
        int s0 = base[o0 + i];
        float e0 = __expf(lrelu(elv[s0] + erd) - m);
        z += e0;
        ushort4 h0 = *reinterpret_cast<const ushort4*>(hb + (size_t)s0 * kH + c4);
        acc.x += b2f(h0.x) * e0; acc.y += b2f(h0.y) * e0;
        acc.z += b2f(h0.z) * e0; acc.w += b2f(h0.w) * e0;
    }
    float iz = 1.0f / z;
    float4 bb = *reinterpret_cast<const float4*>(b + (size_t)v * kH + c4);
    float4 r;
    r.x = fmaxf(acc.x * iz + bb.x, 0.f);
    r.y = fmaxf(acc.y * iz + bb.y, 0.f);
    r.z = fmaxf(acc.z * iz + bb.z, 0.f);
    r.w = fmaxf(acc.w * iz + bb.w, 0.f);
    *reinterpret_cast<float4*>(out + (size_t)nd * kH + c4) = r;
    ushort4 ob;
    ob.x = f2b(r.x); ob.y = f2b(r.y); ob.z = f2b(r.z); ob.w = f2b(r.w);
    *reinterpret_cast<ushort4*>(outb + (size_t)nd * kH + c4) = ob;
}

// ---------------- transformer: 3x3 attention, 8 lanes per (node,head), ushort4 ----------------

__global__ __launch_bounds__(256) void mha3_k(const unsigned short* __restrict__ qkv, unsigned short* __restrict__ o) {
    int grp = blockIdx.x * 32 + (threadIdx.x >> 3);
    int l8 = threadIdx.x & 7;
    if (grp >= kN * kNH) return;
    int b = grp / kNH, h = grp - b * kNH;
    float4 q[3], k[3], vv[3];
#pragma unroll
    for (int s = 0; s < 3; ++s) {
        size_t base = ((size_t)s * kN + b) * 768 + h * 32 + l8 * 4;
        ushort4 qu = *reinterpret_cast<const ushort4*>(qkv + base);
        ushort4 ku = *reinterpret_cast<const ushort4*>(qkv + base + 256);
        ushort4 vu = *reinterpret_cast<const ushort4*>(qkv + base + 512);
        q[s].x = b2f(qu.x); q[s].y = b2f(qu.y); q[s].z = b2f(qu.z); q[s].w = b2f(qu.w);
        k[s].x = b2f(ku.x); k[s].y = b2f(ku.y); k[s].z = b2f(ku.z); k[s].w = b2f(ku.w);
        vv[s].x = b2f(vu.x); vv[s].y = b2f(vu.y); vv[s].z = b2f(vu.z); vv[s].w = b2f(vu.w);
    }
    float sc[3][3];
#pragma unroll
    for (int s = 0; s < 3; ++s)
#pragma unroll
        for (int t = 0; t < 3; ++t) {
            float d = q[s].x * k[t].x + q[s].y * k[t].y + q[s].z * k[t].z + q[s].w * k[t].w;
            d += __shfl_xor(d, 1, 64);
            d += __shfl_xor(d, 2, 64);
            d += __shfl_xor(d, 4, 64);
            sc[s][t] = d * 0.17677669529663687f;
        }
#pragma unroll
    for (int s = 0; s < 3; ++s) {
        float m = fmaxf(sc[s][0], fmaxf(sc[s][1], sc[s][2]));
        float e0 = __expf(sc[s][0] - m), e1 = __expf(sc[s][1] - m), e2 = __expf(sc[s][2] - m);
        float iz = 1.0f / (e0 + e1 + e2);
        ushort4 ob;
        ob.x = f2b((e0 * vv[0].x + e1 * vv[1].x + e2 * vv[2].x) * iz);
        ob.y = f2b((e0 * vv[0].y + e1 * vv[1].y + e2 * vv[2].y) * iz);
        ob.z = f2b((e0 * vv[0].z + e1 * vv[1].z + e2 * vv[2].z) * iz);
        ob.w = f2b((e0 * vv[0].w + e1 * vv[1].w + e2 * vv[2].w) * iz);
        *reinterpret_cast<ushort4*>(o + ((size_t)s * kN + b) * kH + h * 32 + l8 * 4) = ob;
    }
}

// ---------------- view attention / blend ----------------

__global__ void view_comb_k(const float* __restrict__ a1, const float* __restrict__ w0,
                            const float* __restrict__ w1, float* __restrict__ x1,
                            float* __restrict__ x2) {
    int gid = blockIdx.x * 256 + threadIdx.x;
    if (gid >= kN * 64) return;
    int n = gid >> 6;
    int c4 = (gid & 63) << 2;
    float u0 = w0[n], u1 = w0[kN + n], u2 = w0[2 * kN + n];
    float m = fmaxf(u0, fmaxf(u1, u2));
    float e0 = __expf(u0 - m), e1 = __expf(u1 - m), e2 = __expf(u2 - m);
    float iz = 1.f / (e0 + e1 + e2);
    float p0 = e0 * iz, p1 = e1 * iz, p2 = e2 * iz;
    float q0 = w1[n], q1 = w1[kN + n], q2 = w1[2 * kN + n];
    float mq = fmaxf(q0, fmaxf(q1, q2));
    float f0 = __expf(q0 - mq), f1 = __expf(q1 - mq), f2 = __expf(q2 - mq);
    float izq = 1.f / (f0 + f1 + f2);
    float r0 = f0 * izq, r1 = f1 * izq, r2 = f2 * izq;
    float4 A0 = *reinterpret_cast<const float4*>(a1 + ((size_t)0 * kN + n) * 256 + c4);
    float4 A1 = *reinterpret_cast<const float4*>(a1 + ((size_t)1 * kN + n) * 256 + c4);
    float4 A2 = *reinterpret_cast<const float4*>(a1 + ((size_t)2 * kN + n) * 256 + c4);
    float4 o1, o2;
    o1.x = p0 * A0.x + p1 * A1.x + p2 * A2.x;  o2.x = r0 * A0.x + r1 * A1.x + r2 * A2.x;
    o1.y = p0 * A0.y + p1 * A1.y + p2 * A2.y;  o2.y = r0 * A0.y + r1 * A1.y + r2 * A2.y;
    o1.z = p0 * A0.z + p1 * A1.z + p2 * A2.z;  o2.z = r0 * A0.z + r1 * A1.z + r2 * A2.z;
    o1.w = p0 * A0.w + p1 * A1.w + p2 * A2.w;  o2.w = r0 * A0.w + r1 * A1.w + r2 * A2.w;
    *reinterpret_cast<float4*>(x1 + (size_t)n * 256 + c4) = o1;
    *reinterpret_cast<float4*>(x2 + (size_t)n * 256 + c4) = o2;
}

__global__ __launch_bounds__(1024) void randsm_k(const float* __restrict__ rw, float* __restrict__ stats) {
    __shared__ float sm[16];
    __shared__ float ss[16];
    int tid = threadIdx.x;
    float m = -1e30f;
    for (int i = tid; i < kN; i += 1024) m = fmaxf(m, rw[i]);
#pragma unroll
    for (int off = 32; off > 0; off >>= 1) m = fmaxf(m, __shfl_xor(m, off, 64));
    if ((tid & 63) == 0) sm[tid >> 6] = m;
    __syncthreads();
    if (tid == 0) {
        float mm = sm[0];
        for (int i = 1; i < 16; ++i) mm = fmaxf(mm, sm[i]);
        sm[0] = mm;
    }
    __syncthreads();
    float mx = sm[0];
    float s = 0.f;
    for (int i = tid; i < kN; i += 1024) s += __expf(rw[i] - mx);
#pragma unroll
    for (int off = 32; off > 0; off >>= 1) s += __shfl_xor(s, off, 64);
    if ((tid & 63) == 0) ss[tid >> 6] = s;
    __syncthreads();
    if (tid == 0) {
        float z = 0.f;
        for (int i = 0; i < 16; ++i) z += ss[i];
        stats[0] = mx;
        stats[1] = z;
    }
}

__global__ void blend_k(const float* __restrict__ x1, const float* __restrict__ x2,
                        const float* __restrict__ rw, const float* __restrict__ stats,
                        float* __restrict__ g) {
    int gid = blockIdx.x * 256 + threadIdx.x;
    if (gid >= kN * 64) return;
    int n = gid >> 6;
    int c4 = (gid & 63) << 2;
    float aw = __expf(rw[n] - stats[0]) / stats[1];
    float4 v1 = *reinterpret_cast<const float4*>(x1 + (size_t)n * 256 + c4);
    float4 v2 = *reinterpret_cast<const float4*>(x2 + (size_t)n * 256 + c4);
    float4 o;
    o.x = aw * v1.x + (1.f - aw) * v2.x;
    o.y = aw * v1.y + (1.f - aw) * v2.y;
    o.z = aw * v1.z + (1.f - aw) * v2.z;
    o.w = aw * v1.w + (1.f - aw) * v2.w;
    *reinterpret_cast<float4*>(g + (size_t)n * 256 + c4) = o;
}

// ---------------- myGAT gather ----------------

__global__ __launch_bounds__(256) void mygat_gather_k(const int* __restrict__ csr, const int* __restrict__ offs,
                                                      const int* __restrict__ cnt, const float* __restrict__ el,
                                                      const float* __restrict__ er, const float* __restrict__ f,
                                                      float* __restrict__ rst) {
    int node = blockIdx.x * 8 + (threadIdx.x >> 5);
    int c = threadIdx.x & 31;
    if (node >= kN) return;
    int o0 = offs[node], n = cnt[node];
    float erd = er[node];
    float m = -1e30f;
    for (int i = 0; i < n; ++i) {
        int s = csr[o0 + i];
        m = fmaxf(m, lrelu(el[s] + erd));
    }
    float z = 0.f, acc = 0.f;
    for (int i = 0; i < n; ++i) {
        int s = csr[o0 + i];
        float e = __expf(lrelu(el[s] + erd) - m);
        z += e;
        acc += f[(size_t)s * kC + c] * e;
    }
    rst[(size_t)node * kC + c] = acc / z;
}

__global__ void final_k(const float* __restrict__ rst, const float* __restrict__ r2,
                        float* __restrict__ logits) {
    int n = blockIdx.x * 256 + threadIdx.x;
    if (n >= kN) return;
    float vals[kC];
    float ssum = 0.f;
#pragma unroll
    for (int c = 0; c < kC; ++c) {
        vals[c] = rst[(size_t)n * kC + c] + r2[(size_t)n * kC + c];
        ssum += vals[c] * vals[c];
    }
    float inv = 1.0f / fmaxf(sqrtf(ssum), 1e-12f);
#pragma unroll
    for (int c = 0; c < kC; ++c) logits[(size_t)n * kC + c] = vals[c] * inv;
}

// ---------------- host orchestration ----------------

static void run_encoder(const float* xinF, const unsigned short* xinB, float* outp,
                        unsigned short* outB, float* ws, int e,
                        const float* bqkv, const float* bo, const float* b1, const float* b2,
                        const float* g1, const float* be1, const float* g2, const float* be2,
                        hipStream_t stream) {
    float* T2 = ws + OFF_T2;
    float* T3 = ws + OFF_T3;
    unsigned short* BIGB = (unsigned short*)(ws + OFF_BIGB);
    unsigned short* OB   = BIGB + (size_t)kMP * 768;
    unsigned short* SB   = (unsigned short*)(ws + OFF_SB);
    unsigned short* WB   = (unsigned short*)(ws + OFF_WB);
    const unsigned short* WQ = WB + (size_t)e * 196608;
    const unsigned short* WO = WB + 393216 + (size_t)e * 65536;
    const unsigned short* W1 = WB + 524288 + (size_t)e * 262144;
    const unsigned short* W2 = WB + 1048576 + (size_t)e * 262144;
    dim3 blk(256);

    mgemm_k<0, false, true><<<dim3(6, 469, 1), blk, 0, stream>>>(
        xinB, WQ, bqkv, nullptr, BIGB, kSN, 768, 256, 0, 0, 0);
    mha3_k<<<dim3((kN * kNH) / 32), blk, 0, stream>>>(BIGB, OB);
    mgemm_k<0, true, false><<<dim3(2, 469, 1), blk, 0, stream>>>(
        OB, WO, bo, T2, nullptr, kSN, 256, 256, 0, 0, 0);
    ln_add_k<<<dim3(kSN / 4), blk, 0, stream>>>(xinF, T2, g1, be1, T3, SB, kSN);
    mgemm_k<1, false, true><<<dim3(8, 469, 1), blk, 0, stream>>>(
        SB, W1, b1, nullptr, BIGB, kSN, 1024, 256, 0, 0, 0);
    mgemm_k<0, true, false><<<dim3(2, 469, 1), blk, 0, stream>>>(
        BIGB, W2, b2, T2, nullptr, kSN, 256, 1024, 0, 0, 0);
    ln_add_k<<<dim3(kSN / 4), blk, 0, stream>>>(T3, T2, g2, be2, outp, outB, kSN);
}

extern "C" void kernel_launch(void* const* d_in, const int* in_sizes, int n_in,
                              void* d_out, int out_size, void* d_ws, size_t ws_size,
                              hipStream_t stream) {
    (void)in_sizes; (void)n_in; (void)out_size; (void)ws_size;

    const float* x      = (const float*)d_in[0];
    const int*   e_src  = (const int*)d_in[1];
    const int*   e_dst  = (const int*)d_in[2];
    const int*   gsrc   = (const int*)d_in[3];
    const int*   gdst   = (const int*)d_in[4];
    const float* rand_w = (const float*)d_in[5];
    const float* gcn_W  = (const float*)d_in[6];
    const float* gcn_b  = (const float*)d_in[7];
    const float* gat_W  = (const float*)d_in[8];
    const float* gat_as = (const float*)d_in[9];
    const float* gat_ad = (const float*)d_in[10];
    const float* gat_b  = (const float*)d_in[11];
    const float* Wqkv   = (const float*)d_in[12];
    const float* bqkv   = (const float*)d_in[13];
    const float* Wo     = (const float*)d_in[14];
    const float* bo     = (const float*)d_in[15];
    const float* W1     = (const float*)d_in[16];
    const float* b1     = (const float*)d_in[17];
    const float* W2     = (const float*)d_in[18];
    const float* b2     = (const float*)d_in[19];
    const float* ln1g   = (const float*)d_in[20];
    const float* ln1b   = (const float*)d_in[21];
    const float* ln2g   = (const float*)d_in[22];
    const float* ln2b   = (const float*)d_in[23];
    const float* att_P  = (const float*)d_in[24];
    const float* att_Pb = (const float*)d_in[25];
    const float* att_q  = (const float*)d_in[26];
    const float* mg_fc  = (const float*)d_in[27];
    const float* mg_al  = (const float*)d_in[28];
    const float* mg_ar  = (const float*)d_in[29];
    const float* mg_res = (const float*)d_in[30];

    float* ws  = (float*)d_ws;
    float* T1  = ws + OFF_T1;
    float* T2  = ws + OFF_T2;
    float* T3  = ws + OFF_T3;
    float* DNV = ws + OFF_DEG;
    float* EL  = ws + OFF_EL;
    float* ER  = ws + OFF_ER;
    float* W0b = ws + OFF_W0;
    float* W1b = ws + OFF_W1;
    float* FB  = ws + OFF_FB;
    float* R2  = ws + OFF_R2;
    float* RST = ws + OFF_RST;
    float* EL2 = ws + OFF_EL2;
    float* ER2 = ws + OFF_ER2;
    float* ST  = ws + OFF_ST;

    unsigned short* BIGB = (unsigned short*)(ws + OFF_BIGB);
    unsigned short* HB   = BIGB;
    unsigned short* SB   = (unsigned short*)(ws + OFF_SB);
    unsigned short* AB   = (unsigned short*)(ws + OFF_AB);
    unsigned short* WB   = (unsigned short*)(ws + OFF_WB);
    unsigned short* GWB  = (unsigned short*)(ws + OFF_GWB);
    unsigned short* PB   = (unsigned short*)(ws + OFF_PB);

    int* ib    = (int*)(ws + OFF_INT);
    int* CNT   = ib + ICNT;
    int* CNT2  = ib + ICNT2;
    int* OFFS  = ib + IOFF;
    int* OFFS2 = ib + IOFF2;
    int* CUR   = ib + ICUR;
    int* CUR2  = ib + ICUR2;
    int* CSR   = ib + ICSR;
    int* CSR2  = ib + ICSR2;

    float* outp   = (float*)d_out;
    float* a0     = outp;
    float* a1     = outp + (size_t)kSN * kH;
    float* logits = outp + 2 * (size_t)kSN * kH;
    float* gemb   = outp + 2 * (size_t)kSN * kH + (size_t)kN * kC;

    dim3 blk(256);

    // ---- 0a. zero pad-tail rows of bf16 GEMM-A buffers ----
    hipMemsetAsync(SB + (size_t)kSN * 256, 0, (size_t)(kMP - kSN) * 256 * sizeof(unsigned short), stream);
    hipMemsetAsync(AB + (size_t)kSN * 256, 0, (size_t)(kMP - kSN) * 256 * sizeof(unsigned short), stream);
    hipMemsetAsync(BIGB + (size_t)kSN * 1024, 0, (size_t)(kMP - kSN) * 1024 * sizeof(unsigned short), stream);

    // ---- 0b. CSR build ----
    hipMemsetAsync(CNT, 0, (size_t)(kV * kN + kN) * sizeof(int), stream);
    count_k<<<dim3((kV * kE + 255) / 256), blk, 0, stream>>>(e_dst, CNT, kE, kN, kV * kE);
    count_k<<<dim3((kE2 + 255) / 256), blk, 0, stream>>>(gdst, CNT2, kE2, kN, kE2);
    scan_k<<<dim3(kV), dim3(1024), 0, stream>>>(CNT, OFFS, CUR, kN);
    scan_k<<<dim3(1), dim3(1024), 0, stream>>>(CNT2, OFFS2, CUR2, kN);
    fill_csr_k<<<dim3((kV * kE + 255) / 256), blk, 0, stream>>>(e_src, e_dst, CUR, CSR, kE, kN, kV * kE);
    fill_csr_k<<<dim3((kE2 + 255) / 256), blk, 0, stream>>>(gsrc, gdst, CUR2, CSR2, kE2, kN, kE2);
    dinv_k<<<dim3((kV * kN + 255) / 256), blk, 0, stream>>>(CNT, DNV, kV * kN);

    // ---- 0c. weight/activation bf16 conversion ----
    cvt_k<<<dim3((393216 / 4 + 255) / 256), blk, 0, stream>>>(Wqkv, WB, 393216 / 4);
    cvt_k<<<dim3((131072 / 4 + 255) / 256), blk, 0, stream>>>(Wo, WB + 393216, 131072 / 4);
    cvt_k<<<dim3((524288 / 4 + 255) / 256), blk, 0, stream>>>(W1, WB + 524288, 524288 / 4);
    cvt_k<<<dim3((524288 / 4 + 255) / 256), blk, 0, stream>>>(W2, WB + 1048576, 524288 / 4);
    tcvt_k<<<dim3((3 * 65536 + 255) / 256), blk, 0, stream>>>(gcn_W, GWB, 256, 256, 3 * 65536);
    tcvt_k<<<dim3((3 * 65536 + 255) / 256), blk, 0, stream>>>(gat_W, GWB + 3 * 65536, 256, 256, 3 * 65536);
    tcvt_k<<<dim3((2 * 32768 + 255) / 256), blk, 0, stream>>>(att_P, PB, 256, 128, 2 * 32768);
    cvt_k<<<dim3((kSN * 256 / 4 + 255) / 256), blk, 0, stream>>>(x, AB, kSN * 256 / 4);

    // ---- 1. multi-view GCN + relu ----
    mgemm_k<0, false, true><<<dim3(2, 157, 3), blk, 0, stream>>>(
        AB, GWB, nullptr, nullptr, HB, kN, 256, 256, (long)kN * 256, 65536, kN);
    gcn_gather_k<<<dim3(kSN / 4), blk, 0, stream>>>(CSR, OFFS, CNT, DNV, HB, gcn_b, T1, SB);

    // ---- 2. encoder 0 -> a0 ----
    run_encoder(T1, SB, a0, AB, ws, 0, bqkv, bo, b1, b2, ln1g, ln1b, ln2g, ln2b, stream);

    // ---- 3. multi-view GAT + relu ----
    mgemm_k<0, false, true><<<dim3(2, 157, 3), blk, 0, stream>>>(
        AB, GWB + 3 * 65536, nullptr, nullptr, HB, kN, 256, 256, (long)kN * 256, 65536, kN);
    rowdot2b_k<<<dim3(kSN), dim3(64), 0, stream>>>(HB, gat_as, gat_ad, EL, ER, kSN, 256, kN, kH);
    gat_gather_k<<<dim3(kSN / 4), blk, 0, stream>>>(CSR, OFFS, CNT, EL, ER, HB, gat_b, T1, SB);

    // ---- 4. encoder 1 -> a1 ----
    run_encoder(T1, SB, a1, AB, ws, 1, bqkv + 768, bo + 256, b1 + 1024, b2 + 256,
                ln1g + 256, ln1b + 256, ln2g + 256, ln2b + 256, stream);

    // ---- 5. view attention + blend -> gemb ----
    // fused: [60000][256] = a1 @ [att_P0 | att_P1], cols 0..127 tanh, 128..255 relu
    mgemm_k<3, true, false><<<dim3(2, 469, 1), blk, 0, stream>>>(
        AB, PB, att_Pb, T2, nullptr, kSN, 256, 256, 0, 0, 0);
    attdot_k<<<dim3(kSN / 4), blk, 0, stream>>>(T2, att_q, W0b, W1b, kSN);
    float* X1 = T3;
    float* X2 = T3 + (size_t)kN * kH;
    view_comb_k<<<dim3((kN * 64 + 255) / 256), blk, 0, stream>>>(a1, W0b, W1b, X1, X2);
    randsm_k<<<dim3(1), dim3(1024), 0, stream>>>(rand_w, ST);
    blend_k<<<dim3((kN * 64 + 255) / 256), blk, 0, stream>>>(X1, X2, rand_w, ST, gemb);

    // ---- 6. myGATConv -> logits ----
    gemm_k<0><<<dim3(1, (kN + 63) / 64), blk, 0, stream>>>(gemb, mg_fc, (const float*)nullptr, FB, kN, kC, 256);
    rowdot2_k<<<dim3(kN), dim3(64), 0, stream>>>(FB, mg_al, mg_ar, EL2, ER2, kN, kC, kN, 0);
    mygat_gather_k<<<dim3((kN + 7) / 8), blk, 0, stream>>>(CSR2, OFFS2, CNT2, EL2, ER2, FB, RST);
    gemm_k<0><<<dim3(1, (kN + 63) / 64), blk, 0, stream>>>(gemb, mg_res, (const float*)nullptr, R2, kN, kC, 256);
    final_k<<<dim3((kN + 255) / 256), blk, 0, stream>>>(RST, R2, logits);
}

// Round 9
// 1157.399 us; speedup vs baseline: 1.3002x; 1.1491x over previous
//
#include <hip/hip_runtime.h>
#include <hip/hip_bf16.h>
#include <math.h>

// ---------------- problem constants ----------------
namespace {
constexpr int kV  = 3;
constexpr int kN  = 20000;
constexpr int kF  = 256;
constexpr int kH  = 256;
constexpr int kE  = 160000;
constexpr int kC  = 32;
constexpr int kNH = 8;
constexpr int kSN = kV * kN;     // 60000
constexpr int kE2 = kE + kN;     // 180000
constexpr int kMP = 60160;       // padded rows for bf16 GEMM-A buffers

// fp32 workspace layout (float element offsets)
constexpr size_t OFF_T1   = 0;
constexpr size_t OFF_T2   = OFF_T1 + (size_t)kMP * 256;          // reused as bf16 T2B
constexpr size_t OFF_T3   = OFF_T2 + (size_t)kMP * 256;
constexpr size_t OFF_BIGB = OFF_T3 + (size_t)kMP * 256;          // bf16 [kMP*1024]
constexpr size_t OFF_SB   = OFF_BIGB + (size_t)kMP * 512;        // bf16 [kMP*256]
constexpr size_t OFF_AB   = OFF_SB + (size_t)kMP * 128;          // bf16 [kMP*256]
constexpr size_t OFF_WB   = OFF_AB + (size_t)kMP * 128;          // bf16 enc weights
constexpr size_t OFF_GWB  = OFF_WB + 786432;
constexpr size_t OFF_PB   = OFF_GWB + 196608;
constexpr size_t OFF_DEG  = OFF_PB + 32768;
constexpr size_t OFF_EL   = OFF_DEG + (size_t)kV * kN;
constexpr size_t OFF_ER   = OFF_EL  + (size_t)kV * kN;
constexpr size_t OFF_W0   = OFF_ER  + (size_t)kV * kN;
constexpr size_t OFF_W1   = OFF_W0  + (size_t)kV * kN;
constexpr size_t OFF_FB   = OFF_W1  + (size_t)kV * kN;
constexpr size_t OFF_R2   = OFF_FB  + (size_t)kN * kC;
constexpr size_t OFF_RST  = OFF_R2  + (size_t)kN * kC;
constexpr size_t OFF_EL2  = OFF_RST + (size_t)kN * kC;
constexpr size_t OFF_ER2  = OFF_EL2 + kN;
constexpr size_t OFF_ST   = OFF_ER2 + kN;
constexpr size_t OFF_INT  = OFF_ST + 4;
// int layout
constexpr size_t ICNT  = 0;
constexpr size_t ICNT2 = ICNT  + (size_t)kV * kN;
constexpr size_t IOFF  = ICNT2 + kN;
constexpr size_t IOFF2 = IOFF  + (size_t)kV * kN;
constexpr size_t ICUR  = IOFF2 + kN;
constexpr size_t ICUR2 = ICUR  + (size_t)kV * kN;
constexpr size_t ICSR  = ICUR2 + kN;
constexpr size_t ICSR2 = ICSR  + (size_t)kV * kE;
} // namespace

typedef __attribute__((ext_vector_type(4))) float f32x4;
typedef __attribute__((ext_vector_type(8))) __bf16 bf16x8;

__device__ __forceinline__ float lrelu(float x) { return x > 0.f ? x : 0.2f * x; }
__device__ __forceinline__ unsigned short f2b(float f) {
    unsigned u = __float_as_uint(f);
    return (unsigned short)((u + 0x7FFFu + ((u >> 16) & 1u)) >> 16);
}
__device__ __forceinline__ float b2f(unsigned short h) {
    return __uint_as_float((unsigned)h << 16);
}
// tanh via HW exp: tanh(x) = (e^{2x}-1)/(e^{2x}+1), clamped
__device__ __forceinline__ float fast_tanh(float x) {
    float xc = fminf(fmaxf(x, -15.f), 15.f);
    float e = __expf(2.0f * xc);
    return (e - 1.0f) / (e + 1.0f);
}

// ---------------- conversion kernels ----------------

__global__ void cvt_k(const float* __restrict__ in, unsigned short* __restrict__ out, int n4) {
    int i = blockIdx.x * 256 + threadIdx.x;
    if (i >= n4) return;
    float4 v = reinterpret_cast<const float4*>(in)[i];
    ushort4 o;
    o.x = f2b(v.x); o.y = f2b(v.y); o.z = f2b(v.z); o.w = f2b(v.w);
    reinterpret_cast<ushort4*>(out)[i] = o;
}

__global__ void tcvt_k(const float* __restrict__ in, unsigned short* __restrict__ out,
                       int K, int N, int total) {
    int gid = blockIdx.x * 256 + threadIdx.x;
    if (gid >= total) return;
    int per = K * N;
    int v = gid / per, r = gid - v * per;
    int n = r / K, k = r - n * K;
    out[gid] = f2b(in[(size_t)v * per + (size_t)k * N + n]);
}

// ---------------- MFMA bf16 GEMM: double-buffered staging + coalesced epilogue ----------------
// C[M,N] = act(A[M,K] @ W[N,K]^T + bias). 128x128 tile, BK=32, 4 waves, 2-phase dbuf.
// ACT: 0 none, 1 relu, 2 tanh, 3 split (global col<128 tanh else relu).
template <int ACT, bool WF32, bool WB16>
__global__ __launch_bounds__(256) void mgemm_k(const unsigned short* __restrict__ A,
                                               const unsigned short* __restrict__ W,
                                               const float* __restrict__ bias,
                                               float* __restrict__ Cf,
                                               unsigned short* __restrict__ Cb,
                                               int M, int N, int K,
                                               long zA, long zW, long zC) {
    static_assert(WF32 != WB16, "exactly one output path");
    __shared__ __align__(16) unsigned short shbuf[16384];   // 2 x (As 8KB + Ws 8KB); epilogue reuses

    const int tid  = threadIdx.x;
    const int lane = tid & 63;

    // bijective XCD-chunked swizzle of the (x,y) tile index (m204)
    const int gx = gridDim.x;
    const int nwg = gx * gridDim.y;
    const int orig = blockIdx.y * gx + blockIdx.x;
    const int q = nwg >> 3, rr = nwg & 7;
    const int xcd = orig & 7, pos = orig >> 3;
    const int nid = (xcd < rr ? xcd * (q + 1) : rr * (q + 1) + (xcd - rr) * q) + pos;
    const int bm = (nid / gx) * 128, bn = (nid % gx) * 128;

    A += (size_t)blockIdx.z * zA;
    W += (size_t)blockIdx.z * zW;
    const size_t zrow = (size_t)blockIdx.z * zC;

    const int wv = tid >> 6;
    const int wm = (wv >> 1) * 64, wn = (wv & 1) * 64;
    const int fr = lane & 15;
    const int fk = (lane >> 4) * 8;

    const int r0 = tid >> 2, sl0 = (tid & 3) * 8;
    const int r1 = (256 + tid) >> 2, sl1 = ((256 + tid) & 3) * 8;

    f32x4 acc[4][4] = {};

    // prologue: stage tile 0 into buffer 0
    {
        unsigned short* As = shbuf;
        unsigned short* Ws = shbuf + 4096;
        __builtin_amdgcn_global_load_lds((const __attribute__((address_space(1))) void*)(A + (size_t)(bm + r0) * K + sl0),
                                         (__attribute__((address_space(3))) void*)(As + tid * 8), 16, 0, 0);
        __builtin_amdgcn_global_load_lds((const __attribute__((address_space(1))) void*)(W + (size_t)(bn + r0) * K + sl0),
                                         (__attribute__((address_space(3))) void*)(Ws + tid * 8), 16, 0, 0);
        __builtin_amdgcn_global_load_lds((const __attribute__((address_space(1))) void*)(A + (size_t)(bm + r1) * K + sl1),
                                         (__attribute__((address_space(3))) void*)(As + (256 + tid) * 8), 16, 0, 0);
        __builtin_amdgcn_global_load_lds((const __attribute__((address_space(1))) void*)(W + (size_t)(bn + r1) * K + sl1),
                                         (__attribute__((address_space(3))) void*)(Ws + (256 + tid) * 8), 16, 0, 0);
    }
    __syncthreads();

    int cur = 0;
    for (int k0 = 0; k0 < K; k0 += 32) {
        if (k0 + 32 < K) {
            unsigned short* As = shbuf + (cur ^ 1) * 8192;
            unsigned short* Ws = As + 4096;
            const int kn = k0 + 32;
            __builtin_amdgcn_global_load_lds((const __attribute__((address_space(1))) void*)(A + (size_t)(bm + r0) * K + kn + sl0),
                                             (__attribute__((address_space(3))) void*)(As + tid * 8), 16, 0, 0);
            __builtin_amdgcn_global_load_lds((const __attribute__((address_space(1))) void*)(W + (size_t)(bn + r0) * K + kn + sl0),
                                             (__attribute__((address_space(3))) void*)(Ws + tid * 8), 16, 0, 0);
            __builtin_amdgcn_global_load_lds((const __attribute__((address_space(1))) void*)(A + (size_t)(bm + r1) * K + kn + sl1),
                                             (__attribute__((address_space(3))) void*)(As + (256 + tid) * 8), 16, 0, 0);
            __builtin_amdgcn_global_load_lds((const __attribute__((address_space(1))) void*)(W + (size_t)(bn + r1) * K + kn + sl1),
                                             (__attribute__((address_space(3))) void*)(Ws + (256 + tid) * 8), 16, 0, 0);
        }
        const unsigned short* As = shbuf + cur * 8192;
        const unsigned short* Ws = As + 4096;
        bf16x8 av[4], bv[4];
#pragma unroll
        for (int mi = 0; mi < 4; ++mi)
            av[mi] = *reinterpret_cast<const bf16x8*>(As + (wm + mi * 16 + fr) * 32 + fk);
#pragma unroll
        for (int ni = 0; ni < 4; ++ni)
            bv[ni] = *reinterpret_cast<const bf16x8*>(Ws + (wn + ni * 16 + fr) * 32 + fk);
#pragma unroll
        for (int mi = 0; mi < 4; ++mi)
#pragma unroll
            for (int ni = 0; ni < 4; ++ni)
                acc[mi][ni] = __builtin_amdgcn_mfma_f32_16x16x32_bf16(av[mi], bv[ni], acc[mi][ni], 0, 0, 0);
        __syncthreads();
        cur ^= 1;
    }

    const int crow = (lane >> 4) * 4;
    const int ccol = lane & 15;

    if (WB16) {
#pragma unroll
        for (int mi = 0; mi < 4; ++mi)
#pragma unroll
            for (int r = 0; r < 4; ++r) {
                const int row = wm + mi * 16 + crow + r;
#pragma unroll
                for (int ni = 0; ni < 4; ++ni) {
                    const int col = wn + ni * 16 + ccol;
                    float v = acc[mi][ni][r];
                    if (bias) v += bias[bn + col];
                    if (ACT == 1) v = fmaxf(v, 0.f);
                    if (ACT == 2) v = fast_tanh(v);
                    if (ACT == 3) v = (bn + col < 128) ? fast_tanh(v) : fmaxf(v, 0.f);
                    shbuf[row * 128 + col] = f2b(v);
                }
            }
        __syncthreads();
#pragma unroll
        for (int it = 0; it < 8; ++it) {
            const int fl = it * 2048 + tid * 8;
            const int row = fl >> 7, col = fl & 127;
            const int grow = bm + row;
            if (grow < M) {
                uint4 d = *reinterpret_cast<const uint4*>(shbuf + row * 128 + col);
                *reinterpret_cast<uint4*>(Cb + (zrow + grow) * (size_t)N + bn + col) = d;
            }
        }
    } else {
        float* epf = reinterpret_cast<float*>(shbuf);
#pragma unroll
        for (int half = 0; half < 2; ++half) {
            if ((wm >> 6) == half) {
#pragma unroll
                for (int mi = 0; mi < 4; ++mi)
#pragma unroll
                    for (int r = 0; r < 4; ++r) {
                        const int row = mi * 16 + crow + r;
#pragma unroll
                        for (int ni = 0; ni < 4; ++ni) {
                            const int col = wn + ni * 16 + ccol;
                            float v = acc[mi][ni][r];
                            if (bias) v += bias[bn + col];
                            if (ACT == 1) v = fmaxf(v, 0.f);
                            if (ACT == 2) v = fast_tanh(v);
                            if (ACT == 3) v = (bn + col < 128) ? fast_tanh(v) : fmaxf(v, 0.f);
                            epf[row * 128 + col] = v;
                        }
                    }
            }
            __syncthreads();
#pragma unroll
            for (int it = 0; it < 8; ++it) {
                const int fl = it * 1024 + tid * 4;
                const int row = fl >> 7, col = fl & 127;
                const int grow = bm + half * 64 + row;
                if (grow < M) {
                    float4 d = *reinterpret_cast<const float4*>(epf + row * 128 + col);
                    *reinterpret_cast<float4*>(Cf + (zrow + grow) * (size_t)N + bn + col) = d;
                }
            }
            __syncthreads();
        }
    }
}

// ---------------- fp32 GEMM (N=32 tail) ----------------
template <int ACT>
__global__ __launch_bounds__(256) void gemm_k(const float* __restrict__ A,
                                              const float* __restrict__ B,
                                              const float* __restrict__ bias,
                                              float* __restrict__ Cmat,
                                              int M, int Nn, int K) {
    __shared__ float As[16][64];
    __shared__ float Bs[16][68];
    const int tid  = threadIdx.x;
    const int bm   = blockIdx.y * 64;
    const int bn   = blockIdx.x * 64;
    const int tx   = tid & 15, ty = tid >> 4;
    const int arow = tid >> 2;
    const int acol = (tid & 3) << 2;
    const int brow = tid >> 4;
    const int bcol = (tid & 15) << 2;
    const int gm   = bm + arow;
    float acc[4][4] = {{0.f,0.f,0.f,0.f},{0.f,0.f,0.f,0.f},{0.f,0.f,0.f,0.f},{0.f,0.f,0.f,0.f}};

    for (int k0 = 0; k0 < K; k0 += 16) {
        float4 av = make_float4(0.f, 0.f, 0.f, 0.f);
        if (gm < M) av = *reinterpret_cast<const float4*>(A + (size_t)gm * K + (k0 + acol));
        As[acol + 0][arow] = av.x;
        As[acol + 1][arow] = av.y;
        As[acol + 2][arow] = av.z;
        As[acol + 3][arow] = av.w;

        const int gn = bn + bcol;
        const float* Brow = B + (size_t)(k0 + brow) * Nn;
        float4 bv;
        if (gn + 3 < Nn) {
            bv = *reinterpret_cast<const float4*>(Brow + gn);
        } else {
            bv.x = (gn + 0 < Nn) ? Brow[gn + 0] : 0.f;
            bv.y = (gn + 1 < Nn) ? Brow[gn + 1] : 0.f;
            bv.z = (gn + 2 < Nn) ? Brow[gn + 2] : 0.f;
            bv.w = (gn + 3 < Nn) ? Brow[gn + 3] : 0.f;
        }
        *reinterpret_cast<float4*>(&Bs[brow][bcol]) = bv;
        __syncthreads();

#pragma unroll
        for (int k = 0; k < 16; ++k) {
            float4 a4 = *reinterpret_cast<const float4*>(&As[k][ty << 2]);
            float4 b4 = *reinterpret_cast<const float4*>(&Bs[k][tx << 2]);
            acc[0][0] += a4.x * b4.x; acc[0][1] += a4.x * b4.y; acc[0][2] += a4.x * b4.z; acc[0][3] += a4.x * b4.w;
            acc[1][0] += a4.y * b4.x; acc[1][1] += a4.y * b4.y; acc[1][2] += a4.y * b4.z; acc[1][3] += a4.y * b4.w;
            acc[2][0] += a4.z * b4.x; acc[2][1] += a4.z * b4.y; acc[2][2] += a4.z * b4.z; acc[2][3] += a4.z * b4.w;
            acc[3][0] += a4.w * b4.x; acc[3][1] += a4.w * b4.y; acc[3][2] += a4.w * b4.z; acc[3][3] += a4.w * b4.w;
        }
        __syncthreads();
    }

#pragma unroll
    for (int i = 0; i < 4; ++i) {
        int m = bm + (ty << 2) + i;
        if (m >= M) continue;
#pragma unroll
        for (int j = 0; j < 4; ++j) {
            int n = bn + (tx << 2) + j;
            if (n >= Nn) continue;
            float v = acc[i][j];
            if (bias) v += bias[n];
            if (ACT == 1) v = fmaxf(v, 0.f);
            if (ACT == 2) v = fast_tanh(v);
            Cmat[(size_t)m * Nn + n] = v;
        }
    }
}

// out = LN(x+y)*g+b; wave per row, x f32 float4/lane, y bf16 ushort4/lane; 4 rows/block
__global__ __launch_bounds__(256) void ln_add_k(const float* __restrict__ x, const unsigned short* __restrict__ y,
                                                const float* __restrict__ g, const float* __restrict__ b,
                                                float* __restrict__ out, unsigned short* __restrict__ outb,
                                                int rows) {
    int r = blockIdx.x * 4 + (threadIdx.x >> 6);
    if (r >= rows) return;
    int lane = threadIdx.x & 63;
    size_t base = (size_t)r * 256 + lane * 4;
    float4 xv = *reinterpret_cast<const float4*>(x + base);
    ushort4 yu = *reinterpret_cast<const ushort4*>(y + base);
    float4 t;
    t.x = xv.x + b2f(yu.x); t.y = xv.y + b2f(yu.y);
    t.z = xv.z + b2f(yu.z); t.w = xv.w + b2f(yu.w);
    float s = t.x + t.y + t.z + t.w;
#pragma unroll
    for (int off = 32; off > 0; off >>= 1) s += __shfl_xor(s, off, 64);
    float mean = s * (1.0f / 256.0f);
    float4 d;
    d.x = t.x - mean; d.y = t.y - mean; d.z = t.z - mean; d.w = t.w - mean;
    float s2 = d.x * d.x + d.y * d.y + d.z * d.z + d.w * d.w;
#pragma unroll
    for (int off = 32; off > 0; off >>= 1) s2 += __shfl_xor(s2, off, 64);
    float rs = rsqrtf(s2 * (1.0f / 256.0f) + 1e-5f);
    float4 gv = *reinterpret_cast<const float4*>(g + lane * 4);
    float4 bv = *reinterpret_cast<const float4*>(b + lane * 4);
    float4 o;
    o.x = d.x * rs * gv.x + bv.x;
    o.y = d.y * rs * gv.y + bv.y;
    o.z = d.z * rs * gv.z + bv.z;
    o.w = d.w * rs * gv.w + bv.w;
    *reinterpret_cast<float4*>(out + base) = o;
    ushort4 ob;
    ob.x = f2b(o.x); ob.y = f2b(o.y); ob.z = f2b(o.z); ob.w = f2b(o.w);
    *reinterpret_cast<ushort4*>(outb + base) = ob;
}

// per-row dual dot products, fp32 A
__global__ void rowdot2_k(const float* __restrict__ A, const float* __restrict__ v1,
                          const float* __restrict__ v2, float* __restrict__ o1,
                          float* __restrict__ o2, int rows, int K, int rowsPerVec, int vecStride) {
    int r = blockIdx.x;
    if (r >= rows) return;
    int lane = threadIdx.x;
    const float* base = A + (size_t)r * K;
    int vo = (r / rowsPerVec) * vecStride;
    float s1 = 0.f, s2 = 0.f;
    for (int c = lane; c < K; c += 64) {
        float a = base[c];
        s1 += a * v1[vo + c];
        if (v2) s2 += a * v2[vo + c];
    }
#pragma unroll
    for (int off = 32; off > 0; off >>= 1) {
        s1 += __shfl_xor(s1, off, 64);
        s2 += __shfl_xor(s2, off, 64);
    }
    if (lane == 0) { o1[r] = s1; if (o2) o2[r] = s2; }
}

// fused dual 128-dot from bf16 [rows][256]: o1 = row[0:128).q[0:128), o2 = row[128:256).q[128:256)
__global__ __launch_bounds__(256) void attdot_k(const unsigned short* __restrict__ A, const float* __restrict__ q,
                                                float* __restrict__ o1, float* __restrict__ o2, int rows) {
    int r = blockIdx.x * 4 + (threadIdx.x >> 6);
    if (r >= rows) return;
    int lane = threadIdx.x & 63;
    const unsigned short* row = A + (size_t)r * 256;
    ushort2 va = *reinterpret_cast<const ushort2*>(row + lane * 2);
    ushort2 vb = *reinterpret_cast<const ushort2*>(row + 128 + lane * 2);
    float2 qa = *reinterpret_cast<const float2*>(q + lane * 2);
    float2 qb = *reinterpret_cast<const float2*>(q + 128 + lane * 2);
    float s1 = b2f(va.x) * qa.x + b2f(va.y) * qa.y;
    float s2 = b2f(vb.x) * qb.x + b2f(vb.y) * qb.y;
#pragma unroll
    for (int off = 32; off > 0; off >>= 1) {
        s1 += __shfl_xor(s1, off, 64);
        s2 += __shfl_xor(s2, off, 64);
    }
    if (lane == 0) { o1[r] = s1; o2[r] = s2; }
}

// per-row dual dot products, bf16 A, ushort4 per lane
__global__ void rowdot2b_k(const unsigned short* __restrict__ A, const float* __restrict__ v1,
                           const float* __restrict__ v2, float* __restrict__ o1,
                           float* __restrict__ o2, int rows, int K, int rowsPerVec, int vecStride) {
    int r = blockIdx.x;
    if (r >= rows) return;
    int lane = threadIdx.x;
    const unsigned short* base = A + (size_t)r * K;
    int vo = (r / rowsPerVec) * vecStride;
    float s1 = 0.f, s2 = 0.f;
    for (int c = lane * 4; c < K; c += 256) {
        ushort4 a4 = *reinterpret_cast<const ushort4*>(base + c);
        float4 w1 = *reinterpret_cast<const float4*>(v1 + vo + c);
        float4 w2 = *reinterpret_cast<const float4*>(v2 + vo + c);
        s1 += b2f(a4.x) * w1.x + b2f(a4.y) * w1.y + b2f(a4.z) * w1.z + b2f(a4.w) * w1.w;
        s2 += b2f(a4.x) * w2.x + b2f(a4.y) * w2.y + b2f(a4.z) * w2.z + b2f(a4.w) * w2.w;
    }
#pragma unroll
    for (int off = 32; off > 0; off >>= 1) {
        s1 += __shfl_xor(s1, off, 64);
        s2 += __shfl_xor(s2, off, 64);
    }
    if (lane == 0) { o1[r] = s1; o2[r] = s2; }
}

// ---------------- CSR build ----------------

__global__ void count_k(const int* __restrict__ dst, int* __restrict__ cnt, int nE, int nN, int total) {
    int gid = blockIdx.x * 256 + threadIdx.x;
    if (gid >= total) return;
    int v = gid / nE;
    atomicAdd(&cnt[(size_t)v * nN + dst[gid]], 1);
}

__global__ __launch_bounds__(1024) void scan_k(const int* __restrict__ cnt, int* __restrict__ offs,
                                               int* __restrict__ cursor, int nN) {
    int v = blockIdx.x;
    const int* c = cnt + (size_t)v * nN;
    int* o  = offs + (size_t)v * nN;
    int* cu = cursor + (size_t)v * nN;
    int tid = threadIdx.x;
    int chunk = (nN + 1023) >> 10;
    int lo = tid * chunk;
    int hi = lo + chunk < nN ? lo + chunk : nN;
    int s = 0;
    for (int i = lo; i < hi; ++i) s += c[i];
    int lane = tid & 63, wid = tid >> 6;
    int x = s;
#pragma unroll
    for (int off = 1; off < 64; off <<= 1) {
        int y = __shfl_up(x, off, 64);
        if (lane >= off) x += y;
    }
    __shared__ int wsum[16];
    if (lane == 63) wsum[wid] = x;
    __syncthreads();
    if (tid == 0) {
        int a = 0;
        for (int w = 0; w < 16; ++w) { int t = wsum[w]; wsum[w] = a; a += t; }
    }
    __syncthreads();
    int base = x - s + wsum[wid];
    for (int i = lo; i < hi; ++i) { o[i] = base; cu[i] = base; base += c[i]; }
}

__global__ void fill_csr_k(const int* __restrict__ src, const int* __restrict__ dst,
                           int* __restrict__ cursor, int* __restrict__ csr,
                           int nE, int nN, int total) {
    int gid = blockIdx.x * 256 + threadIdx.x;
    if (gid >= total) return;
    int v = gid / nE;
    int pos = atomicAdd(&cursor[(size_t)v * nN + dst[gid]], 1);
    csr[(size_t)v * nE + pos] = src[gid];
}

__global__ void dinv_k(const int* __restrict__ cnt, float* __restrict__ dinv, int n) {
    int gid = blockIdx.x * 256 + threadIdx.x;
    if (gid < n) dinv[gid] = rsqrtf((float)cnt[gid] + 1.0f);
}

// ---------------- GCN gather: one WAVE per node, LDS-free, ushort4/lane ----------------

__global__ __launch_bounds__(256) void gcn_gather_k(const int* __restrict__ csr, const int* __restrict__ offs,
                                                    const int* __restrict__ cnt, const float* __restrict__ dinv,
                                                    const unsigned short* __restrict__ h, const float* __restrict__ b,
                                                    float* __restrict__ out, unsigned short* __restrict__ outb) {
    int nd = blockIdx.x * 4 + (threadIdx.x >> 6);
    if (nd >= kV * kN) return;
    int v  = nd / kN;
    int lane = threadIdx.x & 63;
    int c4 = lane * 4;
    const int* base = csr + (size_t)v * kE;
    int o0 = offs[nd], n = cnt[nd];
    float dd = dinv[nd];
    const float* dv = dinv + (size_t)v * kN;
    const unsigned short* hb = h + (size_t)v * kN * kH;

    ushort4 hs = *reinterpret_cast<const ushort4*>(h + (size_t)nd * kH + c4);
    float wts = dd * dd;
    float4 acc;
    acc.x = b2f(hs.x) * wts; acc.y = b2f(hs.y) * wts;
    acc.z = b2f(hs.z) * wts; acc.w = b2f(hs.w) * wts;
    int i = 0;
    for (; i + 2 <= n; i += 2) {
        int s0 = base[o0 + i], s1 = base[o0 + i + 1];
        float w0 = dv[s0] * dd, w1 = dv[s1] * dd;
        ushort4 h0 = *reinterpret_cast<const ushort4*>(hb + (size_t)s0 * kH + c4);
        ushort4 h1 = *reinterpret_cast<const ushort4*>(hb + (size_t)s1 * kH + c4);
        acc.x += b2f(h0.x) * w0 + b2f(h1.x) * w1;
        acc.y += b2f(h0.y) * w0 + b2f(h1.y) * w1;
        acc.z += b2f(h0.z) * w0 + b2f(h1.z) * w1;
        acc.w += b2f(h0.w) * w0 + b2f(h1.w) * w1;
    }
    if (i < n) {
        int s0 = base[o0 + i];
        float w0 = dv[s0] * dd;
        ushort4 h0 = *reinterpret_cast<const ushort4*>(hb + (size_t)s0 * kH + c4);
        acc.x += b2f(h0.x) * w0; acc.y += b2f(h0.y) * w0;
        acc.z += b2f(h0.z) * w0; acc.w += b2f(h0.w) * w0;
    }
    float4 bb = *reinterpret_cast<const float4*>(b + (size_t)v * kH + c4);
    float4 r;
    r.x = fmaxf(acc.x + bb.x, 0.f);
    r.y = fmaxf(acc.y + bb.y, 0.f);
    r.z = fmaxf(acc.z + bb.z, 0.f);
    r.w = fmaxf(acc.w + bb.w, 0.f);
    *reinterpret_cast<float4*>(out + (size_t)nd * kH + c4) = r;
    ushort4 ob;
    ob.x = f2b(r.x); ob.y = f2b(r.y); ob.z = f2b(r.z); ob.w = f2b(r.w);
    *reinterpret_cast<ushort4*>(outb + (size_t)nd * kH + c4) = ob;
}

// ---------------- GAT gather: one WAVE per node, LDS-free ----------------

__global__ __launch_bounds__(256) void gat_gather_k(const int* __restrict__ csr, const int* __restrict__ offs,
                                                    const int* __restrict__ cnt, const float* __restrict__ el,
                                                    const float* __restrict__ er, const unsigned short* __restrict__ h,
                                                    const float* __restrict__ b, float* __restrict__ out,
                                                    unsigned short* __restrict__ outb) {
    int nd = blockIdx.x * 4 + (threadIdx.x >> 6);
    if (nd >= kV * kN) return;
    int v  = nd / kN;
    int lane = threadIdx.x & 63;
    int c4 = lane * 4;
    const int* base = csr + (size_t)v * kE;
    int o0 = offs[nd], n = cnt[nd];
    float erd = er[nd];
    const float* elv = el + (size_t)v * kN;
    const unsigned short* hb = h + (size_t)v * kN * kH;
    float eself = lrelu(el[nd] + erd);

    float m = eself;
    for (int i = 0; i < n; ++i) m = fmaxf(m, lrelu(elv[base[o0 + i]] + erd));

    float es = __expf(eself - m);
    float z = es;
    ushort4 hs = *reinterpret_cast<const ushort4*>(h + (size_t)nd * kH + c4);
    float4 acc;
    acc.x = b2f(hs.x) * es; acc.y = b2f(hs.y) * es;
    acc.z = b2f(hs.z) * es; acc.w = b2f(hs.w) * es;
    int i = 0;
    for (; i + 2 <= n; i += 2) {
        int s0 = base[o0 + i], s1 = base[o0 + i + 1];
        float e0 = __expf(lrelu(elv[s0] + erd) - m);
        float e1 = __expf(lrelu(elv[s1] + erd) - m);
        z += e0 + e1;
        ushort4 h0 = *reinterpret_cast<const ushort4*>(hb + (size_t)s0 * kH + c4);
        ushort4 h1 = *reinterpret_cast<const ushort4*>(hb + (size_t)s1 * kH + c4);
        acc.x += b2f(h0.x) * e0 + b2f(h1.x) * e1;
        acc.y += b2f(h0.y) * e0 + b2f(h1.y) * e1;
        acc.z += b2f(h0.z) * e0 + b2f(h1.z) * e1;
        acc.w += b2f(h0.w) * e0 + b2f(h1.w) * e1;
    }
    if (i < n) {
        int s0 = base[o0 + i];
        float e0 = __expf(lrelu(elv[s0] + erd) - m);
        z += e0;
        ushort4 h0 = *reinterpret_cast<const ushort4*>(hb + (size_t)s0 * kH + c4);
        acc.x += b2f(h0.x) * e0; acc.y += b2f(h0.y) * e0;
        acc.z += b2f(h0.z) * e0; acc.w += b2f(h0.w) * e0;
    }
    float iz = 1.0f / z;
    float4 bb = *reinterpret_cast<const float4*>(b + (size_t)v * kH + c4);
    float4 r;
    r.x = fmaxf(acc.x * iz + bb.x, 0.f);
    r.y = fmaxf(acc.y * iz + bb.y, 0.f);
    r.z = fmaxf(acc.z * iz + bb.z, 0.f);
    r.w = fmaxf(acc.w * iz + bb.w, 0.f);
    *reinterpret_cast<float4*>(out + (size_t)nd * kH + c4) = r;
    ushort4 ob;
    ob.x = f2b(r.x); ob.y = f2b(r.y); ob.z = f2b(r.z); ob.w = f2b(r.w);
    *reinterpret_cast<ushort4*>(outb + (size_t)nd * kH + c4) = ob;
}

// ---------------- transformer: 3x3 attention, 8 lanes per (node,head), ushort4 ----------------

__global__ __launch_bounds__(256) void mha3_k(const unsigned short* __restrict__ qkv, unsigned short* __restrict__ o) {
    int grp = blockIdx.x * 32 + (threadIdx.x >> 3);
    int l8 = threadIdx.x & 7;
    if (grp >= kN * kNH) return;
    int b = grp / kNH, h = grp - b * kNH;
    float4 q[3], k[3], vv[3];
#pragma unroll
    for (int s = 0; s < 3; ++s) {
        size_t base = ((size_t)s * kN + b) * 768 + h * 32 + l8 * 4;
        ushort4 qu = *reinterpret_cast<const ushort4*>(qkv + base);
        ushort4 ku = *reinterpret_cast<const ushort4*>(qkv + base + 256);
        ushort4 vu = *reinterpret_cast<const ushort4*>(qkv + base + 512);
        q[s].x = b2f(qu.x); q[s].y = b2f(qu.y); q[s].z = b2f(qu.z); q[s].w = b2f(qu.w);
        k[s].x = b2f(ku.x); k[s].y = b2f(ku.y); k[s].z = b2f(ku.z); k[s].w = b2f(ku.w);
        vv[s].x = b2f(vu.x); vv[s].y = b2f(vu.y); vv[s].z = b2f(vu.z); vv[s].w = b2f(vu.w);
    }
    float sc[3][3];
#pragma unroll
    for (int s = 0; s < 3; ++s)
#pragma unroll
        for (int t = 0; t < 3; ++t) {
            float d = q[s].x * k[t].x + q[s].y * k[t].y + q[s].z * k[t].z + q[s].w * k[t].w;
            d += __shfl_xor(d, 1, 64);
            d += __shfl_xor(d, 2, 64);
            d += __shfl_xor(d, 4, 64);
            sc[s][t] = d * 0.17677669529663687f;
        }
#pragma unroll
    for (int s = 0; s < 3; ++s) {
        float m = fmaxf(sc[s][0], fmaxf(sc[s][1], sc[s][2]));
        float e0 = __expf(sc[s][0] - m), e1 = __expf(sc[s][1] - m), e2 = __expf(sc[s][2] - m);
        float iz = 1.0f / (e0 + e1 + e2);
        ushort4 ob;
        ob.x = f2b((e0 * vv[0].x + e1 * vv[1].x + e2 * vv[2].x) * iz);
        ob.y = f2b((e0 * vv[0].y + e1 * vv[1].y + e2 * vv[2].y) * iz);
        ob.z = f2b((e0 * vv[0].z + e1 * vv[1].z + e2 * vv[2].z) * iz);
        ob.w = f2b((e0 * vv[0].w + e1 * vv[1].w + e2 * vv[2].w) * iz);
        *reinterpret_cast<ushort4*>(o + ((size_t)s * kN + b) * kH + h * 32 + l8 * 4) = ob;
    }
}

// ---------------- view attention / blend ----------------

__global__ void view_comb_k(const float* __restrict__ a1, const float* __restrict__ w0,
                            const float* __restrict__ w1, float* __restrict__ x1,
                            float* __restrict__ x2) {
    int gid = blockIdx.x * 256 + threadIdx.x;
    if (gid >= kN * 64) return;
    int n = gid >> 6;
    int c4 = (gid & 63) << 2;
    float u0 = w0[n], u1 = w0[kN + n], u2 = w0[2 * kN + n];
    float m = fmaxf(u0, fmaxf(u1, u2));
    float e0 = __expf(u0 - m), e1 = __expf(u1 - m), e2 = __expf(u2 - m);
    float iz = 1.f / (e0 + e1 + e2);
    float p0 = e0 * iz, p1 = e1 * iz, p2 = e2 * iz;
    float q0 = w1[n], q1 = w1[kN + n], q2 = w1[2 * kN + n];
    float mq = fmaxf(q0, fmaxf(q1, q2));
    float f0 = __expf(q0 - mq), f1 = __expf(q1 - mq), f2 = __expf(q2 - mq);
    float izq = 1.f / (f0 + f1 + f2);
    float r0 = f0 * izq, r1 = f1 * izq, r2 = f2 * izq;
    float4 A0 = *reinterpret_cast<const float4*>(a1 + ((size_t)0 * kN + n) * 256 + c4);
    float4 A1 = *reinterpret_cast<const float4*>(a1 + ((size_t)1 * kN + n) * 256 + c4);
    float4 A2 = *reinterpret_cast<const float4*>(a1 + ((size_t)2 * kN + n) * 256 + c4);
    float4 o1, o2;
    o1.x = p0 * A0.x + p1 * A1.x + p2 * A2.x;  o2.x = r0 * A0.x + r1 * A1.x + r2 * A2.x;
    o1.y = p0 * A0.y + p1 * A1.y + p2 * A2.y;  o2.y = r0 * A0.y + r1 * A1.y + r2 * A2.y;
    o1.z = p0 * A0.z + p1 * A1.z + p2 * A2.z;  o2.z = r0 * A0.z + r1 * A1.z + r2 * A2.z;
    o1.w = p0 * A0.w + p1 * A1.w + p2 * A2.w;  o2.w = r0 * A0.w + r1 * A1.w + r2 * A2.w;
    *reinterpret_cast<float4*>(x1 + (size_t)n * 256 + c4) = o1;
    *reinterpret_cast<float4*>(x2 + (size_t)n * 256 + c4) = o2;
}

__global__ __launch_bounds__(1024) void randsm_k(const float* __restrict__ rw, float* __restrict__ stats) {
    __shared__ float sm[16];
    __shared__ float ss[16];
    int tid = threadIdx.x;
    float m = -1e30f;
    for (int i = tid; i < kN; i += 1024) m = fmaxf(m, rw[i]);
#pragma unroll
    for (int off = 32; off > 0; off >>= 1) m = fmaxf(m, __shfl_xor(m, off, 64));
    if ((tid & 63) == 0) sm[tid >> 6] = m;
    __syncthreads();
    if (tid == 0) {
        float mm = sm[0];
        for (int i = 1; i < 16; ++i) mm = fmaxf(mm, sm[i]);
        sm[0] = mm;
    }
    __syncthreads();
    float mx = sm[0];
    float s = 0.f;
    for (int i = tid; i < kN; i += 1024) s += __expf(rw[i] - mx);
#pragma unroll
    for (int off = 32; off > 0; off >>= 1) s += __shfl_xor(s, off, 64);
    if ((tid & 63) == 0) ss[tid >> 6] = s;
    __syncthreads();
    if (tid == 0) {
        float z = 0.f;
        for (int i = 0; i < 16; ++i) z += ss[i];
        stats[0] = mx;
        stats[1] = z;
    }
}

__global__ void blend_k(const float* __restrict__ x1, const float* __restrict__ x2,
                        const float* __restrict__ rw, const float* __restrict__ stats,
                        float* __restrict__ g) {
    int gid = blockIdx.x * 256 + threadIdx.x;
    if (gid >= kN * 64) return;
    int n = gid >> 6;
    int c4 = (gid & 63) << 2;
    float aw = __expf(rw[n] - stats[0]) / stats[1];
    float4 v1 = *reinterpret_cast<const float4*>(x1 + (size_t)n * 256 + c4);
    float4 v2 = *reinterpret_cast<const float4*>(x2 + (size_t)n * 256 + c4);
    float4 o;
    o.x = aw * v1.x + (1.f - aw) * v2.x;
    o.y = aw * v1.y + (1.f - aw) * v2.y;
    o.z = aw * v1.z + (1.f - aw) * v2.z;
    o.w = aw * v1.w + (1.f - aw) * v2.w;
    *reinterpret_cast<float4*>(g + (size_t)n * 256 + c4) = o;
}

// ---------------- myGAT gather ----------------

__global__ __launch_bounds__(256) void mygat_gather_k(const int* __restrict__ csr, const int* __restrict__ offs,
                                                      const int* __restrict__ cnt, const float* __restrict__ el,
                                                      const float* __restrict__ er, const float* __restrict__ f,
                                                      float* __restrict__ rst) {
    int node = blockIdx.x * 8 + (threadIdx.x >> 5);
    int c = threadIdx.x & 31;
    if (node >= kN) return;
    int o0 = offs[node], n = cnt[node];
    float erd = er[node];
    float m = -1e30f;
    for (int i = 0; i < n; ++i) {
        int s = csr[o0 + i];
        m = fmaxf(m, lrelu(el[s] + erd));
    }
    float z = 0.f, acc = 0.f;
    for (int i = 0; i < n; ++i) {
        int s = csr[o0 + i];
        float e = __expf(lrelu(el[s] + erd) - m);
        z += e;
        acc += f[(size_t)s * kC + c] * e;
    }
    rst[(size_t)node * kC + c] = acc / z;
}

__global__ void final_k(const float* __restrict__ rst, const float* __restrict__ r2,
                        float* __restrict__ logits) {
    int n = blockIdx.x * 256 + threadIdx.x;
    if (n >= kN) return;
    float vals[kC];
    float ssum = 0.f;
#pragma unroll
    for (int c = 0; c < kC; ++c) {
        vals[c] = rst[(size_t)n * kC + c] + r2[(size_t)n * kC + c];
        ssum += vals[c] * vals[c];
    }
    float inv = 1.0f / fmaxf(sqrtf(ssum), 1e-12f);
#pragma unroll
    for (int c = 0; c < kC; ++c) logits[(size_t)n * kC + c] = vals[c] * inv;
}

// ---------------- host orchestration ----------------

static void run_encoder(const float* xinF, const unsigned short* xinB, float* outp,
                        unsigned short* outB, float* ws, int e,
                        const float* bqkv, const float* bo, const float* b1, const float* b2,
                        const float* g1, const float* be1, const float* g2, const float* be2,
                        hipStream_t stream) {
    float* T3 = ws + OFF_T3;
    unsigned short* T2B  = (unsigned short*)(ws + OFF_T2);
    unsigned short* BIGB = (unsigned short*)(ws + OFF_BIGB);
    unsigned short* OB   = BIGB + (size_t)kMP * 768;
    unsigned short* SB   = (unsigned short*)(ws + OFF_SB);
    unsigned short* WB   = (unsigned short*)(ws + OFF_WB);
    const unsigned short* WQ = WB + (size_t)e * 196608;
    const unsigned short* WO = WB + 393216 + (size_t)e * 65536;
    const unsigned short* W1 = WB + 524288 + (size_t)e * 262144;
    const unsigned short* W2 = WB + 1048576 + (size_t)e * 262144;
    dim3 blk(256);

    mgemm_k<0, false, true><<<dim3(6, 469, 1), blk, 0, stream>>>(
        xinB, WQ, bqkv, nullptr, BIGB, kSN, 768, 256, 0, 0, 0);
    mha3_k<<<dim3((kN * kNH) / 32), blk, 0, stream>>>(BIGB, OB);
    // o-proj -> bf16 T2B
    mgemm_k<0, false, true><<<dim3(2, 469, 1), blk, 0, stream>>>(
        OB, WO, bo, nullptr, T2B, kSN, 256, 256, 0, 0, 0);
    ln_add_k<<<dim3(kSN / 4), blk, 0, stream>>>(xinF, T2B, g1, be1, T3, SB, kSN);
    mgemm_k<1, false, true><<<dim3(8, 469, 1), blk, 0, stream>>>(
        SB, W1, b1, nullptr, BIGB, kSN, 1024, 256, 0, 0, 0);
    // ff2 -> bf16 T2B
    mgemm_k<0, false, true><<<dim3(2, 469, 1), blk, 0, stream>>>(
        BIGB, W2, b2, nullptr, T2B, kSN, 256, 1024, 0, 0, 0);
    ln_add_k<<<dim3(kSN / 4), blk, 0, stream>>>(T3, T2B, g2, be2, outp, outB, kSN);
}

extern "C" void kernel_launch(void* const* d_in, const int* in_sizes, int n_in,
                              void* d_out, int out_size, void* d_ws, size_t ws_size,
                              hipStream_t stream) {
    (void)in_sizes; (void)n_in; (void)out_size; (void)ws_size;

    const float* x      = (const float*)d_in[0];
    const int*   e_src  = (const int*)d_in[1];
    const int*   e_dst  = (const int*)d_in[2];
    const int*   gsrc   = (const int*)d_in[3];
    const int*   gdst   = (const int*)d_in[4];
    const float* rand_w = (const float*)d_in[5];
    const float* gcn_W  = (const float*)d_in[6];
    const float* gcn_b  = (const float*)d_in[7];
    const float* gat_W  = (const float*)d_in[8];
    const float* gat_as = (const float*)d_in[9];
    const float* gat_ad = (const float*)d_in[10];
    const float* gat_b  = (const float*)d_in[11];
    const float* Wqkv   = (const float*)d_in[12];
    const float* bqkv   = (const float*)d_in[13];
    const float* Wo     = (const float*)d_in[14];
    const float* bo     = (const float*)d_in[15];
    const float* W1     = (const float*)d_in[16];
    const float* b1     = (const float*)d_in[17];
    const float* W2     = (const float*)d_in[18];
    const float* b2     = (const float*)d_in[19];
    const float* ln1g   = (const float*)d_in[20];
    const float* ln1b   = (const float*)d_in[21];
    const float* ln2g   = (const float*)d_in[22];
    const float* ln2b   = (const float*)d_in[23];
    const float* att_P  = (const float*)d_in[24];
    const float* att_Pb = (const float*)d_in[25];
    const float* att_q  = (const float*)d_in[26];
    const float* mg_fc  = (const float*)d_in[27];
    const float* mg_al  = (const float*)d_in[28];
    const float* mg_ar  = (const float*)d_in[29];
    const float* mg_res = (const float*)d_in[30];

    float* ws  = (float*)d_ws;
    float* T1  = ws + OFF_T1;
    float* T3  = ws + OFF_T3;
    float* DNV = ws + OFF_DEG;
    float* EL  = ws + OFF_EL;
    float* ER  = ws + OFF_ER;
    float* W0b = ws + OFF_W0;
    float* W1b = ws + OFF_W1;
    float* FB  = ws + OFF_FB;
    float* R2  = ws + OFF_R2;
    float* RST = ws + OFF_RST;
    float* EL2 = ws + OFF_EL2;
    float* ER2 = ws + OFF_ER2;
    float* ST  = ws + OFF_ST;

    unsigned short* T2B  = (unsigned short*)(ws + OFF_T2);
    unsigned short* BIGB = (unsigned short*)(ws + OFF_BIGB);
    unsigned short* HB   = BIGB;
    unsigned short* SB   = (unsigned short*)(ws + OFF_SB);
    unsigned short* AB   = (unsigned short*)(ws + OFF_AB);
    unsigned short* WB   = (unsigned short*)(ws + OFF_WB);
    unsigned short* GWB  = (unsigned short*)(ws + OFF_GWB);
    unsigned short* PB   = (unsigned short*)(ws + OFF_PB);

    int* ib    = (int*)(ws + OFF_INT);
    int* CNT   = ib + ICNT;
    int* CNT2  = ib + ICNT2;
    int* OFFS  = ib + IOFF;
    int* OFFS2 = ib + IOFF2;
    int* CUR   = ib + ICUR;
    int* CUR2  = ib + ICUR2;
    int* CSR   = ib + ICSR;
    int* CSR2  = ib + ICSR2;

    float* outp   = (float*)d_out;
    float* a0     = outp;
    float* a1     = outp + (size_t)kSN * kH;
    float* logits = outp + 2 * (size_t)kSN * kH;
    float* gemb   = outp + 2 * (size_t)kSN * kH + (size_t)kN * kC;

    dim3 blk(256);

    // ---- 0a. zero pad-tail rows of bf16 GEMM-A buffers ----
    hipMemsetAsync(SB + (size_t)kSN * 256, 0, (size_t)(kMP - kSN) * 256 * sizeof(unsigned short), stream);
    hipMemsetAsync(AB + (size_t)kSN * 256, 0, (size_t)(kMP - kSN) * 256 * sizeof(unsigned short), stream);
    hipMemsetAsync(BIGB + (size_t)kSN * 1024, 0, (size_t)(kMP - kSN) * 1024 * sizeof(unsigned short), stream);

    // ---- 0b. CSR build ----
    hipMemsetAsync(CNT, 0, (size_t)(kV * kN + kN) * sizeof(int), stream);
    count_k<<<dim3((kV * kE + 255) / 256), blk, 0, stream>>>(e_dst, CNT, kE, kN, kV * kE);
    count_k<<<dim3((kE2 + 255) / 256), blk, 0, stream>>>(gdst, CNT2, kE2, kN, kE2);
    scan_k<<<dim3(kV), dim3(1024), 0, stream>>>(CNT, OFFS, CUR, kN);
    scan_k<<<dim3(1), dim3(1024), 0, stream>>>(CNT2, OFFS2, CUR2, kN);
    fill_csr_k<<<dim3((kV * kE + 255) / 256), blk, 0, stream>>>(e_src, e_dst, CUR, CSR, kE, kN, kV * kE);
    fill_csr_k<<<dim3((kE2 + 255) / 256), blk, 0, stream>>>(gsrc, gdst, CUR2, CSR2, kE2, kN, kE2);
    dinv_k<<<dim3((kV * kN + 255) / 256), blk, 0, stream>>>(CNT, DNV, kV * kN);

    // ---- 0c. weight/activation bf16 conversion ----
    cvt_k<<<dim3((393216 / 4 + 255) / 256), blk, 0, stream>>>(Wqkv, WB, 393216 / 4);
    cvt_k<<<dim3((131072 / 4 + 255) / 256), blk, 0, stream>>>(Wo, WB + 393216, 131072 / 4);
    cvt_k<<<dim3((524288 / 4 + 255) / 256), blk, 0, stream>>>(W1, WB + 524288, 524288 / 4);
    cvt_k<<<dim3((524288 / 4 + 255) / 256), blk, 0, stream>>>(W2, WB + 1048576, 524288 / 4);
    tcvt_k<<<dim3((3 * 65536 + 255) / 256), blk, 0, stream>>>(gcn_W, GWB, 256, 256, 3 * 65536);
    tcvt_k<<<dim3((3 * 65536 + 255) / 256), blk, 0, stream>>>(gat_W, GWB + 3 * 65536, 256, 256, 3 * 65536);
    tcvt_k<<<dim3((2 * 32768 + 255) / 256), blk, 0, stream>>>(att_P, PB, 256, 128, 2 * 32768);
    cvt_k<<<dim3((kSN * 256 / 4 + 255) / 256), blk, 0, stream>>>(x, AB, kSN * 256 / 4);

    // ---- 1. multi-view GCN + relu ----
    mgemm_k<0, false, true><<<dim3(2, 157, 3), blk, 0, stream>>>(
        AB, GWB, nullptr, nullptr, HB, kN, 256, 256, (long)kN * 256, 65536, kN);
    gcn_gather_k<<<dim3(kSN / 4), blk, 0, stream>>>(CSR, OFFS, CNT, DNV, HB, gcn_b, T1, SB);

    // ---- 2. encoder 0 -> a0 ----
    run_encoder(T1, SB, a0, AB, ws, 0, bqkv, bo, b1, b2, ln1g, ln1b, ln2g, ln2b, stream);

    // ---- 3. multi-view GAT + relu ----
    mgemm_k<0, false, true><<<dim3(2, 157, 3), blk, 0, stream>>>(
        AB, GWB + 3 * 65536, nullptr, nullptr, HB, kN, 256, 256, (long)kN * 256, 65536, kN);
    rowdot2b_k<<<dim3(kSN), dim3(64), 0, stream>>>(HB, gat_as, gat_ad, EL, ER, kSN, 256, kN, kH);
    gat_gather_k<<<dim3(kSN / 4), blk, 0, stream>>>(CSR, OFFS, CNT, EL, ER, HB, gat_b, T1, SB);

    // ---- 4. encoder 1 -> a1 ----
    run_encoder(T1, SB, a1, AB, ws, 1, bqkv + 768, bo + 256, b1 + 1024, b2 + 256,
                ln1g + 256, ln1b + 256, ln2g + 256, ln2b + 256, stream);

    // ---- 5. view attention + blend -> gemb ----
    // fused: bf16 [60000][256] = a1 @ [att_P0 | att_P1], cols 0..127 tanh, 128..255 relu
    mgemm_k<3, false, true><<<dim3(2, 469, 1), blk, 0, stream>>>(
        AB, PB, att_Pb, nullptr, T2B, kSN, 256, 256, 0, 0, 0);
    attdot_k<<<dim3(kSN / 4), blk, 0, stream>>>(T2B, att_q, W0b, W1b, kSN);
    float* X1 = T3;
    float* X2 = T3 + (size_t)kN * kH;
    view_comb_k<<<dim3((kN * 64 + 255) / 256), blk, 0, stream>>>(a1, W0b, W1b, X1, X2);
    randsm_k<<<dim3(1), dim3(1024), 0, stream>>>(rand_w, ST);
    blend_k<<<dim3((kN * 64 + 255) / 256), blk, 0, stream>>>(X1, X2, rand_w, ST, gemb);

    // ---- 6. myGATConv -> logits ----
    gemm_k<0><<<dim3(1, (kN + 63) / 64), blk, 0, stream>>>(gemb, mg_fc, (const float*)nullptr, FB, kN, kC, 256);
    rowdot2_k<<<dim3(kN), dim3(64), 0, stream>>>(FB, mg_al, mg_ar, EL2, ER2, kN, kC, kN, 0);
    mygat_gather_k<<<dim3((kN + 7) / 8), blk, 0, stream>>>(CSR2, OFFS2, CNT2, EL2, ER2, FB, RST);
    gemm_k<0><<<dim3(1, (kN + 63) / 64), blk, 0, stream>>>(gemb, mg_res, (const float*)nullptr, R2, kN, kC, 256);
    final_k<<<dim3((kN + 255) / 256), blk, 0, stream>>>(RST, R2, logits);
}

// Round 10
// 1087.891 us; speedup vs baseline: 1.3833x; 1.0639x over previous
//
#include <hip/hip_runtime.h>
#include <hip/hip_bf16.h>
#include <math.h>

// ---------------- problem constants ----------------
namespace {
constexpr int kV  = 3;
constexpr int kN  = 20000;
constexpr int kF  = 256;
constexpr int kH  = 256;
constexpr int kE  = 160000;
constexpr int kC  = 32;
constexpr int kNH = 8;
constexpr int kSN = kV * kN;     // 60000
constexpr int kE2 = kE + kN;     // 180000
constexpr int kMP = 60160;       // padded rows for bf16 GEMM-A buffers

// fp32 workspace layout (float element offsets)
constexpr size_t OFF_T1   = 0;                                   // (spare)
constexpr size_t OFF_T2   = OFF_T1 + (size_t)kMP * 256;          // bf16 T2B
constexpr size_t OFF_T3   = OFF_T2 + (size_t)kMP * 256;          // f32 X1/X2 blend buffers
constexpr size_t OFF_BIGB = OFF_T3 + (size_t)kMP * 256;          // bf16 [kMP*1024]
constexpr size_t OFF_SB   = OFF_BIGB + (size_t)kMP * 512;        // bf16 [kMP*256]
constexpr size_t OFF_AB   = OFF_SB + (size_t)kMP * 128;          // bf16 [kMP*256]
constexpr size_t OFF_WB   = OFF_AB + (size_t)kMP * 128;          // bf16 enc weights
constexpr size_t OFF_GWB  = OFF_WB + 786432;
constexpr size_t OFF_PB   = OFF_GWB + 196608;
constexpr size_t OFF_DEG  = OFF_PB + 32768;
constexpr size_t OFF_EL   = OFF_DEG + (size_t)kV * kN;
constexpr size_t OFF_ER   = OFF_EL  + (size_t)kV * kN;
constexpr size_t OFF_W0   = OFF_ER  + (size_t)kV * kN;
constexpr size_t OFF_W1   = OFF_W0  + (size_t)kV * kN;
constexpr size_t OFF_FB   = OFF_W1  + (size_t)kV * kN;
constexpr size_t OFF_R2   = OFF_FB  + (size_t)kN * kC;
constexpr size_t OFF_RST  = OFF_R2  + (size_t)kN * kC;
constexpr size_t OFF_EL2  = OFF_RST + (size_t)kN * kC;
constexpr size_t OFF_ER2  = OFF_EL2 + kN;
constexpr size_t OFF_ST   = OFF_ER2 + kN;
constexpr size_t OFF_INT  = OFF_ST + 4;
// int layout
constexpr size_t ICNT  = 0;
constexpr size_t ICNT2 = ICNT  + (size_t)kV * kN;
constexpr size_t IOFF  = ICNT2 + kN;
constexpr size_t IOFF2 = IOFF  + (size_t)kV * kN;
constexpr size_t ICUR  = IOFF2 + kN;
constexpr size_t ICUR2 = ICUR  + (size_t)kV * kN;
constexpr size_t ICSR  = ICUR2 + kN;
constexpr size_t ICSR2 = ICSR  + (size_t)kV * kE;
} // namespace

typedef __attribute__((ext_vector_type(4))) float f32x4;
typedef __attribute__((ext_vector_type(8))) __bf16 bf16x8;

__device__ __forceinline__ float lrelu(float x) { return x > 0.f ? x : 0.2f * x; }
__device__ __forceinline__ unsigned short f2b(float f) {
    unsigned u = __float_as_uint(f);
    return (unsigned short)((u + 0x7FFFu + ((u >> 16) & 1u)) >> 16);
}
__device__ __forceinline__ float b2f(unsigned short h) {
    return __uint_as_float((unsigned)h << 16);
}
// tanh via HW exp: tanh(x) = (e^{2x}-1)/(e^{2x}+1), clamped
__device__ __forceinline__ float fast_tanh(float x) {
    float xc = fminf(fmaxf(x, -15.f), 15.f);
    float e = __expf(2.0f * xc);
    return (e - 1.0f) / (e + 1.0f);
}

// ---------------- conversion kernels ----------------

__global__ void cvt_k(const float* __restrict__ in, unsigned short* __restrict__ out, int n4) {
    int i = blockIdx.x * 256 + threadIdx.x;
    if (i >= n4) return;
    float4 v = reinterpret_cast<const float4*>(in)[i];
    ushort4 o;
    o.x = f2b(v.x); o.y = f2b(v.y); o.z = f2b(v.z); o.w = f2b(v.w);
    reinterpret_cast<ushort4*>(out)[i] = o;
}

__global__ void tcvt_k(const float* __restrict__ in, unsigned short* __restrict__ out,
                       int K, int N, int total) {
    int gid = blockIdx.x * 256 + threadIdx.x;
    if (gid >= total) return;
    int per = K * N;
    int v = gid / per, r = gid - v * per;
    int n = r / K, k = r - n * K;
    out[gid] = f2b(in[(size_t)v * per + (size_t)k * N + n]);
}

// ---------------- MFMA bf16 GEMM: double-buffered staging + coalesced epilogue ----------------
// C[M,N] = act(A[M,K] @ W[N,K]^T + bias). 128x128 tile, BK=32, 4 waves, 2-phase dbuf.
// ACT: 0 none, 1 relu, 2 tanh, 3 split (global col<128 tanh else relu).
template <int ACT, bool WF32, bool WB16>
__global__ __launch_bounds__(256) void mgemm_k(const unsigned short* __restrict__ A,
                                               const unsigned short* __restrict__ W,
                                               const float* __restrict__ bias,
                                               float* __restrict__ Cf,
                                               unsigned short* __restrict__ Cb,
                                               int M, int N, int K,
                                               long zA, long zW, long zC) {
    static_assert(WF32 != WB16, "exactly one output path");
    __shared__ __align__(16) unsigned short shbuf[16384];   // 2 x (As 8KB + Ws 8KB); epilogue reuses

    const int tid  = threadIdx.x;
    const int lane = tid & 63;

    // bijective XCD-chunked swizzle of the (x,y) tile index (m204)
    const int gx = gridDim.x;
    const int nwg = gx * gridDim.y;
    const int orig = blockIdx.y * gx + blockIdx.x;
    const int q = nwg >> 3, rr = nwg & 7;
    const int xcd = orig & 7, pos = orig >> 3;
    const int nid = (xcd < rr ? xcd * (q + 1) : rr * (q + 1) + (xcd - rr) * q) + pos;
    const int bm = (nid / gx) * 128, bn = (nid % gx) * 128;

    A += (size_t)blockIdx.z * zA;
    W += (size_t)blockIdx.z * zW;
    const size_t zrow = (size_t)blockIdx.z * zC;

    const int wv = tid >> 6;
    const int wm = (wv >> 1) * 64, wn = (wv & 1) * 64;
    const int fr = lane & 15;
    const int fk = (lane >> 4) * 8;

    const int r0 = tid >> 2, sl0 = (tid & 3) * 8;
    const int r1 = (256 + tid) >> 2, sl1 = ((256 + tid) & 3) * 8;

    f32x4 acc[4][4] = {};

    // prologue: stage tile 0 into buffer 0
    {
        unsigned short* As = shbuf;
        unsigned short* Ws = shbuf + 4096;
        __builtin_amdgcn_global_load_lds((const __attribute__((address_space(1))) void*)(A + (size_t)(bm + r0) * K + sl0),
                                         (__attribute__((address_space(3))) void*)(As + tid * 8), 16, 0, 0);
        __builtin_amdgcn_global_load_lds((const __attribute__((address_space(1))) void*)(W + (size_t)(bn + r0) * K + sl0),
                                         (__attribute__((address_space(3))) void*)(Ws + tid * 8), 16, 0, 0);
        __builtin_amdgcn_global_load_lds((const __attribute__((address_space(1))) void*)(A + (size_t)(bm + r1) * K + sl1),
                                         (__attribute__((address_space(3))) void*)(As + (256 + tid) * 8), 16, 0, 0);
        __builtin_amdgcn_global_load_lds((const __attribute__((address_space(1))) void*)(W + (size_t)(bn + r1) * K + sl1),
                                         (__attribute__((address_space(3))) void*)(Ws + (256 + tid) * 8), 16, 0, 0);
    }
    __syncthreads();

    int cur = 0;
    for (int k0 = 0; k0 < K; k0 += 32) {
        if (k0 + 32 < K) {
            unsigned short* As = shbuf + (cur ^ 1) * 8192;
            unsigned short* Ws = As + 4096;
            const int kn = k0 + 32;
            __builtin_amdgcn_global_load_lds((const __attribute__((address_space(1))) void*)(A + (size_t)(bm + r0) * K + kn + sl0),
                                             (__attribute__((address_space(3))) void*)(As + tid * 8), 16, 0, 0);
            __builtin_amdgcn_global_load_lds((const __attribute__((address_space(1))) void*)(W + (size_t)(bn + r0) * K + kn + sl0),
                                             (__attribute__((address_space(3))) void*)(Ws + tid * 8), 16, 0, 0);
            __builtin_amdgcn_global_load_lds((const __attribute__((address_space(1))) void*)(A + (size_t)(bm + r1) * K + kn + sl1),
                                             (__attribute__((address_space(3))) void*)(As + (256 + tid) * 8), 16, 0, 0);
            __builtin_amdgcn_global_load_lds((const __attribute__((address_space(1))) void*)(W + (size_t)(bn + r1) * K + kn + sl1),
                                             (__attribute__((address_space(3))) void*)(Ws + (256 + tid) * 8), 16, 0, 0);
        }
        const unsigned short* As = shbuf + cur * 8192;
        const unsigned short* Ws = As + 4096;
        bf16x8 av[4], bv[4];
#pragma unroll
        for (int mi = 0; mi < 4; ++mi)
            av[mi] = *reinterpret_cast<const bf16x8*>(As + (wm + mi * 16 + fr) * 32 + fk);
#pragma unroll
        for (int ni = 0; ni < 4; ++ni)
            bv[ni] = *reinterpret_cast<const bf16x8*>(Ws + (wn + ni * 16 + fr) * 32 + fk);
#pragma unroll
        for (int mi = 0; mi < 4; ++mi)
#pragma unroll
            for (int ni = 0; ni < 4; ++ni)
                acc[mi][ni] = __builtin_amdgcn_mfma_f32_16x16x32_bf16(av[mi], bv[ni], acc[mi][ni], 0, 0, 0);
        __syncthreads();
        cur ^= 1;
    }

    const int crow = (lane >> 4) * 4;
    const int ccol = lane & 15;

    if (WB16) {
#pragma unroll
        for (int mi = 0; mi < 4; ++mi)
#pragma unroll
            for (int r = 0; r < 4; ++r) {
                const int row = wm + mi * 16 + crow + r;
#pragma unroll
                for (int ni = 0; ni < 4; ++ni) {
                    const int col = wn + ni * 16 + ccol;
                    float v = acc[mi][ni][r];
                    if (bias) v += bias[bn + col];
                    if (ACT == 1) v = fmaxf(v, 0.f);
                    if (ACT == 2) v = fast_tanh(v);
                    if (ACT == 3) v = (bn + col < 128) ? fast_tanh(v) : fmaxf(v, 0.f);
                    shbuf[row * 128 + col] = f2b(v);
                }
            }
        __syncthreads();
#pragma unroll
        for (int it = 0; it < 8; ++it) {
            const int fl = it * 2048 + tid * 8;
            const int row = fl >> 7, col = fl & 127;
            const int grow = bm + row;
            if (grow < M) {
                uint4 d = *reinterpret_cast<const uint4*>(shbuf + row * 128 + col);
                *reinterpret_cast<uint4*>(Cb + (zrow + grow) * (size_t)N + bn + col) = d;
            }
        }
    } else {
        float* epf = reinterpret_cast<float*>(shbuf);
#pragma unroll
        for (int half = 0; half < 2; ++half) {
            if ((wm >> 6) == half) {
#pragma unroll
                for (int mi = 0; mi < 4; ++mi)
#pragma unroll
                    for (int r = 0; r < 4; ++r) {
                        const int row = mi * 16 + crow + r;
#pragma unroll
                        for (int ni = 0; ni < 4; ++ni) {
                            const int col = wn + ni * 16 + ccol;
                            float v = acc[mi][ni][r];
                            if (bias) v += bias[bn + col];
                            if (ACT == 1) v = fmaxf(v, 0.f);
                            if (ACT == 2) v = fast_tanh(v);
                            if (ACT == 3) v = (bn + col < 128) ? fast_tanh(v) : fmaxf(v, 0.f);
                            epf[row * 128 + col] = v;
                        }
                    }
            }
            __syncthreads();
#pragma unroll
            for (int it = 0; it < 8; ++it) {
                const int fl = it * 1024 + tid * 4;
                const int row = fl >> 7, col = fl & 127;
                const int grow = bm + half * 64 + row;
                if (grow < M) {
                    float4 d = *reinterpret_cast<const float4*>(epf + row * 128 + col);
                    *reinterpret_cast<float4*>(Cf + (zrow + grow) * (size_t)N + bn + col) = d;
                }
            }
            __syncthreads();
        }
    }
}

// ---------------- fp32 GEMM (N=32 tail) ----------------
template <int ACT>
__global__ __launch_bounds__(256) void gemm_k(const float* __restrict__ A,
                                              const float* __restrict__ B,
                                              const float* __restrict__ bias,
                                              float* __restrict__ Cmat,
                                              int M, int Nn, int K) {
    __shared__ float As[16][64];
    __shared__ float Bs[16][68];
    const int tid  = threadIdx.x;
    const int bm   = blockIdx.y * 64;
    const int bn   = blockIdx.x * 64;
    const int tx   = tid & 15, ty = tid >> 4;
    const int arow = tid >> 2;
    const int acol = (tid & 3) << 2;
    const int brow = tid >> 4;
    const int bcol = (tid & 15) << 2;
    const int gm   = bm + arow;
    float acc[4][4] = {{0.f,0.f,0.f,0.f},{0.f,0.f,0.f,0.f},{0.f,0.f,0.f,0.f},{0.f,0.f,0.f,0.f}};

    for (int k0 = 0; k0 < K; k0 += 16) {
        float4 av = make_float4(0.f, 0.f, 0.f, 0.f);
        if (gm < M) av = *reinterpret_cast<const float4*>(A + (size_t)gm * K + (k0 + acol));
        As[acol + 0][arow] = av.x;
        As[acol + 1][arow] = av.y;
        As[acol + 2][arow] = av.z;
        As[acol + 3][arow] = av.w;

        const int gn = bn + bcol;
        const float* Brow = B + (size_t)(k0 + brow) * Nn;
        float4 bv;
        if (gn + 3 < Nn) {
            bv = *reinterpret_cast<const float4*>(Brow + gn);
        } else {
            bv.x = (gn + 0 < Nn) ? Brow[gn + 0] : 0.f;
            bv.y = (gn + 1 < Nn) ? Brow[gn + 1] : 0.f;
            bv.z = (gn + 2 < Nn) ? Brow[gn + 2] : 0.f;
            bv.w = (gn + 3 < Nn) ? Brow[gn + 3] : 0.f;
        }
        *reinterpret_cast<float4*>(&Bs[brow][bcol]) = bv;
        __syncthreads();

#pragma unroll
        for (int k = 0; k < 16; ++k) {
            float4 a4 = *reinterpret_cast<const float4*>(&As[k][ty << 2]);
            float4 b4 = *reinterpret_cast<const float4*>(&Bs[k][tx << 2]);
            acc[0][0] += a4.x * b4.x; acc[0][1] += a4.x * b4.y; acc[0][2] += a4.x * b4.z; acc[0][3] += a4.x * b4.w;
            acc[1][0] += a4.y * b4.x; acc[1][1] += a4.y * b4.y; acc[1][2] += a4.y * b4.z; acc[1][3] += a4.y * b4.w;
            acc[2][0] += a4.z * b4.x; acc[2][1] += a4.z * b4.y; acc[2][2] += a4.z * b4.z; acc[2][3] += a4.z * b4.w;
            acc[3][0] += a4.w * b4.x; acc[3][1] += a4.w * b4.y; acc[3][2] += a4.w * b4.z; acc[3][3] += a4.w * b4.w;
        }
        __syncthreads();
    }

#pragma unroll
    for (int i = 0; i < 4; ++i) {
        int m = bm + (ty << 2) + i;
        if (m >= M) continue;
#pragma unroll
        for (int j = 0; j < 4; ++j) {
            int n = bn + (tx << 2) + j;
            if (n >= Nn) continue;
            float v = acc[i][j];
            if (bias) v += bias[n];
            if (ACT == 1) v = fmaxf(v, 0.f);
            if (ACT == 2) v = fast_tanh(v);
            Cmat[(size_t)m * Nn + n] = v;
        }
    }
}

// out = LN(x+y)*g+b; wave per row; x,y bf16 ushort4/lane; WF32: also write f32.
// In-place x==outb is safe (each wave owns its row; reads precede writes).
template <bool WF32>
__global__ __launch_bounds__(256) void ln_add_k(const unsigned short* __restrict__ x,
                                                const unsigned short* __restrict__ y,
                                                const float* __restrict__ g, const float* __restrict__ b,
                                                float* __restrict__ outf, unsigned short* __restrict__ outb,
                                                int rows) {
    int r = blockIdx.x * 4 + (threadIdx.x >> 6);
    if (r >= rows) return;
    int lane = threadIdx.x & 63;
    size_t base = (size_t)r * 256 + lane * 4;
    ushort4 xu = *reinterpret_cast<const ushort4*>(x + base);
    ushort4 yu = *reinterpret_cast<const ushort4*>(y + base);
    float4 t;
    t.x = b2f(xu.x) + b2f(yu.x); t.y = b2f(xu.y) + b2f(yu.y);
    t.z = b2f(xu.z) + b2f(yu.z); t.w = b2f(xu.w) + b2f(yu.w);
    float s = t.x + t.y + t.z + t.w;
#pragma unroll
    for (int off = 32; off > 0; off >>= 1) s += __shfl_xor(s, off, 64);
    float mean = s * (1.0f / 256.0f);
    float4 d;
    d.x = t.x - mean; d.y = t.y - mean; d.z = t.z - mean; d.w = t.w - mean;
    float s2 = d.x * d.x + d.y * d.y + d.z * d.z + d.w * d.w;
#pragma unroll
    for (int off = 32; off > 0; off >>= 1) s2 += __shfl_xor(s2, off, 64);
    float rs = rsqrtf(s2 * (1.0f / 256.0f) + 1e-5f);
    float4 gv = *reinterpret_cast<const float4*>(g + lane * 4);
    float4 bv = *reinterpret_cast<const float4*>(b + lane * 4);
    float4 o;
    o.x = d.x * rs * gv.x + bv.x;
    o.y = d.y * rs * gv.y + bv.y;
    o.z = d.z * rs * gv.z + bv.z;
    o.w = d.w * rs * gv.w + bv.w;
    if (WF32) *reinterpret_cast<float4*>(outf + base) = o;
    ushort4 ob;
    ob.x = f2b(o.x); ob.y = f2b(o.y); ob.z = f2b(o.z); ob.w = f2b(o.w);
    *reinterpret_cast<ushort4*>(outb + base) = ob;
}

// per-row dual dot products, fp32 A
__global__ void rowdot2_k(const float* __restrict__ A, const float* __restrict__ v1,
                          const float* __restrict__ v2, float* __restrict__ o1,
                          float* __restrict__ o2, int rows, int K, int rowsPerVec, int vecStride) {
    int r = blockIdx.x;
    if (r >= rows) return;
    int lane = threadIdx.x;
    const float* base = A + (size_t)r * K;
    int vo = (r / rowsPerVec) * vecStride;
    float s1 = 0.f, s2 = 0.f;
    for (int c = lane; c < K; c += 64) {
        float a = base[c];
        s1 += a * v1[vo + c];
        if (v2) s2 += a * v2[vo + c];
    }
#pragma unroll
    for (int off = 32; off > 0; off >>= 1) {
        s1 += __shfl_xor(s1, off, 64);
        s2 += __shfl_xor(s2, off, 64);
    }
    if (lane == 0) { o1[r] = s1; if (o2) o2[r] = s2; }
}

// fused dual 128-dot from bf16 [rows][256]
__global__ __launch_bounds__(256) void attdot_k(const unsigned short* __restrict__ A, const float* __restrict__ q,
                                                float* __restrict__ o1, float* __restrict__ o2, int rows) {
    int r = blockIdx.x * 4 + (threadIdx.x >> 6);
    if (r >= rows) return;
    int lane = threadIdx.x & 63;
    const unsigned short* row = A + (size_t)r * 256;
    ushort2 va = *reinterpret_cast<const ushort2*>(row + lane * 2);
    ushort2 vb = *reinterpret_cast<const ushort2*>(row + 128 + lane * 2);
    float2 qa = *reinterpret_cast<const float2*>(q + lane * 2);
    float2 qb = *reinterpret_cast<const float2*>(q + 128 + lane * 2);
    float s1 = b2f(va.x) * qa.x + b2f(va.y) * qa.y;
    float s2 = b2f(vb.x) * qb.x + b2f(vb.y) * qb.y;
#pragma unroll
    for (int off = 32; off > 0; off >>= 1) {
        s1 += __shfl_xor(s1, off, 64);
        s2 += __shfl_xor(s2, off, 64);
    }
    if (lane == 0) { o1[r] = s1; o2[r] = s2; }
}

// per-row dual dot products, bf16 A, ushort4 per lane
__global__ void rowdot2b_k(const unsigned short* __restrict__ A, const float* __restrict__ v1,
                           const float* __restrict__ v2, float* __restrict__ o1,
                           float* __restrict__ o2, int rows, int K, int rowsPerVec, int vecStride) {
    int r = blockIdx.x;
    if (r >= rows) return;
    int lane = threadIdx.x;
    const unsigned short* base = A + (size_t)r * K;
    int vo = (r / rowsPerVec) * vecStride;
    float s1 = 0.f, s2 = 0.f;
    for (int c = lane * 4; c < K; c += 256) {
        ushort4 a4 = *reinterpret_cast<const ushort4*>(base + c);
        float4 w1 = *reinterpret_cast<const float4*>(v1 + vo + c);
        float4 w2 = *reinterpret_cast<const float4*>(v2 + vo + c);
        s1 += b2f(a4.x) * w1.x + b2f(a4.y) * w1.y + b2f(a4.z) * w1.z + b2f(a4.w) * w1.w;
        s2 += b2f(a4.x) * w2.x + b2f(a4.y) * w2.y + b2f(a4.z) * w2.z + b2f(a4.w) * w2.w;
    }
#pragma unroll
    for (int off = 32; off > 0; off >>= 1) {
        s1 += __shfl_xor(s1, off, 64);
        s2 += __shfl_xor(s2, off, 64);
    }
    if (lane == 0) { o1[r] = s1; o2[r] = s2; }
}

// ---------------- CSR build ----------------

__global__ void count_k(const int* __restrict__ dst, int* __restrict__ cnt, int nE, int nN, int total) {
    int gid = blockIdx.x * 256 + threadIdx.x;
    if (gid >= total) return;
    int v = gid / nE;
    atomicAdd(&cnt[(size_t)v * nN + dst[gid]], 1);
}

__global__ __launch_bounds__(1024) void scan_k(const int* __restrict__ cnt, int* __restrict__ offs,
                                               int* __restrict__ cursor, int nN) {
    int v = blockIdx.x;
    const int* c = cnt + (size_t)v * nN;
    int* o  = offs + (size_t)v * nN;
    int* cu = cursor + (size_t)v * nN;
    int tid = threadIdx.x;
    int chunk = (nN + 1023) >> 10;
    int lo = tid * chunk;
    int hi = lo + chunk < nN ? lo + chunk : nN;
    int s = 0;
    for (int i = lo; i < hi; ++i) s += c[i];
    int lane = tid & 63, wid = tid >> 6;
    int x = s;
#pragma unroll
    for (int off = 1; off < 64; off <<= 1) {
        int y = __shfl_up(x, off, 64);
        if (lane >= off) x += y;
    }
    __shared__ int wsum[16];
    if (lane == 63) wsum[wid] = x;
    __syncthreads();
    if (tid == 0) {
        int a = 0;
        for (int w = 0; w < 16; ++w) { int t = wsum[w]; wsum[w] = a; a += t; }
    }
    __syncthreads();
    int base = x - s + wsum[wid];
    for (int i = lo; i < hi; ++i) { o[i] = base; cu[i] = base; base += c[i]; }
}

__global__ void fill_csr_k(const int* __restrict__ src, const int* __restrict__ dst,
                           int* __restrict__ cursor, int* __restrict__ csr,
                           int nE, int nN, int total) {
    int gid = blockIdx.x * 256 + threadIdx.x;
    if (gid >= total) return;
    int v = gid / nE;
    int pos = atomicAdd(&cursor[(size_t)v * nN + dst[gid]], 1);
    csr[(size_t)v * nE + pos] = src[gid];
}

__global__ void dinv_k(const int* __restrict__ cnt, float* __restrict__ dinv, int n) {
    int gid = blockIdx.x * 256 + threadIdx.x;
    if (gid < n) dinv[gid] = rsqrtf((float)cnt[gid] + 1.0f);
}

// ---------------- GCN gather: one WAVE per node, LDS-free, ushort4/lane; bf16 out only ----------------

__global__ __launch_bounds__(256) void gcn_gather_k(const int* __restrict__ csr, const int* __restrict__ offs,
                                                    const int* __restrict__ cnt, const float* __restrict__ dinv,
                                                    const unsigned short* __restrict__ h, const float* __restrict__ b,
                                                    unsigned short* __restrict__ outb) {
    int nd = blockIdx.x * 4 + (threadIdx.x >> 6);
    if (nd >= kV * kN) return;
    int v  = nd / kN;
    int lane = threadIdx.x & 63;
    int c4 = lane * 4;
    const int* base = csr + (size_t)v * kE;
    int o0 = offs[nd], n = cnt[nd];
    float dd = dinv[nd];
    const float* dv = dinv + (size_t)v * kN;
    const unsigned short* hb = h + (size_t)v * kN * kH;

    ushort4 hs = *reinterpret_cast<const ushort4*>(h + (size_t)nd * kH + c4);
    float wts = dd * dd;
    float4 acc;
    acc.x = b2f(hs.x) * wts; acc.y = b2f(hs.y) * wts;
    acc.z = b2f(hs.z) * wts; acc.w = b2f(hs.w) * wts;
    int i = 0;
    for (; i + 2 <= n; i += 2) {
        int s0 = base[o0 + i], s1 = base[o0 + i + 1];
        float w0 = dv[s0] * dd, w1 = dv[s1] * dd;
        ushort4 h0 = *reinterpret_cast<const ushort4*>(hb + (size_t)s0 * kH + c4);
        ushort4 h1 = *reinterpret_cast<const ushort4*>(hb + (size_t)s1 * kH + c4);
        acc.x += b2f(h0.x) * w0 + b2f(h1.x) * w1;
        acc.y += b2f(h0.y) * w0 + b2f(h1.y) * w1;
        acc.z += b2f(h0.z) * w0 + b2f(h1.z) * w1;
        acc.w += b2f(h0.w) * w0 + b2f(h1.w) * w1;
    }
    if (i < n) {
        int s0 = base[o0 + i];
        float w0 = dv[s0] * dd;
        ushort4 h0 = *reinterpret_cast<const ushort4*>(hb + (size_t)s0 * kH + c4);
        acc.x += b2f(h0.x) * w0; acc.y += b2f(h0.y) * w0;
        acc.z += b2f(h0.z) * w0; acc.w += b2f(h0.w) * w0;
    }
    float4 bb = *reinterpret_cast<const float4*>(b + (size_t)v * kH + c4);
    ushort4 ob;
    ob.x = f2b(fmaxf(acc.x + bb.x, 0.f));
    ob.y = f2b(fmaxf(acc.y + bb.y, 0.f));
    ob.z = f2b(fmaxf(acc.z + bb.z, 0.f));
    ob.w = f2b(fmaxf(acc.w + bb.w, 0.f));
    *reinterpret_cast<ushort4*>(outb + (size_t)nd * kH + c4) = ob;
}

// ---------------- GAT gather: one WAVE per node, LDS-free; bf16 out only ----------------

__global__ __launch_bounds__(256) void gat_gather_k(const int* __restrict__ csr, const int* __restrict__ offs,
                                                    const int* __restrict__ cnt, const float* __restrict__ el,
                                                    const float* __restrict__ er, const unsigned short* __restrict__ h,
                                                    const float* __restrict__ b, unsigned short* __restrict__ outb) {
    int nd = blockIdx.x * 4 + (threadIdx.x >> 6);
    if (nd >= kV * kN) return;
    int v  = nd / kN;
    int lane = threadIdx.x & 63;
    int c4 = lane * 4;
    const int* base = csr + (size_t)v * kE;
    int o0 = offs[nd], n = cnt[nd];
    float erd = er[nd];
    const float* elv = el + (size_t)v * kN;
    const unsigned short* hb = h + (size_t)v * kN * kH;
    float eself = lrelu(el[nd] + erd);

    float m = eself;
    for (int i = 0; i < n; ++i) m = fmaxf(m, lrelu(elv[base[o0 + i]] + erd));

    float es = __expf(eself - m);
    float z = es;
    ushort4 hs = *reinterpret_cast<const ushort4*>(h + (size_t)nd * kH + c4);
    float4 acc;
    acc.x = b2f(hs.x) * es; acc.y = b2f(hs.y) * es;
    acc.z = b2f(hs.z) * es; acc.w = b2f(hs.w) * es;
    int i = 0;
    for (; i + 2 <= n; i += 2) {
        int s0 = base[o0 + i], s1 = base[o0 + i + 1];
        float e0 = __expf(lrelu(elv[s0] + erd) - m);
        float e1 = __expf(lrelu(elv[s1] + erd) - m);
        z += e0 + e1;
        ushort4 h0 = *reinterpret_cast<const ushort4*>(hb + (size_t)s0 * kH + c4);
        ushort4 h1 = *reinterpret_cast<const ushort4*>(hb + (size_t)s1 * kH + c4);
        acc.x += b2f(h0.x) * e0 + b2f(h1.x) * e1;
        acc.y += b2f(h0.y) * e0 + b2f(h1.y) * e1;
        acc.z += b2f(h0.z) * e0 + b2f(h1.z) * e1;
        acc.w += b2f(h0.w) * e0 + b2f(h1.w) * e1;
    }
    if (i < n) {
        int s0 = base[o0 + i];
        float e0 = __expf(lrelu(elv[s0] + erd) - m);
        z += e0;
        ushort4 h0 = *reinterpret_cast<const ushort4*>(hb + (size_t)s0 * kH + c4);
        acc.x += b2f(h0.x) * e0; acc.y += b2f(h0.y) * e0;
        acc.z += b2f(h0.z) * e0; acc.w += b2f(h0.w) * e0;
    }
    float iz = 1.0f / z;
    float4 bb = *reinterpret_cast<const float4*>(b + (size_t)v * kH + c4);
    ushort4 ob;
    ob.x = f2b(fmaxf(acc.x * iz + bb.x, 0.f));
    ob.y = f2b(fmaxf(acc.y * iz + bb.y, 0.f));
    ob.z = f2b(fmaxf(acc.z * iz + bb.z, 0.f));
    ob.w = f2b(fmaxf(acc.w * iz + bb.w, 0.f));
    *reinterpret_cast<ushort4*>(outb + (size_t)nd * kH + c4) = ob;
}

// ---------------- transformer: 3x3 attention, 8 lanes per (node,head), ushort4 ----------------

__global__ __launch_bounds__(256) void mha3_k(const unsigned short* __restrict__ qkv, unsigned short* __restrict__ o) {
    int grp = blockIdx.x * 32 + (threadIdx.x >> 3);
    int l8 = threadIdx.x & 7;
    if (grp >= kN * kNH) return;
    int b = grp / kNH, h = grp - b * kNH;
    float4 q[3], k[3], vv[3];
#pragma unroll
    for (int s = 0; s < 3; ++s) {
        size_t base = ((size_t)s * kN + b) * 768 + h * 32 + l8 * 4;
        ushort4 qu = *reinterpret_cast<const ushort4*>(qkv + base);
        ushort4 ku = *reinterpret_cast<const ushort4*>(qkv + base + 256);
        ushort4 vu = *reinterpret_cast<const ushort4*>(qkv + base + 512);
        q[s].x = b2f(qu.x); q[s].y = b2f(qu.y); q[s].z = b2f(qu.z); q[s].w = b2f(qu.w);
        k[s].x = b2f(ku.x); k[s].y = b2f(ku.y); k[s].z = b2f(ku.z); k[s].w = b2f(ku.w);
        vv[s].x = b2f(vu.x); vv[s].y = b2f(vu.y); vv[s].z = b2f(vu.z); vv[s].w = b2f(vu.w);
    }
    float sc[3][3];
#pragma unroll
    for (int s = 0; s < 3; ++s)
#pragma unroll
        for (int t = 0; t < 3; ++t) {
            float d = q[s].x * k[t].x + q[s].y * k[t].y + q[s].z * k[t].z + q[s].w * k[t].w;
            d += __shfl_xor(d, 1, 64);
            d += __shfl_xor(d, 2, 64);
            d += __shfl_xor(d, 4, 64);
            sc[s][t] = d * 0.17677669529663687f;
        }
#pragma unroll
    for (int s = 0; s < 3; ++s) {
        float m = fmaxf(sc[s][0], fmaxf(sc[s][1], sc[s][2]));
        float e0 = __expf(sc[s][0] - m), e1 = __expf(sc[s][1] - m), e2 = __expf(sc[s][2] - m);
        float iz = 1.0f / (e0 + e1 + e2);
        ushort4 ob;
        ob.x = f2b((e0 * vv[0].x + e1 * vv[1].x + e2 * vv[2].x) * iz);
        ob.y = f2b((e0 * vv[0].y + e1 * vv[1].y + e2 * vv[2].y) * iz);
        ob.z = f2b((e0 * vv[0].z + e1 * vv[1].z + e2 * vv[2].z) * iz);
        ob.w = f2b((e0 * vv[0].w + e1 * vv[1].w + e2 * vv[2].w) * iz);
        *reinterpret_cast<ushort4*>(o + ((size_t)s * kN + b) * kH + h * 32 + l8 * 4) = ob;
    }
}

// ---------------- view attention / blend ----------------

__global__ void view_comb_k(const unsigned short* __restrict__ a1b, const float* __restrict__ w0,
                            const float* __restrict__ w1, float* __restrict__ x1,
                            float* __restrict__ x2) {
    int gid = blockIdx.x * 256 + threadIdx.x;
    if (gid >= kN * 64) return;
    int n = gid >> 6;
    int c4 = (gid & 63) << 2;
    float u0 = w0[n], u1 = w0[kN + n], u2 = w0[2 * kN + n];
    float m = fmaxf(u0, fmaxf(u1, u2));
    float e0 = __expf(u0 - m), e1 = __expf(u1 - m), e2 = __expf(u2 - m);
    float iz = 1.f / (e0 + e1 + e2);
    float p0 = e0 * iz, p1 = e1 * iz, p2 = e2 * iz;
    float q0 = w1[n], q1 = w1[kN + n], q2 = w1[2 * kN + n];
    float mq = fmaxf(q0, fmaxf(q1, q2));
    float f0 = __expf(q0 - mq), f1 = __expf(q1 - mq), f2 = __expf(q2 - mq);
    float izq = 1.f / (f0 + f1 + f2);
    float r0 = f0 * izq, r1 = f1 * izq, r2 = f2 * izq;
    ushort4 U0 = *reinterpret_cast<const ushort4*>(a1b + ((size_t)0 * kN + n) * 256 + c4);
    ushort4 U1 = *reinterpret_cast<const ushort4*>(a1b + ((size_t)1 * kN + n) * 256 + c4);
    ushort4 U2 = *reinterpret_cast<const ushort4*>(a1b + ((size_t)2 * kN + n) * 256 + c4);
    float4 A0 = make_float4(b2f(U0.x), b2f(U0.y), b2f(U0.z), b2f(U0.w));
    float4 A1 = make_float4(b2f(U1.x), b2f(U1.y), b2f(U1.z), b2f(U1.w));
    float4 A2 = make_float4(b2f(U2.x), b2f(U2.y), b2f(U2.z), b2f(U2.w));
    float4 o1, o2;
    o1.x = p0 * A0.x + p1 * A1.x + p2 * A2.x;  o2.x = r0 * A0.x + r1 * A1.x + r2 * A2.x;
    o1.y = p0 * A0.y + p1 * A1.y + p2 * A2.y;  o2.y = r0 * A0.y + r1 * A1.y + r2 * A2.y;
    o1.z = p0 * A0.z + p1 * A1.z + p2 * A2.z;  o2.z = r0 * A0.z + r1 * A1.z + r2 * A2.z;
    o1.w = p0 * A0.w + p1 * A1.w + p2 * A2.w;  o2.w = r0 * A0.w + r1 * A1.w + r2 * A2.w;
    *reinterpret_cast<float4*>(x1 + (size_t)n * 256 + c4) = o1;
    *reinterpret_cast<float4*>(x2 + (size_t)n * 256 + c4) = o2;
}

__global__ __launch_bounds__(1024) void randsm_k(const float* __restrict__ rw, float* __restrict__ stats) {
    __shared__ float sm[16];
    __shared__ float ss[16];
    int tid = threadIdx.x;
    float m = -1e30f;
    for (int i = tid; i < kN; i += 1024) m = fmaxf(m, rw[i]);
#pragma unroll
    for (int off = 32; off > 0; off >>= 1) m = fmaxf(m, __shfl_xor(m, off, 64));
    if ((tid & 63) == 0) sm[tid >> 6] = m;
    __syncthreads();
    if (tid == 0) {
        float mm = sm[0];
        for (int i = 1; i < 16; ++i) mm = fmaxf(mm, sm[i]);
        sm[0] = mm;
    }
    __syncthreads();
    float mx = sm[0];
    float s = 0.f;
    for (int i = tid; i < kN; i += 1024) s += __expf(rw[i] - mx);
#pragma unroll
    for (int off = 32; off > 0; off >>= 1) s += __shfl_xor(s, off, 64);
    if ((tid & 63) == 0) ss[tid >> 6] = s;
    __syncthreads();
    if (tid == 0) {
        float z = 0.f;
        for (int i = 0; i < 16; ++i) z += ss[i];
        stats[0] = mx;
        stats[1] = z;
    }
}

__global__ void blend_k(const float* __restrict__ x1, const float* __restrict__ x2,
                        const float* __restrict__ rw, const float* __restrict__ stats,
                        float* __restrict__ g) {
    int gid = blockIdx.x * 256 + threadIdx.x;
    if (gid >= kN * 64) return;
    int n = gid >> 6;
    int c4 = (gid & 63) << 2;
    float aw = __expf(rw[n] - stats[0]) / stats[1];
    float4 v1 = *reinterpret_cast<const float4*>(x1 + (size_t)n * 256 + c4);
    float4 v2 = *reinterpret_cast<const float4*>(x2 + (size_t)n * 256 + c4);
    float4 o;
    o.x = aw * v1.x + (1.f - aw) * v2.x;
    o.y = aw * v1.y + (1.f - aw) * v2.y;
    o.z = aw * v1.z + (1.f - aw) * v2.z;
    o.w = aw * v1.w + (1.f - aw) * v2.w;
    *reinterpret_cast<float4*>(g + (size_t)n * 256 + c4) = o;
}

// ---------------- myGAT gather ----------------

__global__ __launch_bounds__(256) void mygat_gather_k(const int* __restrict__ csr, const int* __restrict__ offs,
                                                      const int* __restrict__ cnt, const float* __restrict__ el,
                                                      const float* __restrict__ er, const float* __restrict__ f,
                                                      float* __restrict__ rst) {
    int node = blockIdx.x * 8 + (threadIdx.x >> 5);
    int c = threadIdx.x & 31;
    if (node >= kN) return;
    int o0 = offs[node], n = cnt[node];
    float erd = er[node];
    float m = -1e30f;
    for (int i = 0; i < n; ++i) {
        int s = csr[o0 + i];
        m = fmaxf(m, lrelu(el[s] + erd));
    }
    float z = 0.f, acc = 0.f;
    for (int i = 0; i < n; ++i) {
        int s = csr[o0 + i];
        float e = __expf(lrelu(el[s] + erd) - m);
        z += e;
        acc += f[(size_t)s * kC + c] * e;
    }
    rst[(size_t)node * kC + c] = acc / z;
}

__global__ void final_k(const float* __restrict__ rst, const float* __restrict__ r2,
                        float* __restrict__ logits) {
    int n = blockIdx.x * 256 + threadIdx.x;
    if (n >= kN) return;
    float vals[kC];
    float ssum = 0.f;
#pragma unroll
    for (int c = 0; c < kC; ++c) {
        vals[c] = rst[(size_t)n * kC + c] + r2[(size_t)n * kC + c];
        ssum += vals[c] * vals[c];
    }
    float inv = 1.0f / fmaxf(sqrtf(ssum), 1e-12f);
#pragma unroll
    for (int c = 0; c < kC; ++c) logits[(size_t)n * kC + c] = vals[c] * inv;
}

// ---------------- host orchestration ----------------

static void run_encoder(unsigned short* xinB, float* outp, unsigned short* outB, float* ws, int e,
                        const float* bqkv, const float* bo, const float* b1, const float* b2,
                        const float* g1, const float* be1, const float* g2, const float* be2,
                        hipStream_t stream) {
    unsigned short* T2B  = (unsigned short*)(ws + OFF_T2);
    unsigned short* BIGB = (unsigned short*)(ws + OFF_BIGB);
    unsigned short* OB   = BIGB + (size_t)kMP * 768;
    unsigned short* WB   = (unsigned short*)(ws + OFF_WB);
    const unsigned short* WQ = WB + (size_t)e * 196608;
    const unsigned short* WO = WB + 393216 + (size_t)e * 65536;
    const unsigned short* W1 = WB + 524288 + (size_t)e * 262144;
    const unsigned short* W2 = WB + 1048576 + (size_t)e * 262144;
    dim3 blk(256);

    mgemm_k<0, false, true><<<dim3(6, 469, 1), blk, 0, stream>>>(
        xinB, WQ, bqkv, nullptr, BIGB, kSN, 768, 256, 0, 0, 0);
    mha3_k<<<dim3((kN * kNH) / 32), blk, 0, stream>>>(BIGB, OB);
    // o-proj -> bf16 T2B
    mgemm_k<0, false, true><<<dim3(2, 469, 1), blk, 0, stream>>>(
        OB, WO, bo, nullptr, T2B, kSN, 256, 256, 0, 0, 0);
    // h1 = LN(xin + oproj) -> bf16 in-place into xinB
    ln_add_k<false><<<dim3(kSN / 4), blk, 0, stream>>>(xinB, T2B, g1, be1, nullptr, xinB, kSN);
    mgemm_k<1, false, true><<<dim3(8, 469, 1), blk, 0, stream>>>(
        xinB, W1, b1, nullptr, BIGB, kSN, 1024, 256, 0, 0, 0);
    // ff2 -> bf16 T2B
    mgemm_k<0, false, true><<<dim3(2, 469, 1), blk, 0, stream>>>(
        BIGB, W2, b2, nullptr, T2B, kSN, 256, 1024, 0, 0, 0);
    // out = LN(h1 + ff) -> f32 outp + bf16 outB
    ln_add_k<true><<<dim3(kSN / 4), blk, 0, stream>>>(xinB, T2B, g2, be2, outp, outB, kSN);
}

extern "C" void kernel_launch(void* const* d_in, const int* in_sizes, int n_in,
                              void* d_out, int out_size, void* d_ws, size_t ws_size,
                              hipStream_t stream) {
    (void)in_sizes; (void)n_in; (void)out_size; (void)ws_size;

    const float* x      = (const float*)d_in[0];
    const int*   e_src  = (const int*)d_in[1];
    const int*   e_dst  = (const int*)d_in[2];
    const int*   gsrc   = (const int*)d_in[3];
    const int*   gdst   = (const int*)d_in[4];
    const float* rand_w = (const float*)d_in[5];
    const float* gcn_W  = (const float*)d_in[6];
    const float* gcn_b  = (const float*)d_in[7];
    const float* gat_W  = (const float*)d_in[8];
    const float* gat_as = (const float*)d_in[9];
    const float* gat_ad = (const float*)d_in[10];
    const float* gat_b  = (const float*)d_in[11];
    const float* Wqkv   = (const float*)d_in[12];
    const float* bqkv   = (const float*)d_in[13];
    const float* Wo     = (const float*)d_in[14];
    const float* bo     = (const float*)d_in[15];
    const float* W1     = (const float*)d_in[16];
    const float* b1     = (const float*)d_in[17];
    const float* W2     = (const float*)d_in[18];
    const float* b2     = (const float*)d_in[19];
    const float* ln1g   = (const float*)d_in[20];
    const float* ln1b   = (const float*)d_in[21];
    const float* ln2g   = (const float*)d_in[22];
    const float* ln2b   = (const float*)d_in[23];
    const float* att_P  = (const float*)d_in[24];
    const float* att_Pb = (const float*)d_in[25];
    const float* att_q  = (const float*)d_in[26];
    const float* mg_fc  = (const float*)d_in[27];
    const float* mg_al  = (const float*)d_in[28];
    const float* mg_ar  = (const float*)d_in[29];
    const float* mg_res = (const float*)d_in[30];

    float* ws  = (float*)d_ws;
    float* T3  = ws + OFF_T3;
    float* DNV = ws + OFF_DEG;
    float* EL  = ws + OFF_EL;
    float* ER  = ws + OFF_ER;
    float* W0b = ws + OFF_W0;
    float* W1b = ws + OFF_W1;
    float* FB  = ws + OFF_FB;
    float* R2  = ws + OFF_R2;
    float* RST = ws + OFF_RST;
    float* EL2 = ws + OFF_EL2;
    float* ER2 = ws + OFF_ER2;
    float* ST  = ws + OFF_ST;

    unsigned short* T2B  = (unsigned short*)(ws + OFF_T2);
    unsigned short* BIGB = (unsigned short*)(ws + OFF_BIGB);
    unsigned short* HB   = BIGB;
    unsigned short* SB   = (unsigned short*)(ws + OFF_SB);
    unsigned short* AB   = (unsigned short*)(ws + OFF_AB);
    unsigned short* WB   = (unsigned short*)(ws + OFF_WB);
    unsigned short* GWB  = (unsigned short*)(ws + OFF_GWB);
    unsigned short* PB   = (unsigned short*)(ws + OFF_PB);

    int* ib    = (int*)(ws + OFF_INT);
    int* CNT   = ib + ICNT;
    int* CNT2  = ib + ICNT2;
    int* OFFS  = ib + IOFF;
    int* OFFS2 = ib + IOFF2;
    int* CUR   = ib + ICUR;
    int* CUR2  = ib + ICUR2;
    int* CSR   = ib + ICSR;
    int* CSR2  = ib + ICSR2;

    float* outp   = (float*)d_out;
    float* a0     = outp;
    float* a1     = outp + (size_t)kSN * kH;
    float* logits = outp + 2 * (size_t)kSN * kH;
    float* gemb   = outp + 2 * (size_t)kSN * kH + (size_t)kN * kC;

    dim3 blk(256);

    // ---- 0a. zero pad-tail rows of bf16 GEMM-A buffers ----
    hipMemsetAsync(SB + (size_t)kSN * 256, 0, (size_t)(kMP - kSN) * 256 * sizeof(unsigned short), stream);
    hipMemsetAsync(AB + (size_t)kSN * 256, 0, (size_t)(kMP - kSN) * 256 * sizeof(unsigned short), stream);
    hipMemsetAsync(BIGB + (size_t)kSN * 1024, 0, (size_t)(kMP - kSN) * 1024 * sizeof(unsigned short), stream);

    // ---- 0b. CSR build ----
    hipMemsetAsync(CNT, 0, (size_t)(kV * kN + kN) * sizeof(int), stream);
    count_k<<<dim3((kV * kE + 255) / 256), blk, 0, stream>>>(e_dst, CNT, kE, kN, kV * kE);
    count_k<<<dim3((kE2 + 255) / 256), blk, 0, stream>>>(gdst, CNT2, kE2, kN, kE2);
    scan_k<<<dim3(kV), dim3(1024), 0, stream>>>(CNT, OFFS, CUR, kN);
    scan_k<<<dim3(1), dim3(1024), 0, stream>>>(CNT2, OFFS2, CUR2, kN);
    fill_csr_k<<<dim3((kV * kE + 255) / 256), blk, 0, stream>>>(e_src, e_dst, CUR, CSR, kE, kN, kV * kE);
    fill_csr_k<<<dim3((kE2 + 255) / 256), blk, 0, stream>>>(gsrc, gdst, CUR2, CSR2, kE2, kN, kE2);
    dinv_k<<<dim3((kV * kN + 255) / 256), blk, 0, stream>>>(CNT, DNV, kV * kN);

    // ---- 0c. weight/activation bf16 conversion ----
    cvt_k<<<dim3((393216 / 4 + 255) / 256), blk, 0, stream>>>(Wqkv, WB, 393216 / 4);
    cvt_k<<<dim3((131072 / 4 + 255) / 256), blk, 0, stream>>>(Wo, WB + 393216, 131072 / 4);
    cvt_k<<<dim3((524288 / 4 + 255) / 256), blk, 0, stream>>>(W1, WB + 524288, 524288 / 4);
    cvt_k<<<dim3((524288 / 4 + 255) / 256), blk, 0, stream>>>(W2, WB + 1048576, 524288 / 4);
    tcvt_k<<<dim3((3 * 65536 + 255) / 256), blk, 0, stream>>>(gcn_W, GWB, 256, 256, 3 * 65536);
    tcvt_k<<<dim3((3 * 65536 + 255) / 256), blk, 0, stream>>>(gat_W, GWB + 3 * 65536, 256, 256, 3 * 65536);
    tcvt_k<<<dim3((2 * 32768 + 255) / 256), blk, 0, stream>>>(att_P, PB, 256, 128, 2 * 32768);
    cvt_k<<<dim3((kSN * 256 / 4 + 255) / 256), blk, 0, stream>>>(x, AB, kSN * 256 / 4);

    // ---- 1. multi-view GCN + relu -> SB (bf16) ----
    mgemm_k<0, false, true><<<dim3(2, 157, 3), blk, 0, stream>>>(
        AB, GWB, nullptr, nullptr, HB, kN, 256, 256, (long)kN * 256, 65536, kN);
    gcn_gather_k<<<dim3(kSN / 4), blk, 0, stream>>>(CSR, OFFS, CNT, DNV, HB, gcn_b, SB);

    // ---- 2. encoder 0 -> a0 f32 + AB bf16 ----
    run_encoder(SB, a0, AB, ws, 0, bqkv, bo, b1, b2, ln1g, ln1b, ln2g, ln2b, stream);

    // ---- 3. multi-view GAT + relu -> SB (bf16) ----
    mgemm_k<0, false, true><<<dim3(2, 157, 3), blk, 0, stream>>>(
        AB, GWB + 3 * 65536, nullptr, nullptr, HB, kN, 256, 256, (long)kN * 256, 65536, kN);
    rowdot2b_k<<<dim3(kSN), dim3(64), 0, stream>>>(HB, gat_as, gat_ad, EL, ER, kSN, 256, kN, kH);
    gat_gather_k<<<dim3(kSN / 4), blk, 0, stream>>>(CSR, OFFS, CNT, EL, ER, HB, gat_b, SB);

    // ---- 4. encoder 1 -> a1 f32 + AB bf16 ----
    run_encoder(SB, a1, AB, ws, 1, bqkv + 768, bo + 256, b1 + 1024, b2 + 256,
                ln1g + 256, ln1b + 256, ln2g + 256, ln2b + 256, stream);

    // ---- 5. view attention + blend -> gemb ----
    mgemm_k<3, false, true><<<dim3(2, 469, 1), blk, 0, stream>>>(
        AB, PB, att_Pb, nullptr, T2B, kSN, 256, 256, 0, 0, 0);
    attdot_k<<<dim3(kSN / 4), blk, 0, stream>>>(T2B, att_q, W0b, W1b, kSN);
    float* X1 = T3;
    float* X2 = T3 + (size_t)kN * kH;
    view_comb_k<<<dim3((kN * 64 + 255) / 256), blk, 0, stream>>>(AB, W0b, W1b, X1, X2);
    randsm_k<<<dim3(1), dim3(1024), 0, stream>>>(rand_w, ST);
    blend_k<<<dim3((kN * 64 + 255) / 256), blk, 0, stream>>>(X1, X2, rand_w, ST, gemb);

    // ---- 6. myGATConv -> logits ----
    gemm_k<0><<<dim3(1, (kN + 63) / 64), blk, 0, stream>>>(gemb, mg_fc, (const float*)nullptr, FB, kN, kC, 256);
    rowdot2_k<<<dim3(kN), dim3(64), 0, stream>>>(FB, mg_al, mg_ar, EL2, ER2, kN, kC, kN, 0);
    mygat_gather_k<<<dim3((kN + 7) / 8), blk, 0, stream>>>(CSR2, OFFS2, CNT2, EL2, ER2, FB, RST);
    gemm_k<0><<<dim3(1, (kN + 63) / 64), blk, 0, stream>>>(gemb, mg_res, (const float*)nullptr, R2, kN, kC, 256);
    final_k<<<dim3((kN + 255) / 256), blk, 0, stream>>>(RST, R2, logits);
}

// Round 12
// 983.920 us; speedup vs baseline: 1.5294x; 1.1057x over previous
//
#include <hip/hip_runtime.h>
#include <hip/hip_bf16.h>
#include <math.h>

// ---------------- problem constants ----------------
namespace {
constexpr int kV  = 3;
constexpr int kN  = 20000;
constexpr int kF  = 256;
constexpr int kH  = 256;
constexpr int kE  = 160000;
constexpr int kC  = 32;
constexpr int kNH = 8;
constexpr int kSN = kV * kN;     // 60000
constexpr int kE2 = kE + kN;     // 180000
constexpr int kMP = 60160;       // padded rows for bf16 GEMM-A buffers

// fp32 workspace layout (float element offsets)
constexpr size_t OFF_T1   = 0;                                   // (spare)
constexpr size_t OFF_T2   = OFF_T1 + (size_t)kMP * 256;          // bf16 T2B
constexpr size_t OFF_T3   = OFF_T2 + (size_t)kMP * 256;          // f32 X1/X2 blend buffers
constexpr size_t OFF_BIGB = OFF_T3 + (size_t)kMP * 256;          // bf16 [kMP*1024]
constexpr size_t OFF_SB   = OFF_BIGB + (size_t)kMP * 512;        // bf16 [kMP*256]
constexpr size_t OFF_AB   = OFF_SB + (size_t)kMP * 128;          // bf16 [kMP*256]
constexpr size_t OFF_WB   = OFF_AB + (size_t)kMP * 128;          // bf16 enc weights
constexpr size_t OFF_GWB  = OFF_WB + 786432;
constexpr size_t OFF_PB   = OFF_GWB + 196608;
constexpr size_t OFF_DEG  = OFF_PB + 32768;
constexpr size_t OFF_EL   = OFF_DEG + (size_t)kV * kN;
constexpr size_t OFF_ER   = OFF_EL  + (size_t)kV * kN;
constexpr size_t OFF_W0   = OFF_ER  + (size_t)kV * kN;
constexpr size_t OFF_W1   = OFF_W0  + (size_t)kV * kN;
constexpr size_t OFF_FB   = OFF_W1  + (size_t)kV * kN;
constexpr size_t OFF_R2   = OFF_FB  + (size_t)kN * kC;
constexpr size_t OFF_RST  = OFF_R2  + (size_t)kN * kC;
constexpr size_t OFF_EL2  = OFF_RST + (size_t)kN * kC;
constexpr size_t OFF_ER2  = OFF_EL2 + kN;
constexpr size_t OFF_ST   = OFF_ER2 + kN;
constexpr size_t OFF_INT  = OFF_ST + 4;
// int layout
constexpr size_t ICNT  = 0;
constexpr size_t ICNT2 = ICNT  + (size_t)kV * kN;
constexpr size_t IOFF  = ICNT2 + kN;
constexpr size_t IOFF2 = IOFF  + (size_t)kV * kN;
constexpr size_t ICUR  = IOFF2 + kN;
constexpr size_t ICUR2 = ICUR  + (size_t)kV * kN;
constexpr size_t ICSR  = ICUR2 + kN;
constexpr size_t ICSR2 = ICSR  + (size_t)kV * kE;
} // namespace

typedef __attribute__((ext_vector_type(4))) float f32x4;
typedef __attribute__((ext_vector_type(8))) __bf16 bf16x8;

__device__ __forceinline__ float lrelu(float x) { return x > 0.f ? x : 0.2f * x; }
__device__ __forceinline__ unsigned short f2b(float f) {
    unsigned u = __float_as_uint(f);
    return (unsigned short)((u + 0x7FFFu + ((u >> 16) & 1u)) >> 16);
}
__device__ __forceinline__ float b2f(unsigned short h) {
    return __uint_as_float((unsigned)h << 16);
}
// tanh via HW exp: tanh(x) = (e^{2x}-1)/(e^{2x}+1), clamped
__device__ __forceinline__ float fast_tanh(float x) {
    float xc = fminf(fmaxf(x, -15.f), 15.f);
    float e = __expf(2.0f * xc);
    return (e - 1.0f) / (e + 1.0f);
}

// ---------------- conversion kernels ----------------

__global__ void cvt_k(const float* __restrict__ in, unsigned short* __restrict__ out, int n4) {
    int i = blockIdx.x * 256 + threadIdx.x;
    if (i >= n4) return;
    float4 v = reinterpret_cast<const float4*>(in)[i];
    ushort4 o;
    o.x = f2b(v.x); o.y = f2b(v.y); o.z = f2b(v.z); o.w = f2b(v.w);
    reinterpret_cast<ushort4*>(out)[i] = o;
}

__global__ void tcvt_k(const float* __restrict__ in, unsigned short* __restrict__ out,
                       int K, int N, int total) {
    int gid = blockIdx.x * 256 + threadIdx.x;
    if (gid >= total) return;
    int per = K * N;
    int v = gid / per, r = gid - v * per;
    int n = r / K, k = r - n * K;
    out[gid] = f2b(in[(size_t)v * per + (size_t)k * N + n]);
}

// ---------------- MFMA bf16 GEMM: double-buffered staging + coalesced epilogue ----------------
// C[M,N] = act(A[M,K] @ W[N,K]^T + bias). 128x128 tile, BK=32, 4 waves, 2-phase dbuf.
// __launch_bounds__(256,4): cap regs at 128/thread -> target 4 blocks/CU (was ~3).
// ACT: 0 none, 1 relu, 2 tanh, 3 split (global col<128 tanh else relu).
template <int ACT, bool WF32, bool WB16>
__global__ __launch_bounds__(256, 4) void mgemm_k(const unsigned short* __restrict__ A,
                                                  const unsigned short* __restrict__ W,
                                                  const float* __restrict__ bias,
                                                  float* __restrict__ Cf,
                                                  unsigned short* __restrict__ Cb,
                                                  int M, int N, int K,
                                                  long zA, long zW, long zC) {
    static_assert(WF32 != WB16, "exactly one output path");
    __shared__ __align__(16) unsigned short shbuf[16384];   // 2 x (As 8KB + Ws 8KB); epilogue reuses

    const int tid  = threadIdx.x;
    const int lane = tid & 63;

    // bijective XCD-chunked swizzle of the (x,y) tile index (m204)
    const int gx = gridDim.x;
    const int nwg = gx * gridDim.y;
    const int orig = blockIdx.y * gx + blockIdx.x;
    const int q = nwg >> 3, rr = nwg & 7;
    const int xcd = orig & 7, pos = orig >> 3;
    const int nid = (xcd < rr ? xcd * (q + 1) : rr * (q + 1) + (xcd - rr) * q) + pos;
    const int bm = (nid / gx) * 128, bn = (nid % gx) * 128;

    A += (size_t)blockIdx.z * zA;
    W += (size_t)blockIdx.z * zW;
    const size_t zrow = (size_t)blockIdx.z * zC;

    const int wv = tid >> 6;
    const int wm = (wv >> 1) * 64, wn = (wv & 1) * 64;
    const int fr = lane & 15;
    const int fk = (lane >> 4) * 8;

    const int r0 = tid >> 2, sl0 = (tid & 3) * 8;
    const int r1 = (256 + tid) >> 2, sl1 = ((256 + tid) & 3) * 8;

    f32x4 acc[4][4] = {};

    // prologue: stage tile 0 into buffer 0
    {
        unsigned short* As = shbuf;
        unsigned short* Ws = shbuf + 4096;
        __builtin_amdgcn_global_load_lds((const __attribute__((address_space(1))) void*)(A + (size_t)(bm + r0) * K + sl0),
                                         (__attribute__((address_space(3))) void*)(As + tid * 8), 16, 0, 0);
        __builtin_amdgcn_global_load_lds((const __attribute__((address_space(1))) void*)(W + (size_t)(bn + r0) * K + sl0),
                                         (__attribute__((address_space(3))) void*)(Ws + tid * 8), 16, 0, 0);
        __builtin_amdgcn_global_load_lds((const __attribute__((address_space(1))) void*)(A + (size_t)(bm + r1) * K + sl1),
                                         (__attribute__((address_space(3))) void*)(As + (256 + tid) * 8), 16, 0, 0);
        __builtin_amdgcn_global_load_lds((const __attribute__((address_space(1))) void*)(W + (size_t)(bn + r1) * K + sl1),
                                         (__attribute__((address_space(3))) void*)(Ws + (256 + tid) * 8), 16, 0, 0);
    }
    __syncthreads();

    int cur = 0;
    for (int k0 = 0; k0 < K; k0 += 32) {
        if (k0 + 32 < K) {
            // issue next-tile loads into the other buffer (overlaps with this tile's compute)
            unsigned short* As = shbuf + (cur ^ 1) * 8192;
            unsigned short* Ws = As + 4096;
            const int kn = k0 + 32;
            __builtin_amdgcn_global_load_lds((const __attribute__((address_space(1))) void*)(A + (size_t)(bm + r0) * K + kn + sl0),
                                             (__attribute__((address_space(3))) void*)(As + tid * 8), 16, 0, 0);
            __builtin_amdgcn_global_load_lds((const __attribute__((address_space(1))) void*)(W + (size_t)(bn + r0) * K + kn + sl0),
                                             (__attribute__((address_space(3))) void*)(Ws + tid * 8), 16, 0, 0);
            __builtin_amdgcn_global_load_lds((const __attribute__((address_space(1))) void*)(A + (size_t)(bm + r1) * K + kn + sl1),
                                             (__attribute__((address_space(3))) void*)(As + (256 + tid) * 8), 16, 0, 0);
            __builtin_amdgcn_global_load_lds((const __attribute__((address_space(1))) void*)(W + (size_t)(bn + r1) * K + kn + sl1),
                                             (__attribute__((address_space(3))) void*)(Ws + (256 + tid) * 8), 16, 0, 0);
        }
        const unsigned short* As = shbuf + cur * 8192;
        const unsigned short* Ws = As + 4096;
        bf16x8 av[4], bv[4];
#pragma unroll
        for (int mi = 0; mi < 4; ++mi)
            av[mi] = *reinterpret_cast<const bf16x8*>(As + (wm + mi * 16 + fr) * 32 + fk);
#pragma unroll
        for (int ni = 0; ni < 4; ++ni)
            bv[ni] = *reinterpret_cast<const bf16x8*>(Ws + (wn + ni * 16 + fr) * 32 + fk);
#pragma unroll
        for (int mi = 0; mi < 4; ++mi)
#pragma unroll
            for (int ni = 0; ni < 4; ++ni)
                acc[mi][ni] = __builtin_amdgcn_mfma_f32_16x16x32_bf16(av[mi], bv[ni], acc[mi][ni], 0, 0, 0);
        __syncthreads();   // drains next-tile loads (in flight during MFMA) + this tile's ds_reads
        cur ^= 1;
    }

    const int crow = (lane >> 4) * 4;
    const int ccol = lane & 15;

    if (WB16) {
#pragma unroll
        for (int mi = 0; mi < 4; ++mi)
#pragma unroll
            for (int r = 0; r < 4; ++r) {
                const int row = wm + mi * 16 + crow + r;
#pragma unroll
                for (int ni = 0; ni < 4; ++ni) {
                    const int col = wn + ni * 16 + ccol;
                    float v = acc[mi][ni][r];
                    if (bias) v += bias[bn + col];
                    if (ACT == 1) v = fmaxf(v, 0.f);
                    if (ACT == 2) v = fast_tanh(v);
                    if (ACT == 3) v = (bn + col < 128) ? fast_tanh(v) : fmaxf(v, 0.f);
                    shbuf[row * 128 + col] = f2b(v);
                }
            }
        __syncthreads();
#pragma unroll
        for (int it = 0; it < 8; ++it) {
            const int fl = it * 2048 + tid * 8;
            const int row = fl >> 7, col = fl & 127;
            const int grow = bm + row;
            if (grow < M) {
                uint4 d = *reinterpret_cast<const uint4*>(shbuf + row * 128 + col);
                *reinterpret_cast<uint4*>(Cb + (zrow + grow) * (size_t)N + bn + col) = d;
            }
        }
    } else {
        float* epf = reinterpret_cast<float*>(shbuf);
#pragma unroll
        for (int half = 0; half < 2; ++half) {
            if ((wm >> 6) == half) {
#pragma unroll
                for (int mi = 0; mi < 4; ++mi)
#pragma unroll
                    for (int r = 0; r < 4; ++r) {
                        const int row = mi * 16 + crow + r;
#pragma unroll
                        for (int ni = 0; ni < 4; ++ni) {
                            const int col = wn + ni * 16 + ccol;
                            float v = acc[mi][ni][r];
                            if (bias) v += bias[bn + col];
                            if (ACT == 1) v = fmaxf(v, 0.f);
                            if (ACT == 2) v = fast_tanh(v);
                            if (ACT == 3) v = (bn + col < 128) ? fast_tanh(v) : fmaxf(v, 0.f);
                            epf[row * 128 + col] = v;
                        }
                    }
            }
            __syncthreads();
#pragma unroll
            for (int it = 0; it < 8; ++it) {
                const int fl = it * 1024 + tid * 4;
                const int row = fl >> 7, col = fl & 127;
                const int grow = bm + half * 64 + row;
                if (grow < M) {
                    float4 d = *reinterpret_cast<const float4*>(epf + row * 128 + col);
                    *reinterpret_cast<float4*>(Cf + (zrow + grow) * (size_t)N + bn + col) = d;
                }
            }
            __syncthreads();
        }
    }
}

// ---------------- fp32 GEMM (N=32 tail) ----------------
template <int ACT>
__global__ __launch_bounds__(256) void gemm_k(const float* __restrict__ A,
                                              const float* __restrict__ B,
                                              const float* __restrict__ bias,
                                              float* __restrict__ Cmat,
                                              int M, int Nn, int K) {
    __shared__ float As[16][64];
    __shared__ float Bs[16][68];
    const int tid  = threadIdx.x;
    const int bm   = blockIdx.y * 64;
    const int bn   = blockIdx.x * 64;
    const int tx   = tid & 15, ty = tid >> 4;
    const int arow = tid >> 2;
    const int acol = (tid & 3) << 2;
    const int brow = tid >> 4;
    const int bcol = (tid & 15) << 2;
    const int gm   = bm + arow;
    float acc[4][4] = {{0.f,0.f,0.f,0.f},{0.f,0.f,0.f,0.f},{0.f,0.f,0.f,0.f},{0.f,0.f,0.f,0.f}};

    for (int k0 = 0; k0 < K; k0 += 16) {
        float4 av = make_float4(0.f, 0.f, 0.f, 0.f);
        if (gm < M) av = *reinterpret_cast<const float4*>(A + (size_t)gm * K + (k0 + acol));
        As[acol + 0][arow] = av.x;
        As[acol + 1][arow] = av.y;
        As[acol + 2][arow] = av.z;
        As[acol + 3][arow] = av.w;

        const int gn = bn + bcol;
        const float* Brow = B + (size_t)(k0 + brow) * Nn;
        float4 bv;
        if (gn + 3 < Nn) {
            bv = *reinterpret_cast<const float4*>(Brow + gn);
        } else {
            bv.x = (gn + 0 < Nn) ? Brow[gn + 0] : 0.f;
            bv.y = (gn + 1 < Nn) ? Brow[gn + 1] : 0.f;
            bv.z = (gn + 2 < Nn) ? Brow[gn + 2] : 0.f;
            bv.w = (gn + 3 < Nn) ? Brow[gn + 3] : 0.f;
        }
        *reinterpret_cast<float4*>(&Bs[brow][bcol]) = bv;
        __syncthreads();

#pragma unroll
        for (int k = 0; k < 16; ++k) {
            float4 a4 = *reinterpret_cast<const float4*>(&As[k][ty << 2]);
            float4 b4 = *reinterpret_cast<const float4*>(&Bs[k][tx << 2]);
            acc[0][0] += a4.x * b4.x; acc[0][1] += a4.x * b4.y; acc[0][2] += a4.x * b4.z; acc[0][3] += a4.x * b4.w;
            acc[1][0] += a4.y * b4.x; acc[1][1] += a4.y * b4.y; acc[1][2] += a4.y * b4.z; acc[1][3] += a4.y * b4.w;
            acc[2][0] += a4.z * b4.x; acc[2][1] += a4.z * b4.y; acc[2][2] += a4.z * b4.z; acc[2][3] += a4.z * b4.w;
            acc[3][0] += a4.w * b4.x; acc[3][1] += a4.w * b4.y; acc[3][2] += a4.w * b4.z; acc[3][3] += a4.w * b4.w;
        }
        __syncthreads();
    }

#pragma unroll
    for (int i = 0; i < 4; ++i) {
        int m = bm + (ty << 2) + i;
        if (m >= M) continue;
#pragma unroll
        for (int j = 0; j < 4; ++j) {
            int n = bn + (tx << 2) + j;
            if (n >= Nn) continue;
            float v = acc[i][j];
            if (bias) v += bias[n];
            if (ACT == 1) v = fmaxf(v, 0.f);
            if (ACT == 2) v = fast_tanh(v);
            Cmat[(size_t)m * Nn + n] = v;
        }
    }
}

// out = LN(x+y)*g+b; wave per row; x,y bf16 ushort4/lane; WF32: also write f32.
// In-place x==outb is safe (each wave owns its row; reads precede writes).
template <bool WF32>
__global__ __launch_bounds__(256) void ln_add_k(const unsigned short* __restrict__ x,
                                                const unsigned short* __restrict__ y,
                                                const float* __restrict__ g, const float* __restrict__ b,
                                                float* __restrict__ outf, unsigned short* __restrict__ outb,
                                                int rows) {
    int r = blockIdx.x * 4 + (threadIdx.x >> 6);
    if (r >= rows) return;
    int lane = threadIdx.x & 63;
    size_t base = (size_t)r * 256 + lane * 4;
    ushort4 xu = *reinterpret_cast<const ushort4*>(x + base);
    ushort4 yu = *reinterpret_cast<const ushort4*>(y + base);
    float4 t;
    t.x = b2f(xu.x) + b2f(yu.x); t.y = b2f(xu.y) + b2f(yu.y);
    t.z = b2f(xu.z) + b2f(yu.z); t.w = b2f(xu.w) + b2f(yu.w);
    float s = t.x + t.y + t.z + t.w;
#pragma unroll
    for (int off = 32; off > 0; off >>= 1) s += __shfl_xor(s, off, 64);
    float mean = s * (1.0f / 256.0f);
    float4 d;
    d.x = t.x - mean; d.y = t.y - mean; d.z = t.z - mean; d.w = t.w - mean;
    float s2 = d.x * d.x + d.y * d.y + d.z * d.z + d.w * d.w;
#pragma unroll
    for (int off = 32; off > 0; off >>= 1) s2 += __shfl_xor(s2, off, 64);
    float rs = rsqrtf(s2 * (1.0f / 256.0f) + 1e-5f);
    float4 gv = *reinterpret_cast<const float4*>(g + lane * 4);
    float4 bv = *reinterpret_cast<const float4*>(b + lane * 4);
    float4 o;
    o.x = d.x * rs * gv.x + bv.x;
    o.y = d.y * rs * gv.y + bv.y;
    o.z = d.z * rs * gv.z + bv.z;
    o.w = d.w * rs * gv.w + bv.w;
    if (WF32) *reinterpret_cast<float4*>(outf + base) = o;
    ushort4 ob;
    ob.x = f2b(o.x); ob.y = f2b(o.y); ob.z = f2b(o.z); ob.w = f2b(o.w);
    *reinterpret_cast<ushort4*>(outb + base) = ob;
}

// per-row dual dot products, fp32 A
__global__ void rowdot2_k(const float* __restrict__ A, const float* __restrict__ v1,
                          const float* __restrict__ v2, float* __restrict__ o1,
                          float* __restrict__ o2, int rows, int K, int rowsPerVec, int vecStride) {
    int r = blockIdx.x;
    if (r >= rows) return;
    int lane = threadIdx.x;
    const float* base = A + (size_t)r * K;
    int vo = (r / rowsPerVec) * vecStride;
    float s1 = 0.f, s2 = 0.f;
    for (int c = lane; c < K; c += 64) {
        float a = base[c];
        s1 += a * v1[vo + c];
        if (v2) s2 += a * v2[vo + c];
    }
#pragma unroll
    for (int off = 32; off > 0; off >>= 1) {
        s1 += __shfl_xor(s1, off, 64);
        s2 += __shfl_xor(s2, off, 64);
    }
    if (lane == 0) { o1[r] = s1; if (o2) o2[r] = s2; }
}

// fused dual 128-dot from bf16 [rows][256]
__global__ __launch_bounds__(256) void attdot_k(const unsigned short* __restrict__ A, const float* __restrict__ q,
                                                float* __restrict__ o1, float* __restrict__ o2, int rows) {
    int r = blockIdx.x * 4 + (threadIdx.x >> 6);
    if (r >= rows) return;
    int lane = threadIdx.x & 63;
    const unsigned short* row = A + (size_t)r * 256;
    ushort2 va = *reinterpret_cast<const ushort2*>(row + lane * 2);
    ushort2 vb = *reinterpret_cast<const ushort2*>(row + 128 + lane * 2);
    float2 qa = *reinterpret_cast<const float2*>(q + lane * 2);
    float2 qb = *reinterpret_cast<const float2*>(q + 128 + lane * 2);
    float s1 = b2f(va.x) * qa.x + b2f(va.y) * qa.y;
    float s2 = b2f(vb.x) * qb.x + b2f(vb.y) * qb.y;
#pragma unroll
    for (int off = 32; off > 0; off >>= 1) {
        s1 += __shfl_xor(s1, off, 64);
        s2 += __shfl_xor(s2, off, 64);
    }
    if (lane == 0) { o1[r] = s1; o2[r] = s2; }
}

// per-row dual dot products, bf16 A, ushort4 per lane
__global__ void rowdot2b_k(const unsigned short* __restrict__ A, const float* __restrict__ v1,
                           const float* __restrict__ v2, float* __restrict__ o1,
                           float* __restrict__ o2, int rows, int K, int rowsPerVec, int vecStride) {
    int r = blockIdx.x;
    if (r >= rows) return;
    int lane = threadIdx.x;
    const unsigned short* base = A + (size_t)r * K;
    int vo = (r / rowsPerVec) * vecStride;
    float s1 = 0.f, s2 = 0.f;
    for (int c = lane * 4; c < K; c += 256) {
        ushort4 a4 = *reinterpret_cast<const ushort4*>(base + c);
        float4 w1 = *reinterpret_cast<const float4*>(v1 + vo + c);
        float4 w2 = *reinterpret_cast<const float4*>(v2 + vo + c);
        s1 += b2f(a4.x) * w1.x + b2f(a4.y) * w1.y + b2f(a4.z) * w1.z + b2f(a4.w) * w1.w;
        s2 += b2f(a4.x) * w2.x + b2f(a4.y) * w2.y + b2f(a4.z) * w2.z + b2f(a4.w) * w2.w;
    }
#pragma unroll
    for (int off = 32; off > 0; off >>= 1) {
        s1 += __shfl_xor(s1, off, 64);
        s2 += __shfl_xor(s2, off, 64);
    }
    if (lane == 0) { o1[r] = s1; o2[r] = s2; }
}

// ---------------- CSR build ----------------

__global__ void count_k(const int* __restrict__ dst, int* __restrict__ cnt, int nE, int nN, int total) {
    int gid = blockIdx.x * 256 + threadIdx.x;
    if (gid >= total) return;
    int v = gid / nE;
    atomicAdd(&cnt[(size_t)v * nN + dst[gid]], 1);
}

__global__ __launch_bounds__(1024) void scan_k(const int* __restrict__ cnt, int* __restrict__ offs,
                                               int* __restrict__ cursor, int nN) {
    int v = blockIdx.x;
    const int* c = cnt + (size_t)v * nN;
    int* o  = offs + (size_t)v * nN;
    int* cu = cursor + (size_t)v * nN;
    int tid = threadIdx.x;
    int chunk = (nN + 1023) >> 10;
    int lo = tid * chunk;
    int hi = lo + chunk < nN ? lo + chunk : nN;
    int s = 0;
    for (int i = lo; i < hi; ++i) s += c[i];
    int lane = tid & 63, wid = tid >> 6;
    int x = s;
#pragma unroll
    for (int off = 1; off < 64; off <<= 1) {
        int y = __shfl_up(x, off, 64);
        if (lane >= off) x += y;
    }
    __shared__ int wsum[16];
    if (lane == 63) wsum[wid] = x;
    __syncthreads();
    if (tid == 0) {
        int a = 0;
        for (int w = 0; w < 16; ++w) { int t = wsum[w]; wsum[w] = a; a += t; }
    }
    __syncthreads();
    int base = x - s + wsum[wid];
    for (int i = lo; i < hi; ++i) { o[i] = base; cu[i] = base; base += c[i]; }
}

__global__ void fill_csr_k(const int* __restrict__ src, const int* __restrict__ dst,
                           int* __restrict__ cursor, int* __restrict__ csr,
                           int nE, int nN, int total) {
    int gid = blockIdx.x * 256 + threadIdx.x;
    if (gid >= total) return;
    int v = gid / nE;
    int pos = atomicAdd(&cursor[(size_t)v * nN + dst[gid]], 1);
    csr[(size_t)v * nE + pos] = src[gid];
}

__global__ void dinv_k(const int* __restrict__ cnt, float* __restrict__ dinv, int n) {
    int gid = blockIdx.x * 256 + threadIdx.x;
    if (gid < n) dinv[gid] = rsqrtf((float)cnt[gid] + 1.0f);
}

// ---------------- GCN gather: one WAVE per node, LDS-free, ushort4/lane; bf16 out only ----------------

__global__ __launch_bounds__(256) void gcn_gather_k(const int* __restrict__ csr, const int* __restrict__ offs,
                                                    const int* __restrict__ cnt, const float* __restrict__ dinv,
                                                    const unsigned short* __restrict__ h, const float* __restrict__ b,
                                                    unsigned short* __restrict__ outb) {
    int nd = blockIdx.x * 4 + (threadIdx.x >> 6);
    if (nd >= kV * kN) return;
    int v  = nd / kN;
    int lane = threadIdx.x & 63;
    int c4 = lane * 4;
    const int* base = csr + (size_t)v * kE;
    int o0 = offs[nd], n = cnt[nd];
    float dd = dinv[nd];
    const float* dv = dinv + (size_t)v * kN;
    const unsigned short* hb = h + (size_t)v * kN * kH;

    ushort4 hs = *reinterpret_cast<const ushort4*>(h + (size_t)nd * kH + c4);
    float wts = dd * dd;
    float4 acc;
    acc.x = b2f(hs.x) * wts; acc.y = b2f(hs.y) * wts;
    acc.z = b2f(hs.z) * wts; acc.w = b2f(hs.w) * wts;
    int i = 0;
    for (; i + 2 <= n; i += 2) {
        int s0 = base[o0 + i], s1 = base[o0 + i + 1];
        float w0 = dv[s0] * dd, w1 = dv[s1] * dd;
        ushort4 h0 = *reinterpret_cast<const ushort4*>(hb + (size_t)s0 * kH + c4);
        ushort4 h1 = *reinterpret_cast<const ushort4*>(hb + (size_t)s1 * kH + c4);
        acc.x += b2f(h0.x) * w0 + b2f(h1.x) * w1;
        acc.y += b2f(h0.y) * w0 + b2f(h1.y) * w1;
        acc.z += b2f(h0.z) * w0 + b2f(h1.z) * w1;
        acc.w += b2f(h0.w) * w0 + b2f(h1.w) * w1;
    }
    if (i < n) {
        int s0 = base[o0 + i];
        float w0 = dv[s0] * dd;
        ushort4 h0 = *reinterpret_cast<const ushort4*>(hb + (size_t)s0 * kH + c4);
        acc.x += b2f(h0.x) * w0; acc.y += b2f(h0.y) * w0;
        acc.z += b2f(h0.z) * w0; acc.w += b2f(h0.w) * w0;
    }
    float4 bb = *reinterpret_cast<const float4*>(b + (size_t)v * kH + c4);
    ushort4 ob;
    ob.x = f2b(fmaxf(acc.x + bb.x, 0.f));
    ob.y = f2b(fmaxf(acc.y + bb.y, 0.f));
    ob.z = f2b(fmaxf(acc.z + bb.z, 0.f));
    ob.w = f2b(fmaxf(acc.w + bb.w, 0.f));
    *reinterpret_cast<ushort4*>(outb + (size_t)nd * kH + c4) = ob;
}

// ---------------- GAT gather: one WAVE per node, LDS-free; bf16 out only ----------------

__global__ __launch_bounds__(256) void gat_gather_k(const int* __restrict__ csr, const int* __restrict__ offs,
                                                    const int* __restrict__ cnt, const float* __restrict__ el,
                                                    const float* __restrict__ er, const unsigned short* __restrict__ h,
                                                    const float* __restrict__ b, unsigned short* __restrict__ outb) {
    int nd = blockIdx.x * 4 + (threadIdx.x >> 6);
    if (nd >= kV * kN) return;
    int v  = nd / kN;
    int lane = threadIdx.x & 63;
    int c4 = lane * 4;
    const int* base = csr + (size_t)v * kE;
    int o0 = offs[nd], n = cnt[nd];
    float erd = er[nd];
    const float* elv = el + (size_t)v * kN;
    const unsigned short* hb = h + (size_t)v * kN * kH;
    float eself = lrelu(el[nd] + erd);

    float m = eself;
    for (int i = 0; i < n; ++i) m = fmaxf(m, lrelu(elv[base[o0 + i]] + erd));

    float es = __expf(eself - m);
    float z = es;
    ushort4 hs = *reinterpret_cast<const ushort4*>(h + (size_t)nd * kH + c4);
    float4 acc;
    acc.x = b2f(hs.x) * es; acc.y = b2f(hs.y) * es;
    acc.z = b2f(hs.z) * es; acc.w = b2f(hs.w) * es;
    int i = 0;
    for (; i + 2 <= n; i += 2) {
        int s0 = base[o0 + i], s1 = base[o0 + i + 1];
        float e0 = __expf(lrelu(elv[s0] + erd) - m);
        float e1 = __expf(lrelu(elv[s1] + erd) - m);
        z += e0 + e1;
        ushort4 h0 = *reinterpret_cast<const ushort4*>(hb + (size_t)s0 * kH + c4);
        ushort4 h1 = *reinterpret_cast<const ushort4*>(hb + (size_t)s1 * kH + c4);
        acc.x += b2f(h0.x) * e0 + b2f(h1.x) * e1;
        acc.y += b2f(h0.y) * e0 + b2f(h1.y) * e1;
        acc.z += b2f(h0.z) * e0 + b2f(h1.z) * e1;
        acc.w += b2f(h0.w) * e0 + b2f(h1.w) * e1;
    }
    if (i < n) {
        int s0 = base[o0 + i];
        float e0 = __expf(lrelu(elv[s0] + erd) - m);
        z += e0;
        ushort4 h0 = *reinterpret_cast<const ushort4*>(hb + (size_t)s0 * kH + c4);
        acc.x += b2f(h0.x) * e0; acc.y += b2f(h0.y) * e0;
        acc.z += b2f(h0.z) * e0; acc.w += b2f(h0.w) * e0;
    }
    float iz = 1.0f / z;
    float4 bb = *reinterpret_cast<const float4*>(b + (size_t)v * kH + c4);
    ushort4 ob;
    ob.x = f2b(fmaxf(acc.x * iz + bb.x, 0.f));
    ob.y = f2b(fmaxf(acc.y * iz + bb.y, 0.f));
    ob.z = f2b(fmaxf(acc.z * iz + bb.z, 0.f));
    ob.w = f2b(fmaxf(acc.w * iz + bb.w, 0.f));
    *reinterpret_cast<ushort4*>(outb + (size_t)nd * kH + c4) = ob;
}

// ---------------- transformer: 3x3 attention, 8 lanes per (node,head), ushort4 ----------------

__global__ __launch_bounds__(256) void mha3_k(const unsigned short* __restrict__ qkv, unsigned short* __restrict__ o) {
    int grp = blockIdx.x * 32 + (threadIdx.x >> 3);
    int l8 = threadIdx.x & 7;
    if (grp >= kN * kNH) return;
    int b = grp / kNH, h = grp - b * kNH;
    float4 q[3], k[3], vv[3];
#pragma unroll
    for (int s = 0; s < 3; ++s) {
        size_t base = ((size_t)s * kN + b) * 768 + h * 32 + l8 * 4;
        ushort4 qu = *reinterpret_cast<const ushort4*>(qkv + base);
        ushort4 ku = *reinterpret_cast<const ushort4*>(qkv + base + 256);
        ushort4 vu = *reinterpret_cast<const ushort4*>(qkv + base + 512);
        q[s].x = b2f(qu.x); q[s].y = b2f(qu.y); q[s].z = b2f(qu.z); q[s].w = b2f(qu.w);
        k[s].x = b2f(ku.x); k[s].y = b2f(ku.y); k[s].z = b2f(ku.z); k[s].w = b2f(ku.w);
        vv[s].x = b2f(vu.x); vv[s].y = b2f(vu.y); vv[s].z = b2f(vu.z); vv[s].w = b2f(vu.w);
    }
    float sc[3][3];
#pragma unroll
    for (int s = 0; s < 3; ++s)
#pragma unroll
        for (int t = 0; t < 3; ++t) {
            float d = q[s].x * k[t].x + q[s].y * k[t].y + q[s].z * k[t].z + q[s].w * k[t].w;
            d += __shfl_xor(d, 1, 64);
            d += __shfl_xor(d, 2, 64);
            d += __shfl_xor(d, 4, 64);
            sc[s][t] = d * 0.17677669529663687f;
        }
#pragma unroll
    for (int s = 0; s < 3; ++s) {
        float m = fmaxf(sc[s][0], fmaxf(sc[s][1], sc[s][2]));
        float e0 = __expf(sc[s][0] - m), e1 = __expf(sc[s][1] - m), e2 = __expf(sc[s][2] - m);
        float iz = 1.0f / (e0 + e1 + e2);
        ushort4 ob;
        ob.x = f2b((e0 * vv[0].x + e1 * vv[1].x + e2 * vv[2].x) * iz);
        ob.y = f2b((e0 * vv[0].y + e1 * vv[1].y + e2 * vv[2].y) * iz);
        ob.z = f2b((e0 * vv[0].z + e1 * vv[1].z + e2 * vv[2].z) * iz);
        ob.w = f2b((e0 * vv[0].w + e1 * vv[1].w + e2 * vv[2].w) * iz);
        *reinterpret_cast<ushort4*>(o + ((size_t)s * kN + b) * kH + h * 32 + l8 * 4) = ob;
    }
}

// ---------------- view attention / blend ----------------

__global__ void view_comb_k(const unsigned short* __restrict__ a1b, const float* __restrict__ w0,
                            const float* __restrict__ w1, float* __restrict__ x1,
                            float* __restrict__ x2) {
    int gid = blockIdx.x * 256 + threadIdx.x;
    if (gid >= kN * 64) return;
    int n = gid >> 6;
    int c4 = (gid & 63) << 2;
    float u0 = w0[n], u1 = w0[kN + n], u2 = w0[2 * kN + n];
    float m = fmaxf(u0, fmaxf(u1, u2));
    float e0 = __expf(u0 - m), e1 = __expf(u1 - m), e2 = __expf(u2 - m);
    float iz = 1.f / (e0 + e1 + e2);
    float p0 = e0 * iz, p1 = e1 * iz, p2 = e2 * iz;
    float q0 = w1[n], q1 = w1[kN + n], q2 = w1[2 * kN + n];
    float mq = fmaxf(q0, fmaxf(q1, q2));
    float f0 = __expf(q0 - mq), f1 = __expf(q1 - mq), f2 = __expf(q2 - mq);
    float izq = 1.f / (f0 + f1 + f2);
    float r0 = f0 * izq, r1 = f1 * izq, r2 = f2 * izq;
    ushort4 U0 = *reinterpret_cast<const ushort4*>(a1b + ((size_t)0 * kN + n) * 256 + c4);
    ushort4 U1 = *reinterpret_cast<const ushort4*>(a1b + ((size_t)1 * kN + n) * 256 + c4);
    ushort4 U2 = *reinterpret_cast<const ushort4*>(a1b + ((size_t)2 * kN + n) * 256 + c4);
    float4 A0 = make_float4(b2f(U0.x), b2f(U0.y), b2f(U0.z), b2f(U0.w));
    float4 A1 = make_float4(b2f(U1.x), b2f(U1.y), b2f(U1.z), b2f(U1.w));
    float4 A2 = make_float4(b2f(U2.x), b2f(U2.y), b2f(U2.z), b2f(U2.w));
    float4 o1, o2;
    o1.x = p0 * A0.x + p1 * A1.x + p2 * A2.x;  o2.x = r0 * A0.x + r1 * A1.x + r2 * A2.x;
    o1.y = p0 * A0.y + p1 * A1.y + p2 * A2.y;  o2.y = r0 * A0.y + r1 * A1.y + r2 * A2.y;
    o1.z = p0 * A0.z + p1 * A1.z + p2 * A2.z;  o2.z = r0 * A0.z + r1 * A1.z + r2 * A2.z;
    o1.w = p0 * A0.w + p1 * A1.w + p2 * A2.w;  o2.w = r0 * A0.w + r1 * A1.w + r2 * A2.w;
    *reinterpret_cast<float4*>(x1 + (size_t)n * 256 + c4) = o1;
    *reinterpret_cast<float4*>(x2 + (size_t)n * 256 + c4) = o2;
}

__global__ __launch_bounds__(1024) void randsm_k(const float* __restrict__ rw, float* __restrict__ stats) {
    __shared__ float sm[16];
    __shared__ float ss[16];
    int tid = threadIdx.x;
    float m = -1e30f;
    for (int i = tid; i < kN; i += 1024) m = fmaxf(m, rw[i]);
#pragma unroll
    for (int off = 32; off > 0; off >>= 1) m = fmaxf(m, __shfl_xor(m, off, 64));
    if ((tid & 63) == 0) sm[tid >> 6] = m;
    __syncthreads();
    if (tid == 0) {
        float mm = sm[0];
        for (int i = 1; i < 16; ++i) mm = fmaxf(mm, sm[i]);
        sm[0] = mm;
    }
    __syncthreads();
    float mx = sm[0];
    float s = 0.f;
    for (int i = tid; i < kN; i += 1024) s += __expf(rw[i] - mx);
#pragma unroll
    for (int off = 32; off > 0; off >>= 1) s += __shfl_xor(s, off, 64);
    if ((tid & 63) == 0) ss[tid >> 6] = s;
    __syncthreads();
    if (tid == 0) {
        float z = 0.f;
        for (int i = 0; i < 16; ++i) z += ss[i];
        stats[0] = mx;
        stats[1] = z;
    }
}

__global__ void blend_k(const float* __restrict__ x1, const float* __restrict__ x2,
                        const float* __restrict__ rw, const float* __restrict__ stats,
                        float* __restrict__ g) {
    int gid = blockIdx.x * 256 + threadIdx.x;
    if (gid >= kN * 64) return;
    int n = gid >> 6;
    int c4 = (gid & 63) << 2;
    float aw = __expf(rw[n] - stats[0]) / stats[1];
    float4 v1 = *reinterpret_cast<const float4*>(x1 + (size_t)n * 256 + c4);
    float4 v2 = *reinterpret_cast<const float4*>(x2 + (size_t)n * 256 + c4);
    float4 o;
    o.x = aw * v1.x + (1.f - aw) * v2.x;
    o.y = aw * v1.y + (1.f - aw) * v2.y;
    o.z = aw * v1.z + (1.f - aw) * v2.z;
    o.w = aw * v1.w + (1.f - aw) * v2.w;
    *reinterpret_cast<float4*>(g + (size_t)n * 256 + c4) = o;
}

// ---------------- myGAT gather ----------------

__global__ __launch_bounds__(256) void mygat_gather_k(const int* __restrict__ csr, const int* __restrict__ offs,
                                                      const int* __restrict__ cnt, const float* __restrict__ el,
                                                      const float* __restrict__ er, const float* __restrict__ f,
                                                      float* __restrict__ rst) {
    int node = blockIdx.x * 8 + (threadIdx.x >> 5);
    int c = threadIdx.x & 31;
    if (node >= kN) return;
    int o0 = offs[node], n = cnt[node];
    float erd = er[node];
    float m = -1e30f;
    for (int i = 0; i < n; ++i) {
        int s = csr[o0 + i];
        m = fmaxf(m, lrelu(el[s] + erd));
    }
    float z = 0.f, acc = 0.f;
    for (int i = 0; i < n; ++i) {
        int s = csr[o0 + i];
        float e = __expf(lrelu(el[s] + erd) - m);
        z += e;
        acc += f[(size_t)s * kC + c] * e;
    }
    rst[(size_t)node * kC + c] = acc / z;
}

__global__ void final_k(const float* __restrict__ rst, const float* __restrict__ r2,
                        float* __restrict__ logits) {
    int n = blockIdx.x * 256 + threadIdx.x;
    if (n >= kN) return;
    float vals[kC];
    float ssum = 0.f;
#pragma unroll
    for (int c = 0; c < kC; ++c) {
        vals[c] = rst[(size_t)n * kC + c] + r2[(size_t)n * kC + c];
        ssum += vals[c] * vals[c];
    }
    float inv = 1.0f / fmaxf(sqrtf(ssum), 1e-12f);
#pragma unroll
    for (int c = 0; c < kC; ++c) logits[(size_t)n * kC + c] = vals[c] * inv;
}

// ---------------- host orchestration ----------------

static void run_encoder(unsigned short* xinB, float* outp, unsigned short* outB, float* ws, int e,
                        const float* bqkv, const float* bo, const float* b1, const float* b2,
                        const float* g1, const float* be1, const float* g2, const float* be2,
                        hipStream_t stream) {
    unsigned short* T2B  = (unsigned short*)(ws + OFF_T2);
    unsigned short* BIGB = (unsigned short*)(ws + OFF_BIGB);
    unsigned short* OB   = BIGB + (size_t)kMP * 768;
    unsigned short* WB   = (unsigned short*)(ws + OFF_WB);
    const unsigned short* WQ = WB + (size_t)e * 196608;
    const unsigned short* WO = WB + 393216 + (size_t)e * 65536;
    const unsigned short* W1 = WB + 524288 + (size_t)e * 262144;
    const unsigned short* W2 = WB + 1048576 + (size_t)e * 262144;
    dim3 blk(256);

    mgemm_k<0, false, true><<<dim3(6, 469, 1), blk, 0, stream>>>(
        xinB, WQ, bqkv, nullptr, BIGB, kSN, 768, 256, 0, 0, 0);
    mha3_k<<<dim3((kN * kNH) / 32), blk, 0, stream>>>(BIGB, OB);
    mgemm_k<0, false, true><<<dim3(2, 469, 1), blk, 0, stream>>>(
        OB, WO, bo, nullptr, T2B, kSN, 256, 256, 0, 0, 0);
    ln_add_k<false><<<dim3(kSN / 4), blk, 0, stream>>>(xinB, T2B, g1, be1, nullptr, xinB, kSN);
    mgemm_k<1, false, true><<<dim3(8, 469, 1), blk, 0, stream>>>(
        xinB, W1, b1, nullptr, BIGB, kSN, 1024, 256, 0, 0, 0);
    mgemm_k<0, false, true><<<dim3(2, 469, 1), blk, 0, stream>>>(
        BIGB, W2, b2, nullptr, T2B, kSN, 256, 1024, 0, 0, 0);
    ln_add_k<true><<<dim3(kSN / 4), blk, 0, stream>>>(xinB, T2B, g2, be2, outp, outB, kSN);
}

extern "C" void kernel_launch(void* const* d_in, const int* in_sizes, int n_in,
                              void* d_out, int out_size, void* d_ws, size_t ws_size,
                              hipStream_t stream) {
    (void)in_sizes; (void)n_in; (void)out_size; (void)ws_size;

    const float* x      = (const float*)d_in[0];
    const int*   e_src  = (const int*)d_in[1];
    const int*   e_dst  = (const int*)d_in[2];
    const int*   gsrc   = (const int*)d_in[3];
    const int*   gdst   = (const int*)d_in[4];
    const float* rand_w = (const float*)d_in[5];
    const float* gcn_W  = (const float*)d_in[6];
    const float* gcn_b  = (const float*)d_in[7];
    const float* gat_W  = (const float*)d_in[8];
    const float* gat_as = (const float*)d_in[9];
    const float* gat_ad = (const float*)d_in[10];
    const float* gat_b  = (const float*)d_in[11];
    const float* Wqkv   = (const float*)d_in[12];
    const float* bqkv   = (const float*)d_in[13];
    const float* Wo     = (const float*)d_in[14];
    const float* bo     = (const float*)d_in[15];
    const float* W1     = (const float*)d_in[16];
    const float* b1     = (const float*)d_in[17];
    const float* W2     = (const float*)d_in[18];
    const float* b2     = (const float*)d_in[19];
    const float* ln1g   = (const float*)d_in[20];
    const float* ln1b   = (const float*)d_in[21];
    const float* ln2g   = (const float*)d_in[22];
    const float* ln2b   = (const float*)d_in[23];
    const float* att_P  = (const float*)d_in[24];
    const float* att_Pb = (const float*)d_in[25];
    const float* att_q  = (const float*)d_in[26];
    const float* mg_fc  = (const float*)d_in[27];
    const float* mg_al  = (const float*)d_in[28];
    const float* mg_ar  = (const float*)d_in[29];
    const float* mg_res = (const float*)d_in[30];

    float* ws  = (float*)d_ws;
    float* T3  = ws + OFF_T3;
    float* DNV = ws + OFF_DEG;
    float* EL  = ws + OFF_EL;
    float* ER  = ws + OFF_ER;
    float* W0b = ws + OFF_W0;
    float* W1b = ws + OFF_W1;
    float* FB  = ws + OFF_FB;
    float* R2  = ws + OFF_R2;
    float* RST = ws + OFF_RST;
    float* EL2 = ws + OFF_EL2;
    float* ER2 = ws + OFF_ER2;
    float* ST  = ws + OFF_ST;

    unsigned short* T2B  = (unsigned short*)(ws + OFF_T2);
    unsigned short* BIGB = (unsigned short*)(ws + OFF_BIGB);
    unsigned short* HB   = BIGB;
    unsigned short* SB   = (unsigned short*)(ws + OFF_SB);
    unsigned short* AB   = (unsigned short*)(ws + OFF_AB);
    unsigned short* WB   = (unsigned short*)(ws + OFF_WB);
    unsigned short* GWB  = (unsigned short*)(ws + OFF_GWB);
    unsigned short* PB   = (unsigned short*)(ws + OFF_PB);

    int* ib    = (int*)(ws + OFF_INT);
    int* CNT   = ib + ICNT;
    int* CNT2  = ib + ICNT2;
    int* OFFS  = ib + IOFF;
    int* OFFS2 = ib + IOFF2;
    int* CUR   = ib + ICUR;
    int* CUR2  = ib + ICUR2;
    int* CSR   = ib + ICSR;
    int* CSR2  = ib + ICSR2;

    float* outp   = (float*)d_out;
    float* a0     = outp;
    float* a1     = outp + (size_t)kSN * kH;
    float* logits = outp + 2 * (size_t)kSN * kH;
    float* gemb   = outp + 2 * (size_t)kSN * kH + (size_t)kN * kC;

    dim3 blk(256);

    // ---- 0a. zero pad-tail rows of bf16 GEMM-A buffers ----
    hipMemsetAsync(SB + (size_t)kSN * 256, 0, (size_t)(kMP - kSN) * 256 * sizeof(unsigned short), stream);
    hipMemsetAsync(AB + (size_t)kSN * 256, 0, (size_t)(kMP - kSN) * 256 * sizeof(unsigned short), stream);
    hipMemsetAsync(BIGB + (size_t)kSN * 1024, 0, (size_t)(kMP - kSN) * 1024 * sizeof(unsigned short), stream);

    // ---- 0b. CSR build ----
    hipMemsetAsync(CNT, 0, (size_t)(kV * kN + kN) * sizeof(int), stream);
    count_k<<<dim3((kV * kE + 255) / 256), blk, 0, stream>>>(e_dst, CNT, kE, kN, kV * kE);
    count_k<<<dim3((kE2 + 255) / 256), blk, 0, stream>>>(gdst, CNT2, kE2, kN, kE2);
    scan_k<<<dim3(kV), dim3(1024), 0, stream>>>(CNT, OFFS, CUR, kN);
    scan_k<<<dim3(1), dim3(1024), 0, stream>>>(CNT2, OFFS2, CUR2, kN);
    fill_csr_k<<<dim3((kV * kE + 255) / 256), blk, 0, stream>>>(e_src, e_dst, CUR, CSR, kE, kN, kV * kE);
    fill_csr_k<<<dim3((kE2 + 255) / 256), blk, 0, stream>>>(gsrc, gdst, CUR2, CSR2, kE2, kN, kE2);
    dinv_k<<<dim3((kV * kN + 255) / 256), blk, 0, stream>>>(CNT, DNV, kV * kN);

    // ---- 0c. weight/activation bf16 conversion ----
    cvt_k<<<dim3((393216 / 4 + 255) / 256), blk, 0, stream>>>(Wqkv, WB, 393216 / 4);
    cvt_k<<<dim3((131072 / 4 + 255) / 256), blk, 0, stream>>>(Wo, WB + 393216, 131072 / 4);
    cvt_k<<<dim3((524288 / 4 + 255) / 256), blk, 0, stream>>>(W1, WB + 524288, 524288 / 4);
    cvt_k<<<dim3((524288 / 4 + 255) / 256), blk, 0, stream>>>(W2, WB + 1048576, 524288 / 4);
    tcvt_k<<<dim3((3 * 65536 + 255) / 256), blk, 0, stream>>>(gcn_W, GWB, 256, 256, 3 * 65536);
    tcvt_k<<<dim3((3 * 65536 + 255) / 256), blk, 0, stream>>>(gat_W, GWB + 3 * 65536, 256, 256, 3 * 65536);
    tcvt_k<<<dim3((2 * 32768 + 255) / 256), blk, 0, stream>>>(att_P, PB, 256, 128, 2 * 32768);
    cvt_k<<<dim3((kSN * 256 / 4 + 255) / 256), blk, 0, stream>>>(x, AB, kSN * 256 / 4);

    // ---- 1. multi-view GCN + relu -> SB (bf16) ----
    mgemm_k<0, false, true><<<dim3(2, 157, 3), blk, 0, stream>>>(
        AB, GWB, nullptr, nullptr, HB, kN, 256, 256, (long)kN * 256, 65536, kN);
    gcn_gather_k<<<dim3(kSN / 4), blk, 0, stream>>>(CSR, OFFS, CNT, DNV, HB, gcn_b, SB);

    // ---- 2. encoder 0 -> a0 f32 + AB bf16 ----
    run_encoder(SB, a0, AB, ws, 0, bqkv, bo, b1, b2, ln1g, ln1b, ln2g, ln2b, stream);

    // ---- 3. multi-view GAT + relu -> SB (bf16) ----
    mgemm_k<0, false, true><<<dim3(2, 157, 3), blk, 0, stream>>>(
        AB, GWB + 3 * 65536, nullptr, nullptr, HB, kN, 256, 256, (long)kN * 256, 65536, kN);
    rowdot2b_k<<<dim3(kSN), dim3(64), 0, stream>>>(HB, gat_as, gat_ad, EL, ER, kSN, 256, kN, kH);
    gat_gather_k<<<dim3(kSN / 4), blk, 0, stream>>>(CSR, OFFS, CNT, EL, ER, HB, gat_b, SB);

    // ---- 4. encoder 1 -> a1 f32 + AB bf16 ----
    run_encoder(SB, a1, AB, ws, 1, bqkv + 768, bo + 256, b1 + 1024, b2 + 256,
                ln1g + 256, ln1b + 256, ln2g + 256, ln2b + 256, stream);

    // ---- 5. view attention + blend -> gemb ----
    mgemm_k<3, false, true><<<dim3(2, 469, 1), blk, 0, stream>>>(
        AB, PB, att_Pb, nullptr, T2B, kSN, 256, 256, 0, 0, 0);
    attdot_k<<<dim3(kSN / 4), blk, 0, stream>>>(T2B, att_q, W0b, W1b, kSN);
    float* X1 = T3;
    float* X2 = T3 + (size_t)kN * kH;
    view_comb_k<<<dim3((kN * 64 + 255) / 256), blk, 0, stream>>>(AB, W0b, W1b, X1, X2);
    randsm_k<<<dim3(1), dim3(1024), 0, stream>>>(rand_w, ST);
    blend_k<<<dim3((kN * 64 + 255) / 256), blk, 0, stream>>>(X1, X2, rand_w, ST, gemb);

    // ---- 6. myGATConv -> logits ----
    gemm_k<0><<<dim3(1, (kN + 63) / 64), blk, 0, stream>>>(gemb, mg_fc, (const float*)nullptr, FB, kN, kC, 256);
    rowdot2_k<<<dim3(kN), dim3(64), 0, stream>>>(FB, mg_al, mg_ar, EL2, ER2, kN, kC, kN, 0);
    mygat_gather_k<<<dim3((kN + 7) / 8), blk, 0, stream>>>(CSR2, OFFS2, CNT2, EL2, ER2, FB, RST);
    gemm_k<0><<<dim3(1, (kN + 63) / 64), blk, 0, stream>>>(gemb, mg_res, (const float*)nullptr, R2, kN, kC, 256);
    final_k<<<dim3((kN + 255) / 256), blk, 0, stream>>>(RST, R2, logits);
}

// Round 13
// 979.509 us; speedup vs baseline: 1.5363x; 1.0045x over previous
//
#include <hip/hip_runtime.h>
#include <hip/hip_bf16.h>
#include <math.h>

// ---------------- problem constants ----------------
namespace {
constexpr int kV  = 3;
constexpr int kN  = 20000;
constexpr int kF  = 256;
constexpr int kH  = 256;
constexpr int kE  = 160000;
constexpr int kC  = 32;
constexpr int kNH = 8;
constexpr int kSN = kV * kN;     // 60000
constexpr int kE2 = kE + kN;     // 180000
constexpr int kMP = 60160;       // padded rows for bf16 GEMM-A buffers

// fp32 workspace layout (float element offsets)
constexpr size_t OFF_T1   = 0;                                   // (spare)
constexpr size_t OFF_T2   = OFF_T1 + (size_t)kMP * 256;          // bf16 T2B
constexpr size_t OFF_T3   = OFF_T2 + (size_t)kMP * 256;          // f32 X1/X2 blend buffers
constexpr size_t OFF_BIGB = OFF_T3 + (size_t)kMP * 256;          // bf16 [kMP*1024]
constexpr size_t OFF_SB   = OFF_BIGB + (size_t)kMP * 512;        // bf16 [kMP*256]
constexpr size_t OFF_AB   = OFF_SB + (size_t)kMP * 128;          // bf16 [kMP*256]
constexpr size_t OFF_WB   = OFF_AB + (size_t)kMP * 128;          // bf16 enc weights
constexpr size_t OFF_GWB  = OFF_WB + 786432;
constexpr size_t OFF_PB   = OFF_GWB + 196608;
constexpr size_t OFF_DEG  = OFF_PB + 32768;
constexpr size_t OFF_EL   = OFF_DEG + (size_t)kV * kN;
constexpr size_t OFF_ER   = OFF_EL  + (size_t)kV * kN;
constexpr size_t OFF_W0   = OFF_ER  + (size_t)kV * kN;
constexpr size_t OFF_W1   = OFF_W0  + (size_t)kV * kN;
constexpr size_t OFF_FB   = OFF_W1  + (size_t)kV * kN;
constexpr size_t OFF_R2   = OFF_FB  + (size_t)kN * kC;
constexpr size_t OFF_RST  = OFF_R2  + (size_t)kN * kC;
constexpr size_t OFF_EL2  = OFF_RST + (size_t)kN * kC;
constexpr size_t OFF_ER2  = OFF_EL2 + kN;
constexpr size_t OFF_ST   = OFF_ER2 + kN;
constexpr size_t OFF_INT  = OFF_ST + 4;
// int layout
constexpr size_t ICNT  = 0;
constexpr size_t ICNT2 = ICNT  + (size_t)kV * kN;
constexpr size_t IOFF  = ICNT2 + kN;
constexpr size_t IOFF2 = IOFF  + (size_t)kV * kN;
constexpr size_t ICUR  = IOFF2 + kN;
constexpr size_t ICUR2 = ICUR  + (size_t)kV * kN;
constexpr size_t ICSR  = ICUR2 + kN;
constexpr size_t ICSR2 = ICSR  + (size_t)kV * kE;
} // namespace

typedef __attribute__((ext_vector_type(4))) float f32x4;
typedef __attribute__((ext_vector_type(8))) __bf16 bf16x8;

__device__ __forceinline__ float lrelu(float x) { return x > 0.f ? x : 0.2f * x; }
__device__ __forceinline__ unsigned short f2b(float f) {
    unsigned u = __float_as_uint(f);
    return (unsigned short)((u + 0x7FFFu + ((u >> 16) & 1u)) >> 16);
}
__device__ __forceinline__ float b2f(unsigned short h) {
    return __uint_as_float((unsigned)h << 16);
}
// tanh via HW exp: tanh(x) = (e^{2x}-1)/(e^{2x}+1), clamped
__device__ __forceinline__ float fast_tanh(float x) {
    float xc = fminf(fmaxf(x, -15.f), 15.f);
    float e = __expf(2.0f * xc);
    return (e - 1.0f) / (e + 1.0f);
}

// ---------------- conversion kernels ----------------

__global__ void cvt_k(const float* __restrict__ in, unsigned short* __restrict__ out, int n4) {
    int i = blockIdx.x * 256 + threadIdx.x;
    if (i >= n4) return;
    float4 v = reinterpret_cast<const float4*>(in)[i];
    ushort4 o;
    o.x = f2b(v.x); o.y = f2b(v.y); o.z = f2b(v.z); o.w = f2b(v.w);
    reinterpret_cast<ushort4*>(out)[i] = o;
}

__global__ void tcvt_k(const float* __restrict__ in, unsigned short* __restrict__ out,
                       int K, int N, int total) {
    int gid = blockIdx.x * 256 + threadIdx.x;
    if (gid >= total) return;
    int per = K * N;
    int v = gid / per, r = gid - v * per;
    int n = r / K, k = r - n * K;
    out[gid] = f2b(in[(size_t)v * per + (size_t)k * N + n]);
}

// ---------------- MFMA bf16 GEMM: dbuf + XOR-slot-swizzled LDS + strength-reduced pointers ----
// C[M,N] = act(A[M,K] @ W[N,K]^T + bias). 128x128 tile, BK=32, 4 waves, 2-phase dbuf.
// LDS swizzle (rule 21): linear LDS dest; global SOURCE pre-swizzled so LDS slot s of row r
// holds global 16B-slot s^((r>>1)&3); reader XORs the same constant. 8-way -> 2-way conflicts.
// ACT: 0 none, 1 relu, 2 tanh, 3 split (global col<128 tanh else relu).
template <int ACT, bool WF32, bool WB16>
__global__ __launch_bounds__(256, 4) void mgemm_k(const unsigned short* __restrict__ A,
                                                  const unsigned short* __restrict__ W,
                                                  const float* __restrict__ bias,
                                                  float* __restrict__ Cf,
                                                  unsigned short* __restrict__ Cb,
                                                  int M, int N, int K,
                                                  long zA, long zW, long zC) {
    static_assert(WF32 != WB16, "exactly one output path");
    __shared__ __align__(16) unsigned short shbuf[16384];   // 2 x (As 8KB + Ws 8KB); epilogue reuses

    const int tid  = threadIdx.x;
    const int lane = tid & 63;

    // bijective XCD-chunked swizzle of the (x,y) tile index (m204)
    const int gx = gridDim.x;
    const int nwg = gx * gridDim.y;
    const int orig = blockIdx.y * gx + blockIdx.x;
    const int q = nwg >> 3, rr = nwg & 7;
    const int xcd = orig & 7, pos = orig >> 3;
    const int nid = (xcd < rr ? xcd * (q + 1) : rr * (q + 1) + (xcd - rr) * q) + pos;
    const int bm = (nid / gx) * 128, bn = (nid % gx) * 128;

    A += (size_t)blockIdx.z * zA;
    W += (size_t)blockIdx.z * zW;
    const size_t zrow = (size_t)blockIdx.z * zC;

    const int wv = tid >> 6;
    const int wm = (wv >> 1) * 64, wn = (wv & 1) * 64;
    const int fr = lane & 15;

    // staging constants: LDS row r0 (and 64+r0), swizzled global slot offset
    const int r0 = tid >> 2;
    const int xorv = (r0 >> 1) & 3;
    const int slo = ((tid & 3) ^ xorv) * 8;   // element offset within 32-elem K-row

    // strength-reduced global pointers (advance by 32 elements per K-step)
    const unsigned short* pa0 = A + (size_t)(bm + r0) * K + slo;
    const unsigned short* pw0 = W + (size_t)(bn + r0) * K + slo;
    const unsigned short* pa1 = A + (size_t)(bm + 64 + r0) * K + slo;
    const unsigned short* pw1 = W + (size_t)(bn + 64 + r0) * K + slo;

    // reader: swizzled LDS slot, compile-time per lane
    const int slr = (((lane >> 4) ^ ((fr >> 1) & 3))) * 8;

    f32x4 acc[4][4] = {};

    // prologue: stage tile 0 into buffer 0
    {
        unsigned short* As = shbuf;
        unsigned short* Ws = shbuf + 4096;
        __builtin_amdgcn_global_load_lds((const __attribute__((address_space(1))) void*)pa0,
                                         (__attribute__((address_space(3))) void*)(As + tid * 8), 16, 0, 0);
        __builtin_amdgcn_global_load_lds((const __attribute__((address_space(1))) void*)pw0,
                                         (__attribute__((address_space(3))) void*)(Ws + tid * 8), 16, 0, 0);
        __builtin_amdgcn_global_load_lds((const __attribute__((address_space(1))) void*)pa1,
                                         (__attribute__((address_space(3))) void*)(As + (256 + tid) * 8), 16, 0, 0);
        __builtin_amdgcn_global_load_lds((const __attribute__((address_space(1))) void*)pw1,
                                         (__attribute__((address_space(3))) void*)(Ws + (256 + tid) * 8), 16, 0, 0);
        pa0 += 32; pw0 += 32; pa1 += 32; pw1 += 32;
    }
    __syncthreads();

    int cur = 0;
    for (int k0 = 0; k0 < K; k0 += 32) {
        if (k0 + 32 < K) {
            // issue next-tile loads into the other buffer (overlaps with this tile's compute)
            unsigned short* As = shbuf + (cur ^ 1) * 8192;
            unsigned short* Ws = As + 4096;
            __builtin_amdgcn_global_load_lds((const __attribute__((address_space(1))) void*)pa0,
                                             (__attribute__((address_space(3))) void*)(As + tid * 8), 16, 0, 0);
            __builtin_amdgcn_global_load_lds((const __attribute__((address_space(1))) void*)pw0,
                                             (__attribute__((address_space(3))) void*)(Ws + tid * 8), 16, 0, 0);
            __builtin_amdgcn_global_load_lds((const __attribute__((address_space(1))) void*)pa1,
                                             (__attribute__((address_space(3))) void*)(As + (256 + tid) * 8), 16, 0, 0);
            __builtin_amdgcn_global_load_lds((const __attribute__((address_space(1))) void*)pw1,
                                             (__attribute__((address_space(3))) void*)(Ws + (256 + tid) * 8), 16, 0, 0);
            pa0 += 32; pw0 += 32; pa1 += 32; pw1 += 32;
        }
        const unsigned short* As = shbuf + cur * 8192;
        const unsigned short* Ws = As + 4096;
        bf16x8 av[4], bv[4];
#pragma unroll
        for (int mi = 0; mi < 4; ++mi)
            av[mi] = *reinterpret_cast<const bf16x8*>(As + (wm + mi * 16 + fr) * 32 + slr);
#pragma unroll
        for (int ni = 0; ni < 4; ++ni)
            bv[ni] = *reinterpret_cast<const bf16x8*>(Ws + (wn + ni * 16 + fr) * 32 + slr);
#pragma unroll
        for (int mi = 0; mi < 4; ++mi)
#pragma unroll
            for (int ni = 0; ni < 4; ++ni)
                acc[mi][ni] = __builtin_amdgcn_mfma_f32_16x16x32_bf16(av[mi], bv[ni], acc[mi][ni], 0, 0, 0);
        __syncthreads();   // drains next-tile loads (in flight during MFMA) + this tile's ds_reads
        cur ^= 1;
    }

    const int crow = (lane >> 4) * 4;
    const int ccol = lane & 15;

    if (WB16) {
#pragma unroll
        for (int mi = 0; mi < 4; ++mi)
#pragma unroll
            for (int r = 0; r < 4; ++r) {
                const int row = wm + mi * 16 + crow + r;
#pragma unroll
                for (int ni = 0; ni < 4; ++ni) {
                    const int col = wn + ni * 16 + ccol;
                    float v = acc[mi][ni][r];
                    if (bias) v += bias[bn + col];
                    if (ACT == 1) v = fmaxf(v, 0.f);
                    if (ACT == 2) v = fast_tanh(v);
                    if (ACT == 3) v = (bn + col < 128) ? fast_tanh(v) : fmaxf(v, 0.f);
                    shbuf[row * 128 + col] = f2b(v);
                }
            }
        __syncthreads();
#pragma unroll
        for (int it = 0; it < 8; ++it) {
            const int fl = it * 2048 + tid * 8;
            const int row = fl >> 7, col = fl & 127;
            const int grow = bm + row;
            if (grow < M) {
                uint4 d = *reinterpret_cast<const uint4*>(shbuf + row * 128 + col);
                *reinterpret_cast<uint4*>(Cb + (zrow + grow) * (size_t)N + bn + col) = d;
            }
        }
    } else {
        float* epf = reinterpret_cast<float*>(shbuf);
#pragma unroll
        for (int half = 0; half < 2; ++half) {
            if ((wm >> 6) == half) {
#pragma unroll
                for (int mi = 0; mi < 4; ++mi)
#pragma unroll
                    for (int r = 0; r < 4; ++r) {
                        const int row = mi * 16 + crow + r;
#pragma unroll
                        for (int ni = 0; ni < 4; ++ni) {
                            const int col = wn + ni * 16 + ccol;
                            float v = acc[mi][ni][r];
                            if (bias) v += bias[bn + col];
                            if (ACT == 1) v = fmaxf(v, 0.f);
                            if (ACT == 2) v = fast_tanh(v);
                            if (ACT == 3) v = (bn + col < 128) ? fast_tanh(v) : fmaxf(v, 0.f);
                            epf[row * 128 + col] = v;
                        }
                    }
            }
            __syncthreads();
#pragma unroll
            for (int it = 0; it < 8; ++it) {
                const int fl = it * 1024 + tid * 4;
                const int row = fl >> 7, col = fl & 127;
                const int grow = bm + half * 64 + row;
                if (grow < M) {
                    float4 d = *reinterpret_cast<const float4*>(epf + row * 128 + col);
                    *reinterpret_cast<float4*>(Cf + (zrow + grow) * (size_t)N + bn + col) = d;
                }
            }
            __syncthreads();
        }
    }
}

// ---------------- fp32 GEMM (N=32 tail) ----------------
template <int ACT>
__global__ __launch_bounds__(256) void gemm_k(const float* __restrict__ A,
                                              const float* __restrict__ B,
                                              const float* __restrict__ bias,
                                              float* __restrict__ Cmat,
                                              int M, int Nn, int K) {
    __shared__ float As[16][64];
    __shared__ float Bs[16][68];
    const int tid  = threadIdx.x;
    const int bm   = blockIdx.y * 64;
    const int bn   = blockIdx.x * 64;
    const int tx   = tid & 15, ty = tid >> 4;
    const int arow = tid >> 2;
    const int acol = (tid & 3) << 2;
    const int brow = tid >> 4;
    const int bcol = (tid & 15) << 2;
    const int gm   = bm + arow;
    float acc[4][4] = {{0.f,0.f,0.f,0.f},{0.f,0.f,0.f,0.f},{0.f,0.f,0.f,0.f},{0.f,0.f,0.f,0.f}};

    for (int k0 = 0; k0 < K; k0 += 16) {
        float4 av = make_float4(0.f, 0.f, 0.f, 0.f);
        if (gm < M) av = *reinterpret_cast<const float4*>(A + (size_t)gm * K + (k0 + acol));
        As[acol + 0][arow] = av.x;
        As[acol + 1][arow] = av.y;
        As[acol + 2][arow] = av.z;
        As[acol + 3][arow] = av.w;

        const int gn = bn + bcol;
        const float* Brow = B + (size_t)(k0 + brow) * Nn;
        float4 bv;
        if (gn + 3 < Nn) {
            bv = *reinterpret_cast<const float4*>(Brow + gn);
        } else {
            bv.x = (gn + 0 < Nn) ? Brow[gn + 0] : 0.f;
            bv.y = (gn + 1 < Nn) ? Brow[gn + 1] : 0.f;
            bv.z = (gn + 2 < Nn) ? Brow[gn + 2] : 0.f;
            bv.w = (gn + 3 < Nn) ? Brow[gn + 3] : 0.f;
        }
        *reinterpret_cast<float4*>(&Bs[brow][bcol]) = bv;
        __syncthreads();

#pragma unroll
        for (int k = 0; k < 16; ++k) {
            float4 a4 = *reinterpret_cast<const float4*>(&As[k][ty << 2]);
            float4 b4 = *reinterpret_cast<const float4*>(&Bs[k][tx << 2]);
            acc[0][0] += a4.x * b4.x; acc[0][1] += a4.x * b4.y; acc[0][2] += a4.x * b4.z; acc[0][3] += a4.x * b4.w;
            acc[1][0] += a4.y * b4.x; acc[1][1] += a4.y * b4.y; acc[1][2] += a4.y * b4.z; acc[1][3] += a4.y * b4.w;
            acc[2][0] += a4.z * b4.x; acc[2][1] += a4.z * b4.y; acc[2][2] += a4.z * b4.z; acc[2][3] += a4.z * b4.w;
            acc[3][0] += a4.w * b4.x; acc[3][1] += a4.w * b4.y; acc[3][2] += a4.w * b4.z; acc[3][3] += a4.w * b4.w;
        }
        __syncthreads();
    }

#pragma unroll
    for (int i = 0; i < 4; ++i) {
        int m = bm + (ty << 2) + i;
        if (m >= M) continue;
#pragma unroll
        for (int j = 0; j < 4; ++j) {
            int n = bn + (tx << 2) + j;
            if (n >= Nn) continue;
            float v = acc[i][j];
            if (bias) v += bias[n];
            if (ACT == 1) v = fmaxf(v, 0.f);
            if (ACT == 2) v = fast_tanh(v);
            Cmat[(size_t)m * Nn + n] = v;
        }
    }
}

// out = LN(x+y)*g+b; wave per row; x,y bf16 ushort4/lane; WF32: also write f32.
// In-place x==outb is safe (each wave owns its row; reads precede writes).
template <bool WF32>
__global__ __launch_bounds__(256) void ln_add_k(const unsigned short* __restrict__ x,
                                                const unsigned short* __restrict__ y,
                                                const float* __restrict__ g, const float* __restrict__ b,
                                                float* __restrict__ outf, unsigned short* __restrict__ outb,
                                                int rows) {
    int r = blockIdx.x * 4 + (threadIdx.x >> 6);
    if (r >= rows) return;
    int lane = threadIdx.x & 63;
    size_t base = (size_t)r * 256 + lane * 4;
    ushort4 xu = *reinterpret_cast<const ushort4*>(x + base);
    ushort4 yu = *reinterpret_cast<const ushort4*>(y + base);
    float4 t;
    t.x = b2f(xu.x) + b2f(yu.x); t.y = b2f(xu.y) + b2f(yu.y);
    t.z = b2f(xu.z) + b2f(yu.z); t.w = b2f(xu.w) + b2f(yu.w);
    float s = t.x + t.y + t.z + t.w;
#pragma unroll
    for (int off = 32; off > 0; off >>= 1) s += __shfl_xor(s, off, 64);
    float mean = s * (1.0f / 256.0f);
    float4 d;
    d.x = t.x - mean; d.y = t.y - mean; d.z = t.z - mean; d.w = t.w - mean;
    float s2 = d.x * d.x + d.y * d.y + d.z * d.z + d.w * d.w;
#pragma unroll
    for (int off = 32; off > 0; off >>= 1) s2 += __shfl_xor(s2, off, 64);
    float rs = rsqrtf(s2 * (1.0f / 256.0f) + 1e-5f);
    float4 gv = *reinterpret_cast<const float4*>(g + lane * 4);
    float4 bv = *reinterpret_cast<const float4*>(b + lane * 4);
    float4 o;
    o.x = d.x * rs * gv.x + bv.x;
    o.y = d.y * rs * gv.y + bv.y;
    o.z = d.z * rs * gv.z + bv.z;
    o.w = d.w * rs * gv.w + bv.w;
    if (WF32) *reinterpret_cast<float4*>(outf + base) = o;
    ushort4 ob;
    ob.x = f2b(o.x); ob.y = f2b(o.y); ob.z = f2b(o.z); ob.w = f2b(o.w);
    *reinterpret_cast<ushort4*>(outb + base) = ob;
}

// per-row dual dot products, fp32 A
__global__ void rowdot2_k(const float* __restrict__ A, const float* __restrict__ v1,
                          const float* __restrict__ v2, float* __restrict__ o1,
                          float* __restrict__ o2, int rows, int K, int rowsPerVec, int vecStride) {
    int r = blockIdx.x;
    if (r >= rows) return;
    int lane = threadIdx.x;
    const float* base = A + (size_t)r * K;
    int vo = (r / rowsPerVec) * vecStride;
    float s1 = 0.f, s2 = 0.f;
    for (int c = lane; c < K; c += 64) {
        float a = base[c];
        s1 += a * v1[vo + c];
        if (v2) s2 += a * v2[vo + c];
    }
#pragma unroll
    for (int off = 32; off > 0; off >>= 1) {
        s1 += __shfl_xor(s1, off, 64);
        s2 += __shfl_xor(s2, off, 64);
    }
    if (lane == 0) { o1[r] = s1; if (o2) o2[r] = s2; }
}

// fused dual 128-dot from bf16 [rows][256]
__global__ __launch_bounds__(256) void attdot_k(const unsigned short* __restrict__ A, const float* __restrict__ q,
                                                float* __restrict__ o1, float* __restrict__ o2, int rows) {
    int r = blockIdx.x * 4 + (threadIdx.x >> 6);
    if (r >= rows) return;
    int lane = threadIdx.x & 63;
    const unsigned short* row = A + (size_t)r * 256;
    ushort2 va = *reinterpret_cast<const ushort2*>(row + lane * 2);
    ushort2 vb = *reinterpret_cast<const ushort2*>(row + 128 + lane * 2);
    float2 qa = *reinterpret_cast<const float2*>(q + lane * 2);
    float2 qb = *reinterpret_cast<const float2*>(q + 128 + lane * 2);
    float s1 = b2f(va.x) * qa.x + b2f(va.y) * qa.y;
    float s2 = b2f(vb.x) * qb.x + b2f(vb.y) * qb.y;
#pragma unroll
    for (int off = 32; off > 0; off >>= 1) {
        s1 += __shfl_xor(s1, off, 64);
        s2 += __shfl_xor(s2, off, 64);
    }
    if (lane == 0) { o1[r] = s1; o2[r] = s2; }
}

// per-row dual dot products, bf16 A, ushort4 per lane
__global__ void rowdot2b_k(const unsigned short* __restrict__ A, const float* __restrict__ v1,
                           const float* __restrict__ v2, float* __restrict__ o1,
                           float* __restrict__ o2, int rows, int K, int rowsPerVec, int vecStride) {
    int r = blockIdx.x;
    if (r >= rows) return;
    int lane = threadIdx.x;
    const unsigned short* base = A + (size_t)r * K;
    int vo = (r / rowsPerVec) * vecStride;
    float s1 = 0.f, s2 = 0.f;
    for (int c = lane * 4; c < K; c += 256) {
        ushort4 a4 = *reinterpret_cast<const ushort4*>(base + c);
        float4 w1 = *reinterpret_cast<const float4*>(v1 + vo + c);
        float4 w2 = *reinterpret_cast<const float4*>(v2 + vo + c);
        s1 += b2f(a4.x) * w1.x + b2f(a4.y) * w1.y + b2f(a4.z) * w1.z + b2f(a4.w) * w1.w;
        s2 += b2f(a4.x) * w2.x + b2f(a4.y) * w2.y + b2f(a4.z) * w2.z + b2f(a4.w) * w2.w;
    }
#pragma unroll
    for (int off = 32; off > 0; off >>= 1) {
        s1 += __shfl_xor(s1, off, 64);
        s2 += __shfl_xor(s2, off, 64);
    }
    if (lane == 0) { o1[r] = s1; o2[r] = s2; }
}

// ---------------- CSR build ----------------

__global__ void count_k(const int* __restrict__ dst, int* __restrict__ cnt, int nE, int nN, int total) {
    int gid = blockIdx.x * 256 + threadIdx.x;
    if (gid >= total) return;
    int v = gid / nE;
    atomicAdd(&cnt[(size_t)v * nN + dst[gid]], 1);
}

__global__ __launch_bounds__(1024) void scan_k(const int* __restrict__ cnt, int* __restrict__ offs,
                                               int* __restrict__ cursor, int nN) {
    int v = blockIdx.x;
    const int* c = cnt + (size_t)v * nN;
    int* o  = offs + (size_t)v * nN;
    int* cu = cursor + (size_t)v * nN;
    int tid = threadIdx.x;
    int chunk = (nN + 1023) >> 10;
    int lo = tid * chunk;
    int hi = lo + chunk < nN ? lo + chunk : nN;
    int s = 0;
    for (int i = lo; i < hi; ++i) s += c[i];
    int lane = tid & 63, wid = tid >> 6;
    int x = s;
#pragma unroll
    for (int off = 1; off < 64; off <<= 1) {
        int y = __shfl_up(x, off, 64);
        if (lane >= off) x += y;
    }
    __shared__ int wsum[16];
    if (lane == 63) wsum[wid] = x;
    __syncthreads();
    if (tid == 0) {
        int a = 0;
        for (int w = 0; w < 16; ++w) { int t = wsum[w]; wsum[w] = a; a += t; }
    }
    __syncthreads();
    int base = x - s + wsum[wid];
    for (int i = lo; i < hi; ++i) { o[i] = base; cu[i] = base; base += c[i]; }
}

__global__ void fill_csr_k(const int* __restrict__ src, const int* __restrict__ dst,
                           int* __restrict__ cursor, int* __restrict__ csr,
                           int nE, int nN, int total) {
    int gid = blockIdx.x * 256 + threadIdx.x;
    if (gid >= total) return;
    int v = gid / nE;
    int pos = atomicAdd(&cursor[(size_t)v * nN + dst[gid]], 1);
    csr[(size_t)v * nE + pos] = src[gid];
}

__global__ void dinv_k(const int* __restrict__ cnt, float* __restrict__ dinv, int n) {
    int gid = blockIdx.x * 256 + threadIdx.x;
    if (gid < n) dinv[gid] = rsqrtf((float)cnt[gid] + 1.0f);
}

// ---------------- GCN gather: one WAVE per node, LDS-free, ushort4/lane; bf16 out only ----------------

__global__ __launch_bounds__(256) void gcn_gather_k(const int* __restrict__ csr, const int* __restrict__ offs,
                                                    const int* __restrict__ cnt, const float* __restrict__ dinv,
                                                    const unsigned short* __restrict__ h, const float* __restrict__ b,
                                                    unsigned short* __restrict__ outb) {
    int nd = blockIdx.x * 4 + (threadIdx.x >> 6);
    if (nd >= kV * kN) return;
    int v  = nd / kN;
    int lane = threadIdx.x & 63;
    int c4 = lane * 4;
    const int* base = csr + (size_t)v * kE;
    int o0 = offs[nd], n = cnt[nd];
    float dd = dinv[nd];
    const float* dv = dinv + (size_t)v * kN;
    const unsigned short* hb = h + (size_t)v * kN * kH;

    ushort4 hs = *reinterpret_cast<const ushort4*>(h + (size_t)nd * kH + c4);
    float wts = dd * dd;
    float4 acc;
    acc.x = b2f(hs.x) * wts; acc.y = b2f(hs.y) * wts;
    acc.z = b2f(hs.z) * wts; acc.w = b2f(hs.w) * wts;
    int i = 0;
    for (; i + 2 <= n; i += 2) {
        int s0 = base[o0 + i], s1 = base[o0 + i + 1];
        float w0 = dv[s0] * dd, w1 = dv[s1] * dd;
        ushort4 h0 = *reinterpret_cast<const ushort4*>(hb + (size_t)s0 * kH + c4);
        ushort4 h1 = *reinterpret_cast<const ushort4*>(hb + (size_t)s1 * kH + c4);
        acc.x += b2f(h0.x) * w0 + b2f(h1.x) * w1;
        acc.y += b2f(h0.y) * w0 + b2f(h1.y) * w1;
        acc.z += b2f(h0.z) * w0 + b2f(h1.z) * w1;
        acc.w += b2f(h0.w) * w0 + b2f(h1.w) * w1;
    }
    if (i < n) {
        int s0 = base[o0 + i];
        float w0 = dv[s0] * dd;
        ushort4 h0 = *reinterpret_cast<const ushort4*>(hb + (size_t)s0 * kH + c4);
        acc.x += b2f(h0.x) * w0; acc.y += b2f(h0.y) * w0;
        acc.z += b2f(h0.z) * w0; acc.w += b2f(h0.w) * w0;
    }
    float4 bb = *reinterpret_cast<const float4*>(b + (size_t)v * kH + c4);
    ushort4 ob;
    ob.x = f2b(fmaxf(acc.x + bb.x, 0.f));
    ob.y = f2b(fmaxf(acc.y + bb.y, 0.f));
    ob.z = f2b(fmaxf(acc.z + bb.z, 0.f));
    ob.w = f2b(fmaxf(acc.w + bb.w, 0.f));
    *reinterpret_cast<ushort4*>(outb + (size_t)nd * kH + c4) = ob;
}

// ---------------- GAT gather: one WAVE per node, LDS-free; bf16 out only ----------------

__global__ __launch_bounds__(256) void gat_gather_k(const int* __restrict__ csr, const int* __restrict__ offs,
                                                    const int* __restrict__ cnt, const float* __restrict__ el,
                                                    const float* __restrict__ er, const unsigned short* __restrict__ h,
                                                    const float* __restrict__ b, unsigned short* __restrict__ outb) {
    int nd = blockIdx.x * 4 + (threadIdx.x >> 6);
    if (nd >= kV * kN) return;
    int v  = nd / kN;
    int lane = threadIdx.x & 63;
    int c4 = lane * 4;
    const int* base = csr + (size_t)v * kE;
    int o0 = offs[nd], n = cnt[nd];
    float erd = er[nd];
    const float* elv = el + (size_t)v * kN;
    const unsigned short* hb = h + (size_t)v * kN * kH;
    float eself = lrelu(el[nd] + erd);

    float m = eself;
    for (int i = 0; i < n; ++i) m = fmaxf(m, lrelu(elv[base[o0 + i]] + erd));

    float es = __expf(eself - m);
    float z = es;
    ushort4 hs = *reinterpret_cast<const ushort4*>(h + (size_t)nd * kH + c4);
    float4 acc;
    acc.x = b2f(hs.x) * es; acc.y = b2f(hs.y) * es;
    acc.z = b2f(hs.z) * es; acc.w = b2f(hs.w) * es;
    int i = 0;
    for (; i + 2 <= n; i += 2) {
        int s0 = base[o0 + i], s1 = base[o0 + i + 1];
        float e0 = __expf(lrelu(elv[s0] + erd) - m);
        float e1 = __expf(lrelu(elv[s1] + erd) - m);
        z += e0 + e1;
        ushort4 h0 = *reinterpret_cast<const ushort4*>(hb + (size_t)s0 * kH + c4);
        ushort4 h1 = *reinterpret_cast<const ushort4*>(hb + (size_t)s1 * kH + c4);
        acc.x += b2f(h0.x) * e0 + b2f(h1.x) * e1;
        acc.y += b2f(h0.y) * e0 + b2f(h1.y) * e1;
        acc.z += b2f(h0.z) * e0 + b2f(h1.z) * e1;
        acc.w += b2f(h0.w) * e0 + b2f(h1.w) * e1;
    }
    if (i < n) {
        int s0 = base[o0 + i];
        float e0 = __expf(lrelu(elv[s0] + erd) - m);
        z += e0;
        ushort4 h0 = *reinterpret_cast<const ushort4*>(hb + (size_t)s0 * kH + c4);
        acc.x += b2f(h0.x) * e0; acc.y += b2f(h0.y) * e0;
        acc.z += b2f(h0.z) * e0; acc.w += b2f(h0.w) * e0;
    }
    float iz = 1.0f / z;
    float4 bb = *reinterpret_cast<const float4*>(b + (size_t)v * kH + c4);
    ushort4 ob;
    ob.x = f2b(fmaxf(acc.x * iz + bb.x, 0.f));
    ob.y = f2b(fmaxf(acc.y * iz + bb.y, 0.f));
    ob.z = f2b(fmaxf(acc.z * iz + bb.z, 0.f));
    ob.w = f2b(fmaxf(acc.w * iz + bb.w, 0.f));
    *reinterpret_cast<ushort4*>(outb + (size_t)nd * kH + c4) = ob;
}

// ---------------- transformer: 3x3 attention, 8 lanes per (node,head), ushort4 ----------------

__global__ __launch_bounds__(256) void mha3_k(const unsigned short* __restrict__ qkv, unsigned short* __restrict__ o) {
    int grp = blockIdx.x * 32 + (threadIdx.x >> 3);
    int l8 = threadIdx.x & 7;
    if (grp >= kN * kNH) return;
    int b = grp / kNH, h = grp - b * kNH;
    float4 q[3], k[3], vv[3];
#pragma unroll
    for (int s = 0; s < 3; ++s) {
        size_t base = ((size_t)s * kN + b) * 768 + h * 32 + l8 * 4;
        ushort4 qu = *reinterpret_cast<const ushort4*>(qkv + base);
        ushort4 ku = *reinterpret_cast<const ushort4*>(qkv + base + 256);
        ushort4 vu = *reinterpret_cast<const ushort4*>(qkv + base + 512);
        q[s].x = b2f(qu.x); q[s].y = b2f(qu.y); q[s].z = b2f(qu.z); q[s].w = b2f(qu.w);
        k[s].x = b2f(ku.x); k[s].y = b2f(ku.y); k[s].z = b2f(ku.z); k[s].w = b2f(ku.w);
        vv[s].x = b2f(vu.x); vv[s].y = b2f(vu.y); vv[s].z = b2f(vu.z); vv[s].w = b2f(vu.w);
    }
    float sc[3][3];
#pragma unroll
    for (int s = 0; s < 3; ++s)
#pragma unroll
        for (int t = 0; t < 3; ++t) {
            float d = q[s].x * k[t].x + q[s].y * k[t].y + q[s].z * k[t].z + q[s].w * k[t].w;
            d += __shfl_xor(d, 1, 64);
            d += __shfl_xor(d, 2, 64);
            d += __shfl_xor(d, 4, 64);
            sc[s][t] = d * 0.17677669529663687f;
        }
#pragma unroll
    for (int s = 0; s < 3; ++s) {
        float m = fmaxf(sc[s][0], fmaxf(sc[s][1], sc[s][2]));
        float e0 = __expf(sc[s][0] - m), e1 = __expf(sc[s][1] - m), e2 = __expf(sc[s][2] - m);
        float iz = 1.0f / (e0 + e1 + e2);
        ushort4 ob;
        ob.x = f2b((e0 * vv[0].x + e1 * vv[1].x + e2 * vv[2].x) * iz);
        ob.y = f2b((e0 * vv[0].y + e1 * vv[1].y + e2 * vv[2].y) * iz);
        ob.z = f2b((e0 * vv[0].z + e1 * vv[1].z + e2 * vv[2].z) * iz);
        ob.w = f2b((e0 * vv[0].w + e1 * vv[1].w + e2 * vv[2].w) * iz);
        *reinterpret_cast<ushort4*>(o + ((size_t)s * kN + b) * kH + h * 32 + l8 * 4) = ob;
    }
}

// ---------------- view attention / blend ----------------

__global__ void view_comb_k(const unsigned short* __restrict__ a1b, const float* __restrict__ w0,
                            const float* __restrict__ w1, float* __restrict__ x1,
                            float* __restrict__ x2) {
    int gid = blockIdx.x * 256 + threadIdx.x;
    if (gid >= kN * 64) return;
    int n = gid >> 6;
    int c4 = (gid & 63) << 2;
    float u0 = w0[n], u1 = w0[kN + n], u2 = w0[2 * kN + n];
    float m = fmaxf(u0, fmaxf(u1, u2));
    float e0 = __expf(u0 - m), e1 = __expf(u1 - m), e2 = __expf(u2 - m);
    float iz = 1.f / (e0 + e1 + e2);
    float p0 = e0 * iz, p1 = e1 * iz, p2 = e2 * iz;
    float q0 = w1[n], q1 = w1[kN + n], q2 = w1[2 * kN + n];
    float mq = fmaxf(q0, fmaxf(q1, q2));
    float f0 = __expf(q0 - mq), f1 = __expf(q1 - mq), f2 = __expf(q2 - mq);
    float izq = 1.f / (f0 + f1 + f2);
    float r0 = f0 * izq, r1 = f1 * izq, r2 = f2 * izq;
    ushort4 U0 = *reinterpret_cast<const ushort4*>(a1b + ((size_t)0 * kN + n) * 256 + c4);
    ushort4 U1 = *reinterpret_cast<const ushort4*>(a1b + ((size_t)1 * kN + n) * 256 + c4);
    ushort4 U2 = *reinterpret_cast<const ushort4*>(a1b + ((size_t)2 * kN + n) * 256 + c4);
    float4 A0 = make_float4(b2f(U0.x), b2f(U0.y), b2f(U0.z), b2f(U0.w));
    float4 A1 = make_float4(b2f(U1.x), b2f(U1.y), b2f(U1.z), b2f(U1.w));
    float4 A2 = make_float4(b2f(U2.x), b2f(U2.y), b2f(U2.z), b2f(U2.w));
    float4 o1, o2;
    o1.x = p0 * A0.x + p1 * A1.x + p2 * A2.x;  o2.x = r0 * A0.x + r1 * A1.x + r2 * A2.x;
    o1.y = p0 * A0.y + p1 * A1.y + p2 * A2.y;  o2.y = r0 * A0.y + r1 * A1.y + r2 * A2.y;
    o1.z = p0 * A0.z + p1 * A1.z + p2 * A2.z;  o2.z = r0 * A0.z + r1 * A1.z + r2 * A2.z;
    o1.w = p0 * A0.w + p1 * A1.w + p2 * A2.w;  o2.w = r0 * A0.w + r1 * A1.w + r2 * A2.w;
    *reinterpret_cast<float4*>(x1 + (size_t)n * 256 + c4) = o1;
    *reinterpret_cast<float4*>(x2 + (size_t)n * 256 + c4) = o2;
}

__global__ __launch_bounds__(1024) void randsm_k(const float* __restrict__ rw, float* __restrict__ stats) {
    __shared__ float sm[16];
    __shared__ float ss[16];
    int tid = threadIdx.x;
    float m = -1e30f;
    for (int i = tid; i < kN; i += 1024) m = fmaxf(m, rw[i]);
#pragma unroll
    for (int off = 32; off > 0; off >>= 1) m = fmaxf(m, __shfl_xor(m, off, 64));
    if ((tid & 63) == 0) sm[tid >> 6] = m;
    __syncthreads();
    if (tid == 0) {
        float mm = sm[0];
        for (int i = 1; i < 16; ++i) mm = fmaxf(mm, sm[i]);
        sm[0] = mm;
    }
    __syncthreads();
    float mx = sm[0];
    float s = 0.f;
    for (int i = tid; i < kN; i += 1024) s += __expf(rw[i] - mx);
#pragma unroll
    for (int off = 32; off > 0; off >>= 1) s += __shfl_xor(s, off, 64);
    if ((tid & 63) == 0) ss[tid >> 6] = s;
    __syncthreads();
    if (tid == 0) {
        float z = 0.f;
        for (int i = 0; i < 16; ++i) z += ss[i];
        stats[0] = mx;
        stats[1] = z;
    }
}

__global__ void blend_k(const float* __restrict__ x1, const float* __restrict__ x2,
                        const float* __restrict__ rw, const float* __restrict__ stats,
                        float* __restrict__ g) {
    int gid = blockIdx.x * 256 + threadIdx.x;
    if (gid >= kN * 64) return;
    int n = gid >> 6;
    int c4 = (gid & 63) << 2;
    float aw = __expf(rw[n] - stats[0]) / stats[1];
    float4 v1 = *reinterpret_cast<const float4*>(x1 + (size_t)n * 256 + c4);
    float4 v2 = *reinterpret_cast<const float4*>(x2 + (size_t)n * 256 + c4);
    float4 o;
    o.x = aw * v1.x + (1.f - aw) * v2.x;
    o.y = aw * v1.y + (1.f - aw) * v2.y;
    o.z = aw * v1.z + (1.f - aw) * v2.z;
    o.w = aw * v1.w + (1.f - aw) * v2.w;
    *reinterpret_cast<float4*>(g + (size_t)n * 256 + c4) = o;
}

// ---------------- myGAT gather ----------------

__global__ __launch_bounds__(256) void mygat_gather_k(const int* __restrict__ csr, const int* __restrict__ offs,
                                                      const int* __restrict__ cnt, const float* __restrict__ el,
                                                      const float* __restrict__ er, const float* __restrict__ f,
                                                      float* __restrict__ rst) {
    int node = blockIdx.x * 8 + (threadIdx.x >> 5);
    int c = threadIdx.x & 31;
    if (node >= kN) return;
    int o0 = offs[node], n = cnt[node];
    float erd = er[node];
    float m = -1e30f;
    for (int i = 0; i < n; ++i) {
        int s = csr[o0 + i];
        m = fmaxf(m, lrelu(el[s] + erd));
    }
    float z = 0.f, acc = 0.f;
    for (int i = 0; i < n; ++i) {
        int s = csr[o0 + i];
        float e = __expf(lrelu(el[s] + erd) - m);
        z += e;
        acc += f[(size_t)s * kC + c] * e;
    }
    rst[(size_t)node * kC + c] = acc / z;
}

__global__ void final_k(const float* __restrict__ rst, const float* __restrict__ r2,
                        float* __restrict__ logits) {
    int n = blockIdx.x * 256 + threadIdx.x;
    if (n >= kN) return;
    float vals[kC];
    float ssum = 0.f;
#pragma unroll
    for (int c = 0; c < kC; ++c) {
        vals[c] = rst[(size_t)n * kC + c] + r2[(size_t)n * kC + c];
        ssum += vals[c] * vals[c];
    }
    float inv = 1.0f / fmaxf(sqrtf(ssum), 1e-12f);
#pragma unroll
    for (int c = 0; c < kC; ++c) logits[(size_t)n * kC + c] = vals[c] * inv;
}

// ---------------- host orchestration ----------------

static void run_encoder(unsigned short* xinB, float* outp, unsigned short* outB, float* ws, int e,
                        const float* bqkv, const float* bo, const float* b1, const float* b2,
                        const float* g1, const float* be1, const float* g2, const float* be2,
                        hipStream_t stream) {
    unsigned short* T2B  = (unsigned short*)(ws + OFF_T2);
    unsigned short* BIGB = (unsigned short*)(ws + OFF_BIGB);
    unsigned short* OB   = BIGB + (size_t)kMP * 768;
    unsigned short* WB   = (unsigned short*)(ws + OFF_WB);
    const unsigned short* WQ = WB + (size_t)e * 196608;
    const unsigned short* WO = WB + 393216 + (size_t)e * 65536;
    const unsigned short* W1 = WB + 524288 + (size_t)e * 262144;
    const unsigned short* W2 = WB + 1048576 + (size_t)e * 262144;
    dim3 blk(256);

    mgemm_k<0, false, true><<<dim3(6, 469, 1), blk, 0, stream>>>(
        xinB, WQ, bqkv, nullptr, BIGB, kSN, 768, 256, 0, 0, 0);
    mha3_k<<<dim3((kN * kNH) / 32), blk, 0, stream>>>(BIGB, OB);
    mgemm_k<0, false, true><<<dim3(2, 469, 1), blk, 0, stream>>>(
        OB, WO, bo, nullptr, T2B, kSN, 256, 256, 0, 0, 0);
    ln_add_k<false><<<dim3(kSN / 4), blk, 0, stream>>>(xinB, T2B, g1, be1, nullptr, xinB, kSN);
    mgemm_k<1, false, true><<<dim3(8, 469, 1), blk, 0, stream>>>(
        xinB, W1, b1, nullptr, BIGB, kSN, 1024, 256, 0, 0, 0);
    mgemm_k<0, false, true><<<dim3(2, 469, 1), blk, 0, stream>>>(
        BIGB, W2, b2, nullptr, T2B, kSN, 256, 1024, 0, 0, 0);
    ln_add_k<true><<<dim3(kSN / 4), blk, 0, stream>>>(xinB, T2B, g2, be2, outp, outB, kSN);
}

extern "C" void kernel_launch(void* const* d_in, const int* in_sizes, int n_in,
                              void* d_out, int out_size, void* d_ws, size_t ws_size,
                              hipStream_t stream) {
    (void)in_sizes; (void)n_in; (void)out_size; (void)ws_size;

    const float* x      = (const float*)d_in[0];
    const int*   e_src  = (const int*)d_in[1];
    const int*   e_dst  = (const int*)d_in[2];
    const int*   gsrc   = (const int*)d_in[3];
    const int*   gdst   = (const int*)d_in[4];
    const float* rand_w = (const float*)d_in[5];
    const float* gcn_W  = (const float*)d_in[6];
    const float* gcn_b  = (const float*)d_in[7];
    const float* gat_W  = (const float*)d_in[8];
    const float* gat_as = (const float*)d_in[9];
    const float* gat_ad = (const float*)d_in[10];
    const float* gat_b  = (const float*)d_in[11];
    const float* Wqkv   = (const float*)d_in[12];
    const float* bqkv   = (const float*)d_in[13];
    const float* Wo     = (const float*)d_in[14];
    const float* bo     = (const float*)d_in[15];
    const float* W1     = (const float*)d_in[16];
    const float* b1     = (const float*)d_in[17];
    const float* W2     = (const float*)d_in[18];
    const float* b2     = (const float*)d_in[19];
    const float* ln1g   = (const float*)d_in[20];
    const float* ln1b   = (const float*)d_in[21];
    const float* ln2g   = (const float*)d_in[22];
    const float* ln2b   = (const float*)d_in[23];
    const float* att_P  = (const float*)d_in[24];
    const float* att_Pb = (const float*)d_in[25];
    const float* att_q  = (const float*)d_in[26];
    const float* mg_fc  = (const float*)d_in[27];
    const float* mg_al  = (const float*)d_in[28];
    const float* mg_ar  = (const float*)d_in[29];
    const float* mg_res = (const float*)d_in[30];

    float* ws  = (float*)d_ws;
    float* T3  = ws + OFF_T3;
    float* DNV = ws + OFF_DEG;
    float* EL  = ws + OFF_EL;
    float* ER  = ws + OFF_ER;
    float* W0b = ws + OFF_W0;
    float* W1b = ws + OFF_W1;
    float* FB  = ws + OFF_FB;
    float* R2  = ws + OFF_R2;
    float* RST = ws + OFF_RST;
    float* EL2 = ws + OFF_EL2;
    float* ER2 = ws + OFF_ER2;
    float* ST  = ws + OFF_ST;

    unsigned short* T2B  = (unsigned short*)(ws + OFF_T2);
    unsigned short* BIGB = (unsigned short*)(ws + OFF_BIGB);
    unsigned short* HB   = BIGB;
    unsigned short* SB   = (unsigned short*)(ws + OFF_SB);
    unsigned short* AB   = (unsigned short*)(ws + OFF_AB);
    unsigned short* WB   = (unsigned short*)(ws + OFF_WB);
    unsigned short* GWB  = (unsigned short*)(ws + OFF_GWB);
    unsigned short* PB   = (unsigned short*)(ws + OFF_PB);

    int* ib    = (int*)(ws + OFF_INT);
    int* CNT   = ib + ICNT;
    int* CNT2  = ib + ICNT2;
    int* OFFS  = ib + IOFF;
    int* OFFS2 = ib + IOFF2;
    int* CUR   = ib + ICUR;
    int* CUR2  = ib + ICUR2;
    int* CSR   = ib + ICSR;
    int* CSR2  = ib + ICSR2;

    float* outp   = (float*)d_out;
    float* a0     = outp;
    float* a1     = outp + (size_t)kSN * kH;
    float* logits = outp + 2 * (size_t)kSN * kH;
    float* gemb   = outp + 2 * (size_t)kSN * kH + (size_t)kN * kC;

    dim3 blk(256);

    // ---- 0a. zero pad-tail rows of bf16 GEMM-A buffers ----
    hipMemsetAsync(SB + (size_t)kSN * 256, 0, (size_t)(kMP - kSN) * 256 * sizeof(unsigned short), stream);
    hipMemsetAsync(AB + (size_t)kSN * 256, 0, (size_t)(kMP - kSN) * 256 * sizeof(unsigned short), stream);
    hipMemsetAsync(BIGB + (size_t)kSN * 1024, 0, (size_t)(kMP - kSN) * 1024 * sizeof(unsigned short), stream);

    // ---- 0b. CSR build ----
    hipMemsetAsync(CNT, 0, (size_t)(kV * kN + kN) * sizeof(int), stream);
    count_k<<<dim3((kV * kE + 255) / 256), blk, 0, stream>>>(e_dst, CNT, kE, kN, kV * kE);
    count_k<<<dim3((kE2 + 255) / 256), blk, 0, stream>>>(gdst, CNT2, kE2, kN, kE2);
    scan_k<<<dim3(kV), dim3(1024), 0, stream>>>(CNT, OFFS, CUR, kN);
    scan_k<<<dim3(1), dim3(1024), 0, stream>>>(CNT2, OFFS2, CUR2, kN);
    fill_csr_k<<<dim3((kV * kE + 255) / 256), blk, 0, stream>>>(e_src, e_dst, CUR, CSR, kE, kN, kV * kE);
    fill_csr_k<<<dim3((kE2 + 255) / 256), blk, 0, stream>>>(gsrc, gdst, CUR2, CSR2, kE2, kN, kE2);
    dinv_k<<<dim3((kV * kN + 255) / 256), blk, 0, stream>>>(CNT, DNV, kV * kN);

    // ---- 0c. weight/activation bf16 conversion ----
    cvt_k<<<dim3((393216 / 4 + 255) / 256), blk, 0, stream>>>(Wqkv, WB, 393216 / 4);
    cvt_k<<<dim3((131072 / 4 + 255) / 256), blk, 0, stream>>>(Wo, WB + 393216, 131072 / 4);
    cvt_k<<<dim3((524288 / 4 + 255) / 256), blk, 0, stream>>>(W1, WB + 524288, 524288 / 4);
    cvt_k<<<dim3((524288 / 4 + 255) / 256), blk, 0, stream>>>(W2, WB + 1048576, 524288 / 4);
    tcvt_k<<<dim3((3 * 65536 + 255) / 256), blk, 0, stream>>>(gcn_W, GWB, 256, 256, 3 * 65536);
    tcvt_k<<<dim3((3 * 65536 + 255) / 256), blk, 0, stream>>>(gat_W, GWB + 3 * 65536, 256, 256, 3 * 65536);
    tcvt_k<<<dim3((2 * 32768 + 255) / 256), blk, 0, stream>>>(att_P, PB, 256, 128, 2 * 32768);
    cvt_k<<<dim3((kSN * 256 / 4 + 255) / 256), blk, 0, stream>>>(x, AB, kSN * 256 / 4);

    // ---- 1. multi-view GCN + relu -> SB (bf16) ----
    mgemm_k<0, false, true><<<dim3(2, 157, 3), blk, 0, stream>>>(
        AB, GWB, nullptr, nullptr, HB, kN, 256, 256, (long)kN * 256, 65536, kN);
    gcn_gather_k<<<dim3(kSN / 4), blk, 0, stream>>>(CSR, OFFS, CNT, DNV, HB, gcn_b, SB);

    // ---- 2. encoder 0 -> a0 f32 + AB bf16 ----
    run_encoder(SB, a0, AB, ws, 0, bqkv, bo, b1, b2, ln1g, ln1b, ln2g, ln2b, stream);

    // ---- 3. multi-view GAT + relu -> SB (bf16) ----
    mgemm_k<0, false, true><<<dim3(2, 157, 3), blk, 0, stream>>>(
        AB, GWB + 3 * 65536, nullptr, nullptr, HB, kN, 256, 256, (long)kN * 256, 65536, kN);
    rowdot2b_k<<<dim3(kSN), dim3(64), 0, stream>>>(HB, gat_as, gat_ad, EL, ER, kSN, 256, kN, kH);
    gat_gather_k<<<dim3(kSN / 4), blk, 0, stream>>>(CSR, OFFS, CNT, EL, ER, HB, gat_b, SB);

    // ---- 4. encoder 1 -> a1 f32 + AB bf16 ----
    run_encoder(SB, a1, AB, ws, 1, bqkv + 768, bo + 256, b1 + 1024, b2 + 256,
                ln1g + 256, ln1b + 256, ln2g + 256, ln2b + 256, stream);

    // ---- 5. view attention + blend -> gemb ----
    mgemm_k<3, false, true><<<dim3(2, 469, 1), blk, 0, stream>>>(
        AB, PB, att_Pb, nullptr, T2B, kSN, 256, 256, 0, 0, 0);
    attdot_k<<<dim3(kSN / 4), blk, 0, stream>>>(T2B, att_q, W0b, W1b, kSN);
    float* X1 = T3;
    float* X2 = T3 + (size_t)kN * kH;
    view_comb_k<<<dim3((kN * 64 + 255) / 256), blk, 0, stream>>>(AB, W0b, W1b, X1, X2);
    randsm_k<<<dim3(1), dim3(1024), 0, stream>>>(rand_w, ST);
    blend_k<<<dim3((kN * 64 + 255) / 256), blk, 0, stream>>>(X1, X2, rand_w, ST, gemb);

    // ---- 6. myGATConv -> logits ----
    gemm_k<0><<<dim3(1, (kN + 63) / 64), blk, 0, stream>>>(gemb, mg_fc, (const float*)nullptr, FB, kN, kC, 256);
    rowdot2_k<<<dim3(kN), dim3(64), 0, stream>>>(FB, mg_al, mg_ar, EL2, ER2, kN, kC, kN, 0);
    mygat_gather_k<<<dim3((kN + 7) / 8), blk, 0, stream>>>(CSR2, OFFS2, CNT2, EL2, ER2, FB, RST);
    gemm_k<0><<<dim3(1, (kN + 63) / 64), blk, 0, stream>>>(gemb, mg_res, (const float*)nullptr, R2, kN, kC, 256);
    final_k<<<dim3((kN + 255) / 256), blk, 0, stream>>>(RST, R2, logits);
}

// Round 14
// 935.143 us; speedup vs baseline: 1.6092x; 1.0474x over previous
//
#include <hip/hip_runtime.h>
#include <hip/hip_bf16.h>
#include <math.h>

// ---------------- problem constants ----------------
namespace {
constexpr int kV  = 3;
constexpr int kN  = 20000;
constexpr int kF  = 256;
constexpr int kH  = 256;
constexpr int kE  = 160000;
constexpr int kC  = 32;
constexpr int kNH = 8;
constexpr int kSN = kV * kN;     // 60000
constexpr int kE2 = kE + kN;     // 180000
constexpr int kMP = 60160;       // padded rows for bf16 GEMM-A buffers (=235*256)
constexpr int kNP = 20224;       // padded rows for gemb bf16 (=158*128)

// fp32 workspace layout (float element offsets)
constexpr size_t OFF_T1   = 0;                                   // GB bf16 / FB128 f32 / WMG bf16
constexpr size_t OFF_GB   = OFF_T1;                              // bf16 [kNP*256] = 2,588,672 floats
constexpr size_t OFF_FB1  = OFF_T1 + 2600000;                    // f32 [20000*128] = 2,560,000
constexpr size_t OFF_WMG  = OFF_T1 + 5200000;                    // bf16 [128*256] = 16384 floats
constexpr size_t OFF_T2   = OFF_T1 + (size_t)kMP * 256;          // bf16 T2B
constexpr size_t OFF_T3   = OFF_T2 + (size_t)kMP * 256;          // (spare)
constexpr size_t OFF_BIGB = OFF_T3 + (size_t)kMP * 256;          // bf16 [kMP*1024]
constexpr size_t OFF_SB   = OFF_BIGB + (size_t)kMP * 512;        // bf16 [kMP*256]
constexpr size_t OFF_AB   = OFF_SB + (size_t)kMP * 128;          // bf16 [kMP*256]
constexpr size_t OFF_WB   = OFF_AB + (size_t)kMP * 128;          // bf16 enc weights
constexpr size_t OFF_GWB  = OFF_WB + 786432;
constexpr size_t OFF_PB   = OFF_GWB + 196608;
constexpr size_t OFF_DEG  = OFF_PB + 32768;
constexpr size_t OFF_EL   = OFF_DEG + (size_t)kV * kN;
constexpr size_t OFF_ER   = OFF_EL  + (size_t)kV * kN;
constexpr size_t OFF_W0   = OFF_ER  + (size_t)kV * kN;
constexpr size_t OFF_W1   = OFF_W0  + (size_t)kV * kN;
constexpr size_t OFF_RST  = OFF_W1  + (size_t)kV * kN;
constexpr size_t OFF_EL2  = OFF_RST + (size_t)kN * kC;
constexpr size_t OFF_ER2  = OFF_EL2 + kN;
constexpr size_t OFF_ST   = OFF_ER2 + kN;
constexpr size_t OFF_INT  = OFF_ST + 4;
// int layout
constexpr size_t ICNT  = 0;
constexpr size_t ICNT2 = ICNT  + (size_t)kV * kN;
constexpr size_t IOFF  = ICNT2 + kN;
constexpr size_t IOFF2 = IOFF  + (size_t)kV * kN;
constexpr size_t ICUR  = IOFF2 + kN;
constexpr size_t ICUR2 = ICUR  + (size_t)kV * kN;
constexpr size_t ICSR  = ICUR2 + kN;
constexpr size_t ICSR2 = ICSR  + (size_t)kV * kE;
} // namespace

typedef __attribute__((ext_vector_type(4))) float f32x4;
typedef __attribute__((ext_vector_type(8))) __bf16 bf16x8;

__device__ __forceinline__ float lrelu(float x) { return x > 0.f ? x : 0.2f * x; }
__device__ __forceinline__ unsigned short f2b(float f) {
    unsigned u = __float_as_uint(f);
    return (unsigned short)((u + 0x7FFFu + ((u >> 16) & 1u)) >> 16);
}
__device__ __forceinline__ float b2f(unsigned short h) {
    return __uint_as_float((unsigned)h << 16);
}
// tanh via HW exp: tanh(x) = (e^{2x}-1)/(e^{2x}+1), clamped
__device__ __forceinline__ float fast_tanh(float x) {
    float xc = fminf(fmaxf(x, -15.f), 15.f);
    float e = __expf(2.0f * xc);
    return (e - 1.0f) / (e + 1.0f);
}

// ---------------- conversion kernels ----------------

__global__ void cvt_k(const float* __restrict__ in, unsigned short* __restrict__ out, int n4) {
    int i = blockIdx.x * 256 + threadIdx.x;
    if (i >= n4) return;
    float4 v = reinterpret_cast<const float4*>(in)[i];
    ushort4 o;
    o.x = f2b(v.x); o.y = f2b(v.y); o.z = f2b(v.z); o.w = f2b(v.w);
    reinterpret_cast<ushort4*>(out)[i] = o;
}

__global__ void tcvt_k(const float* __restrict__ in, unsigned short* __restrict__ out,
                       int K, int N, int total) {
    int gid = blockIdx.x * 256 + threadIdx.x;
    if (gid >= total) return;
    int per = K * N;
    int v = gid / per, r = gid - v * per;
    int n = r / K, k = r - n * K;
    out[gid] = f2b(in[(size_t)v * per + (size_t)k * N + n]);
}

// ---------------- MFMA bf16 GEMM: dbuf + XOR-slot-swizzled LDS + strength-reduced pointers ----
// C[M,N] = act(A[M,K] @ W[N,K]^T + bias). 128x128 tile, BK=32, 4 waves, 2-phase dbuf.
// ACT: 0 none, 1 relu, 2 tanh, 3 split (global col<128 tanh else relu).
template <int ACT, bool WF32, bool WB16>
__global__ __launch_bounds__(256, 4) void mgemm_k(const unsigned short* __restrict__ A,
                                                  const unsigned short* __restrict__ W,
                                                  const float* __restrict__ bias,
                                                  float* __restrict__ Cf,
                                                  unsigned short* __restrict__ Cb,
                                                  int M, int N, int K,
                                                  long zA, long zW, long zC) {
    static_assert(WF32 != WB16, "exactly one output path");
    __shared__ __align__(16) unsigned short shbuf[16384];   // 2 x (As 8KB + Ws 8KB); epilogue reuses

    const int tid  = threadIdx.x;
    const int lane = tid & 63;

    // bijective XCD-chunked swizzle of the (x,y) tile index (m204)
    const int gx = gridDim.x;
    const int nwg = gx * gridDim.y;
    const int orig = blockIdx.y * gx + blockIdx.x;
    const int q = nwg >> 3, rr = nwg & 7;
    const int xcd = orig & 7, pos = orig >> 3;
    const int nid = (xcd < rr ? xcd * (q + 1) : rr * (q + 1) + (xcd - rr) * q) + pos;
    const int bm = (nid / gx) * 128, bn = (nid % gx) * 128;

    A += (size_t)blockIdx.z * zA;
    W += (size_t)blockIdx.z * zW;
    const size_t zrow = (size_t)blockIdx.z * zC;

    const int wv = tid >> 6;
    const int wm = (wv >> 1) * 64, wn = (wv & 1) * 64;
    const int fr = lane & 15;

    const int r0 = tid >> 2;
    const int xorv = (r0 >> 1) & 3;
    const int slo = ((tid & 3) ^ xorv) * 8;

    const unsigned short* pa0 = A + (size_t)(bm + r0) * K + slo;
    const unsigned short* pw0 = W + (size_t)(bn + r0) * K + slo;
    const unsigned short* pa1 = A + (size_t)(bm + 64 + r0) * K + slo;
    const unsigned short* pw1 = W + (size_t)(bn + 64 + r0) * K + slo;

    const int slr = (((lane >> 4) ^ ((fr >> 1) & 3))) * 8;

    f32x4 acc[4][4] = {};

    // prologue: stage tile 0 into buffer 0
    {
        unsigned short* As = shbuf;
        unsigned short* Ws = shbuf + 4096;
        __builtin_amdgcn_global_load_lds((const __attribute__((address_space(1))) void*)pa0,
                                         (__attribute__((address_space(3))) void*)(As + tid * 8), 16, 0, 0);
        __builtin_amdgcn_global_load_lds((const __attribute__((address_space(1))) void*)pw0,
                                         (__attribute__((address_space(3))) void*)(Ws + tid * 8), 16, 0, 0);
        __builtin_amdgcn_global_load_lds((const __attribute__((address_space(1))) void*)pa1,
                                         (__attribute__((address_space(3))) void*)(As + (256 + tid) * 8), 16, 0, 0);
        __builtin_amdgcn_global_load_lds((const __attribute__((address_space(1))) void*)pw1,
                                         (__attribute__((address_space(3))) void*)(Ws + (256 + tid) * 8), 16, 0, 0);
        pa0 += 32; pw0 += 32; pa1 += 32; pw1 += 32;
    }
    __syncthreads();

    int cur = 0;
    for (int k0 = 0; k0 < K; k0 += 32) {
        if (k0 + 32 < K) {
            unsigned short* As = shbuf + (cur ^ 1) * 8192;
            unsigned short* Ws = As + 4096;
            __builtin_amdgcn_global_load_lds((const __attribute__((address_space(1))) void*)pa0,
                                             (__attribute__((address_space(3))) void*)(As + tid * 8), 16, 0, 0);
            __builtin_amdgcn_global_load_lds((const __attribute__((address_space(1))) void*)pw0,
                                             (__attribute__((address_space(3))) void*)(Ws + tid * 8), 16, 0, 0);
            __builtin_amdgcn_global_load_lds((const __attribute__((address_space(1))) void*)pa1,
                                             (__attribute__((address_space(3))) void*)(As + (256 + tid) * 8), 16, 0, 0);
            __builtin_amdgcn_global_load_lds((const __attribute__((address_space(1))) void*)pw1,
                                             (__attribute__((address_space(3))) void*)(Ws + (256 + tid) * 8), 16, 0, 0);
            pa0 += 32; pw0 += 32; pa1 += 32; pw1 += 32;
        }
        const unsigned short* As = shbuf + cur * 8192;
        const unsigned short* Ws = As + 4096;
        bf16x8 av[4], bv[4];
#pragma unroll
        for (int mi = 0; mi < 4; ++mi)
            av[mi] = *reinterpret_cast<const bf16x8*>(As + (wm + mi * 16 + fr) * 32 + slr);
#pragma unroll
        for (int ni = 0; ni < 4; ++ni)
            bv[ni] = *reinterpret_cast<const bf16x8*>(Ws + (wn + ni * 16 + fr) * 32 + slr);
#pragma unroll
        for (int mi = 0; mi < 4; ++mi)
#pragma unroll
            for (int ni = 0; ni < 4; ++ni)
                acc[mi][ni] = __builtin_amdgcn_mfma_f32_16x16x32_bf16(av[mi], bv[ni], acc[mi][ni], 0, 0, 0);
        __syncthreads();
        cur ^= 1;
    }

    const int crow = (lane >> 4) * 4;
    const int ccol = lane & 15;

    if (WB16) {
#pragma unroll
        for (int mi = 0; mi < 4; ++mi)
#pragma unroll
            for (int r = 0; r < 4; ++r) {
                const int row = wm + mi * 16 + crow + r;
#pragma unroll
                for (int ni = 0; ni < 4; ++ni) {
                    const int col = wn + ni * 16 + ccol;
                    float v = acc[mi][ni][r];
                    if (bias) v += bias[bn + col];
                    if (ACT == 1) v = fmaxf(v, 0.f);
                    if (ACT == 2) v = fast_tanh(v);
                    if (ACT == 3) v = (bn + col < 128) ? fast_tanh(v) : fmaxf(v, 0.f);
                    shbuf[row * 128 + col] = f2b(v);
                }
            }
        __syncthreads();
#pragma unroll
        for (int it = 0; it < 8; ++it) {
            const int fl = it * 2048 + tid * 8;
            const int row = fl >> 7, col = fl & 127;
            const int grow = bm + row;
            if (grow < M) {
                uint4 d = *reinterpret_cast<const uint4*>(shbuf + row * 128 + col);
                *reinterpret_cast<uint4*>(Cb + (zrow + grow) * (size_t)N + bn + col) = d;
            }
        }
    } else {
        float* epf = reinterpret_cast<float*>(shbuf);
#pragma unroll
        for (int half = 0; half < 2; ++half) {
            if ((wm >> 6) == half) {
#pragma unroll
                for (int mi = 0; mi < 4; ++mi)
#pragma unroll
                    for (int r = 0; r < 4; ++r) {
                        const int row = mi * 16 + crow + r;
#pragma unroll
                        for (int ni = 0; ni < 4; ++ni) {
                            const int col = wn + ni * 16 + ccol;
                            float v = acc[mi][ni][r];
                            if (bias) v += bias[bn + col];
                            if (ACT == 1) v = fmaxf(v, 0.f);
                            if (ACT == 2) v = fast_tanh(v);
                            if (ACT == 3) v = (bn + col < 128) ? fast_tanh(v) : fmaxf(v, 0.f);
                            epf[row * 128 + col] = v;
                        }
                    }
            }
            __syncthreads();
#pragma unroll
            for (int it = 0; it < 8; ++it) {
                const int fl = it * 1024 + tid * 4;
                const int row = fl >> 7, col = fl & 127;
                const int grow = bm + half * 64 + row;
                if (grow < M) {
                    float4 d = *reinterpret_cast<const float4*>(epf + row * 128 + col);
                    *reinterpret_cast<float4*>(Cf + (zrow + grow) * (size_t)N + bn + col) = d;
                }
            }
            __syncthreads();
        }
    }
}

// out = LN(x+y)*g+b; wave per row; x,y bf16 ushort4/lane; WF32: also write f32.
template <bool WF32>
__global__ __launch_bounds__(256) void ln_add_k(const unsigned short* __restrict__ x,
                                                const unsigned short* __restrict__ y,
                                                const float* __restrict__ g, const float* __restrict__ b,
                                                float* __restrict__ outf, unsigned short* __restrict__ outb,
                                                int rows) {
    int r = blockIdx.x * 4 + (threadIdx.x >> 6);
    if (r >= rows) return;
    int lane = threadIdx.x & 63;
    size_t base = (size_t)r * 256 + lane * 4;
    ushort4 xu = *reinterpret_cast<const ushort4*>(x + base);
    ushort4 yu = *reinterpret_cast<const ushort4*>(y + base);
    float4 t;
    t.x = b2f(xu.x) + b2f(yu.x); t.y = b2f(xu.y) + b2f(yu.y);
    t.z = b2f(xu.z) + b2f(yu.z); t.w = b2f(xu.w) + b2f(yu.w);
    float s = t.x + t.y + t.z + t.w;
#pragma unroll
    for (int off = 32; off > 0; off >>= 1) s += __shfl_xor(s, off, 64);
    float mean = s * (1.0f / 256.0f);
    float4 d;
    d.x = t.x - mean; d.y = t.y - mean; d.z = t.z - mean; d.w = t.w - mean;
    float s2 = d.x * d.x + d.y * d.y + d.z * d.z + d.w * d.w;
#pragma unroll
    for (int off = 32; off > 0; off >>= 1) s2 += __shfl_xor(s2, off, 64);
    float rs = rsqrtf(s2 * (1.0f / 256.0f) + 1e-5f);
    float4 gv = *reinterpret_cast<const float4*>(g + lane * 4);
    float4 bv = *reinterpret_cast<const float4*>(b + lane * 4);
    float4 o;
    o.x = d.x * rs * gv.x + bv.x;
    o.y = d.y * rs * gv.y + bv.y;
    o.z = d.z * rs * gv.z + bv.z;
    o.w = d.w * rs * gv.w + bv.w;
    if (WF32) *reinterpret_cast<float4*>(outf + base) = o;
    ushort4 ob;
    ob.x = f2b(o.x); ob.y = f2b(o.y); ob.z = f2b(o.z); ob.w = f2b(o.w);
    *reinterpret_cast<ushort4*>(outb + base) = ob;
}

// fused dual 128-dot from bf16 [rows][256]
__global__ __launch_bounds__(256) void attdot_k(const unsigned short* __restrict__ A, const float* __restrict__ q,
                                                float* __restrict__ o1, float* __restrict__ o2, int rows) {
    int r = blockIdx.x * 4 + (threadIdx.x >> 6);
    if (r >= rows) return;
    int lane = threadIdx.x & 63;
    const unsigned short* row = A + (size_t)r * 256;
    ushort2 va = *reinterpret_cast<const ushort2*>(row + lane * 2);
    ushort2 vb = *reinterpret_cast<const ushort2*>(row + 128 + lane * 2);
    float2 qa = *reinterpret_cast<const float2*>(q + lane * 2);
    float2 qb = *reinterpret_cast<const float2*>(q + 128 + lane * 2);
    float s1 = b2f(va.x) * qa.x + b2f(va.y) * qa.y;
    float s2 = b2f(vb.x) * qb.x + b2f(vb.y) * qb.y;
#pragma unroll
    for (int off = 32; off > 0; off >>= 1) {
        s1 += __shfl_xor(s1, off, 64);
        s2 += __shfl_xor(s2, off, 64);
    }
    if (lane == 0) { o1[r] = s1; o2[r] = s2; }
}

// per-row dual dot products, bf16 A, ushort4 per lane
__global__ void rowdot2b_k(const unsigned short* __restrict__ A, const float* __restrict__ v1,
                           const float* __restrict__ v2, float* __restrict__ o1,
                           float* __restrict__ o2, int rows, int K, int rowsPerVec, int vecStride) {
    int r = blockIdx.x;
    if (r >= rows) return;
    int lane = threadIdx.x;
    const unsigned short* base = A + (size_t)r * K;
    int vo = (r / rowsPerVec) * vecStride;
    float s1 = 0.f, s2 = 0.f;
    for (int c = lane * 4; c < K; c += 256) {
        ushort4 a4 = *reinterpret_cast<const ushort4*>(base + c);
        float4 w1 = *reinterpret_cast<const float4*>(v1 + vo + c);
        float4 w2 = *reinterpret_cast<const float4*>(v2 + vo + c);
        s1 += b2f(a4.x) * w1.x + b2f(a4.y) * w1.y + b2f(a4.z) * w1.z + b2f(a4.w) * w1.w;
        s2 += b2f(a4.x) * w2.x + b2f(a4.y) * w2.y + b2f(a4.z) * w2.z + b2f(a4.w) * w2.w;
    }
#pragma unroll
    for (int off = 32; off > 0; off >>= 1) {
        s1 += __shfl_xor(s1, off, 64);
        s2 += __shfl_xor(s2, off, 64);
    }
    if (lane == 0) { o1[r] = s1; o2[r] = s2; }
}

// myGAT edge-logit dots from FB128 f32 [rows][128] (cols 0..31 = fc output)
__global__ __launch_bounds__(256) void mgdot_k(const float* __restrict__ F, const float* __restrict__ al,
                                               const float* __restrict__ ar, float* __restrict__ o1,
                                               float* __restrict__ o2, int rows) {
    int r = blockIdx.x * 4 + (threadIdx.x >> 6);
    if (r >= rows) return;
    int lane = threadIdx.x & 63;
    float s1 = 0.f, s2 = 0.f;
    if (lane < 32) {
        float a = F[(size_t)r * 128 + lane];
        s1 = a * al[lane];
        s2 = a * ar[lane];
    }
#pragma unroll
    for (int off = 32; off > 0; off >>= 1) {
        s1 += __shfl_xor(s1, off, 64);
        s2 += __shfl_xor(s2, off, 64);
    }
    if (lane == 0) { o1[r] = s1; o2[r] = s2; }
}

// ---------------- CSR build ----------------

__global__ void count_k(const int* __restrict__ dst, int* __restrict__ cnt, int nE, int nN, int total) {
    int gid = blockIdx.x * 256 + threadIdx.x;
    if (gid >= total) return;
    int v = gid / nE;
    atomicAdd(&cnt[(size_t)v * nN + dst[gid]], 1);
}

__global__ __launch_bounds__(1024) void scan_k(const int* __restrict__ cnt, int* __restrict__ offs,
                                               int* __restrict__ cursor, int nN) {
    int v = blockIdx.x;
    const int* c = cnt + (size_t)v * nN;
    int* o  = offs + (size_t)v * nN;
    int* cu = cursor + (size_t)v * nN;
    int tid = threadIdx.x;
    int chunk = (nN + 1023) >> 10;
    int lo = tid * chunk;
    int hi = lo + chunk < nN ? lo + chunk : nN;
    int s = 0;
    for (int i = lo; i < hi; ++i) s += c[i];
    int lane = tid & 63, wid = tid >> 6;
    int x = s;
#pragma unroll
    for (int off = 1; off < 64; off <<= 1) {
        int y = __shfl_up(x, off, 64);
        if (lane >= off) x += y;
    }
    __shared__ int wsum[16];
    if (lane == 63) wsum[wid] = x;
    __syncthreads();
    if (tid == 0) {
        int a = 0;
        for (int w = 0; w < 16; ++w) { int t = wsum[w]; wsum[w] = a; a += t; }
    }
    __syncthreads();
    int base = x - s + wsum[wid];
    for (int i = lo; i < hi; ++i) { o[i] = base; cu[i] = base; base += c[i]; }
}

__global__ void fill_csr_k(const int* __restrict__ src, const int* __restrict__ dst,
                           int* __restrict__ cursor, int* __restrict__ csr,
                           int nE, int nN, int total) {
    int gid = blockIdx.x * 256 + threadIdx.x;
    if (gid >= total) return;
    int v = gid / nE;
    int pos = atomicAdd(&cursor[(size_t)v * nN + dst[gid]], 1);
    csr[(size_t)v * nE + pos] = src[gid];
}

__global__ void dinv_k(const int* __restrict__ cnt, float* __restrict__ dinv, int n) {
    int gid = blockIdx.x * 256 + threadIdx.x;
    if (gid < n) dinv[gid] = rsqrtf((float)cnt[gid] + 1.0f);
}

// ---------------- GCN gather: one WAVE per node, LDS-free, ushort4/lane; bf16 out only ----------------

__global__ __launch_bounds__(256) void gcn_gather_k(const int* __restrict__ csr, const int* __restrict__ offs,
                                                    const int* __restrict__ cnt, const float* __restrict__ dinv,
                                                    const unsigned short* __restrict__ h, const float* __restrict__ b,
                                                    unsigned short* __restrict__ outb) {
    int nd = blockIdx.x * 4 + (threadIdx.x >> 6);
    if (nd >= kV * kN) return;
    int v  = nd / kN;
    int lane = threadIdx.x & 63;
    int c4 = lane * 4;
    const int* base = csr + (size_t)v * kE;
    int o0 = offs[nd], n = cnt[nd];
    float dd = dinv[nd];
    const float* dv = dinv + (size_t)v * kN;
    const unsigned short* hb = h + (size_t)v * kN * kH;

    ushort4 hs = *reinterpret_cast<const ushort4*>(h + (size_t)nd * kH + c4);
    float wts = dd * dd;
    float4 acc;
    acc.x = b2f(hs.x) * wts; acc.y = b2f(hs.y) * wts;
    acc.z = b2f(hs.z) * wts; acc.w = b2f(hs.w) * wts;
    int i = 0;
    for (; i + 2 <= n; i += 2) {
        int s0 = base[o0 + i], s1 = base[o0 + i + 1];
        float w0 = dv[s0] * dd, w1 = dv[s1] * dd;
        ushort4 h0 = *reinterpret_cast<const ushort4*>(hb + (size_t)s0 * kH + c4);
        ushort4 h1 = *reinterpret_cast<const ushort4*>(hb + (size_t)s1 * kH + c4);
        acc.x += b2f(h0.x) * w0 + b2f(h1.x) * w1;
        acc.y += b2f(h0.y) * w0 + b2f(h1.y) * w1;
        acc.z += b2f(h0.z) * w0 + b2f(h1.z) * w1;
        acc.w += b2f(h0.w) * w0 + b2f(h1.w) * w1;
    }
    if (i < n) {
        int s0 = base[o0 + i];
        float w0 = dv[s0] * dd;
        ushort4 h0 = *reinterpret_cast<const ushort4*>(hb + (size_t)s0 * kH + c4);
        acc.x += b2f(h0.x) * w0; acc.y += b2f(h0.y) * w0;
        acc.z += b2f(h0.z) * w0; acc.w += b2f(h0.w) * w0;
    }
    float4 bb = *reinterpret_cast<const float4*>(b + (size_t)v * kH + c4);
    ushort4 ob;
    ob.x = f2b(fmaxf(acc.x + bb.x, 0.f));
    ob.y = f2b(fmaxf(acc.y + bb.y, 0.f));
    ob.z = f2b(fmaxf(acc.z + bb.z, 0.f));
    ob.w = f2b(fmaxf(acc.w + bb.w, 0.f));
    *reinterpret_cast<ushort4*>(outb + (size_t)nd * kH + c4) = ob;
}

// ---------------- GAT gather: one WAVE per node, LDS-free; bf16 out only ----------------

__global__ __launch_bounds__(256) void gat_gather_k(const int* __restrict__ csr, const int* __restrict__ offs,
                                                    const int* __restrict__ cnt, const float* __restrict__ el,
                                                    const float* __restrict__ er, const unsigned short* __restrict__ h,
                                                    const float* __restrict__ b, unsigned short* __restrict__ outb) {
    int nd = blockIdx.x * 4 + (threadIdx.x >> 6);
    if (nd >= kV * kN) return;
    int v  = nd / kN;
    int lane = threadIdx.x & 63;
    int c4 = lane * 4;
    const int* base = csr + (size_t)v * kE;
    int o0 = offs[nd], n = cnt[nd];
    float erd = er[nd];
    const float* elv = el + (size_t)v * kN;
    const unsigned short* hb = h + (size_t)v * kN * kH;
    float eself = lrelu(el[nd] + erd);

    float m = eself;
    for (int i = 0; i < n; ++i) m = fmaxf(m, lrelu(elv[base[o0 + i]] + erd));

    float es = __expf(eself - m);
    float z = es;
    ushort4 hs = *reinterpret_cast<const ushort4*>(h + (size_t)nd * kH + c4);
    float4 acc;
    acc.x = b2f(hs.x) * es; acc.y = b2f(hs.y) * es;
    acc.z = b2f(hs.z) * es; acc.w = b2f(hs.w) * es;
    int i = 0;
    for (; i + 2 <= n; i += 2) {
        int s0 = base[o0 + i], s1 = base[o0 + i + 1];
        float e0 = __expf(lrelu(elv[s0] + erd) - m);
        float e1 = __expf(lrelu(elv[s1] + erd) - m);
        z += e0 + e1;
        ushort4 h0 = *reinterpret_cast<const ushort4*>(hb + (size_t)s0 * kH + c4);
        ushort4 h1 = *reinterpret_cast<const ushort4*>(hb + (size_t)s1 * kH + c4);
        acc.x += b2f(h0.x) * e0 + b2f(h1.x) * e1;
        acc.y += b2f(h0.y) * e0 + b2f(h1.y) * e1;
        acc.z += b2f(h0.z) * e0 + b2f(h1.z) * e1;
        acc.w += b2f(h0.w) * e0 + b2f(h1.w) * e1;
    }
    if (i < n) {
        int s0 = base[o0 + i];
        float e0 = __expf(lrelu(elv[s0] + erd) - m);
        z += e0;
        ushort4 h0 = *reinterpret_cast<const ushort4*>(hb + (size_t)s0 * kH + c4);
        acc.x += b2f(h0.x) * e0; acc.y += b2f(h0.y) * e0;
        acc.z += b2f(h0.z) * e0; acc.w += b2f(h0.w) * e0;
    }
    float iz = 1.0f / z;
    float4 bb = *reinterpret_cast<const float4*>(b + (size_t)v * kH + c4);
    ushort4 ob;
    ob.x = f2b(fmaxf(acc.x * iz + bb.x, 0.f));
    ob.y = f2b(fmaxf(acc.y * iz + bb.y, 0.f));
    ob.z = f2b(fmaxf(acc.z * iz + bb.z, 0.f));
    ob.w = f2b(fmaxf(acc.w * iz + bb.w, 0.f));
    *reinterpret_cast<ushort4*>(outb + (size_t)nd * kH + c4) = ob;
}

// ---------------- transformer: 3x3 attention, 8 lanes per (node,head), ushort4 ----------------

__global__ __launch_bounds__(256) void mha3_k(const unsigned short* __restrict__ qkv, unsigned short* __restrict__ o) {
    int grp = blockIdx.x * 32 + (threadIdx.x >> 3);
    int l8 = threadIdx.x & 7;
    if (grp >= kN * kNH) return;
    int b = grp / kNH, h = grp - b * kNH;
    float4 q[3], k[3], vv[3];
#pragma unroll
    for (int s = 0; s < 3; ++s) {
        size_t base = ((size_t)s * kN + b) * 768 + h * 32 + l8 * 4;
        ushort4 qu = *reinterpret_cast<const ushort4*>(qkv + base);
        ushort4 ku = *reinterpret_cast<const ushort4*>(qkv + base + 256);
        ushort4 vu = *reinterpret_cast<const ushort4*>(qkv + base + 512);
        q[s].x = b2f(qu.x); q[s].y = b2f(qu.y); q[s].z = b2f(qu.z); q[s].w = b2f(qu.w);
        k[s].x = b2f(ku.x); k[s].y = b2f(ku.y); k[s].z = b2f(ku.z); k[s].w = b2f(ku.w);
        vv[s].x = b2f(vu.x); vv[s].y = b2f(vu.y); vv[s].z = b2f(vu.z); vv[s].w = b2f(vu.w);
    }
    float sc[3][3];
#pragma unroll
    for (int s = 0; s < 3; ++s)
#pragma unroll
        for (int t = 0; t < 3; ++t) {
            float d = q[s].x * k[t].x + q[s].y * k[t].y + q[s].z * k[t].z + q[s].w * k[t].w;
            d += __shfl_xor(d, 1, 64);
            d += __shfl_xor(d, 2, 64);
            d += __shfl_xor(d, 4, 64);
            sc[s][t] = d * 0.17677669529663687f;
        }
#pragma unroll
    for (int s = 0; s < 3; ++s) {
        float m = fmaxf(sc[s][0], fmaxf(sc[s][1], sc[s][2]));
        float e0 = __expf(sc[s][0] - m), e1 = __expf(sc[s][1] - m), e2 = __expf(sc[s][2] - m);
        float iz = 1.0f / (e0 + e1 + e2);
        ushort4 ob;
        ob.x = f2b((e0 * vv[0].x + e1 * vv[1].x + e2 * vv[2].x) * iz);
        ob.y = f2b((e0 * vv[0].y + e1 * vv[1].y + e2 * vv[2].y) * iz);
        ob.z = f2b((e0 * vv[0].z + e1 * vv[1].z + e2 * vv[2].z) * iz);
        ob.w = f2b((e0 * vv[0].w + e1 * vv[1].w + e2 * vv[2].w) * iz);
        *reinterpret_cast<ushort4*>(o + ((size_t)s * kN + b) * kH + h * 32 + l8 * 4) = ob;
    }
}

// ---------------- fused view attention + blend: writes gemb f32 + GB bf16 ----------------

__global__ void view_blend_k(const unsigned short* __restrict__ a1b, const float* __restrict__ w0,
                             const float* __restrict__ w1, const float* __restrict__ rw,
                             const float* __restrict__ stats, float* __restrict__ gout,
                             unsigned short* __restrict__ gb) {
    int gid = blockIdx.x * 256 + threadIdx.x;
    if (gid >= kN * 64) return;
    int n = gid >> 6;
    int c4 = (gid & 63) << 2;
    float u0 = w0[n], u1 = w0[kN + n], u2 = w0[2 * kN + n];
    float m = fmaxf(u0, fmaxf(u1, u2));
    float e0 = __expf(u0 - m), e1 = __expf(u1 - m), e2 = __expf(u2 - m);
    float iz = 1.f / (e0 + e1 + e2);
    float p0 = e0 * iz, p1 = e1 * iz, p2 = e2 * iz;
    float q0 = w1[n], q1 = w1[kN + n], q2 = w1[2 * kN + n];
    float mq = fmaxf(q0, fmaxf(q1, q2));
    float f0 = __expf(q0 - mq), f1 = __expf(q1 - mq), f2 = __expf(q2 - mq);
    float izq = 1.f / (f0 + f1 + f2);
    float r0 = f0 * izq, r1 = f1 * izq, r2 = f2 * izq;
    float aw = __expf(rw[n] - stats[0]) / stats[1];
    // blended weights per view: wv = aw*p + (1-aw)*r
    float b0 = aw * p0 + (1.f - aw) * r0;
    float b1v = aw * p1 + (1.f - aw) * r1;
    float b2v = aw * p2 + (1.f - aw) * r2;
    ushort4 U0 = *reinterpret_cast<const ushort4*>(a1b + ((size_t)0 * kN + n) * 256 + c4);
    ushort4 U1 = *reinterpret_cast<const ushort4*>(a1b + ((size_t)1 * kN + n) * 256 + c4);
    ushort4 U2 = *reinterpret_cast<const ushort4*>(a1b + ((size_t)2 * kN + n) * 256 + c4);
    float4 o;
    o.x = b0 * b2f(U0.x) + b1v * b2f(U1.x) + b2v * b2f(U2.x);
    o.y = b0 * b2f(U0.y) + b1v * b2f(U1.y) + b2v * b2f(U2.y);
    o.z = b0 * b2f(U0.z) + b1v * b2f(U1.z) + b2v * b2f(U2.z);
    o.w = b0 * b2f(U0.w) + b1v * b2f(U1.w) + b2v * b2f(U2.w);
    *reinterpret_cast<float4*>(gout + (size_t)n * 256 + c4) = o;
    ushort4 ob;
    ob.x = f2b(o.x); ob.y = f2b(o.y); ob.z = f2b(o.z); ob.w = f2b(o.w);
    *reinterpret_cast<ushort4*>(gb + (size_t)n * 256 + c4) = ob;
}

__global__ __launch_bounds__(1024) void randsm_k(const float* __restrict__ rw, float* __restrict__ stats) {
    __shared__ float sm[16];
    __shared__ float ss[16];
    int tid = threadIdx.x;
    float m = -1e30f;
    for (int i = tid; i < kN; i += 1024) m = fmaxf(m, rw[i]);
#pragma unroll
    for (int off = 32; off > 0; off >>= 1) m = fmaxf(m, __shfl_xor(m, off, 64));
    if ((tid & 63) == 0) sm[tid >> 6] = m;
    __syncthreads();
    if (tid == 0) {
        float mm = sm[0];
        for (int i = 1; i < 16; ++i) mm = fmaxf(mm, sm[i]);
        sm[0] = mm;
    }
    __syncthreads();
    float mx = sm[0];
    float s = 0.f;
    for (int i = tid; i < kN; i += 1024) s += __expf(rw[i] - mx);
#pragma unroll
    for (int off = 32; off > 0; off >>= 1) s += __shfl_xor(s, off, 64);
    if ((tid & 63) == 0) ss[tid >> 6] = s;
    __syncthreads();
    if (tid == 0) {
        float z = 0.f;
        for (int i = 0; i < 16; ++i) z += ss[i];
        stats[0] = mx;
        stats[1] = z;
    }
}

// ---------------- myGAT gather (f = FB128 stride 128, cols 0..31) ----------------

__global__ __launch_bounds__(256) void mygat_gather_k(const int* __restrict__ csr, const int* __restrict__ offs,
                                                      const int* __restrict__ cnt, const float* __restrict__ el,
                                                      const float* __restrict__ er, const float* __restrict__ f,
                                                      float* __restrict__ rst) {
    int node = blockIdx.x * 8 + (threadIdx.x >> 5);
    int c = threadIdx.x & 31;
    if (node >= kN) return;
    int o0 = offs[node], n = cnt[node];
    float erd = er[node];
    float m = -1e30f;
    for (int i = 0; i < n; ++i) {
        int s = csr[o0 + i];
        m = fmaxf(m, lrelu(el[s] + erd));
    }
    float z = 0.f, acc = 0.f;
    for (int i = 0; i < n; ++i) {
        int s = csr[o0 + i];
        float e = __expf(lrelu(el[s] + erd) - m);
        z += e;
        acc += f[(size_t)s * 128 + c] * e;
    }
    rst[(size_t)node * kC + c] = acc / z;
}

__global__ void final_k(const float* __restrict__ rst, const float* __restrict__ F,
                        float* __restrict__ logits) {
    int n = blockIdx.x * 256 + threadIdx.x;
    if (n >= kN) return;
    float vals[kC];
    float ssum = 0.f;
#pragma unroll
    for (int c = 0; c < kC; ++c) {
        vals[c] = rst[(size_t)n * kC + c] + F[(size_t)n * 128 + 32 + c];
        ssum += vals[c] * vals[c];
    }
    float inv = 1.0f / fmaxf(sqrtf(ssum), 1e-12f);
#pragma unroll
    for (int c = 0; c < kC; ++c) logits[(size_t)n * kC + c] = vals[c] * inv;
}

// ---------------- host orchestration ----------------

static void run_encoder(unsigned short* xinB, float* outp, unsigned short* outB, float* ws, int e,
                        const float* bqkv, const float* bo, const float* b1, const float* b2,
                        const float* g1, const float* be1, const float* g2, const float* be2,
                        hipStream_t stream) {
    unsigned short* T2B  = (unsigned short*)(ws + OFF_T2);
    unsigned short* BIGB = (unsigned short*)(ws + OFF_BIGB);
    unsigned short* OB   = BIGB + (size_t)kMP * 768;
    unsigned short* WB   = (unsigned short*)(ws + OFF_WB);
    const unsigned short* WQ = WB + (size_t)e * 196608;
    const unsigned short* WO = WB + 393216 + (size_t)e * 65536;
    const unsigned short* W1 = WB + 524288 + (size_t)e * 262144;
    const unsigned short* W2 = WB + 1048576 + (size_t)e * 262144;
    dim3 blk(256);

    mgemm_k<0, false, true><<<dim3(6, 469, 1), blk, 0, stream>>>(
        xinB, WQ, bqkv, nullptr, BIGB, kSN, 768, 256, 0, 0, 0);
    mha3_k<<<dim3((kN * kNH) / 32), blk, 0, stream>>>(BIGB, OB);
    mgemm_k<0, false, true><<<dim3(2, 469, 1), blk, 0, stream>>>(
        OB, WO, bo, nullptr, T2B, kSN, 256, 256, 0, 0, 0);
    ln_add_k<false><<<dim3(kSN / 4), blk, 0, stream>>>(xinB, T2B, g1, be1, nullptr, xinB, kSN);
    mgemm_k<1, false, true><<<dim3(8, 469, 1), blk, 0, stream>>>(
        xinB, W1, b1, nullptr, BIGB, kSN, 1024, 256, 0, 0, 0);
    mgemm_k<0, false, true><<<dim3(2, 469, 1), blk, 0, stream>>>(
        BIGB, W2, b2, nullptr, T2B, kSN, 256, 1024, 0, 0, 0);
    ln_add_k<true><<<dim3(kSN / 4), blk, 0, stream>>>(xinB, T2B, g2, be2, outp, outB, kSN);
}

extern "C" void kernel_launch(void* const* d_in, const int* in_sizes, int n_in,
                              void* d_out, int out_size, void* d_ws, size_t ws_size,
                              hipStream_t stream) {
    (void)in_sizes; (void)n_in; (void)out_size; (void)ws_size;

    const float* x      = (const float*)d_in[0];
    const int*   e_src  = (const int*)d_in[1];
    const int*   e_dst  = (const int*)d_in[2];
    const int*   gsrc   = (const int*)d_in[3];
    const int*   gdst   = (const int*)d_in[4];
    const float* rand_w = (const float*)d_in[5];
    const float* gcn_W  = (const float*)d_in[6];
    const float* gcn_b  = (const float*)d_in[7];
    const float* gat_W  = (const float*)d_in[8];
    const float* gat_as = (const float*)d_in[9];
    const float* gat_ad = (const float*)d_in[10];
    const float* gat_b  = (const float*)d_in[11];
    const float* Wqkv   = (const float*)d_in[12];
    const float* bqkv   = (const float*)d_in[13];
    const float* Wo     = (const float*)d_in[14];
    const float* bo     = (const float*)d_in[15];
    const float* W1     = (const float*)d_in[16];
    const float* b1     = (const float*)d_in[17];
    const float* W2     = (const float*)d_in[18];
    const float* b2     = (const float*)d_in[19];
    const float* ln1g   = (const float*)d_in[20];
    const float* ln1b   = (const float*)d_in[21];
    const float* ln2g   = (const float*)d_in[22];
    const float* ln2b   = (const float*)d_in[23];
    const float* att_P  = (const float*)d_in[24];
    const float* att_Pb = (const float*)d_in[25];
    const float* att_q  = (const float*)d_in[26];
    const float* mg_fc  = (const float*)d_in[27];
    const float* mg_al  = (const float*)d_in[28];
    const float* mg_ar  = (const float*)d_in[29];
    const float* mg_res = (const float*)d_in[30];

    float* ws  = (float*)d_ws;
    float* DNV = ws + OFF_DEG;
    float* EL  = ws + OFF_EL;
    float* ER  = ws + OFF_ER;
    float* W0b = ws + OFF_W0;
    float* W1b = ws + OFF_W1;
    float* RST = ws + OFF_RST;
    float* EL2 = ws + OFF_EL2;
    float* ER2 = ws + OFF_ER2;
    float* ST  = ws + OFF_ST;
    float* FB128 = ws + OFF_FB1;

    unsigned short* GB   = (unsigned short*)(ws + OFF_GB);
    unsigned short* WMG  = (unsigned short*)(ws + OFF_WMG);
    unsigned short* T2B  = (unsigned short*)(ws + OFF_T2);
    unsigned short* BIGB = (unsigned short*)(ws + OFF_BIGB);
    unsigned short* HB   = BIGB;
    unsigned short* SB   = (unsigned short*)(ws + OFF_SB);
    unsigned short* AB   = (unsigned short*)(ws + OFF_AB);
    unsigned short* WB   = (unsigned short*)(ws + OFF_WB);
    unsigned short* GWB  = (unsigned short*)(ws + OFF_GWB);
    unsigned short* PB   = (unsigned short*)(ws + OFF_PB);

    int* ib    = (int*)(ws + OFF_INT);
    int* CNT   = ib + ICNT;
    int* CNT2  = ib + ICNT2;
    int* OFFS  = ib + IOFF;
    int* OFFS2 = ib + IOFF2;
    int* CUR   = ib + ICUR;
    int* CUR2  = ib + ICUR2;
    int* CSR   = ib + ICSR;
    int* CSR2  = ib + ICSR2;

    float* outp   = (float*)d_out;
    float* a0     = outp;
    float* a1     = outp + (size_t)kSN * kH;
    float* logits = outp + 2 * (size_t)kSN * kH;
    float* gemb   = outp + 2 * (size_t)kSN * kH + (size_t)kN * kC;

    dim3 blk(256);

    // ---- 0a. zero pad-tail rows of bf16 GEMM-A buffers ----
    hipMemsetAsync(SB + (size_t)kSN * 256, 0, (size_t)(kMP - kSN) * 256 * sizeof(unsigned short), stream);
    hipMemsetAsync(AB + (size_t)kSN * 256, 0, (size_t)(kMP - kSN) * 256 * sizeof(unsigned short), stream);
    hipMemsetAsync(BIGB + (size_t)kSN * 1024, 0, (size_t)(kMP - kSN) * 1024 * sizeof(unsigned short), stream);
    hipMemsetAsync(GB + (size_t)kN * 256, 0, (size_t)(kNP - kN) * 256 * sizeof(unsigned short), stream);
    hipMemsetAsync(WMG, 0, 128 * 256 * sizeof(unsigned short), stream);

    // ---- 0b. CSR build ----
    hipMemsetAsync(CNT, 0, (size_t)(kV * kN + kN) * sizeof(int), stream);
    count_k<<<dim3((kV * kE + 255) / 256), blk, 0, stream>>>(e_dst, CNT, kE, kN, kV * kE);
    count_k<<<dim3((kE2 + 255) / 256), blk, 0, stream>>>(gdst, CNT2, kE2, kN, kE2);
    scan_k<<<dim3(kV), dim3(1024), 0, stream>>>(CNT, OFFS, CUR, kN);
    scan_k<<<dim3(1), dim3(1024), 0, stream>>>(CNT2, OFFS2, CUR2, kN);
    fill_csr_k<<<dim3((kV * kE + 255) / 256), blk, 0, stream>>>(e_src, e_dst, CUR, CSR, kE, kN, kV * kE);
    fill_csr_k<<<dim3((kE2 + 255) / 256), blk, 0, stream>>>(gsrc, gdst, CUR2, CSR2, kE2, kN, kE2);
    dinv_k<<<dim3((kV * kN + 255) / 256), blk, 0, stream>>>(CNT, DNV, kV * kN);

    // ---- 0c. weight/activation bf16 conversion ----
    cvt_k<<<dim3((393216 / 4 + 255) / 256), blk, 0, stream>>>(Wqkv, WB, 393216 / 4);
    cvt_k<<<dim3((131072 / 4 + 255) / 256), blk, 0, stream>>>(Wo, WB + 393216, 131072 / 4);
    cvt_k<<<dim3((524288 / 4 + 255) / 256), blk, 0, stream>>>(W1, WB + 524288, 524288 / 4);
    cvt_k<<<dim3((524288 / 4 + 255) / 256), blk, 0, stream>>>(W2, WB + 1048576, 524288 / 4);
    tcvt_k<<<dim3((3 * 65536 + 255) / 256), blk, 0, stream>>>(gcn_W, GWB, 256, 256, 3 * 65536);
    tcvt_k<<<dim3((3 * 65536 + 255) / 256), blk, 0, stream>>>(gat_W, GWB + 3 * 65536, 256, 256, 3 * 65536);
    tcvt_k<<<dim3((2 * 32768 + 255) / 256), blk, 0, stream>>>(att_P, PB, 256, 128, 2 * 32768);
    tcvt_k<<<dim3((8192 + 255) / 256), blk, 0, stream>>>(mg_fc, WMG, 256, 32, 8192);
    tcvt_k<<<dim3((8192 + 255) / 256), blk, 0, stream>>>(mg_res, WMG + 32 * 256, 256, 32, 8192);
    cvt_k<<<dim3((kSN * 256 / 4 + 255) / 256), blk, 0, stream>>>(x, AB, kSN * 256 / 4);

    // ---- 1. multi-view GCN + relu -> SB (bf16) ----
    mgemm_k<0, false, true><<<dim3(2, 157, 3), blk, 0, stream>>>(
        AB, GWB, nullptr, nullptr, HB, kN, 256, 256, (long)kN * 256, 65536, kN);
    gcn_gather_k<<<dim3(kSN / 4), blk, 0, stream>>>(CSR, OFFS, CNT, DNV, HB, gcn_b, SB);

    // ---- 2. encoder 0 -> a0 f32 + AB bf16 ----
    run_encoder(SB, a0, AB, ws, 0, bqkv, bo, b1, b2, ln1g, ln1b, ln2g, ln2b, stream);

    // ---- 3. multi-view GAT + relu -> SB (bf16) ----
    mgemm_k<0, false, true><<<dim3(2, 157, 3), blk, 0, stream>>>(
        AB, GWB + 3 * 65536, nullptr, nullptr, HB, kN, 256, 256, (long)kN * 256, 65536, kN);
    rowdot2b_k<<<dim3(kSN), dim3(64), 0, stream>>>(HB, gat_as, gat_ad, EL, ER, kSN, 256, kN, kH);
    gat_gather_k<<<dim3(kSN / 4), blk, 0, stream>>>(CSR, OFFS, CNT, EL, ER, HB, gat_b, SB);

    // ---- 4. encoder 1 -> a1 f32 + AB bf16 ----
    run_encoder(SB, a1, AB, ws, 1, bqkv + 768, bo + 256, b1 + 1024, b2 + 256,
                ln1g + 256, ln1b + 256, ln2g + 256, ln2b + 256, stream);

    // ---- 5. view attention + fused blend -> gemb f32 + GB bf16 ----
    mgemm_k<3, false, true><<<dim3(2, 469, 1), blk, 0, stream>>>(
        AB, PB, att_Pb, nullptr, T2B, kSN, 256, 256, 0, 0, 0);
    attdot_k<<<dim3(kSN / 4), blk, 0, stream>>>(T2B, att_q, W0b, W1b, kSN);
    randsm_k<<<dim3(1), dim3(1024), 0, stream>>>(rand_w, ST);
    view_blend_k<<<dim3((kN * 64 + 255) / 256), blk, 0, stream>>>(AB, W0b, W1b, rand_w, ST, gemb, GB);

    // ---- 6. myGATConv -> logits (fc|res packed as one N=128 MFMA GEMM) ----
    mgemm_k<0, true, false><<<dim3(1, kNP / 128, 1), blk, 0, stream>>>(
        GB, WMG, nullptr, FB128, nullptr, kN, 128, 256, 0, 0, 0);
    mgdot_k<<<dim3((kN + 3) / 4), blk, 0, stream>>>(FB128, mg_al, mg_ar, EL2, ER2, kN);
    mygat_gather_k<<<dim3((kN + 7) / 8), blk, 0, stream>>>(CSR2, OFFS2, CNT2, EL2, ER2, FB128, RST);
    final_k<<<dim3((kN + 255) / 256), blk, 0, stream>>>(RST, FB128, logits);
}